// Round 1
// baseline (1960.967 us; speedup 1.0000x reference)
//
#include <hip/hip_runtime.h>
#include <hip/hip_bf16.h>

// GNNEncoder: node/edge MLP+LN preproc, Linear+BN+ReLU encoder, 3x GATConv
// (edge-featured, self-loops fill='mean') + BN/ReLU/residual, mean-pool + MLP.
//
// Key reductions:
//  - (ea@eW)@a_e == ea@(eW@a_e): only scalar al_e per edge per layer needed.
//  - loop_attr@v == mean(incoming al_e): loop_attr never materialized.
//  - dst-CSR built once -> exact segment softmax, no float atomics.

#define WAVE 64

// ---------------- small prep kernels ----------------

__global__ void vprep(const float* __restrict__ eW, const float* __restrict__ a_e,
                      float* __restrict__ v) {
  int t = threadIdx.x;
  if (t < 96) {
    int l = t >> 5, k = t & 31;
    const float* w = eW + l * (32 * 64) + k * 64;
    const float* a = a_e + l * 64;
    float s = 0.f;
    for (int c = 0; c < 64; ++c) s += w[c] * a[c];
    v[t] = s;  // v[l*32+k]
  }
}

__global__ void deg_kernel(const int* __restrict__ dst, int ne, int* __restrict__ deg) {
  int i = blockIdx.x * blockDim.x + threadIdx.x;
  int stride = gridDim.x * blockDim.x;
  for (; i < ne; i += stride) atomicAdd(&deg[dst[i]], 1);
}

__global__ __launch_bounds__(1024) void scan_kernel(const int* __restrict__ deg,
                                                    int* __restrict__ off, int n) {
  __shared__ int buf[1024];
  __shared__ int carry;
  int t = threadIdx.x;
  if (t == 0) { carry = 0; off[0] = 0; }
  __syncthreads();
  for (int base = 0; base < n; base += 1024) {
    int i = base + t;
    buf[t] = (i < n) ? deg[i] : 0;
    __syncthreads();
    for (int s = 1; s < 1024; s <<= 1) {
      int add = (t >= s) ? buf[t - s] : 0;
      __syncthreads();
      buf[t] += add;
      __syncthreads();
    }
    int prev = carry;
    if (i < n) off[i + 1] = prev + buf[t];
    __syncthreads();
    if (t == 1023) carry = prev + buf[1023];
    __syncthreads();
  }
}

__global__ void scatter_kernel(const int* __restrict__ src, const int* __restrict__ dst,
                               int ne, const int* __restrict__ off, int* __restrict__ cnt,
                               int* __restrict__ edge_pos, int* __restrict__ csr_src) {
  int i = blockIdx.x * blockDim.x + threadIdx.x;
  int stride = gridDim.x * blockDim.x;
  for (; i < ne; i += stride) {
    int d = dst[i];
    int p = off[d] + atomicAdd(&cnt[d], 1);
    edge_pos[i] = p;
    csr_src[p] = src[i];
  }
}

// ---------------- edge preproc: MLP+LN -> al_e (3 scalars/edge) ----------------
// block = 256 (4 waves), 16 edges per wave.
__global__ __launch_bounds__(256) void edge_pre(
    const float* __restrict__ ea_in, const float* __restrict__ W1, const float* __restrict__ b1,
    const float* __restrict__ W2, const float* __restrict__ b2,
    const float* __restrict__ lng, const float* __restrict__ lnb,
    const float* __restrict__ v, const int* __restrict__ edge_pos,
    float* __restrict__ al_e3, int ne) {
  __shared__ __align__(16) float sW1[32 * 64];
  __shared__ __align__(16) float sW2[64 * 32];
  __shared__ __align__(16) float sea[4][16 * 32];
  __shared__ __align__(16) float st[4][16 * 64];
  int tid = threadIdx.x;
  for (int i = tid; i < 32 * 64; i += 256) sW1[i] = W1[i];
  for (int i = tid; i < 64 * 32; i += 256) sW2[i] = W2[i];
  int w = tid >> 6, lane = tid & 63;
  long eb = (long)(blockIdx.x * 4 + w) * 16;
  {
    long gbase = eb * 32;
    long limit = (long)ne * 32;
    for (int i = lane; i < 16 * 32; i += 64) {
      long g = gbase + i;
      sea[w][i] = (g < limit) ? ea_in[g] : 0.f;
    }
  }
  __syncthreads();
  // phase 1: t[j=lane] = relu(ea@W1 + b1) for 16 edges
  float t_acc[16];
#pragma unroll
  for (int m = 0; m < 16; ++m) t_acc[m] = 0.f;
  for (int k = 0; k < 32; k += 4) {
    float w0 = sW1[(k + 0) * 64 + lane];
    float w1 = sW1[(k + 1) * 64 + lane];
    float w2 = sW1[(k + 2) * 64 + lane];
    float w3 = sW1[(k + 3) * 64 + lane];
#pragma unroll
    for (int m = 0; m < 16; ++m) {
      float4 e4 = *reinterpret_cast<const float4*>(&sea[w][m * 32 + k]);
      t_acc[m] += e4.x * w0 + e4.y * w1 + e4.z * w2 + e4.w * w3;
    }
  }
  float b1v = b1[lane];
#pragma unroll
  for (int m = 0; m < 16; ++m) st[w][m * 64 + lane] = fmaxf(t_acc[m] + b1v, 0.f);
  __syncthreads();
  // phase 2: y[i=lane&31] = t@W2 + b2; lane's half (hh) covers 8 edges
  int hh = lane >> 5, ii = lane & 31;
  float y[8];
#pragma unroll
  for (int m = 0; m < 8; ++m) y[m] = 0.f;
  for (int j = 0; j < 64; j += 4) {
    float w0 = sW2[(j + 0) * 32 + ii];
    float w1 = sW2[(j + 1) * 32 + ii];
    float w2 = sW2[(j + 2) * 32 + ii];
    float w3 = sW2[(j + 3) * 32 + ii];
#pragma unroll
    for (int m = 0; m < 8; ++m) {
      float4 t4 = *reinterpret_cast<const float4*>(&st[w][(hh * 8 + m) * 64 + j]);
      y[m] += t4.x * w0 + t4.y * w1 + t4.z * w2 + t4.w * w3;
    }
  }
  float b2v = b2[ii], lngv = lng[ii], lnbv = lnb[ii];
  float v0 = v[0 * 32 + ii], v1 = v[1 * 32 + ii], v2 = v[2 * 32 + ii];
#pragma unroll
  for (int m = 0; m < 8; ++m) {
    float yv = y[m] + b2v;
    float s = yv, q = yv * yv;
#pragma unroll
    for (int o = 1; o < 32; o <<= 1) {
      s += __shfl_xor(s, o, 32);
      q += __shfl_xor(q, o, 32);
    }
    float mean = s * (1.f / 32.f);
    float var = q * (1.f / 32.f) - mean * mean;
    float istd = rsqrtf(var + 1e-5f);
    float e = (yv - mean) * istd * lngv + lnbv;
    float a0 = e * v0, a1 = e * v1, a2 = e * v2;
#pragma unroll
    for (int o = 1; o < 32; o <<= 1) {
      a0 += __shfl_xor(a0, o, 32);
      a1 += __shfl_xor(a1, o, 32);
      a2 += __shfl_xor(a2, o, 32);
    }
    if (ii == m) {  // one lane per 32-group writes its group's edge
      long em = eb + hh * 8 + m;
      if (em < ne) {
        int pos = edge_pos[em];
        al_e3[pos] = a0;
        al_e3[(long)ne + pos] = a1;
        al_e3[2L * ne + pos] = a2;
      }
    }
  }
}

// ---------------- node preproc: MLP+LN + encoder Linear (z) ----------------
// block = 256 (4 waves), 32 nodes per block (8 per wave).
__global__ __launch_bounds__(256) void node_pre(
    const float* __restrict__ x, const float* __restrict__ W1, const float* __restrict__ b1,
    const float* __restrict__ W2, const float* __restrict__ b2,
    const float* __restrict__ lng, const float* __restrict__ lnb,
    const float* __restrict__ encW, const float* __restrict__ encb,
    float* __restrict__ z_out, float* __restrict__ part, int n) {
  __shared__ __align__(16) float sx[32][128];   // x rows; reused for h1
  __shared__ __align__(16) float st[32][256];   // hidden activations
  __shared__ float sred[4][128];
  int tid = threadIdx.x;
  int w = tid >> 6, lane = tid & 63;
  long nodeBase = (long)blockIdx.x * 32;
  {
    const float* gx = x + nodeBase * 128;
    long limit = ((long)n - nodeBase) * 128;
    float* sxf = &sx[0][0];
    for (int i = tid; i < 32 * 128; i += 256) sxf[i] = (i < limit) ? gx[i] : 0.f;
  }
  __syncthreads();
  int lm0 = w * 8;
  // phase 1: t = relu(x@W1+b1); j = lane + 64*{0..3}
  float tA[8], tB[8], tC[8], tD[8];
#pragma unroll
  for (int m = 0; m < 8; ++m) tA[m] = tB[m] = tC[m] = tD[m] = 0.f;
  for (int k = 0; k < 128; k += 4) {
    float wv[4][4];
#pragma unroll
    for (int kk = 0; kk < 4; ++kk) {
      const float* wp = W1 + (long)(k + kk) * 256 + lane;
      wv[kk][0] = wp[0]; wv[kk][1] = wp[64]; wv[kk][2] = wp[128]; wv[kk][3] = wp[192];
    }
#pragma unroll
    for (int m = 0; m < 8; ++m) {
      float4 x4 = *reinterpret_cast<const float4*>(&sx[lm0 + m][k]);
      tA[m] += x4.x * wv[0][0] + x4.y * wv[1][0] + x4.z * wv[2][0] + x4.w * wv[3][0];
      tB[m] += x4.x * wv[0][1] + x4.y * wv[1][1] + x4.z * wv[2][1] + x4.w * wv[3][1];
      tC[m] += x4.x * wv[0][2] + x4.y * wv[1][2] + x4.z * wv[2][2] + x4.w * wv[3][2];
      tD[m] += x4.x * wv[0][3] + x4.y * wv[1][3] + x4.z * wv[2][3] + x4.w * wv[3][3];
    }
  }
  {
    float b0 = b1[lane], bb1 = b1[lane + 64], b2_ = b1[lane + 128], b3 = b1[lane + 192];
#pragma unroll
    for (int m = 0; m < 8; ++m) {
      st[lm0 + m][lane] = fmaxf(tA[m] + b0, 0.f);
      st[lm0 + m][lane + 64] = fmaxf(tB[m] + bb1, 0.f);
      st[lm0 + m][lane + 128] = fmaxf(tC[m] + b2_, 0.f);
      st[lm0 + m][lane + 192] = fmaxf(tD[m] + b3, 0.f);
    }
  }
  __syncthreads();
  // phase 2: y = t@W2 + b2; i = lane, lane+64
  float yA[8], yB[8];
#pragma unroll
  for (int m = 0; m < 8; ++m) yA[m] = yB[m] = 0.f;
  for (int j = 0; j < 256; j += 4) {
    float wv[4][2];
#pragma unroll
    for (int kk = 0; kk < 4; ++kk) {
      const float* wp = W2 + (long)(j + kk) * 128 + lane;
      wv[kk][0] = wp[0]; wv[kk][1] = wp[64];
    }
#pragma unroll
    for (int m = 0; m < 8; ++m) {
      float4 t4 = *reinterpret_cast<const float4*>(&st[lm0 + m][j]);
      yA[m] += t4.x * wv[0][0] + t4.y * wv[1][0] + t4.z * wv[2][0] + t4.w * wv[3][0];
      yB[m] += t4.x * wv[0][1] + t4.y * wv[1][1] + t4.z * wv[2][1] + t4.w * wv[3][1];
    }
  }
  // phase 3: LN(128) per node; write h1 into sx (own rows only)
  {
    float bA = b2[lane], bB = b2[lane + 64];
    float gA = lng[lane], gB = lng[lane + 64];
    float oA = lnb[lane], oB = lnb[lane + 64];
#pragma unroll
    for (int m = 0; m < 8; ++m) {
      float y0 = yA[m] + bA, y1 = yB[m] + bB;
      float s = y0 + y1, q = y0 * y0 + y1 * y1;
#pragma unroll
      for (int o = 1; o < 64; o <<= 1) {
        s += __shfl_xor(s, o);
        q += __shfl_xor(q, o);
      }
      float mean = s * (1.f / 128.f);
      float var = q * (1.f / 128.f) - mean * mean;
      float istd = rsqrtf(var + 1e-5f);
      sx[lm0 + m][lane] = (y0 - mean) * istd * gA + oA;
      sx[lm0 + m][lane + 64] = (y1 - mean) * istd * gB + oB;
    }
  }
  __syncthreads();
  // phase 4: z = h1 @ encW + encb -> z_out; BN partials
  float z[8];
#pragma unroll
  for (int m = 0; m < 8; ++m) z[m] = 0.f;
  for (int k = 0; k < 128; k += 4) {
    float w0 = encW[(long)k * 64 + lane];
    float w1 = encW[(long)(k + 1) * 64 + lane];
    float w2 = encW[(long)(k + 2) * 64 + lane];
    float w3 = encW[(long)(k + 3) * 64 + lane];
#pragma unroll
    for (int m = 0; m < 8; ++m) {
      float4 h4 = *reinterpret_cast<const float4*>(&sx[lm0 + m][k]);
      z[m] += h4.x * w0 + h4.y * w1 + h4.z * w2 + h4.w * w3;
    }
  }
  float ebv = encb[lane];
  float psum = 0.f, psq = 0.f;
#pragma unroll
  for (int m = 0; m < 8; ++m) {
    long nd = nodeBase + lm0 + m;
    if (nd < n) {
      float zz = z[m] + ebv;
      z_out[nd * 64 + lane] = zz;
      psum += zz; psq += zz * zz;
    }
  }
  sred[w][lane] = psum;
  sred[w][64 + lane] = psq;
  __syncthreads();
  if (tid < 128)
    part[(long)blockIdx.x * 128 + tid] =
        sred[0][tid] + sred[1][tid] + sred[2][tid] + sred[3][tid];
}

// ---------------- per-layer: xs = h@W, al_s, al_d ----------------
__global__ __launch_bounds__(256) void xs_kernel(
    const float* __restrict__ h, const float* __restrict__ W,
    const float* __restrict__ a_s, const float* __restrict__ a_d,
    float* __restrict__ xs, float* __restrict__ al_s, float* __restrict__ al_d, int n) {
  __shared__ __align__(16) float sW[64 * 64];
  __shared__ __align__(16) float sh[32][64];
  int tid = threadIdx.x, w = tid >> 6, lane = tid & 63;
  for (int i = tid; i < 4096; i += 256) sW[i] = W[i];
  long nodeBase = (long)blockIdx.x * 32;
  {
    const float* gh = h + nodeBase * 64;
    long limit = ((long)n - nodeBase) * 64;
    float* shf = &sh[0][0];
    for (int i = tid; i < 2048; i += 256) shf[i] = (i < limit) ? gh[i] : 0.f;
  }
  __syncthreads();
  int lm0 = w * 8;
  float acc[8];
#pragma unroll
  for (int m = 0; m < 8; ++m) acc[m] = 0.f;
  for (int k = 0; k < 64; k += 4) {
    float w0 = sW[(k + 0) * 64 + lane];
    float w1 = sW[(k + 1) * 64 + lane];
    float w2 = sW[(k + 2) * 64 + lane];
    float w3 = sW[(k + 3) * 64 + lane];
#pragma unroll
    for (int m = 0; m < 8; ++m) {
      float4 h4 = *reinterpret_cast<const float4*>(&sh[lm0 + m][k]);
      acc[m] += h4.x * w0 + h4.y * w1 + h4.z * w2 + h4.w * w3;
    }
  }
  float asv = a_s[lane], adv = a_d[lane];
#pragma unroll
  for (int m = 0; m < 8; ++m) {
    long nd = nodeBase + lm0 + m;
    float ps = acc[m] * asv, pd = acc[m] * adv;
#pragma unroll
    for (int o = 1; o < 64; o <<= 1) {
      ps += __shfl_xor(ps, o);
      pd += __shfl_xor(pd, o);
    }
    if (nd < n) {
      xs[nd * 64 + lane] = acc[m];
      if (lane == 0) { al_s[nd] = ps; al_d[nd] = pd; }
    }
  }
}

// ---------------- per-layer: GAT attention + aggregation ----------------
#define DEGCAP 128
__global__ __launch_bounds__(256) void gat_kernel(
    const int* __restrict__ off, const int* __restrict__ csr_src,
    const float* __restrict__ al_e, const float* __restrict__ al_s,
    const float* __restrict__ al_d, const float* __restrict__ xs,
    const float* __restrict__ bias, float* __restrict__ gat_out,
    float* __restrict__ part, int n) {
  __shared__ float s_ex[4][DEGCAP];
  __shared__ int s_src[4][DEGCAP];
  __shared__ float sred[4][128];
  int tid = threadIdx.x, w = tid >> 6, lane = tid & 63;
  int gw = blockIdx.x * 4 + w;
  int nW = gridDim.x * 4;
  float psum = 0.f, psq = 0.f;
  float bv = bias[lane];
  for (int node = gw; node < n; node += nW) {
    int s0 = off[node], s1 = off[node + 1];
    int deg = s1 - s0;
    bool fits = (deg <= DEGCAP);
    float aldn = al_d[node];
    float lmax = -3.402823466e38f, lsum_ae = 0.f;
    for (int base = 0; base < deg; base += 64) {
      int k = base + lane;
      if (k < deg) {
        int sc = csr_src[s0 + k];
        float ae = al_e[s0 + k];
        float a = al_s[sc] + aldn + ae;
        float al = (a >= 0.f) ? a : 0.2f * a;
        lmax = fmaxf(lmax, al);
        lsum_ae += ae;
        if (fits) { s_ex[w][k] = al; s_src[w][k] = sc; }
      }
    }
#pragma unroll
    for (int o = 1; o < 64; o <<= 1) {
      lmax = fmaxf(lmax, __shfl_xor(lmax, o));
      lsum_ae += __shfl_xor(lsum_ae, o);
    }
    float ae_self = lsum_ae / fmaxf((float)deg, 1.f);
    float a_self = al_s[node] + aldn + ae_self;
    float al_self = (a_self >= 0.f) ? a_self : 0.2f * a_self;
    float mx = fmaxf(lmax, al_self);
    float lsum = 0.f;
    if (fits) {
      for (int base = 0; base < deg; base += 64) {
        int k = base + lane;
        if (k < deg) {
          float ex = expf(s_ex[w][k] - mx);
          s_ex[w][k] = ex;
          lsum += ex;
        }
      }
    } else {
      for (int base = 0; base < deg; base += 64) {
        int k = base + lane;
        if (k < deg) {
          int sc = csr_src[s0 + k];
          float a = al_s[sc] + aldn + al_e[s0 + k];
          float al = (a >= 0.f) ? a : 0.2f * a;
          lsum += expf(al - mx);
        }
      }
    }
#pragma unroll
    for (int o = 1; o < 64; o <<= 1) lsum += __shfl_xor(lsum, o);
    float ex_self = expf(al_self - mx);
    float inv = 1.f / (lsum + ex_self + 1e-16f);
    float acc = ex_self * xs[(long)node * 64 + lane];
    if (fits) {
      for (int k = 0; k < deg; ++k) {
        float exk = s_ex[w][k];
        int sck = s_src[w][k];
        acc += exk * xs[(long)sck * 64 + lane];
      }
    } else {
      for (int k = 0; k < deg; ++k) {
        int sck = csr_src[s0 + k];
        float a = al_s[sck] + aldn + al_e[s0 + k];
        float al = (a >= 0.f) ? a : 0.2f * a;
        acc += expf(al - mx) * xs[(long)sck * 64 + lane];
      }
    }
    float outv = acc * inv + bv;
    gat_out[(long)node * 64 + lane] = outv;
    psum += outv;
    psq += outv * outv;
  }
  sred[w][lane] = psum;
  sred[w][64 + lane] = psq;
  __syncthreads();
  if (tid < 128)
    part[(long)blockIdx.x * 128 + tid] =
        sred[0][tid] + sred[1][tid] + sred[2][tid] + sred[3][tid];
}

// ---------------- BN finalize + apply ----------------
__global__ __launch_bounds__(1024) void bn_finalize(const float* __restrict__ part, int nblk,
                                                    float invN, float* __restrict__ stats) {
  __shared__ float sh[1024];
  int t = threadIdx.x;
  int c = t & 127, g = t >> 7;
  float s = 0.f;
  for (int b = g; b < nblk; b += 8) s += part[(long)b * 128 + c];
  sh[t] = s;
  __syncthreads();
  if (t < 128) {
    float tot = 0.f;
#pragma unroll
    for (int g2 = 0; g2 < 8; ++g2) tot += sh[g2 * 128 + t];
    sh[t] = tot;
  }
  __syncthreads();
  if (t < 64) {
    float mean = sh[t] * invN;
    float var = sh[64 + t] * invN - mean * mean;
    stats[t] = mean;
    stats[64 + t] = rsqrtf(var + 1e-5f);
  }
}

__global__ void bn_apply(const float* __restrict__ z, const float* __restrict__ stats,
                         const float* __restrict__ g, const float* __restrict__ b,
                         float* __restrict__ h, long total, int mode) {
  long i = (long)blockIdx.x * blockDim.x + threadIdx.x;
  long stride = (long)gridDim.x * blockDim.x;
  for (; i < total; i += stride) {
    int c = (int)(i & 63);
    float vv = (z[i] - stats[c]) * stats[64 + c] * g[c] + b[c];
    vv = fmaxf(vv, 0.f);
    if (mode) h[i] += vv; else h[i] = vv;
  }
}

// ---------------- final pool + MLP ----------------
__global__ void gsum_part(const float* __restrict__ h, int n, float* __restrict__ part) {
  __shared__ float sh[4][64];
  int tid = threadIdx.x, w = tid >> 6, lane = tid & 63;
  int gw = blockIdx.x * 4 + w, nW = gridDim.x * 4;
  float s = 0.f;
  for (int node = gw; node < n; node += nW) s += h[(long)node * 64 + lane];
  sh[w][lane] = s;
  __syncthreads();
  if (tid < 64)
    part[(long)blockIdx.x * 64 + tid] =
        sh[0][tid] + sh[1][tid] + sh[2][tid] + sh[3][tid];
}

__global__ void final_kernel(const float* __restrict__ part, int nblk,
                             const float* __restrict__ out_W, const float* __restrict__ out_b,
                             float* __restrict__ out, float invN) {
  __shared__ float g[64];
  int c = threadIdx.x;  // 64 threads
  float s = 0.f;
  for (int b = 0; b < nblk; ++b) s += part[(long)b * 64 + c];
  g[c] = s * invN;
  __syncthreads();
  float acc = out_b[c];
  for (int k = 0; k < 64; ++k) acc += g[k] * out_W[k * 64 + c];
  out[c] = fmaxf(acc, 0.f);
}

// ---------------- host launch ----------------
extern "C" void kernel_launch(void* const* d_in, const int* in_sizes, int n_in,
                              void* d_out, int out_size, void* d_ws, size_t ws_size,
                              hipStream_t stream) {
  const float* x        = (const float*)d_in[0];
  const int*   eidx     = (const int*)d_in[1];
  const float* eattr    = (const float*)d_in[2];
  const float* np_W1    = (const float*)d_in[3];
  const float* np_b1    = (const float*)d_in[4];
  const float* np_W2    = (const float*)d_in[5];
  const float* np_b2    = (const float*)d_in[6];
  const float* np_ln_g  = (const float*)d_in[7];
  const float* np_ln_b  = (const float*)d_in[8];
  const float* ep_W1    = (const float*)d_in[9];
  const float* ep_b1    = (const float*)d_in[10];
  const float* ep_W2    = (const float*)d_in[11];
  const float* ep_b2    = (const float*)d_in[12];
  const float* ep_ln_g  = (const float*)d_in[13];
  const float* ep_ln_b  = (const float*)d_in[14];
  const float* enc_W    = (const float*)d_in[15];
  const float* enc_b    = (const float*)d_in[16];
  const float* enc_bn_g = (const float*)d_in[17];
  const float* enc_bn_b = (const float*)d_in[18];
  const float* gat_W    = (const float*)d_in[19];
  const float* gat_eW   = (const float*)d_in[20];
  const float* att_src  = (const float*)d_in[21];
  const float* att_dst  = (const float*)d_in[22];
  const float* att_edge = (const float*)d_in[23];
  const float* gat_b    = (const float*)d_in[24];
  const float* bn_g     = (const float*)d_in[25];
  const float* bn_b     = (const float*)d_in[26];
  const float* out_W    = (const float*)d_in[27];
  const float* out_b    = (const float*)d_in[28];

  const int n = in_sizes[0] / 128;   // 50000
  const int ne = in_sizes[1] / 2;    // 800000
  const int* srcp = eidx;
  const int* dstp = eidx + ne;

  // workspace carve-up (~56.5 MB)
  float* f = (float*)d_ws;
  float* hbuf  = f; f += (long)n * 64;
  float* xsbuf = f; f += (long)n * 64;
  float* zbuf  = f; f += (long)n * 64;
  float* alsb  = f; f += n;
  float* aldb  = f; f += n;
  float* ale3  = f; f += 3L * ne;
  float* vbuf  = f; f += 96;
  float* stats = f; f += 128;
  float* part  = f; f += 262144;
  int* ip = (int*)f;
  int* edge_pos = ip; ip += ne;
  int* csr_src  = ip; ip += ne;
  int* degb     = ip; ip += n;
  int* cntb     = ip; ip += n;
  int* offb     = ip; ip += n + 1;

  const int nbNode = (n + 31) / 32;

  hipMemsetAsync(degb, 0, (size_t)n * sizeof(int), stream);
  hipMemsetAsync(cntb, 0, (size_t)n * sizeof(int), stream);
  vprep<<<1, 128, 0, stream>>>(gat_eW, att_edge, vbuf);
  deg_kernel<<<1024, 256, 0, stream>>>(dstp, ne, degb);
  scan_kernel<<<1, 1024, 0, stream>>>(degb, offb, n);
  scatter_kernel<<<1024, 256, 0, stream>>>(srcp, dstp, ne, offb, cntb, edge_pos, csr_src);
  edge_pre<<<(ne + 63) / 64, 256, 0, stream>>>(eattr, ep_W1, ep_b1, ep_W2, ep_b2,
                                               ep_ln_g, ep_ln_b, vbuf, edge_pos, ale3, ne);
  node_pre<<<nbNode, 256, 0, stream>>>(x, np_W1, np_b1, np_W2, np_b2, np_ln_g, np_ln_b,
                                       enc_W, enc_b, zbuf, part, n);
  bn_finalize<<<1, 1024, 0, stream>>>(part, nbNode, 1.f / n, stats);
  bn_apply<<<2048, 256, 0, stream>>>(zbuf, stats, enc_bn_g, enc_bn_b, hbuf, (long)n * 64, 0);
  for (int l = 0; l < 3; ++l) {
    xs_kernel<<<nbNode, 256, 0, stream>>>(hbuf, gat_W + (long)l * 4096, att_src + l * 64,
                                          att_dst + l * 64, xsbuf, alsb, aldb, n);
    gat_kernel<<<2048, 256, 0, stream>>>(offb, csr_src, ale3 + (long)l * ne, alsb, aldb,
                                         xsbuf, gat_b + l * 64, zbuf, part, n);
    bn_finalize<<<1, 1024, 0, stream>>>(part, 2048, 1.f / n, stats);
    bn_apply<<<2048, 256, 0, stream>>>(zbuf, stats, bn_g + l * 64, bn_b + l * 64, hbuf,
                                       (long)n * 64, 1);
  }
  gsum_part<<<1024, 256, 0, stream>>>(hbuf, n, part);
  final_kernel<<<1, 64, 0, stream>>>(part, 1024, out_W, out_b, (float*)d_out, 1.f / n);
}

// Round 2
// 1427.222 us; speedup vs baseline: 1.3740x; 1.3740x over previous
//
#include <hip/hip_runtime.h>
#include <hip/hip_bf16.h>

// GNNEncoder on MI355X. Algebraic reductions:
//  - (ea@eW)@a_e == ea@(eW@a_e): only 3 scalars al_e per edge needed.
//  - loop_attr contribution == mean(incoming al_e) by linearity.
//  - edge LN+dot folded: al = istd*(sum y*(g*v) - mean*G) + C.
// dst-CSR built once (deg -> scan -> scatter), exact segment softmax, no float atomics.

__device__ __forceinline__ unsigned pack2bf(float a, float b) {
  unsigned ua = __float_as_uint(a); ua += 0x7fffu + ((ua >> 16) & 1u);
  unsigned ub = __float_as_uint(b); ub += 0x7fffu + ((ub >> 16) & 1u);
  return (ua >> 16) | (ub & 0xffff0000u);
}
__device__ __forceinline__ float bflo(unsigned u) { return __uint_as_float(u << 16); }
__device__ __forceinline__ float bfhi(unsigned u) { return __uint_as_float(u & 0xffff0000u); }

// ---------------- prep: v = eW@a_e, gv = lng*v, G = sum(lng*v), C = sum(lnb*v) ----------------
__global__ void vprep2(const float* __restrict__ eW, const float* __restrict__ a_e,
                       const float* __restrict__ lng, const float* __restrict__ lnb,
                       float* __restrict__ vg) {
  __shared__ float sv[96];
  int t = threadIdx.x;  // 128 threads
  if (t < 96) {
    int l = t >> 5, i = t & 31;
    const float* w = eW + l * 2048 + i * 64;
    const float* a = a_e + l * 64;
    float s = 0.f;
    for (int c = 0; c < 64; ++c) s += w[c] * a[c];
    sv[t] = s;
    vg[t] = s * lng[i];
  }
  __syncthreads();
  if (t < 3) {
    float G = 0.f, C = 0.f;
    for (int i = 0; i < 32; ++i) {
      float vv = sv[t * 32 + i];
      G += lng[i] * vv;
      C += lnb[i] * vv;
    }
    vg[96 + t] = G;
    vg[99 + t] = C;
  }
}

__global__ void deg_kernel(const int* __restrict__ dst, int ne, int* __restrict__ deg) {
  int i = blockIdx.x * blockDim.x + threadIdx.x;
  int stride = gridDim.x * blockDim.x;
  for (; i < ne; i += stride) atomicAdd(&deg[dst[i]], 1);
}

// thread-serial chunks + one 1024-wide scan
__global__ __launch_bounds__(1024) void scan2(const int* __restrict__ deg,
                                              int* __restrict__ off, int n) {
  __shared__ int sh[1024];
  int t = threadIdx.x;
  int C = (n + 1023) >> 10;
  int b0 = t * C, b1 = min(n, b0 + C);
  int s = 0;
  for (int j = b0; j < b1; ++j) s += deg[j];
  sh[t] = s;
  __syncthreads();
  for (int o = 1; o < 1024; o <<= 1) {
    int add = (t >= o) ? sh[t - o] : 0;
    __syncthreads();
    sh[t] += add;
    __syncthreads();
  }
  int run = (t == 0) ? 0 : sh[t - 1];
  if (t == 0) off[0] = 0;
  for (int j = b0; j < b1; ++j) { run += deg[j]; off[j + 1] = run; }
}

__global__ void scatter_kernel(const int* __restrict__ src, const int* __restrict__ dst,
                               int ne, const int* __restrict__ off, int* __restrict__ cnt,
                               int* __restrict__ edge_pos, int* __restrict__ csr_src) {
  int i = blockIdx.x * blockDim.x + threadIdx.x;
  int stride = gridDim.x * blockDim.x;
  for (; i < ne; i += stride) {
    int d = dst[i];
    int p = off[d] + atomicAdd(&cnt[d], 1);
    edge_pos[i] = p;
    csr_src[p] = src[i];
  }
}

// ---------------- edge preproc v2: MLP(32->64->32)+LN -> al_e (3 scalars/edge) ----------------
// block 256 thr, 128 edges. Register-blocked f32 GEMM, bf16 LDS activations.
#define ET 128
__global__ __launch_bounds__(256, 3) void edge_pre2(
    const float* __restrict__ ea, const float* __restrict__ W1, const float* __restrict__ b1,
    const float* __restrict__ W2, const float* __restrict__ b2,
    const float* __restrict__ vg, const int* __restrict__ edge_pos,
    float* __restrict__ ale3, int ne) {
  __shared__ __align__(16) float sW1[32 * 64];     // [k][j]
  __shared__ __align__(16) float sW2[64 * 36];     // [k][i] pad 36
  __shared__ __align__(16) unsigned short sea[ET * 48];  // bf16 [m][k] pad 48
  __shared__ __align__(16) unsigned short stt[ET * 72];  // bf16 [m][j] pad 72; reused as f32 yb[ET*36]
  int tid = threadIdx.x;
  for (int i = tid; i < 2048; i += 256) sW1[i] = W1[i];
  for (int i = tid; i < 2048; i += 256) sW2[(i >> 5) * 36 + (i & 31)] = W2[i];
  long eb = (long)blockIdx.x * ET;
  {  // stage ea -> bf16
    const float4* g4 = (const float4*)(ea + eb * 32);
    for (int i4 = tid; i4 < ET * 8; i4 += 256) {
      int m = i4 >> 3, c = (i4 & 7) * 4;
      float4 v = (eb + m < ne) ? g4[i4] : make_float4(0.f, 0.f, 0.f, 0.f);
      unsigned lo = pack2bf(v.x, v.y), hi = pack2bf(v.z, v.w);
      *(uint2*)&sea[m * 48 + c] = make_uint2(lo, hi);
    }
  }
  __syncthreads();
  // ---- phase 1: T = relu(ea@W1 + b1), T in bf16 LDS ----
  {
    int ji = tid & 15, mi = tid >> 4;
    int j0 = ji * 4;
    float acc[8][4];
#pragma unroll
    for (int q = 0; q < 8; ++q)
#pragma unroll
      for (int c = 0; c < 4; ++c) acc[q][c] = 0.f;
    for (int k = 0; k < 32; k += 4) {
      float4 w0 = *(const float4*)&sW1[(k + 0) * 64 + j0];
      float4 w1 = *(const float4*)&sW1[(k + 1) * 64 + j0];
      float4 w2 = *(const float4*)&sW1[(k + 2) * 64 + j0];
      float4 w3 = *(const float4*)&sW1[(k + 3) * 64 + j0];
#pragma unroll
      for (int q = 0; q < 8; ++q) {
        int m = mi + 16 * q;
        uint2 av = *(const uint2*)&sea[m * 48 + k];
        float a0 = bflo(av.x), a1 = bfhi(av.x), a2 = bflo(av.y), a3 = bfhi(av.y);
        acc[q][0] += a0 * w0.x + a1 * w1.x + a2 * w2.x + a3 * w3.x;
        acc[q][1] += a0 * w0.y + a1 * w1.y + a2 * w2.y + a3 * w3.y;
        acc[q][2] += a0 * w0.z + a1 * w1.z + a2 * w2.z + a3 * w3.z;
        acc[q][3] += a0 * w0.w + a1 * w1.w + a2 * w2.w + a3 * w3.w;
      }
    }
    float4 bb = *(const float4*)&b1[j0];
#pragma unroll
    for (int q = 0; q < 8; ++q) {
      int m = mi + 16 * q;
      float t0 = fmaxf(acc[q][0] + bb.x, 0.f), t1 = fmaxf(acc[q][1] + bb.y, 0.f);
      float t2 = fmaxf(acc[q][2] + bb.z, 0.f), t3 = fmaxf(acc[q][3] + bb.w, 0.f);
      *(uint2*)&stt[m * 72 + j0] = make_uint2(pack2bf(t0, t1), pack2bf(t2, t3));
    }
  }
  __syncthreads();
  // ---- phase 2: Y = T@W2 + b2 ----
  int ii = tid & 7, mi2 = tid >> 3;
  int i0 = ii * 4;
  float y[4][4];
#pragma unroll
  for (int q = 0; q < 4; ++q)
#pragma unroll
    for (int c = 0; c < 4; ++c) y[q][c] = 0.f;
  for (int k8 = 0; k8 < 64; k8 += 8) {
    float4 wA0 = *(const float4*)&sW2[(k8 + 0) * 36 + i0];
    float4 wA1 = *(const float4*)&sW2[(k8 + 1) * 36 + i0];
    float4 wA2 = *(const float4*)&sW2[(k8 + 2) * 36 + i0];
    float4 wA3 = *(const float4*)&sW2[(k8 + 3) * 36 + i0];
    float4 wB0 = *(const float4*)&sW2[(k8 + 4) * 36 + i0];
    float4 wB1 = *(const float4*)&sW2[(k8 + 5) * 36 + i0];
    float4 wB2 = *(const float4*)&sW2[(k8 + 6) * 36 + i0];
    float4 wB3 = *(const float4*)&sW2[(k8 + 7) * 36 + i0];
#pragma unroll
    for (int q = 0; q < 4; ++q) {
      int m = mi2 + 32 * q;
      uint4 tv = *(const uint4*)&stt[m * 72 + k8];
      float t0 = bflo(tv.x), t1 = bfhi(tv.x), t2 = bflo(tv.y), t3 = bfhi(tv.y);
      float t4 = bflo(tv.z), t5 = bfhi(tv.z), t6 = bflo(tv.w), t7 = bfhi(tv.w);
      y[q][0] += t0 * wA0.x + t1 * wA1.x + t2 * wA2.x + t3 * wA3.x + t4 * wB0.x + t5 * wB1.x + t6 * wB2.x + t7 * wB3.x;
      y[q][1] += t0 * wA0.y + t1 * wA1.y + t2 * wA2.y + t3 * wA3.y + t4 * wB0.y + t5 * wB1.y + t6 * wB2.y + t7 * wB3.y;
      y[q][2] += t0 * wA0.z + t1 * wA1.z + t2 * wA2.z + t3 * wA3.z + t4 * wB0.z + t5 * wB1.z + t6 * wB2.z + t7 * wB3.z;
      y[q][3] += t0 * wA0.w + t1 * wA1.w + t2 * wA2.w + t3 * wA3.w + t4 * wB0.w + t5 * wB1.w + t6 * wB2.w + t7 * wB3.w;
    }
  }
  __syncthreads();  // all T reads done; reuse stt as f32 yb[m][36]
  float* yb = (float*)stt;
  {
    float4 b2v = *(const float4*)&b2[i0];
#pragma unroll
    for (int q = 0; q < 4; ++q) {
      int m = mi2 + 32 * q;
      float4 o;
      o.x = y[q][0] + b2v.x; o.y = y[q][1] + b2v.y; o.z = y[q][2] + b2v.z; o.w = y[q][3] + b2v.w;
      *(float4*)&yb[m * 36 + i0] = o;
    }
  }
  __syncthreads();
  // ---- LN + fold with v: al_l = istd*(S_l - mean*G_l) + C_l ----
  {
    int m = tid >> 1, hh = tid & 1;
    const float* yr = &yb[m * 36 + hh * 16];
    float4 y0 = *(const float4*)&yr[0], y1 = *(const float4*)&yr[4];
    float4 y2 = *(const float4*)&yr[8], y3 = *(const float4*)&yr[12];
    float s = y0.x + y0.y + y0.z + y0.w + y1.x + y1.y + y1.z + y1.w +
              y2.x + y2.y + y2.z + y2.w + y3.x + y3.y + y3.z + y3.w;
    float sq = y0.x * y0.x + y0.y * y0.y + y0.z * y0.z + y0.w * y0.w +
               y1.x * y1.x + y1.y * y1.y + y1.z * y1.z + y1.w * y1.w +
               y2.x * y2.x + y2.y * y2.y + y2.z * y2.z + y2.w * y2.w +
               y3.x * y3.x + y3.y * y3.y + y3.z * y3.z + y3.w * y3.w;
    s += __shfl_xor(s, 1);
    sq += __shfl_xor(sq, 1);
    float mean = s * (1.f / 32.f);
    float var = sq * (1.f / 32.f) - mean * mean;
    float istd = rsqrtf(var + 1e-5f);
    float a[3];
#pragma unroll
    for (int l = 0; l < 3; ++l) {
      const float* gvp = &vg[l * 32 + hh * 16];
      float4 g0 = *(const float4*)&gvp[0], g1 = *(const float4*)&gvp[4];
      float4 g2 = *(const float4*)&gvp[8], g3 = *(const float4*)&gvp[12];
      float S = y0.x * g0.x + y0.y * g0.y + y0.z * g0.z + y0.w * g0.w +
                y1.x * g1.x + y1.y * g1.y + y1.z * g1.z + y1.w * g1.w +
                y2.x * g2.x + y2.y * g2.y + y2.z * g2.z + y2.w * g2.w +
                y3.x * g3.x + y3.y * g3.y + y3.z * g3.z + y3.w * g3.w;
      S += __shfl_xor(S, 1);
      a[l] = istd * (S - mean * vg[96 + l]) + vg[99 + l];
    }
    long em = eb + m;
    if (hh == 0 && em < ne) {
      int pos = edge_pos[em];
      ale3[(long)pos * 3 + 0] = a[0];
      ale3[(long)pos * 3 + 1] = a[1];
      ale3[(long)pos * 3 + 2] = a[2];
    }
  }
}

// ---------------- node preproc v2: MLP(128->256->128)+LN + enc Linear(128->64) ----------------
// block 256 thr, 64 nodes; hidden chunked 4x64 so LDS stays small. Weights streamed from L2.
#define NT 64
__global__ __launch_bounds__(256, 3) void node_pre2(
    const float* __restrict__ x, const float* __restrict__ W1, const float* __restrict__ b1,
    const float* __restrict__ W2, const float* __restrict__ b2,
    const float* __restrict__ lng, const float* __restrict__ lnb,
    const float* __restrict__ encW, const float* __restrict__ encb,
    float* __restrict__ z_out, float* __restrict__ part, int n) {
  __shared__ __align__(16) float sx[NT * 132];  // x rows; later f32 yb / h1
  __shared__ __align__(16) float stc[NT * 68];  // T chunk; later BN partial scratch
  __shared__ float sgb[256];
  int tid = threadIdx.x;
  long nb = (long)blockIdx.x * NT;
  for (int i = tid; i < 128; i += 256) { sgb[i] = lng[i]; sgb[128 + i] = lnb[i]; }
  {
    const float4* g4 = (const float4*)(x + nb * 128);
    for (int i4 = tid; i4 < NT * 32; i4 += 256) {
      int m = i4 >> 5, c = (i4 & 31) * 4;
      float4 v = (nb + m < n) ? g4[i4] : make_float4(0.f, 0.f, 0.f, 0.f);
      *(float4*)&sx[m * 132 + c] = v;
    }
  }
  int ji = tid & 31, mi = tid >> 5;  // shared mapping for ph1/ph2/ph3
  int j0b = ji * 2, i0 = ji * 4, z0 = ji * 2;
  float acc2[8][4];
#pragma unroll
  for (int q = 0; q < 8; ++q)
#pragma unroll
    for (int c = 0; c < 4; ++c) acc2[q][c] = 0.f;
  for (int jc = 0; jc < 4; ++jc) {
    __syncthreads();  // prev ph2 reads of stc done (also covers initial stage)
    float a1[8][2];
#pragma unroll
    for (int q = 0; q < 8; ++q) { a1[q][0] = 0.f; a1[q][1] = 0.f; }
    for (int k = 0; k < 128; k += 4) {
      const float* wp = W1 + (long)k * 256 + jc * 64 + j0b;
      float2 w0 = *(const float2*)(wp);
      float2 w1 = *(const float2*)(wp + 256);
      float2 w2 = *(const float2*)(wp + 512);
      float2 w3 = *(const float2*)(wp + 768);
#pragma unroll
      for (int q = 0; q < 8; ++q) {
        int m = mi + 8 * q;
        float4 xv = *(const float4*)&sx[m * 132 + k];
        a1[q][0] += xv.x * w0.x + xv.y * w1.x + xv.z * w2.x + xv.w * w3.x;
        a1[q][1] += xv.x * w0.y + xv.y * w1.y + xv.z * w2.y + xv.w * w3.y;
      }
    }
    float2 bb = *(const float2*)&b1[jc * 64 + j0b];
#pragma unroll
    for (int q = 0; q < 8; ++q) {
      int m = mi + 8 * q;
      float2 o;
      o.x = fmaxf(a1[q][0] + bb.x, 0.f);
      o.y = fmaxf(a1[q][1] + bb.y, 0.f);
      *(float2*)&stc[m * 68 + j0b] = o;
    }
    __syncthreads();
    for (int k = 0; k < 64; k += 4) {
      const float* wp2 = W2 + (long)(jc * 64 + k) * 128 + i0;
      float4 w0 = *(const float4*)(wp2);
      float4 w1 = *(const float4*)(wp2 + 128);
      float4 w2 = *(const float4*)(wp2 + 256);
      float4 w3 = *(const float4*)(wp2 + 384);
#pragma unroll
      for (int q = 0; q < 8; ++q) {
        int m = mi + 8 * q;
        float4 tv = *(const float4*)&stc[m * 68 + k];
        acc2[q][0] += tv.x * w0.x + tv.y * w1.x + tv.z * w2.x + tv.w * w3.x;
        acc2[q][1] += tv.x * w0.y + tv.y * w1.y + tv.z * w2.y + tv.w * w3.y;
        acc2[q][2] += tv.x * w0.z + tv.y * w1.z + tv.z * w2.z + tv.w * w3.z;
        acc2[q][3] += tv.x * w0.w + tv.y * w1.w + tv.z * w2.w + tv.w * w3.w;
      }
    }
  }
  __syncthreads();  // sx (x) no longer needed; reuse as yb
  float* yb = sx;
  {
    float4 b2v = *(const float4*)&b2[i0];
#pragma unroll
    for (int q = 0; q < 8; ++q) {
      int m = mi + 8 * q;
      float4 o;
      o.x = acc2[q][0] + b2v.x; o.y = acc2[q][1] + b2v.y;
      o.z = acc2[q][2] + b2v.z; o.w = acc2[q][3] + b2v.w;
      *(float4*)&yb[m * 132 + i0] = o;
    }
  }
  __syncthreads();
  // ---- LN(128) per node: 4 threads per node; write h1 in place ----
  {
    int m = tid >> 2, qq = tid & 3;
    float* yr = &yb[m * 132 + qq * 32];
    float4 yv[8];
#pragma unroll
    for (int c = 0; c < 8; ++c) yv[c] = *(const float4*)&yr[c * 4];
    float s = 0.f, sq = 0.f;
#pragma unroll
    for (int c = 0; c < 8; ++c) {
      s += yv[c].x + yv[c].y + yv[c].z + yv[c].w;
      sq += yv[c].x * yv[c].x + yv[c].y * yv[c].y + yv[c].z * yv[c].z + yv[c].w * yv[c].w;
    }
    s += __shfl_xor(s, 1); s += __shfl_xor(s, 2);
    sq += __shfl_xor(sq, 1); sq += __shfl_xor(sq, 2);
    float mean = s * (1.f / 128.f);
    float var = sq * (1.f / 128.f) - mean * mean;
    float istd = rsqrtf(var + 1e-5f);
#pragma unroll
    for (int c = 0; c < 8; ++c) {
      int cc = qq * 32 + c * 4;
      float4 g = *(const float4*)&sgb[cc];
      float4 b = *(const float4*)&sgb[128 + cc];
      float4 o;
      o.x = (yv[c].x - mean) * istd * g.x + b.x;
      o.y = (yv[c].y - mean) * istd * g.y + b.y;
      o.z = (yv[c].z - mean) * istd * g.z + b.z;
      o.w = (yv[c].w - mean) * istd * g.w + b.w;
      *(float4*)&yr[c * 4] = o;
    }
  }
  __syncthreads();
  // ---- enc: z = h1 @ encW + encb; BN partials ----
  float az[8][2];
#pragma unroll
  for (int q = 0; q < 8; ++q) { az[q][0] = 0.f; az[q][1] = 0.f; }
  for (int k = 0; k < 128; k += 4) {
    const float* wp3 = encW + (long)k * 64 + z0;
    float2 e0 = *(const float2*)(wp3);
    float2 e1 = *(const float2*)(wp3 + 64);
    float2 e2 = *(const float2*)(wp3 + 128);
    float2 e3 = *(const float2*)(wp3 + 192);
#pragma unroll
    for (int q = 0; q < 8; ++q) {
      int m = mi + 8 * q;
      float4 hv = *(const float4*)&yb[m * 132 + k];
      az[q][0] += hv.x * e0.x + hv.y * e1.x + hv.z * e2.x + hv.w * e3.x;
      az[q][1] += hv.x * e0.y + hv.y * e1.y + hv.z * e2.y + hv.w * e3.y;
    }
  }
  float2 ebv = *(const float2*)&encb[z0];
  float ps0 = 0.f, ps1 = 0.f, pq0 = 0.f, pq1 = 0.f;
#pragma unroll
  for (int q = 0; q < 8; ++q) {
    long nd = nb + mi + 8 * q;
    if (nd < n) {
      float za = az[q][0] + ebv.x, zb = az[q][1] + ebv.y;
      *(float2*)&z_out[nd * 64 + z0] = make_float2(za, zb);
      ps0 += za; ps1 += zb; pq0 += za * za; pq1 += zb * zb;
    }
  }
  __syncthreads();  // stc free
  float* sr = stc;  // [8 groups][128]
  sr[mi * 128 + z0] = ps0; sr[mi * 128 + z0 + 1] = ps1;
  sr[mi * 128 + 64 + z0] = pq0; sr[mi * 128 + 64 + z0 + 1] = pq1;
  __syncthreads();
  if (tid < 128) {
    float t = 0.f;
#pragma unroll
    for (int g = 0; g < 8; ++g) t += sr[g * 128 + tid];
    part[(long)blockIdx.x * 128 + tid] = t;
  }
}

// ---------------- per-layer: xs = h@W, al_s, al_d ----------------
__global__ __launch_bounds__(256) void xs_kernel(
    const float* __restrict__ h, const float* __restrict__ W,
    const float* __restrict__ a_s, const float* __restrict__ a_d,
    float* __restrict__ xs, float* __restrict__ al_s, float* __restrict__ al_d, int n) {
  __shared__ __align__(16) float sW[64 * 64];
  __shared__ __align__(16) float sh[32][64];
  int tid = threadIdx.x, w = tid >> 6, lane = tid & 63;
  for (int i = tid; i < 4096; i += 256) sW[i] = W[i];
  long nodeBase = (long)blockIdx.x * 32;
  {
    const float* gh = h + nodeBase * 64;
    long limit = ((long)n - nodeBase) * 64;
    float* shf = &sh[0][0];
    for (int i = tid; i < 2048; i += 256) shf[i] = (i < limit) ? gh[i] : 0.f;
  }
  __syncthreads();
  int lm0 = w * 8;
  float acc[8];
#pragma unroll
  for (int m = 0; m < 8; ++m) acc[m] = 0.f;
  for (int k = 0; k < 64; k += 4) {
    float w0 = sW[(k + 0) * 64 + lane];
    float w1 = sW[(k + 1) * 64 + lane];
    float w2 = sW[(k + 2) * 64 + lane];
    float w3 = sW[(k + 3) * 64 + lane];
#pragma unroll
    for (int m = 0; m < 8; ++m) {
      float4 h4 = *reinterpret_cast<const float4*>(&sh[lm0 + m][k]);
      acc[m] += h4.x * w0 + h4.y * w1 + h4.z * w2 + h4.w * w3;
    }
  }
  float asv = a_s[lane], adv = a_d[lane];
#pragma unroll
  for (int m = 0; m < 8; ++m) {
    long nd = nodeBase + lm0 + m;
    float ps = acc[m] * asv, pd = acc[m] * adv;
#pragma unroll
    for (int o = 1; o < 64; o <<= 1) {
      ps += __shfl_xor(ps, o);
      pd += __shfl_xor(pd, o);
    }
    if (nd < n) {
      xs[nd * 64 + lane] = acc[m];
      if (lane == 0) { al_s[nd] = ps; al_d[nd] = pd; }
    }
  }
}

// ---------------- GAT v3: quarter-wave (16 lanes) per node, float4 channels/lane ----------------
#define QCAP 128
__global__ __launch_bounds__(256) void gat3(
    const int* __restrict__ off, const int* __restrict__ csr_src,
    const float* __restrict__ ale3, int lsel,
    const float* __restrict__ al_s, const float* __restrict__ al_d,
    const float* __restrict__ xs, const float* __restrict__ bias,
    float* __restrict__ gat_out, float* __restrict__ part, int n) {
  __shared__ float2 sal[16][QCAP];   // (al_or_ex, src-as-float)
  __shared__ float sred[4][128];
  int tid = threadIdx.x, w = tid >> 6, lane = tid & 63;
  int qt = tid >> 4, q = tid & 15;
  const float4* xs4 = (const float4*)xs;
  float4 bv = *(const float4*)&bias[q * 4];
  float4 psum = make_float4(0.f, 0.f, 0.f, 0.f), psq = psum;
  for (int node = blockIdx.x * 16 + qt; node < n; node += gridDim.x * 16) {
    int s0 = off[node];
    int deg = off[node + 1] - s0;
    bool fits = (deg <= QCAP);
    float aldn = al_d[node];
    float lmax = -3.402823466e38f, lsae = 0.f;
    for (int k = q; k < deg; k += 16) {
      int sc = csr_src[s0 + k];
      float ae = ale3[(long)(s0 + k) * 3 + lsel];
      float a = al_s[sc] + aldn + ae;
      float al = (a >= 0.f) ? a : 0.2f * a;
      lmax = fmaxf(lmax, al);
      lsae += ae;
      if (fits) sal[qt][k] = make_float2(al, __int_as_float(sc));
    }
#pragma unroll
    for (int o = 1; o < 16; o <<= 1) {
      lmax = fmaxf(lmax, __shfl_xor(lmax, o));
      lsae += __shfl_xor(lsae, o);
    }
    float ae_self = lsae / fmaxf((float)deg, 1.f);
    float a_self = al_s[node] + aldn + ae_self;
    float al_self = (a_self >= 0.f) ? a_self : 0.2f * a_self;
    float mx = fmaxf(lmax, al_self);
    float lsum = 0.f;
    if (fits) {
      for (int k = q; k < deg; k += 16) {
        float ex = __expf(sal[qt][k].x - mx);
        sal[qt][k].x = ex;
        lsum += ex;
      }
    } else {
      for (int k = q; k < deg; k += 16) {
        int sc = csr_src[s0 + k];
        float a = al_s[sc] + aldn + ale3[(long)(s0 + k) * 3 + lsel];
        float al = (a >= 0.f) ? a : 0.2f * a;
        lsum += __expf(al - mx);
      }
    }
#pragma unroll
    for (int o = 1; o < 16; o <<= 1) lsum += __shfl_xor(lsum, o);
    float exs = __expf(al_self - mx);
    float inv = 1.f / (lsum + exs + 1e-16f);
    float4 xv = xs4[(long)node * 16 + q];
    float4 acc;
    acc.x = exs * xv.x; acc.y = exs * xv.y; acc.z = exs * xv.z; acc.w = exs * xv.w;
    if (fits) {
      int k = 0;
      for (; k + 4 <= deg; k += 4) {
        float2 p0 = sal[qt][k], p1 = sal[qt][k + 1], p2 = sal[qt][k + 2], p3 = sal[qt][k + 3];
        float4 x0 = xs4[(long)__float_as_int(p0.y) * 16 + q];
        float4 x1 = xs4[(long)__float_as_int(p1.y) * 16 + q];
        float4 x2 = xs4[(long)__float_as_int(p2.y) * 16 + q];
        float4 x3 = xs4[(long)__float_as_int(p3.y) * 16 + q];
        acc.x += p0.x * x0.x + p1.x * x1.x + p2.x * x2.x + p3.x * x3.x;
        acc.y += p0.x * x0.y + p1.x * x1.y + p2.x * x2.y + p3.x * x3.y;
        acc.z += p0.x * x0.z + p1.x * x1.z + p2.x * x2.z + p3.x * x3.z;
        acc.w += p0.x * x0.w + p1.x * x1.w + p2.x * x2.w + p3.x * x3.w;
      }
      for (; k < deg; ++k) {
        float2 p = sal[qt][k];
        float4 xk = xs4[(long)__float_as_int(p.y) * 16 + q];
        acc.x += p.x * xk.x; acc.y += p.x * xk.y; acc.z += p.x * xk.z; acc.w += p.x * xk.w;
      }
    } else {
      for (int k = 0; k < deg; ++k) {
        int sc = csr_src[s0 + k];
        float a = al_s[sc] + aldn + ale3[(long)(s0 + k) * 3 + lsel];
        float al = (a >= 0.f) ? a : 0.2f * a;
        float ex = __expf(al - mx);
        float4 xk = xs4[(long)sc * 16 + q];
        acc.x += ex * xk.x; acc.y += ex * xk.y; acc.z += ex * xk.z; acc.w += ex * xk.w;
      }
    }
    acc.x = acc.x * inv + bv.x; acc.y = acc.y * inv + bv.y;
    acc.z = acc.z * inv + bv.z; acc.w = acc.w * inv + bv.w;
    *(float4*)&gat_out[(long)node * 64 + q * 4] = acc;
    psum.x += acc.x; psum.y += acc.y; psum.z += acc.z; psum.w += acc.w;
    psq.x += acc.x * acc.x; psq.y += acc.y * acc.y; psq.z += acc.z * acc.z; psq.w += acc.w * acc.w;
  }
  // reduce across the 4 quarters in each wave
#pragma unroll
  for (int o = 16; o < 64; o <<= 1) {
    psum.x += __shfl_xor(psum.x, o); psum.y += __shfl_xor(psum.y, o);
    psum.z += __shfl_xor(psum.z, o); psum.w += __shfl_xor(psum.w, o);
    psq.x += __shfl_xor(psq.x, o); psq.y += __shfl_xor(psq.y, o);
    psq.z += __shfl_xor(psq.z, o); psq.w += __shfl_xor(psq.w, o);
  }
  if (lane < 16) {
    sred[w][lane * 4 + 0] = psum.x; sred[w][lane * 4 + 1] = psum.y;
    sred[w][lane * 4 + 2] = psum.z; sred[w][lane * 4 + 3] = psum.w;
    sred[w][64 + lane * 4 + 0] = psq.x; sred[w][64 + lane * 4 + 1] = psq.y;
    sred[w][64 + lane * 4 + 2] = psq.z; sred[w][64 + lane * 4 + 3] = psq.w;
  }
  __syncthreads();
  if (tid < 128)
    part[(long)blockIdx.x * 128 + tid] =
        sred[0][tid] + sred[1][tid] + sred[2][tid] + sred[3][tid];
}

// ---------------- BN finalize + apply ----------------
__global__ __launch_bounds__(1024) void bn_finalize(const float* __restrict__ part, int nblk,
                                                    float invN, float* __restrict__ stats) {
  __shared__ float sh[1024];
  int t = threadIdx.x;
  int c = t & 127, g = t >> 7;
  float s = 0.f;
  for (int b = g; b < nblk; b += 8) s += part[(long)b * 128 + c];
  sh[t] = s;
  __syncthreads();
  if (t < 128) {
    float tot = 0.f;
#pragma unroll
    for (int g2 = 0; g2 < 8; ++g2) tot += sh[g2 * 128 + t];
    sh[t] = tot;
  }
  __syncthreads();
  if (t < 64) {
    float mean = sh[t] * invN;
    float var = sh[64 + t] * invN - mean * mean;
    stats[t] = mean;
    stats[64 + t] = rsqrtf(var + 1e-5f);
  }
}

__global__ void bn_apply(const float* __restrict__ z, const float* __restrict__ stats,
                         const float* __restrict__ g, const float* __restrict__ b,
                         float* __restrict__ h, long total, int mode) {
  long i = (long)blockIdx.x * blockDim.x + threadIdx.x;
  long stride = (long)gridDim.x * blockDim.x;
  for (; i < total; i += stride) {
    int c = (int)(i & 63);
    float vv = (z[i] - stats[c]) * stats[64 + c] * g[c] + b[c];
    vv = fmaxf(vv, 0.f);
    if (mode) h[i] += vv; else h[i] = vv;
  }
}

// ---------------- final pool + MLP ----------------
__global__ void gsum_part(const float* __restrict__ h, int n, float* __restrict__ part) {
  __shared__ float sh[4][64];
  int tid = threadIdx.x, w = tid >> 6, lane = tid & 63;
  int gw = blockIdx.x * 4 + w, nW = gridDim.x * 4;
  float s = 0.f;
  for (int node = gw; node < n; node += nW) s += h[(long)node * 64 + lane];
  sh[w][lane] = s;
  __syncthreads();
  if (tid < 64)
    part[(long)blockIdx.x * 64 + tid] =
        sh[0][tid] + sh[1][tid] + sh[2][tid] + sh[3][tid];
}

__global__ void final_kernel(const float* __restrict__ part, int nblk,
                             const float* __restrict__ out_W, const float* __restrict__ out_b,
                             float* __restrict__ out, float invN) {
  __shared__ float g[64];
  int c = threadIdx.x;  // 64 threads
  float s = 0.f;
  for (int b = 0; b < nblk; ++b) s += part[(long)b * 64 + c];
  g[c] = s * invN;
  __syncthreads();
  float acc = out_b[c];
  for (int k = 0; k < 64; ++k) acc += g[k] * out_W[k * 64 + c];
  out[c] = fmaxf(acc, 0.f);
}

// ---------------- host launch ----------------
extern "C" void kernel_launch(void* const* d_in, const int* in_sizes, int n_in,
                              void* d_out, int out_size, void* d_ws, size_t ws_size,
                              hipStream_t stream) {
  const float* x        = (const float*)d_in[0];
  const int*   eidx     = (const int*)d_in[1];
  const float* eattr    = (const float*)d_in[2];
  const float* np_W1    = (const float*)d_in[3];
  const float* np_b1    = (const float*)d_in[4];
  const float* np_W2    = (const float*)d_in[5];
  const float* np_b2    = (const float*)d_in[6];
  const float* np_ln_g  = (const float*)d_in[7];
  const float* np_ln_b  = (const float*)d_in[8];
  const float* ep_W1    = (const float*)d_in[9];
  const float* ep_b1    = (const float*)d_in[10];
  const float* ep_W2    = (const float*)d_in[11];
  const float* ep_b2    = (const float*)d_in[12];
  const float* ep_ln_g  = (const float*)d_in[13];
  const float* ep_ln_b  = (const float*)d_in[14];
  const float* enc_W    = (const float*)d_in[15];
  const float* enc_b    = (const float*)d_in[16];
  const float* enc_bn_g = (const float*)d_in[17];
  const float* enc_bn_b = (const float*)d_in[18];
  const float* gat_W    = (const float*)d_in[19];
  const float* gat_eW   = (const float*)d_in[20];
  const float* att_src  = (const float*)d_in[21];
  const float* att_dst  = (const float*)d_in[22];
  const float* att_edge = (const float*)d_in[23];
  const float* gat_b    = (const float*)d_in[24];
  const float* bn_g     = (const float*)d_in[25];
  const float* bn_b     = (const float*)d_in[26];
  const float* out_W    = (const float*)d_in[27];
  const float* out_b    = (const float*)d_in[28];

  const int n = in_sizes[0] / 128;   // 50000
  const int ne = in_sizes[1] / 2;    // 800000
  const int* srcp = eidx;
  const int* dstp = eidx + ne;

  float* f = (float*)d_ws;
  float* hbuf  = f; f += (long)n * 64;
  float* xsbuf = f; f += (long)n * 64;
  float* zbuf  = f; f += (long)n * 64;
  float* alsb  = f; f += n;
  float* aldb  = f; f += n;
  float* ale3  = f; f += 3L * ne;
  float* vgbuf = f; f += 128;
  float* stats = f; f += 128;
  float* part  = f; f += 262144;
  int* ip = (int*)f;
  int* edge_pos = ip; ip += ne;
  int* csr_src  = ip; ip += ne;
  int* degb     = ip; ip += n;
  int* cntb     = ip; ip += n;
  int* offb     = ip; ip += n + 1;

  const int nbEdge = (ne + ET - 1) / ET;     // 6250
  const int nbNode = (n + NT - 1) / NT;      // 782
  const int nbXs   = (n + 31) / 32;

  hipMemsetAsync(degb, 0, (size_t)n * sizeof(int), stream);
  hipMemsetAsync(cntb, 0, (size_t)n * sizeof(int), stream);
  vprep2<<<1, 128, 0, stream>>>(gat_eW, att_edge, ep_ln_g, ep_ln_b, vgbuf);
  deg_kernel<<<1024, 256, 0, stream>>>(dstp, ne, degb);
  scan2<<<1, 1024, 0, stream>>>(degb, offb, n);
  scatter_kernel<<<1024, 256, 0, stream>>>(srcp, dstp, ne, offb, cntb, edge_pos, csr_src);
  edge_pre2<<<nbEdge, 256, 0, stream>>>(eattr, ep_W1, ep_b1, ep_W2, ep_b2,
                                        vgbuf, edge_pos, ale3, ne);
  node_pre2<<<nbNode, 256, 0, stream>>>(x, np_W1, np_b1, np_W2, np_b2, np_ln_g, np_ln_b,
                                        enc_W, enc_b, zbuf, part, n);
  bn_finalize<<<1, 1024, 0, stream>>>(part, nbNode, 1.f / n, stats);
  bn_apply<<<2048, 256, 0, stream>>>(zbuf, stats, enc_bn_g, enc_bn_b, hbuf, (long)n * 64, 0);
  for (int l = 0; l < 3; ++l) {
    xs_kernel<<<nbXs, 256, 0, stream>>>(hbuf, gat_W + (long)l * 4096, att_src + l * 64,
                                        att_dst + l * 64, xsbuf, alsb, aldb, n);
    gat3<<<1024, 256, 0, stream>>>(offb, csr_src, ale3, l, alsb, aldb,
                                   xsbuf, gat_b + l * 64, zbuf, part, n);
    bn_finalize<<<1, 1024, 0, stream>>>(part, 1024, 1.f / n, stats);
    bn_apply<<<2048, 256, 0, stream>>>(zbuf, stats, bn_g + l * 64, bn_b + l * 64, hbuf,
                                       (long)n * 64, 1);
  }
  gsum_part<<<1024, 256, 0, stream>>>(hbuf, n, part);
  final_kernel<<<1, 64, 0, stream>>>(part, 1024, out_W, out_b, (float*)d_out, 1.f / n);
}

// Round 3
// 1291.301 us; speedup vs baseline: 1.5186x; 1.1053x over previous
//
#include <hip/hip_runtime.h>
#include <hip/hip_bf16.h>

// GNNEncoder on MI355X. Algebraic reductions:
//  - (ea@eW)@a_e == ea@(eW@a_e): only 3 scalars al_e per edge needed.
//  - loop_attr contribution == mean(incoming al_e) by linearity.
//  - edge LN+dot folded: al = istd*(sum y*(g*v) - mean*G) + C.
// dst-CSR (int2{src,eid}) built once; al_e written CONTIGUOUS in edge order and
// gathered via eid in gat3 (L2-resident) -- no random sub-line scatters of values.
// BN apply fused into xs_bn / gsum_bn (no standalone bn_apply passes).

__device__ __forceinline__ unsigned pack2bf(float a, float b) {
  unsigned ua = __float_as_uint(a); ua += 0x7fffu + ((ua >> 16) & 1u);
  unsigned ub = __float_as_uint(b); ub += 0x7fffu + ((ub >> 16) & 1u);
  return (ua >> 16) | (ub & 0xffff0000u);
}
__device__ __forceinline__ unsigned short f2bf(float x) {
  unsigned u = __float_as_uint(x); u += 0x7fffu + ((u >> 16) & 1u);
  return (unsigned short)(u >> 16);
}
__device__ __forceinline__ float bflo(unsigned u) { return __uint_as_float(u << 16); }
__device__ __forceinline__ float bfhi(unsigned u) { return __uint_as_float(u & 0xffff0000u); }

// ---------------- prep: v = eW@a_e, gv = lng*v, G = sum(lng*v), C = sum(lnb*v) ----------------
__global__ void vprep2(const float* __restrict__ eW, const float* __restrict__ a_e,
                       const float* __restrict__ lng, const float* __restrict__ lnb,
                       float* __restrict__ vg) {
  __shared__ float sv[96];
  int t = threadIdx.x;  // 128 threads
  if (t < 96) {
    int l = t >> 5, i = t & 31;
    const float* w = eW + l * 2048 + i * 64;
    const float* a = a_e + l * 64;
    float s = 0.f;
    for (int c = 0; c < 64; ++c) s += w[c] * a[c];
    sv[t] = s;
    vg[t] = s * lng[i];
  }
  __syncthreads();
  if (t < 3) {
    float G = 0.f, C = 0.f;
    for (int i = 0; i < 32; ++i) {
      float vv = sv[t * 32 + i];
      G += lng[i] * vv;
      C += lnb[i] * vv;
    }
    vg[96 + t] = G;
    vg[99 + t] = C;
  }
}

__global__ void deg_kernel(const int* __restrict__ dst, int ne, int* __restrict__ deg) {
  int i = blockIdx.x * blockDim.x + threadIdx.x;
  int stride = gridDim.x * blockDim.x;
  for (; i < ne; i += stride) atomicAdd(&deg[dst[i]], 1);
}

// thread-serial chunks + one 1024-wide scan
__global__ __launch_bounds__(1024) void scan2(const int* __restrict__ deg,
                                              int* __restrict__ off, int n) {
  __shared__ int sh[1024];
  int t = threadIdx.x;
  int C = (n + 1023) >> 10;
  int b0 = t * C, b1 = min(n, b0 + C);
  int s = 0;
  for (int j = b0; j < b1; ++j) s += deg[j];
  sh[t] = s;
  __syncthreads();
  for (int o = 1; o < 1024; o <<= 1) {
    int add = (t >= o) ? sh[t - o] : 0;
    __syncthreads();
    sh[t] += add;
    __syncthreads();
  }
  int run = (t == 0) ? 0 : sh[t - 1];
  if (t == 0) off[0] = 0;
  for (int j = b0; j < b1; ++j) { run += deg[j]; off[j + 1] = run; }
}

__global__ void scatter_kernel(const int* __restrict__ src, const int* __restrict__ dst,
                               int ne, const int* __restrict__ off, int* __restrict__ cnt,
                               int2* __restrict__ csr) {
  int i = blockIdx.x * blockDim.x + threadIdx.x;
  int stride = gridDim.x * blockDim.x;
  for (; i < ne; i += stride) {
    int d = dst[i];
    int p = off[d] + atomicAdd(&cnt[d], 1);
    csr[p] = make_int2(src[i], i);
  }
}

// ---------------- edge preproc: MLP(32->64->32)+LN -> al_e, CONTIGUOUS SoA ----------------
#define ET 128
__global__ __launch_bounds__(256, 3) void edge_pre2(
    const float* __restrict__ ea, const float* __restrict__ W1, const float* __restrict__ b1,
    const float* __restrict__ W2, const float* __restrict__ b2,
    const float* __restrict__ vg, float* __restrict__ ale, int ne) {
  __shared__ __align__(16) float sW1[32 * 64];     // [k][j]
  __shared__ __align__(16) float sW2[64 * 36];     // [k][i] pad 36
  __shared__ __align__(16) unsigned short sea[ET * 48];  // bf16 [m][k] pad 48
  __shared__ __align__(16) unsigned short stt[ET * 72];  // bf16 [m][j] pad 72; reused as f32 yb[ET*36]
  int tid = threadIdx.x;
  for (int i = tid; i < 2048; i += 256) sW1[i] = W1[i];
  for (int i = tid; i < 2048; i += 256) sW2[(i >> 5) * 36 + (i & 31)] = W2[i];
  long eb = (long)blockIdx.x * ET;
  {  // stage ea -> bf16
    const float4* g4 = (const float4*)(ea + eb * 32);
    for (int i4 = tid; i4 < ET * 8; i4 += 256) {
      int m = i4 >> 3, c = (i4 & 7) * 4;
      float4 v = (eb + m < ne) ? g4[i4] : make_float4(0.f, 0.f, 0.f, 0.f);
      unsigned lo = pack2bf(v.x, v.y), hi = pack2bf(v.z, v.w);
      *(uint2*)&sea[m * 48 + c] = make_uint2(lo, hi);
    }
  }
  __syncthreads();
  // ---- phase 1: T = relu(ea@W1 + b1), T in bf16 LDS ----
  {
    int ji = tid & 15, mi = tid >> 4;
    int j0 = ji * 4;
    float acc[8][4];
#pragma unroll
    for (int q = 0; q < 8; ++q)
#pragma unroll
      for (int c = 0; c < 4; ++c) acc[q][c] = 0.f;
    for (int k = 0; k < 32; k += 4) {
      float4 w0 = *(const float4*)&sW1[(k + 0) * 64 + j0];
      float4 w1 = *(const float4*)&sW1[(k + 1) * 64 + j0];
      float4 w2 = *(const float4*)&sW1[(k + 2) * 64 + j0];
      float4 w3 = *(const float4*)&sW1[(k + 3) * 64 + j0];
#pragma unroll
      for (int q = 0; q < 8; ++q) {
        int m = mi + 16 * q;
        uint2 av = *(const uint2*)&sea[m * 48 + k];
        float a0 = bflo(av.x), a1 = bfhi(av.x), a2 = bflo(av.y), a3 = bfhi(av.y);
        acc[q][0] += a0 * w0.x + a1 * w1.x + a2 * w2.x + a3 * w3.x;
        acc[q][1] += a0 * w0.y + a1 * w1.y + a2 * w2.y + a3 * w3.y;
        acc[q][2] += a0 * w0.z + a1 * w1.z + a2 * w2.z + a3 * w3.z;
        acc[q][3] += a0 * w0.w + a1 * w1.w + a2 * w2.w + a3 * w3.w;
      }
    }
    float4 bb = *(const float4*)&b1[j0];
#pragma unroll
    for (int q = 0; q < 8; ++q) {
      int m = mi + 16 * q;
      float t0 = fmaxf(acc[q][0] + bb.x, 0.f), t1 = fmaxf(acc[q][1] + bb.y, 0.f);
      float t2 = fmaxf(acc[q][2] + bb.z, 0.f), t3 = fmaxf(acc[q][3] + bb.w, 0.f);
      *(uint2*)&stt[m * 72 + j0] = make_uint2(pack2bf(t0, t1), pack2bf(t2, t3));
    }
  }
  __syncthreads();
  // ---- phase 2: Y = T@W2 + b2 ----
  int ii = tid & 7, mi2 = tid >> 3;
  int i0 = ii * 4;
  float y[4][4];
#pragma unroll
  for (int q = 0; q < 4; ++q)
#pragma unroll
    for (int c = 0; c < 4; ++c) y[q][c] = 0.f;
  for (int k8 = 0; k8 < 64; k8 += 8) {
    float4 wA0 = *(const float4*)&sW2[(k8 + 0) * 36 + i0];
    float4 wA1 = *(const float4*)&sW2[(k8 + 1) * 36 + i0];
    float4 wA2 = *(const float4*)&sW2[(k8 + 2) * 36 + i0];
    float4 wA3 = *(const float4*)&sW2[(k8 + 3) * 36 + i0];
    float4 wB0 = *(const float4*)&sW2[(k8 + 4) * 36 + i0];
    float4 wB1 = *(const float4*)&sW2[(k8 + 5) * 36 + i0];
    float4 wB2 = *(const float4*)&sW2[(k8 + 6) * 36 + i0];
    float4 wB3 = *(const float4*)&sW2[(k8 + 7) * 36 + i0];
#pragma unroll
    for (int q = 0; q < 4; ++q) {
      int m = mi2 + 32 * q;
      uint4 tv = *(const uint4*)&stt[m * 72 + k8];
      float t0 = bflo(tv.x), t1 = bfhi(tv.x), t2 = bflo(tv.y), t3 = bfhi(tv.y);
      float t4 = bflo(tv.z), t5 = bfhi(tv.z), t6 = bflo(tv.w), t7 = bfhi(tv.w);
      y[q][0] += t0 * wA0.x + t1 * wA1.x + t2 * wA2.x + t3 * wA3.x + t4 * wB0.x + t5 * wB1.x + t6 * wB2.x + t7 * wB3.x;
      y[q][1] += t0 * wA0.y + t1 * wA1.y + t2 * wA2.y + t3 * wA3.y + t4 * wB0.y + t5 * wB1.y + t6 * wB2.y + t7 * wB3.y;
      y[q][2] += t0 * wA0.z + t1 * wA1.z + t2 * wA2.z + t3 * wA3.z + t4 * wB0.z + t5 * wB1.z + t6 * wB2.z + t7 * wB3.z;
      y[q][3] += t0 * wA0.w + t1 * wA1.w + t2 * wA2.w + t3 * wA3.w + t4 * wB0.w + t5 * wB1.w + t6 * wB2.w + t7 * wB3.w;
    }
  }
  __syncthreads();  // all T reads done; reuse stt as f32 yb[m*36]
  float* yb = (float*)stt;
  {
    float4 b2v = *(const float4*)&b2[i0];
#pragma unroll
    for (int q = 0; q < 4; ++q) {
      int m = mi2 + 32 * q;
      float4 o;
      o.x = y[q][0] + b2v.x; o.y = y[q][1] + b2v.y; o.z = y[q][2] + b2v.z; o.w = y[q][3] + b2v.w;
      *(float4*)&yb[m * 36 + i0] = o;
    }
  }
  __syncthreads();
  // ---- LN + fold with v: al_l = istd*(S_l - mean*G_l) + C_l; write contiguous SoA ----
  {
    int m = tid >> 1, hh = tid & 1;
    const float* yr = &yb[m * 36 + hh * 16];
    float4 y0 = *(const float4*)&yr[0], y1 = *(const float4*)&yr[4];
    float4 y2 = *(const float4*)&yr[8], y3 = *(const float4*)&yr[12];
    float s = y0.x + y0.y + y0.z + y0.w + y1.x + y1.y + y1.z + y1.w +
              y2.x + y2.y + y2.z + y2.w + y3.x + y3.y + y3.z + y3.w;
    float sq = y0.x * y0.x + y0.y * y0.y + y0.z * y0.z + y0.w * y0.w +
               y1.x * y1.x + y1.y * y1.y + y1.z * y1.z + y1.w * y1.w +
               y2.x * y2.x + y2.y * y2.y + y2.z * y2.z + y2.w * y2.w +
               y3.x * y3.x + y3.y * y3.y + y3.z * y3.z + y3.w * y3.w;
    s += __shfl_xor(s, 1);
    sq += __shfl_xor(sq, 1);
    float mean = s * (1.f / 32.f);
    float var = sq * (1.f / 32.f) - mean * mean;
    float istd = rsqrtf(var + 1e-5f);
    float a[3];
#pragma unroll
    for (int l = 0; l < 3; ++l) {
      const float* gvp = &vg[l * 32 + hh * 16];
      float4 g0 = *(const float4*)&gvp[0], g1 = *(const float4*)&gvp[4];
      float4 g2 = *(const float4*)&gvp[8], g3 = *(const float4*)&gvp[12];
      float S = y0.x * g0.x + y0.y * g0.y + y0.z * g0.z + y0.w * g0.w +
                y1.x * g1.x + y1.y * g1.y + y1.z * g1.z + y1.w * g1.w +
                y2.x * g2.x + y2.y * g2.y + y2.z * g2.z + y2.w * g2.w +
                y3.x * g3.x + y3.y * g3.y + y3.z * g3.z + y3.w * g3.w;
      S += __shfl_xor(S, 1);
      a[l] = istd * (S - mean * vg[96 + l]) + vg[99 + l];
    }
    long em = eb + m;
    if (hh == 0 && em < ne) {
      ale[em] = a[0];
      ale[(long)ne + em] = a[1];
      ale[2L * ne + em] = a[2];
    }
  }
}

// ---------------- node preproc: MLP(128->256->128)+LN + enc Linear(128->64) ----------------
#define NT 64
__global__ __launch_bounds__(256, 3) void node_pre2(
    const float* __restrict__ x, const float* __restrict__ W1, const float* __restrict__ b1,
    const float* __restrict__ W2, const float* __restrict__ b2,
    const float* __restrict__ lng, const float* __restrict__ lnb,
    const float* __restrict__ encW, const float* __restrict__ encb,
    float* __restrict__ z_out, float* __restrict__ part, int n) {
  __shared__ __align__(16) float sx[NT * 132];  // x rows; later f32 yb / h1
  __shared__ __align__(16) float stc[NT * 68];  // T chunk; later BN partial scratch
  __shared__ float sgb[256];
  int tid = threadIdx.x;
  long nb = (long)blockIdx.x * NT;
  for (int i = tid; i < 128; i += 256) { sgb[i] = lng[i]; sgb[128 + i] = lnb[i]; }
  {
    const float4* g4 = (const float4*)(x + nb * 128);
    for (int i4 = tid; i4 < NT * 32; i4 += 256) {
      int m = i4 >> 5, c = (i4 & 31) * 4;
      float4 v = (nb + m < n) ? g4[i4] : make_float4(0.f, 0.f, 0.f, 0.f);
      *(float4*)&sx[m * 132 + c] = v;
    }
  }
  int ji = tid & 31, mi = tid >> 5;
  int j0b = ji * 2, i0 = ji * 4, z0 = ji * 2;
  float acc2[8][4];
#pragma unroll
  for (int q = 0; q < 8; ++q)
#pragma unroll
    for (int c = 0; c < 4; ++c) acc2[q][c] = 0.f;
  for (int jc = 0; jc < 4; ++jc) {
    __syncthreads();
    float a1[8][2];
#pragma unroll
    for (int q = 0; q < 8; ++q) { a1[q][0] = 0.f; a1[q][1] = 0.f; }
    for (int k = 0; k < 128; k += 4) {
      const float* wp = W1 + (long)k * 256 + jc * 64 + j0b;
      float2 w0 = *(const float2*)(wp);
      float2 w1 = *(const float2*)(wp + 256);
      float2 w2 = *(const float2*)(wp + 512);
      float2 w3 = *(const float2*)(wp + 768);
#pragma unroll
      for (int q = 0; q < 8; ++q) {
        int m = mi + 8 * q;
        float4 xv = *(const float4*)&sx[m * 132 + k];
        a1[q][0] += xv.x * w0.x + xv.y * w1.x + xv.z * w2.x + xv.w * w3.x;
        a1[q][1] += xv.x * w0.y + xv.y * w1.y + xv.z * w2.y + xv.w * w3.y;
      }
    }
    float2 bb = *(const float2*)&b1[jc * 64 + j0b];
#pragma unroll
    for (int q = 0; q < 8; ++q) {
      int m = mi + 8 * q;
      float2 o;
      o.x = fmaxf(a1[q][0] + bb.x, 0.f);
      o.y = fmaxf(a1[q][1] + bb.y, 0.f);
      *(float2*)&stc[m * 68 + j0b] = o;
    }
    __syncthreads();
    for (int k = 0; k < 64; k += 4) {
      const float* wp2 = W2 + (long)(jc * 64 + k) * 128 + i0;
      float4 w0 = *(const float4*)(wp2);
      float4 w1 = *(const float4*)(wp2 + 128);
      float4 w2 = *(const float4*)(wp2 + 256);
      float4 w3 = *(const float4*)(wp2 + 384);
#pragma unroll
      for (int q = 0; q < 8; ++q) {
        int m = mi + 8 * q;
        float4 tv = *(const float4*)&stc[m * 68 + k];
        acc2[q][0] += tv.x * w0.x + tv.y * w1.x + tv.z * w2.x + tv.w * w3.x;
        acc2[q][1] += tv.x * w0.y + tv.y * w1.y + tv.z * w2.y + tv.w * w3.y;
        acc2[q][2] += tv.x * w0.z + tv.y * w1.z + tv.z * w2.z + tv.w * w3.z;
        acc2[q][3] += tv.x * w0.w + tv.y * w1.w + tv.z * w2.w + tv.w * w3.w;
      }
    }
  }
  __syncthreads();
  float* yb = sx;
  {
    float4 b2v = *(const float4*)&b2[i0];
#pragma unroll
    for (int q = 0; q < 8; ++q) {
      int m = mi + 8 * q;
      float4 o;
      o.x = acc2[q][0] + b2v.x; o.y = acc2[q][1] + b2v.y;
      o.z = acc2[q][2] + b2v.z; o.w = acc2[q][3] + b2v.w;
      *(float4*)&yb[m * 132 + i0] = o;
    }
  }
  __syncthreads();
  {
    int m = tid >> 2, qq = tid & 3;
    float* yr = &yb[m * 132 + qq * 32];
    float4 yv[8];
#pragma unroll
    for (int c = 0; c < 8; ++c) yv[c] = *(const float4*)&yr[c * 4];
    float s = 0.f, sq = 0.f;
#pragma unroll
    for (int c = 0; c < 8; ++c) {
      s += yv[c].x + yv[c].y + yv[c].z + yv[c].w;
      sq += yv[c].x * yv[c].x + yv[c].y * yv[c].y + yv[c].z * yv[c].z + yv[c].w * yv[c].w;
    }
    s += __shfl_xor(s, 1); s += __shfl_xor(s, 2);
    sq += __shfl_xor(sq, 1); sq += __shfl_xor(sq, 2);
    float mean = s * (1.f / 128.f);
    float var = sq * (1.f / 128.f) - mean * mean;
    float istd = rsqrtf(var + 1e-5f);
#pragma unroll
    for (int c = 0; c < 8; ++c) {
      int cc = qq * 32 + c * 4;
      float4 g = *(const float4*)&sgb[cc];
      float4 b = *(const float4*)&sgb[128 + cc];
      float4 o;
      o.x = (yv[c].x - mean) * istd * g.x + b.x;
      o.y = (yv[c].y - mean) * istd * g.y + b.y;
      o.z = (yv[c].z - mean) * istd * g.z + b.z;
      o.w = (yv[c].w - mean) * istd * g.w + b.w;
      *(float4*)&yr[c * 4] = o;
    }
  }
  __syncthreads();
  float az[8][2];
#pragma unroll
  for (int q = 0; q < 8; ++q) { az[q][0] = 0.f; az[q][1] = 0.f; }
  for (int k = 0; k < 128; k += 4) {
    const float* wp3 = encW + (long)k * 64 + z0;
    float2 e0 = *(const float2*)(wp3);
    float2 e1 = *(const float2*)(wp3 + 64);
    float2 e2 = *(const float2*)(wp3 + 128);
    float2 e3 = *(const float2*)(wp3 + 192);
#pragma unroll
    for (int q = 0; q < 8; ++q) {
      int m = mi + 8 * q;
      float4 hv = *(const float4*)&yb[m * 132 + k];
      az[q][0] += hv.x * e0.x + hv.y * e1.x + hv.z * e2.x + hv.w * e3.x;
      az[q][1] += hv.x * e0.y + hv.y * e1.y + hv.z * e2.y + hv.w * e3.y;
    }
  }
  float2 ebv = *(const float2*)&encb[z0];
  float ps0 = 0.f, ps1 = 0.f, pq0 = 0.f, pq1 = 0.f;
#pragma unroll
  for (int q = 0; q < 8; ++q) {
    long nd = nb + mi + 8 * q;
    if (nd < n) {
      float za = az[q][0] + ebv.x, zb = az[q][1] + ebv.y;
      *(float2*)&z_out[nd * 64 + z0] = make_float2(za, zb);
      ps0 += za; ps1 += zb; pq0 += za * za; pq1 += zb * zb;
    }
  }
  __syncthreads();
  float* sr = stc;
  sr[mi * 128 + z0] = ps0; sr[mi * 128 + z0 + 1] = ps1;
  sr[mi * 128 + 64 + z0] = pq0; sr[mi * 128 + 64 + z0 + 1] = pq1;
  __syncthreads();
  if (tid < 128) {
    float t = 0.f;
#pragma unroll
    for (int g = 0; g < 8; ++g) t += sr[g * 128 + tid];
    part[(long)blockIdx.x * 128 + tid] = t;
  }
}

// ---- fused: BN-apply(+residual into h) + xs = h@W (bf16 out) + al_s/al_d ----
__global__ __launch_bounds__(256) void xs_bn(
    const float* __restrict__ z, const float* __restrict__ stats,
    const float* __restrict__ bng, const float* __restrict__ bnb,
    float* __restrict__ hbuf, int mode,
    const float* __restrict__ W, const float* __restrict__ a_s, const float* __restrict__ a_d,
    unsigned short* __restrict__ xsb, float* __restrict__ al_s, float* __restrict__ al_d,
    int n) {
  __shared__ __align__(16) float sW[64 * 64];
  __shared__ __align__(16) float sh[32][64];
  int tid = threadIdx.x, w = tid >> 6, lane = tid & 63;
  for (int i = tid; i < 4096; i += 256) sW[i] = W[i];
  long nodeBase = (long)blockIdx.x * 32;
  float sm = stats[lane], sv = stats[64 + lane], gg = bng[lane], bb = bnb[lane];
  int lm0 = w * 8;
#pragma unroll
  for (int m = 0; m < 8; ++m) {
    long nd = nodeBase + lm0 + m;
    float hv = 0.f;
    if (nd < n) {
      float t = fmaxf((z[nd * 64 + lane] - sm) * sv * gg + bb, 0.f);
      hv = mode ? hbuf[nd * 64 + lane] + t : t;
      hbuf[nd * 64 + lane] = hv;
    }
    sh[lm0 + m][lane] = hv;
  }
  __syncthreads();
  float acc[8];
#pragma unroll
  for (int m = 0; m < 8; ++m) acc[m] = 0.f;
  for (int k = 0; k < 64; k += 4) {
    float w0 = sW[(k + 0) * 64 + lane];
    float w1 = sW[(k + 1) * 64 + lane];
    float w2 = sW[(k + 2) * 64 + lane];
    float w3 = sW[(k + 3) * 64 + lane];
#pragma unroll
    for (int m = 0; m < 8; ++m) {
      float4 h4 = *reinterpret_cast<const float4*>(&sh[lm0 + m][k]);
      acc[m] += h4.x * w0 + h4.y * w1 + h4.z * w2 + h4.w * w3;
    }
  }
  float asv = a_s[lane], adv = a_d[lane];
#pragma unroll
  for (int m = 0; m < 8; ++m) {
    long nd = nodeBase + lm0 + m;
    float ps = acc[m] * asv, pd = acc[m] * adv;
#pragma unroll
    for (int o = 1; o < 64; o <<= 1) {
      ps += __shfl_xor(ps, o);
      pd += __shfl_xor(pd, o);
    }
    if (nd < n) {
      xsb[nd * 64 + lane] = f2bf(acc[m]);
      if (lane == 0) { al_s[nd] = ps; al_d[nd] = pd; }
    }
  }
}

// ---------------- GAT: quarter-wave (16 lanes) per node, bf16 xs gather ----------------
#define QCAP 128
__global__ __launch_bounds__(256) void gat3(
    const int* __restrict__ off, const int2* __restrict__ csr,
    const float* __restrict__ ale,   // this layer's plane, indexed by edge id
    const float* __restrict__ al_s, const float* __restrict__ al_d,
    const unsigned short* __restrict__ xsb, const float* __restrict__ bias,
    float* __restrict__ gat_out, float* __restrict__ part, int n) {
  __shared__ float2 sal[16][QCAP];   // (al_or_ex, src-as-float)
  __shared__ float sred[4][128];
  int tid = threadIdx.x, w = tid >> 6, lane = tid & 63;
  int qt = tid >> 4, q = tid & 15;
  const uint2* xr = (const uint2*)xsb;   // row = 16 uint2
  float4 bv = *(const float4*)&bias[q * 4];
  float4 psum = make_float4(0.f, 0.f, 0.f, 0.f), psq = psum;
  for (int node = blockIdx.x * 16 + qt; node < n; node += gridDim.x * 16) {
    int s0 = off[node];
    int deg = off[node + 1] - s0;
    bool fits = (deg <= QCAP);
    float aldn = al_d[node];
    float lmax = -3.402823466e38f, lsae = 0.f;
    for (int k = q; k < deg; k += 16) {
      int2 ce = csr[s0 + k];
      float ae = ale[ce.y];
      float a = al_s[ce.x] + aldn + ae;
      float al = (a >= 0.f) ? a : 0.2f * a;
      lmax = fmaxf(lmax, al);
      lsae += ae;
      if (fits) sal[qt][k] = make_float2(al, __int_as_float(ce.x));
    }
#pragma unroll
    for (int o = 1; o < 16; o <<= 1) {
      lmax = fmaxf(lmax, __shfl_xor(lmax, o));
      lsae += __shfl_xor(lsae, o);
    }
    float ae_self = lsae / fmaxf((float)deg, 1.f);
    float a_self = al_s[node] + aldn + ae_self;
    float al_self = (a_self >= 0.f) ? a_self : 0.2f * a_self;
    float mx = fmaxf(lmax, al_self);
    float lsum = 0.f;
    if (fits) {
      for (int k = q; k < deg; k += 16) {
        float ex = __expf(sal[qt][k].x - mx);
        sal[qt][k].x = ex;
        lsum += ex;
      }
    } else {
      for (int k = q; k < deg; k += 16) {
        int2 ce = csr[s0 + k];
        float a = al_s[ce.x] + aldn + ale[ce.y];
        float al = (a >= 0.f) ? a : 0.2f * a;
        lsum += __expf(al - mx);
      }
    }
#pragma unroll
    for (int o = 1; o < 16; o <<= 1) lsum += __shfl_xor(lsum, o);
    float exs = __expf(al_self - mx);
    float inv = 1.f / (lsum + exs + 1e-16f);
    uint2 xv = xr[(long)node * 16 + q];
    float4 acc;
    acc.x = exs * bflo(xv.x); acc.y = exs * bfhi(xv.x);
    acc.z = exs * bflo(xv.y); acc.w = exs * bfhi(xv.y);
    if (fits) {
      int k = 0;
      for (; k + 4 <= deg; k += 4) {
        float2 p0 = sal[qt][k], p1 = sal[qt][k + 1], p2 = sal[qt][k + 2], p3 = sal[qt][k + 3];
        uint2 x0 = xr[(long)__float_as_int(p0.y) * 16 + q];
        uint2 x1 = xr[(long)__float_as_int(p1.y) * 16 + q];
        uint2 x2 = xr[(long)__float_as_int(p2.y) * 16 + q];
        uint2 x3 = xr[(long)__float_as_int(p3.y) * 16 + q];
        acc.x += p0.x * bflo(x0.x) + p1.x * bflo(x1.x) + p2.x * bflo(x2.x) + p3.x * bflo(x3.x);
        acc.y += p0.x * bfhi(x0.x) + p1.x * bfhi(x1.x) + p2.x * bfhi(x2.x) + p3.x * bfhi(x3.x);
        acc.z += p0.x * bflo(x0.y) + p1.x * bflo(x1.y) + p2.x * bflo(x2.y) + p3.x * bflo(x3.y);
        acc.w += p0.x * bfhi(x0.y) + p1.x * bfhi(x1.y) + p2.x * bfhi(x2.y) + p3.x * bfhi(x3.y);
      }
      for (; k < deg; ++k) {
        float2 p = sal[qt][k];
        uint2 xk = xr[(long)__float_as_int(p.y) * 16 + q];
        acc.x += p.x * bflo(xk.x); acc.y += p.x * bfhi(xk.x);
        acc.z += p.x * bflo(xk.y); acc.w += p.x * bfhi(xk.y);
      }
    } else {
      for (int k = 0; k < deg; ++k) {
        int2 ce = csr[s0 + k];
        float a = al_s[ce.x] + aldn + ale[ce.y];
        float al = (a >= 0.f) ? a : 0.2f * a;
        float ex = __expf(al - mx);
        uint2 xk = xr[(long)ce.x * 16 + q];
        acc.x += ex * bflo(xk.x); acc.y += ex * bfhi(xk.x);
        acc.z += ex * bflo(xk.y); acc.w += ex * bfhi(xk.y);
      }
    }
    acc.x = acc.x * inv + bv.x; acc.y = acc.y * inv + bv.y;
    acc.z = acc.z * inv + bv.z; acc.w = acc.w * inv + bv.w;
    *(float4*)&gat_out[(long)node * 64 + q * 4] = acc;
    psum.x += acc.x; psum.y += acc.y; psum.z += acc.z; psum.w += acc.w;
    psq.x += acc.x * acc.x; psq.y += acc.y * acc.y; psq.z += acc.z * acc.z; psq.w += acc.w * acc.w;
  }
#pragma unroll
  for (int o = 16; o < 64; o <<= 1) {
    psum.x += __shfl_xor(psum.x, o); psum.y += __shfl_xor(psum.y, o);
    psum.z += __shfl_xor(psum.z, o); psum.w += __shfl_xor(psum.w, o);
    psq.x += __shfl_xor(psq.x, o); psq.y += __shfl_xor(psq.y, o);
    psq.z += __shfl_xor(psq.z, o); psq.w += __shfl_xor(psq.w, o);
  }
  if (lane < 16) {
    sred[w][lane * 4 + 0] = psum.x; sred[w][lane * 4 + 1] = psum.y;
    sred[w][lane * 4 + 2] = psum.z; sred[w][lane * 4 + 3] = psum.w;
    sred[w][64 + lane * 4 + 0] = psq.x; sred[w][64 + lane * 4 + 1] = psq.y;
    sred[w][64 + lane * 4 + 2] = psq.z; sred[w][64 + lane * 4 + 3] = psq.w;
  }
  __syncthreads();
  if (tid < 128)
    part[(long)blockIdx.x * 128 + tid] =
        sred[0][tid] + sred[1][tid] + sred[2][tid] + sred[3][tid];
}

// ---------------- BN finalize ----------------
__global__ __launch_bounds__(1024) void bn_finalize(const float* __restrict__ part, int nblk,
                                                    float invN, float* __restrict__ stats) {
  __shared__ float sh[1024];
  int t = threadIdx.x;
  int c = t & 127, g = t >> 7;
  float s = 0.f;
  for (int b = g; b < nblk; b += 8) s += part[(long)b * 128 + c];
  sh[t] = s;
  __syncthreads();
  if (t < 128) {
    float tot = 0.f;
#pragma unroll
    for (int g2 = 0; g2 < 8; ++g2) tot += sh[g2 * 128 + t];
    sh[t] = tot;
  }
  __syncthreads();
  if (t < 64) {
    float mean = sh[t] * invN;
    float var = sh[64 + t] * invN - mean * mean;
    stats[t] = mean;
    stats[64 + t] = rsqrtf(var + 1e-5f);
  }
}

// ---- fused: last BN-apply + residual + global mean partials (no h write) ----
__global__ void gsum_bn(const float* __restrict__ z, const float* __restrict__ stats,
                        const float* __restrict__ bng, const float* __restrict__ bnb,
                        const float* __restrict__ hprev, int n, float* __restrict__ part) {
  __shared__ float sh[4][64];
  int tid = threadIdx.x, w = tid >> 6, lane = tid & 63;
  float sm = stats[lane], sv = stats[64 + lane], gg = bng[lane], bb = bnb[lane];
  int gw = blockIdx.x * 4 + w, nW = gridDim.x * 4;
  float s = 0.f;
  for (int node = gw; node < n; node += nW) {
    float t = fmaxf((z[(long)node * 64 + lane] - sm) * sv * gg + bb, 0.f);
    s += hprev[(long)node * 64 + lane] + t;
  }
  sh[w][lane] = s;
  __syncthreads();
  if (tid < 64)
    part[(long)blockIdx.x * 64 + tid] =
        sh[0][tid] + sh[1][tid] + sh[2][tid] + sh[3][tid];
}

__global__ void final_kernel(const float* __restrict__ part, int nblk,
                             const float* __restrict__ out_W, const float* __restrict__ out_b,
                             float* __restrict__ out, float invN) {
  __shared__ float g[64];
  int c = threadIdx.x;  // 64 threads
  float s = 0.f;
  for (int b = 0; b < nblk; ++b) s += part[(long)b * 64 + c];
  g[c] = s * invN;
  __syncthreads();
  float acc = out_b[c];
  for (int k = 0; k < 64; ++k) acc += g[k] * out_W[k * 64 + c];
  out[c] = fmaxf(acc, 0.f);
}

// ---------------- host launch ----------------
extern "C" void kernel_launch(void* const* d_in, const int* in_sizes, int n_in,
                              void* d_out, int out_size, void* d_ws, size_t ws_size,
                              hipStream_t stream) {
  const float* x        = (const float*)d_in[0];
  const int*   eidx     = (const int*)d_in[1];
  const float* eattr    = (const float*)d_in[2];
  const float* np_W1    = (const float*)d_in[3];
  const float* np_b1    = (const float*)d_in[4];
  const float* np_W2    = (const float*)d_in[5];
  const float* np_b2    = (const float*)d_in[6];
  const float* np_ln_g  = (const float*)d_in[7];
  const float* np_ln_b  = (const float*)d_in[8];
  const float* ep_W1    = (const float*)d_in[9];
  const float* ep_b1    = (const float*)d_in[10];
  const float* ep_W2    = (const float*)d_in[11];
  const float* ep_b2    = (const float*)d_in[12];
  const float* ep_ln_g  = (const float*)d_in[13];
  const float* ep_ln_b  = (const float*)d_in[14];
  const float* enc_W    = (const float*)d_in[15];
  const float* enc_b    = (const float*)d_in[16];
  const float* enc_bn_g = (const float*)d_in[17];
  const float* enc_bn_b = (const float*)d_in[18];
  const float* gat_W    = (const float*)d_in[19];
  const float* gat_eW   = (const float*)d_in[20];
  const float* att_src  = (const float*)d_in[21];
  const float* att_dst  = (const float*)d_in[22];
  const float* att_edge = (const float*)d_in[23];
  const float* gat_b    = (const float*)d_in[24];
  const float* bn_g     = (const float*)d_in[25];
  const float* bn_b     = (const float*)d_in[26];
  const float* out_W    = (const float*)d_in[27];
  const float* out_b    = (const float*)d_in[28];

  const int n = in_sizes[0] / 128;   // 50000
  const int ne = in_sizes[1] / 2;    // 800000
  const int* srcp = eidx;
  const int* dstp = eidx + ne;

  float* f = (float*)d_ws;
  float* hbuf  = f; f += (long)n * 64;
  float* zbuf  = f; f += (long)n * 64;
  float* alsb  = f; f += n;
  float* aldb  = f; f += n;
  float* ale   = f; f += 3L * ne;
  float* vgbuf = f; f += 128;
  float* stats = f; f += 128;
  float* part  = f; f += 131072;      // 1024 x 128
  float* part2 = f; f += 16384;       // 256 x 64
  unsigned short* xsb = (unsigned short*)f; f += (long)n * 32;  // n*64 bf16
  int* ip = (int*)f;
  int2* csr = (int2*)ip; ip += 2L * ne;
  int* degb = ip; ip += n;
  int* cntb = ip; ip += n;
  int* offb = ip; ip += n + 1;

  const int nbEdge = (ne + ET - 1) / ET;     // 6250
  const int nbNode = (n + NT - 1) / NT;      // 782
  const int nbXs   = (n + 31) / 32;          // 1563

  hipMemsetAsync(degb, 0, (size_t)n * sizeof(int), stream);
  hipMemsetAsync(cntb, 0, (size_t)n * sizeof(int), stream);
  vprep2<<<1, 128, 0, stream>>>(gat_eW, att_edge, ep_ln_g, ep_ln_b, vgbuf);
  deg_kernel<<<1024, 256, 0, stream>>>(dstp, ne, degb);
  scan2<<<1, 1024, 0, stream>>>(degb, offb, n);
  scatter_kernel<<<1024, 256, 0, stream>>>(srcp, dstp, ne, offb, cntb, csr);
  edge_pre2<<<nbEdge, 256, 0, stream>>>(eattr, ep_W1, ep_b1, ep_W2, ep_b2, vgbuf, ale, ne);
  node_pre2<<<nbNode, 256, 0, stream>>>(x, np_W1, np_b1, np_W2, np_b2, np_ln_g, np_ln_b,
                                        enc_W, enc_b, zbuf, part, n);
  bn_finalize<<<1, 1024, 0, stream>>>(part, nbNode, 1.f / n, stats);
  xs_bn<<<nbXs, 256, 0, stream>>>(zbuf, stats, enc_bn_g, enc_bn_b, hbuf, 0,
                                  gat_W, att_src, att_dst, xsb, alsb, aldb, n);
  for (int l = 0; l < 3; ++l) {
    gat3<<<1024, 256, 0, stream>>>(offb, csr, ale + (long)l * ne, alsb, aldb,
                                   xsb, gat_b + l * 64, zbuf, part, n);
    bn_finalize<<<1, 1024, 0, stream>>>(part, 1024, 1.f / n, stats);
    if (l < 2) {
      xs_bn<<<nbXs, 256, 0, stream>>>(zbuf, stats, bn_g + l * 64, bn_b + l * 64, hbuf, 1,
                                      gat_W + (long)(l + 1) * 4096, att_src + (l + 1) * 64,
                                      att_dst + (l + 1) * 64, xsb, alsb, aldb, n);
    } else {
      gsum_bn<<<256, 256, 0, stream>>>(zbuf, stats, bn_g + l * 64, bn_b + l * 64,
                                       hbuf, n, part2);
    }
  }
  final_kernel<<<1, 64, 0, stream>>>(part2, 256, out_W, out_b, (float*)d_out, 1.f / n);
}

// Round 4
// 952.453 us; speedup vs baseline: 2.0589x; 1.3558x over previous
//
#include <hip/hip_runtime.h>
#include <hip/hip_bf16.h>

// GNNEncoder on MI355X. Algebraic reductions:
//  - (ea@eW)@a_e == ea@(eW@a_e): only 3 scalars al_e per edge needed.
//  - loop_attr contribution == mean(incoming al_e) by linearity.
//  - edge LN+dot folded: al = istd*(sum y*(g*v) - mean*G) + C.
// dst-CSR (int2{src,eid}) built once; al_e written CONTIGUOUS in edge order and
// gathered via eid in gat3 (L2-resident).
// edge_pre3: MFMA bf16, wave = 32 edges, A-frags straight from global, weights
// pre-packed in B-fragment order by wpack (tiny per-lane state -> no scratch).

typedef short bf16x8 __attribute__((ext_vector_type(8)));
typedef float f32x4 __attribute__((ext_vector_type(4)));
union U8 { uint4 u; bf16x8 v; };

__device__ __forceinline__ unsigned pack2bf(float a, float b) {
  unsigned ua = __float_as_uint(a); ua += 0x7fffu + ((ua >> 16) & 1u);
  unsigned ub = __float_as_uint(b); ub += 0x7fffu + ((ub >> 16) & 1u);
  return (ua >> 16) | (ub & 0xffff0000u);
}
__device__ __forceinline__ unsigned short f2bf(float x) {
  unsigned u = __float_as_uint(x); u += 0x7fffu + ((u >> 16) & 1u);
  return (unsigned short)(u >> 16);
}
__device__ __forceinline__ float bflo(unsigned u) { return __uint_as_float(u << 16); }
__device__ __forceinline__ float bfhi(unsigned u) { return __uint_as_float(u & 0xffff0000u); }

// ---------------- prep: v = eW@a_e, gv = lng*v, G = sum(lng*v), C = sum(lnb*v) ----------------
__global__ void vprep2(const float* __restrict__ eW, const float* __restrict__ a_e,
                       const float* __restrict__ lng, const float* __restrict__ lnb,
                       float* __restrict__ vg) {
  __shared__ float sv[96];
  int t = threadIdx.x;  // 128 threads
  if (t < 96) {
    int l = t >> 5, i = t & 31;
    const float* w = eW + l * 2048 + i * 64;
    const float* a = a_e + l * 64;
    float s = 0.f;
    for (int c = 0; c < 64; ++c) s += w[c] * a[c];
    sv[t] = s;
    vg[t] = s * lng[i];
  }
  __syncthreads();
  if (t < 3) {
    float G = 0.f, C = 0.f;
    for (int i = 0; i < 32; ++i) {
      float vv = sv[t * 32 + i];
      G += lng[i] * vv;
      C += lnb[i] * vv;
    }
    vg[96 + t] = G;
    vg[99 + t] = C;
  }
}

// pack W1[32x64], W2[64x32] into bf16 MFMA B-fragment order.
// B-frag (16x16x32): lane l elem j holds B[k=(l>>4)*8+j][col=(l&15)] of the tile.
__global__ void wpack(const float* __restrict__ W1, const float* __restrict__ W2,
                      unsigned short* __restrict__ wb) {
  int t = threadIdx.x;  // 256
  for (int i = t; i < 2048; i += 256) {
    int nt = i >> 9, rem = i & 511, l = rem >> 3, j = rem & 7;
    int k = ((l >> 4) << 3) + j, col = (nt << 4) + (l & 15);
    wb[i] = f2bf(W1[k * 64 + col]);
  }
  for (int i = t; i < 2048; i += 256) {
    int sn = i >> 9, rem = i & 511, l = rem >> 3, j = rem & 7;
    int s = sn >> 1, nt = sn & 1;
    int k = s * 32 + ((l >> 4) << 3) + j, col = (nt << 4) + (l & 15);
    wb[2048 + i] = f2bf(W2[k * 32 + col]);
  }
}

__global__ void deg_kernel(const int* __restrict__ dst, int ne, int* __restrict__ deg) {
  int i = blockIdx.x * blockDim.x + threadIdx.x;
  int stride = gridDim.x * blockDim.x;
  for (; i < ne; i += stride) atomicAdd(&deg[dst[i]], 1);
}

__global__ __launch_bounds__(1024) void scan2(const int* __restrict__ deg,
                                              int* __restrict__ off, int n) {
  __shared__ int sh[1024];
  int t = threadIdx.x;
  int C = (n + 1023) >> 10;
  int b0 = t * C, b1 = min(n, b0 + C);
  int s = 0;
  for (int j = b0; j < b1; ++j) s += deg[j];
  sh[t] = s;
  __syncthreads();
  for (int o = 1; o < 1024; o <<= 1) {
    int add = (t >= o) ? sh[t - o] : 0;
    __syncthreads();
    sh[t] += add;
    __syncthreads();
  }
  int run = (t == 0) ? 0 : sh[t - 1];
  if (t == 0) off[0] = 0;
  for (int j = b0; j < b1; ++j) { run += deg[j]; off[j + 1] = run; }
}

__global__ void scatter_kernel(const int* __restrict__ src, const int* __restrict__ dst,
                               int ne, const int* __restrict__ off, int* __restrict__ cnt,
                               int2* __restrict__ csr) {
  int i = blockIdx.x * blockDim.x + threadIdx.x;
  int stride = gridDim.x * blockDim.x;
  for (; i < ne; i += stride) {
    int d = dst[i];
    int p = off[d] + atomicAdd(&cnt[d], 1);
    csr[p] = make_int2(src[i], i);
  }
}

// ---------------- edge preproc v3: MFMA. block=256 (4 waves), 128 edges ----------------
#define EB 128
__global__ __launch_bounds__(256) void edge_pre3(
    const float* __restrict__ ea, const unsigned short* __restrict__ wb,
    const float* __restrict__ b1, const float* __restrict__ b2,
    const float* __restrict__ vg, float* __restrict__ ale, int ne) {
  __shared__ __align__(16) unsigned short swb[4096];       // B1 frags [0,2048), B2 frags [2048,4096)
  __shared__ __align__(16) unsigned short sT[4][32 * 72];  // per-wave T, row stride 72 (144B, 16B-aligned)
  int tid = threadIdx.x, w = tid >> 6, lane = tid & 63;
  {
    const uint4* g = (const uint4*)wb;
    uint4* s = (uint4*)swb;
    for (int i = tid; i < 512; i += 256) s[i] = g[i];
  }
  __syncthreads();
  int lm = lane & 15, lq = lane >> 4;
  long e0 = (long)blockIdx.x * EB + w * 32;
  // ---- A-fragments straight from global (2 M-halves of 16 edges) ----
  bf16x8 afr[2];
#pragma unroll
  for (int h = 0; h < 2; ++h) {
    long e = e0 + h * 16 + lm;
    if (e >= ne) e = ne - 1;
    const float4* p = (const float4*)(ea + e * 32 + lq * 8);
    float4 u = p[0], v = p[1];
    U8 cc;
    cc.u = make_uint4(pack2bf(u.x, u.y), pack2bf(u.z, u.w), pack2bf(v.x, v.y), pack2bf(v.z, v.w));
    afr[h] = cc.v;
  }
  // ---- GEMM1: T[32x64] = ea @ W1 ----
  f32x4 zero = {0.f, 0.f, 0.f, 0.f};
  f32x4 c1[2][4];
#pragma unroll
  for (int h = 0; h < 2; ++h)
#pragma unroll
    for (int nt = 0; nt < 4; ++nt) c1[h][nt] = zero;
#pragma unroll
  for (int nt = 0; nt < 4; ++nt) {
    bf16x8 bf = *(const bf16x8*)&swb[nt * 512 + lane * 8];
#pragma unroll
    for (int h = 0; h < 2; ++h)
      c1[h][nt] = __builtin_amdgcn_mfma_f32_16x16x32_bf16(afr[h], bf, c1[h][nt], 0, 0, 0);
  }
  // relu + bias -> bf16 T in LDS (row-major [32][72])
  {
    float b1v[4];
#pragma unroll
    for (int nt = 0; nt < 4; ++nt) b1v[nt] = b1[nt * 16 + lm];
#pragma unroll
    for (int h = 0; h < 2; ++h)
#pragma unroll
      for (int nt = 0; nt < 4; ++nt)
#pragma unroll
        for (int r = 0; r < 4; ++r) {
          float tv = fmaxf(c1[h][nt][r] + b1v[nt], 0.f);
          sT[w][(h * 16 + lq * 4 + r) * 72 + nt * 16 + lm] = f2bf(tv);
        }
  }
  __syncthreads();  // cheap; removes any LDS write->read ordering doubt
  // ---- GEMM2: Y[32x32] = T @ W2 ----
  f32x4 c2[2][2];
#pragma unroll
  for (int h = 0; h < 2; ++h)
#pragma unroll
    for (int nt = 0; nt < 2; ++nt) c2[h][nt] = zero;
#pragma unroll
  for (int h = 0; h < 2; ++h)
#pragma unroll
    for (int s = 0; s < 2; ++s) {
      bf16x8 at = *(const bf16x8*)&sT[w][(h * 16 + lm) * 72 + s * 32 + lq * 8];
#pragma unroll
      for (int nt = 0; nt < 2; ++nt) {
        bf16x8 bf = *(const bf16x8*)&swb[2048 + (s * 2 + nt) * 512 + lane * 8];
        c2[h][nt] = __builtin_amdgcn_mfma_f32_16x16x32_bf16(at, bf, c2[h][nt], 0, 0, 0);
      }
    }
  // ---- LN + fold: a_l = istd*(S_l - mean*G_l) + C_l ----
  float b2v0 = b2[lm], b2v1 = b2[16 + lm];
  float gv00 = vg[lm], gv01 = vg[16 + lm];
  float gv10 = vg[32 + lm], gv11 = vg[48 + lm];
  float gv20 = vg[64 + lm], gv21 = vg[80 + lm];
  float G0 = vg[96], G1 = vg[97], G2 = vg[98];
  float C0 = vg[99], C1 = vg[100], C2 = vg[101];
#pragma unroll
  for (int h = 0; h < 2; ++h) {
    float s4[4], q4[4], d0[4], d1[4], d2[4];
#pragma unroll
    for (int r = 0; r < 4; ++r) {
      float ya = c2[h][0][r] + b2v0;
      float yb = c2[h][1][r] + b2v1;
      s4[r] = ya + yb;
      q4[r] = ya * ya + yb * yb;
      d0[r] = ya * gv00 + yb * gv01;
      d1[r] = ya * gv10 + yb * gv11;
      d2[r] = ya * gv20 + yb * gv21;
    }
#pragma unroll
    for (int o = 1; o < 16; o <<= 1) {
#pragma unroll
      for (int r = 0; r < 4; ++r) {
        s4[r] += __shfl_xor(s4[r], o);
        q4[r] += __shfl_xor(q4[r], o);
        d0[r] += __shfl_xor(d0[r], o);
        d1[r] += __shfl_xor(d1[r], o);
        d2[r] += __shfl_xor(d2[r], o);
      }
    }
    if (lm < 4) {
      int r = lm;
      long e = e0 + h * 16 + lq * 4 + r;
      if (e < ne) {
        float mean = s4[r] * (1.f / 32.f);
        float var = q4[r] * (1.f / 32.f) - mean * mean;
        float istd = rsqrtf(var + 1e-5f);
        ale[e] = istd * (d0[r] - mean * G0) + C0;
        ale[(long)ne + e] = istd * (d1[r] - mean * G1) + C1;
        ale[2L * ne + e] = istd * (d2[r] - mean * G2) + C2;
      }
    }
  }
}

// ---------------- node preproc: MLP(128->256->128)+LN + enc Linear(128->64) ----------------
#define NT 64
__global__ __launch_bounds__(256, 3) void node_pre2(
    const float* __restrict__ x, const float* __restrict__ W1, const float* __restrict__ b1,
    const float* __restrict__ W2, const float* __restrict__ b2,
    const float* __restrict__ lng, const float* __restrict__ lnb,
    const float* __restrict__ encW, const float* __restrict__ encb,
    float* __restrict__ z_out, float* __restrict__ part, int n) {
  __shared__ __align__(16) float sx[NT * 132];  // x rows; later f32 yb / h1
  __shared__ __align__(16) float stc[NT * 68];  // T chunk; later BN partial scratch
  __shared__ float sgb[256];
  int tid = threadIdx.x;
  long nb = (long)blockIdx.x * NT;
  for (int i = tid; i < 128; i += 256) { sgb[i] = lng[i]; sgb[128 + i] = lnb[i]; }
  {
    const float4* g4 = (const float4*)(x + nb * 128);
    for (int i4 = tid; i4 < NT * 32; i4 += 256) {
      int m = i4 >> 5, c = (i4 & 31) * 4;
      float4 v = (nb + m < n) ? g4[i4] : make_float4(0.f, 0.f, 0.f, 0.f);
      *(float4*)&sx[m * 132 + c] = v;
    }
  }
  int ji = tid & 31, mi = tid >> 5;
  int j0b = ji * 2, i0 = ji * 4, z0 = ji * 2;
  float acc2[8][4];
#pragma unroll
  for (int q = 0; q < 8; ++q)
#pragma unroll
    for (int c = 0; c < 4; ++c) acc2[q][c] = 0.f;
  for (int jc = 0; jc < 4; ++jc) {
    __syncthreads();
    float a1[8][2];
#pragma unroll
    for (int q = 0; q < 8; ++q) { a1[q][0] = 0.f; a1[q][1] = 0.f; }
    for (int k = 0; k < 128; k += 4) {
      const float* wp = W1 + (long)k * 256 + jc * 64 + j0b;
      float2 w0 = *(const float2*)(wp);
      float2 w1 = *(const float2*)(wp + 256);
      float2 w2 = *(const float2*)(wp + 512);
      float2 w3 = *(const float2*)(wp + 768);
#pragma unroll
      for (int q = 0; q < 8; ++q) {
        int m = mi + 8 * q;
        float4 xv = *(const float4*)&sx[m * 132 + k];
        a1[q][0] += xv.x * w0.x + xv.y * w1.x + xv.z * w2.x + xv.w * w3.x;
        a1[q][1] += xv.x * w0.y + xv.y * w1.y + xv.z * w2.y + xv.w * w3.y;
      }
    }
    float2 bb = *(const float2*)&b1[jc * 64 + j0b];
#pragma unroll
    for (int q = 0; q < 8; ++q) {
      int m = mi + 8 * q;
      float2 o;
      o.x = fmaxf(a1[q][0] + bb.x, 0.f);
      o.y = fmaxf(a1[q][1] + bb.y, 0.f);
      *(float2*)&stc[m * 68 + j0b] = o;
    }
    __syncthreads();
    for (int k = 0; k < 64; k += 4) {
      const float* wp2 = W2 + (long)(jc * 64 + k) * 128 + i0;
      float4 w0 = *(const float4*)(wp2);
      float4 w1 = *(const float4*)(wp2 + 128);
      float4 w2 = *(const float4*)(wp2 + 256);
      float4 w3 = *(const float4*)(wp2 + 384);
#pragma unroll
      for (int q = 0; q < 8; ++q) {
        int m = mi + 8 * q;
        float4 tv = *(const float4*)&stc[m * 68 + k];
        acc2[q][0] += tv.x * w0.x + tv.y * w1.x + tv.z * w2.x + tv.w * w3.x;
        acc2[q][1] += tv.x * w0.y + tv.y * w1.y + tv.z * w2.y + tv.w * w3.y;
        acc2[q][2] += tv.x * w0.z + tv.y * w1.z + tv.z * w2.z + tv.w * w3.z;
        acc2[q][3] += tv.x * w0.w + tv.y * w1.w + tv.z * w2.w + tv.w * w3.w;
      }
    }
  }
  __syncthreads();
  float* yb = sx;
  {
    float4 b2v = *(const float4*)&b2[i0];
#pragma unroll
    for (int q = 0; q < 8; ++q) {
      int m = mi + 8 * q;
      float4 o;
      o.x = acc2[q][0] + b2v.x; o.y = acc2[q][1] + b2v.y;
      o.z = acc2[q][2] + b2v.z; o.w = acc2[q][3] + b2v.w;
      *(float4*)&yb[m * 132 + i0] = o;
    }
  }
  __syncthreads();
  {
    int m = tid >> 2, qq = tid & 3;
    float* yr = &yb[m * 132 + qq * 32];
    float4 yv[8];
#pragma unroll
    for (int c = 0; c < 8; ++c) yv[c] = *(const float4*)&yr[c * 4];
    float s = 0.f, sq = 0.f;
#pragma unroll
    for (int c = 0; c < 8; ++c) {
      s += yv[c].x + yv[c].y + yv[c].z + yv[c].w;
      sq += yv[c].x * yv[c].x + yv[c].y * yv[c].y + yv[c].z * yv[c].z + yv[c].w * yv[c].w;
    }
    s += __shfl_xor(s, 1); s += __shfl_xor(s, 2);
    sq += __shfl_xor(sq, 1); sq += __shfl_xor(sq, 2);
    float mean = s * (1.f / 128.f);
    float var = sq * (1.f / 128.f) - mean * mean;
    float istd = rsqrtf(var + 1e-5f);
#pragma unroll
    for (int c = 0; c < 8; ++c) {
      int cc = qq * 32 + c * 4;
      float4 g = *(const float4*)&sgb[cc];
      float4 b = *(const float4*)&sgb[128 + cc];
      float4 o;
      o.x = (yv[c].x - mean) * istd * g.x + b.x;
      o.y = (yv[c].y - mean) * istd * g.y + b.y;
      o.z = (yv[c].z - mean) * istd * g.z + b.z;
      o.w = (yv[c].w - mean) * istd * g.w + b.w;
      *(float4*)&yr[c * 4] = o;
    }
  }
  __syncthreads();
  float az[8][2];
#pragma unroll
  for (int q = 0; q < 8; ++q) { az[q][0] = 0.f; az[q][1] = 0.f; }
  for (int k = 0; k < 128; k += 4) {
    const float* wp3 = encW + (long)k * 64 + z0;
    float2 e0 = *(const float2*)(wp3);
    float2 e1 = *(const float2*)(wp3 + 64);
    float2 e2 = *(const float2*)(wp3 + 128);
    float2 e3 = *(const float2*)(wp3 + 192);
#pragma unroll
    for (int q = 0; q < 8; ++q) {
      int m = mi + 8 * q;
      float4 hv = *(const float4*)&yb[m * 132 + k];
      az[q][0] += hv.x * e0.x + hv.y * e1.x + hv.z * e2.x + hv.w * e3.x;
      az[q][1] += hv.x * e0.y + hv.y * e1.y + hv.z * e2.y + hv.w * e3.y;
    }
  }
  float2 ebv = *(const float2*)&encb[z0];
  float ps0 = 0.f, ps1 = 0.f, pq0 = 0.f, pq1 = 0.f;
#pragma unroll
  for (int q = 0; q < 8; ++q) {
    long nd = nb + mi + 8 * q;
    if (nd < n) {
      float za = az[q][0] + ebv.x, zb = az[q][1] + ebv.y;
      *(float2*)&z_out[nd * 64 + z0] = make_float2(za, zb);
      ps0 += za; ps1 += zb; pq0 += za * za; pq1 += zb * zb;
    }
  }
  __syncthreads();
  float* sr = stc;
  sr[mi * 128 + z0] = ps0; sr[mi * 128 + z0 + 1] = ps1;
  sr[mi * 128 + 64 + z0] = pq0; sr[mi * 128 + 64 + z0 + 1] = pq1;
  __syncthreads();
  if (tid < 128) {
    float t = 0.f;
#pragma unroll
    for (int g = 0; g < 8; ++g) t += sr[g * 128 + tid];
    part[(long)blockIdx.x * 128 + tid] = t;
  }
}

// ---- fused: BN-apply(+residual into h) + xs = h@W (bf16 out) + al_s/al_d ----
__global__ __launch_bounds__(256) void xs_bn(
    const float* __restrict__ z, const float* __restrict__ stats,
    const float* __restrict__ bng, const float* __restrict__ bnb,
    float* __restrict__ hbuf, int mode,
    const float* __restrict__ W, const float* __restrict__ a_s, const float* __restrict__ a_d,
    unsigned short* __restrict__ xsb, float* __restrict__ al_s, float* __restrict__ al_d,
    int n) {
  __shared__ __align__(16) float sW[64 * 64];
  __shared__ __align__(16) float sh[32][64];
  int tid = threadIdx.x, w = tid >> 6, lane = tid & 63;
  for (int i = tid; i < 4096; i += 256) sW[i] = W[i];
  long nodeBase = (long)blockIdx.x * 32;
  float sm = stats[lane], sv = stats[64 + lane], gg = bng[lane], bb = bnb[lane];
  int lm0 = w * 8;
#pragma unroll
  for (int m = 0; m < 8; ++m) {
    long nd = nodeBase + lm0 + m;
    float hv = 0.f;
    if (nd < n) {
      float t = fmaxf((z[nd * 64 + lane] - sm) * sv * gg + bb, 0.f);
      hv = mode ? hbuf[nd * 64 + lane] + t : t;
      hbuf[nd * 64 + lane] = hv;
    }
    sh[lm0 + m][lane] = hv;
  }
  __syncthreads();
  float acc[8];
#pragma unroll
  for (int m = 0; m < 8; ++m) acc[m] = 0.f;
  for (int k = 0; k < 64; k += 4) {
    float w0 = sW[(k + 0) * 64 + lane];
    float w1 = sW[(k + 1) * 64 + lane];
    float w2 = sW[(k + 2) * 64 + lane];
    float w3 = sW[(k + 3) * 64 + lane];
#pragma unroll
    for (int m = 0; m < 8; ++m) {
      float4 h4 = *reinterpret_cast<const float4*>(&sh[lm0 + m][k]);
      acc[m] += h4.x * w0 + h4.y * w1 + h4.z * w2 + h4.w * w3;
    }
  }
  float asv = a_s[lane], adv = a_d[lane];
#pragma unroll
  for (int m = 0; m < 8; ++m) {
    long nd = nodeBase + lm0 + m;
    float ps = acc[m] * asv, pd = acc[m] * adv;
#pragma unroll
    for (int o = 1; o < 64; o <<= 1) {
      ps += __shfl_xor(ps, o);
      pd += __shfl_xor(pd, o);
    }
    if (nd < n) {
      xsb[nd * 64 + lane] = f2bf(acc[m]);
      if (lane == 0) { al_s[nd] = ps; al_d[nd] = pd; }
    }
  }
}

// ---------------- GAT: quarter-wave (16 lanes) per node, bf16 xs gather ----------------
#define QCAP 128
__global__ __launch_bounds__(256) void gat3(
    const int* __restrict__ off, const int2* __restrict__ csr,
    const float* __restrict__ ale,   // this layer's plane, indexed by edge id
    const float* __restrict__ al_s, const float* __restrict__ al_d,
    const unsigned short* __restrict__ xsb, const float* __restrict__ bias,
    float* __restrict__ gat_out, float* __restrict__ part, int n) {
  __shared__ float2 sal[16][QCAP];   // (al_or_ex, src-as-float)
  __shared__ float sred[4][128];
  int tid = threadIdx.x, w = tid >> 6, lane = tid & 63;
  int qt = tid >> 4, q = tid & 15;
  const uint2* xr = (const uint2*)xsb;   // row = 16 uint2
  float4 bv = *(const float4*)&bias[q * 4];
  float4 psum = make_float4(0.f, 0.f, 0.f, 0.f), psq = psum;
  for (int node = blockIdx.x * 16 + qt; node < n; node += gridDim.x * 16) {
    int s0 = off[node];
    int deg = off[node + 1] - s0;
    bool fits = (deg <= QCAP);
    float aldn = al_d[node];
    float lmax = -3.402823466e38f, lsae = 0.f;
    for (int k = q; k < deg; k += 16) {
      int2 ce = csr[s0 + k];
      float ae = ale[ce.y];
      float a = al_s[ce.x] + aldn + ae;
      float al = (a >= 0.f) ? a : 0.2f * a;
      lmax = fmaxf(lmax, al);
      lsae += ae;
      if (fits) sal[qt][k] = make_float2(al, __int_as_float(ce.x));
    }
#pragma unroll
    for (int o = 1; o < 16; o <<= 1) {
      lmax = fmaxf(lmax, __shfl_xor(lmax, o));
      lsae += __shfl_xor(lsae, o);
    }
    float ae_self = lsae / fmaxf((float)deg, 1.f);
    float a_self = al_s[node] + aldn + ae_self;
    float al_self = (a_self >= 0.f) ? a_self : 0.2f * a_self;
    float mx = fmaxf(lmax, al_self);
    float lsum = 0.f;
    if (fits) {
      for (int k = q; k < deg; k += 16) {
        float ex = __expf(sal[qt][k].x - mx);
        sal[qt][k].x = ex;
        lsum += ex;
      }
    } else {
      for (int k = q; k < deg; k += 16) {
        int2 ce = csr[s0 + k];
        float a = al_s[ce.x] + aldn + ale[ce.y];
        float al = (a >= 0.f) ? a : 0.2f * a;
        lsum += __expf(al - mx);
      }
    }
#pragma unroll
    for (int o = 1; o < 16; o <<= 1) lsum += __shfl_xor(lsum, o);
    float exs = __expf(al_self - mx);
    float inv = 1.f / (lsum + exs + 1e-16f);
    uint2 xv = xr[(long)node * 16 + q];
    float4 acc;
    acc.x = exs * bflo(xv.x); acc.y = exs * bfhi(xv.x);
    acc.z = exs * bflo(xv.y); acc.w = exs * bfhi(xv.y);
    if (fits) {
      int k = 0;
      for (; k + 4 <= deg; k += 4) {
        float2 p0 = sal[qt][k], p1 = sal[qt][k + 1], p2 = sal[qt][k + 2], p3 = sal[qt][k + 3];
        uint2 x0 = xr[(long)__float_as_int(p0.y) * 16 + q];
        uint2 x1 = xr[(long)__float_as_int(p1.y) * 16 + q];
        uint2 x2 = xr[(long)__float_as_int(p2.y) * 16 + q];
        uint2 x3 = xr[(long)__float_as_int(p3.y) * 16 + q];
        acc.x += p0.x * bflo(x0.x) + p1.x * bflo(x1.x) + p2.x * bflo(x2.x) + p3.x * bflo(x3.x);
        acc.y += p0.x * bfhi(x0.x) + p1.x * bfhi(x1.x) + p2.x * bfhi(x2.x) + p3.x * bfhi(x3.x);
        acc.z += p0.x * bflo(x0.y) + p1.x * bflo(x1.y) + p2.x * bflo(x2.y) + p3.x * bflo(x3.y);
        acc.w += p0.x * bfhi(x0.y) + p1.x * bfhi(x1.y) + p2.x * bfhi(x2.y) + p3.x * bfhi(x3.y);
      }
      for (; k < deg; ++k) {
        float2 p = sal[qt][k];
        uint2 xk = xr[(long)__float_as_int(p.y) * 16 + q];
        acc.x += p.x * bflo(xk.x); acc.y += p.x * bfhi(xk.x);
        acc.z += p.x * bflo(xk.y); acc.w += p.x * bfhi(xk.y);
      }
    } else {
      for (int k = 0; k < deg; ++k) {
        int2 ce = csr[s0 + k];
        float a = al_s[ce.x] + aldn + ale[ce.y];
        float al = (a >= 0.f) ? a : 0.2f * a;
        float ex = __expf(al - mx);
        uint2 xk = xr[(long)ce.x * 16 + q];
        acc.x += ex * bflo(xk.x); acc.y += ex * bfhi(xk.x);
        acc.z += ex * bflo(xk.y); acc.w += ex * bfhi(xk.y);
      }
    }
    acc.x = acc.x * inv + bv.x; acc.y = acc.y * inv + bv.y;
    acc.z = acc.z * inv + bv.z; acc.w = acc.w * inv + bv.w;
    *(float4*)&gat_out[(long)node * 64 + q * 4] = acc;
    psum.x += acc.x; psum.y += acc.y; psum.z += acc.z; psum.w += acc.w;
    psq.x += acc.x * acc.x; psq.y += acc.y * acc.y; psq.z += acc.z * acc.z; psq.w += acc.w * acc.w;
  }
#pragma unroll
  for (int o = 16; o < 64; o <<= 1) {
    psum.x += __shfl_xor(psum.x, o); psum.y += __shfl_xor(psum.y, o);
    psum.z += __shfl_xor(psum.z, o); psum.w += __shfl_xor(psum.w, o);
    psq.x += __shfl_xor(psq.x, o); psq.y += __shfl_xor(psq.y, o);
    psq.z += __shfl_xor(psq.z, o); psq.w += __shfl_xor(psq.w, o);
  }
  if (lane < 16) {
    sred[w][lane * 4 + 0] = psum.x; sred[w][lane * 4 + 1] = psum.y;
    sred[w][lane * 4 + 2] = psum.z; sred[w][lane * 4 + 3] = psum.w;
    sred[w][64 + lane * 4 + 0] = psq.x; sred[w][64 + lane * 4 + 1] = psq.y;
    sred[w][64 + lane * 4 + 2] = psq.z; sred[w][64 + lane * 4 + 3] = psq.w;
  }
  __syncthreads();
  if (tid < 128)
    part[(long)blockIdx.x * 128 + tid] =
        sred[0][tid] + sred[1][tid] + sred[2][tid] + sred[3][tid];
}

// ---------------- BN finalize ----------------
__global__ __launch_bounds__(1024) void bn_finalize(const float* __restrict__ part, int nblk,
                                                    float invN, float* __restrict__ stats) {
  __shared__ float sh[1024];
  int t = threadIdx.x;
  int c = t & 127, g = t >> 7;
  float s = 0.f;
  for (int b = g; b < nblk; b += 8) s += part[(long)b * 128 + c];
  sh[t] = s;
  __syncthreads();
  if (t < 128) {
    float tot = 0.f;
#pragma unroll
    for (int g2 = 0; g2 < 8; ++g2) tot += sh[g2 * 128 + t];
    sh[t] = tot;
  }
  __syncthreads();
  if (t < 64) {
    float mean = sh[t] * invN;
    float var = sh[64 + t] * invN - mean * mean;
    stats[t] = mean;
    stats[64 + t] = rsqrtf(var + 1e-5f);
  }
}

// ---- fused: last BN-apply + residual + global mean partials (no h write) ----
__global__ void gsum_bn(const float* __restrict__ z, const float* __restrict__ stats,
                        const float* __restrict__ bng, const float* __restrict__ bnb,
                        const float* __restrict__ hprev, int n, float* __restrict__ part) {
  __shared__ float sh[4][64];
  int tid = threadIdx.x, w = tid >> 6, lane = tid & 63;
  float sm = stats[lane], sv = stats[64 + lane], gg = bng[lane], bb = bnb[lane];
  int gw = blockIdx.x * 4 + w, nW = gridDim.x * 4;
  float s = 0.f;
  for (int node = gw; node < n; node += nW) {
    float t = fmaxf((z[(long)node * 64 + lane] - sm) * sv * gg + bb, 0.f);
    s += hprev[(long)node * 64 + lane] + t;
  }
  sh[w][lane] = s;
  __syncthreads();
  if (tid < 64)
    part[(long)blockIdx.x * 64 + tid] =
        sh[0][tid] + sh[1][tid] + sh[2][tid] + sh[3][tid];
}

__global__ void final_kernel(const float* __restrict__ part, int nblk,
                             const float* __restrict__ out_W, const float* __restrict__ out_b,
                             float* __restrict__ out, float invN) {
  __shared__ float g[64];
  int c = threadIdx.x;  // 64 threads
  float s = 0.f;
  for (int b = 0; b < nblk; ++b) s += part[(long)b * 64 + c];
  g[c] = s * invN;
  __syncthreads();
  float acc = out_b[c];
  for (int k = 0; k < 64; ++k) acc += g[k] * out_W[k * 64 + c];
  out[c] = fmaxf(acc, 0.f);
}

// ---------------- host launch ----------------
extern "C" void kernel_launch(void* const* d_in, const int* in_sizes, int n_in,
                              void* d_out, int out_size, void* d_ws, size_t ws_size,
                              hipStream_t stream) {
  const float* x        = (const float*)d_in[0];
  const int*   eidx     = (const int*)d_in[1];
  const float* eattr    = (const float*)d_in[2];
  const float* np_W1    = (const float*)d_in[3];
  const float* np_b1    = (const float*)d_in[4];
  const float* np_W2    = (const float*)d_in[5];
  const float* np_b2    = (const float*)d_in[6];
  const float* np_ln_g  = (const float*)d_in[7];
  const float* np_ln_b  = (const float*)d_in[8];
  const float* ep_W1    = (const float*)d_in[9];
  const float* ep_b1    = (const float*)d_in[10];
  const float* ep_W2    = (const float*)d_in[11];
  const float* ep_b2    = (const float*)d_in[12];
  const float* ep_ln_g  = (const float*)d_in[13];
  const float* ep_ln_b  = (const float*)d_in[14];
  const float* enc_W    = (const float*)d_in[15];
  const float* enc_b    = (const float*)d_in[16];
  const float* enc_bn_g = (const float*)d_in[17];
  const float* enc_bn_b = (const float*)d_in[18];
  const float* gat_W    = (const float*)d_in[19];
  const float* gat_eW   = (const float*)d_in[20];
  const float* att_src  = (const float*)d_in[21];
  const float* att_dst  = (const float*)d_in[22];
  const float* att_edge = (const float*)d_in[23];
  const float* gat_b    = (const float*)d_in[24];
  const float* bn_g     = (const float*)d_in[25];
  const float* bn_b     = (const float*)d_in[26];
  const float* out_W    = (const float*)d_in[27];
  const float* out_b    = (const float*)d_in[28];

  const int n = in_sizes[0] / 128;   // 50000
  const int ne = in_sizes[1] / 2;    // 800000
  const int* srcp = eidx;
  const int* dstp = eidx + ne;

  float* f = (float*)d_ws;
  float* hbuf  = f; f += (long)n * 64;
  float* zbuf  = f; f += (long)n * 64;
  float* alsb  = f; f += n;
  float* aldb  = f; f += n;
  float* ale   = f; f += 3L * ne;
  float* vgbuf = f; f += 128;
  float* stats = f; f += 128;
  float* part  = f; f += 131072;      // 1024 x 128
  float* part2 = f; f += 16384;       // 256 x 64
  unsigned short* wbb = (unsigned short*)f; f += 2048;          // 4096 bf16
  unsigned short* xsb = (unsigned short*)f; f += (long)n * 32;  // n*64 bf16
  int* ip = (int*)f;
  int2* csr = (int2*)ip; ip += 2L * ne;
  int* degb = ip; ip += n;
  int* cntb = ip; ip += n;
  int* offb = ip; ip += n + 1;

  const int nbEdge = (ne + EB - 1) / EB;     // 6250
  const int nbNode = (n + NT - 1) / NT;      // 782
  const int nbXs   = (n + 31) / 32;          // 1563

  hipMemsetAsync(degb, 0, (size_t)n * sizeof(int), stream);
  hipMemsetAsync(cntb, 0, (size_t)n * sizeof(int), stream);
  vprep2<<<1, 128, 0, stream>>>(gat_eW, att_edge, ep_ln_g, ep_ln_b, vgbuf);
  wpack<<<1, 256, 0, stream>>>(ep_W1, ep_W2, wbb);
  deg_kernel<<<1024, 256, 0, stream>>>(dstp, ne, degb);
  scan2<<<1, 1024, 0, stream>>>(degb, offb, n);
  scatter_kernel<<<1024, 256, 0, stream>>>(srcp, dstp, ne, offb, cntb, csr);
  edge_pre3<<<nbEdge, 256, 0, stream>>>(eattr, wbb, ep_b1, ep_b2, vgbuf, ale, ne);
  node_pre2<<<nbNode, 256, 0, stream>>>(x, np_W1, np_b1, np_W2, np_b2, np_ln_g, np_ln_b,
                                        enc_W, enc_b, zbuf, part, n);
  bn_finalize<<<1, 1024, 0, stream>>>(part, nbNode, 1.f / n, stats);
  xs_bn<<<nbXs, 256, 0, stream>>>(zbuf, stats, enc_bn_g, enc_bn_b, hbuf, 0,
                                  gat_W, att_src, att_dst, xsb, alsb, aldb, n);
  for (int l = 0; l < 3; ++l) {
    gat3<<<1024, 256, 0, stream>>>(offb, csr, ale + (long)l * ne, alsb, aldb,
                                   xsb, gat_b + l * 64, zbuf, part, n);
    bn_finalize<<<1, 1024, 0, stream>>>(part, 1024, 1.f / n, stats);
    if (l < 2) {
      xs_bn<<<nbXs, 256, 0, stream>>>(zbuf, stats, bn_g + l * 64, bn_b + l * 64, hbuf, 1,
                                      gat_W + (long)(l + 1) * 4096, att_src + (l + 1) * 64,
                                      att_dst + (l + 1) * 64, xsb, alsb, aldb, n);
    } else {
      gsum_bn<<<256, 256, 0, stream>>>(zbuf, stats, bn_g + l * 64, bn_b + l * 64,
                                       hbuf, n, part2);
    }
  }
  final_kernel<<<1, 64, 0, stream>>>(part2, 256, out_W, out_b, (float*)d_out, 1.f / n);
}

// Round 6
// 850.360 us; speedup vs baseline: 2.3060x; 1.1201x over previous
//
#include <hip/hip_runtime.h>
#include <hip/hip_bf16.h>

// GNNEncoder on MI355X. Algebraic reductions:
//  - (ea@eW)@a_e == ea@(eW@a_e): only 3 scalars al_e per edge needed.
//  - loop_attr contribution == mean(incoming al_e) by linearity.
//  - edge LN+dot folded: al = istd*(sum y*(g*v) - mean*G) + C.
// dst-CSR built once; scatter order from atomics is made DETERMINISTIC by a
// per-segment sort on edge id (csr_sort) -- graph-replay == launch_once bitwise.
// edge_pre3 / node_pre3: MFMA bf16, weights pre-packed into B-fragment order,
// tiny per-lane state (no scratch traffic), XOR-swizzled LDS activations.

typedef short bf16x8 __attribute__((ext_vector_type(8)));
typedef float f32x4 __attribute__((ext_vector_type(4)));
union U8 { uint4 u; bf16x8 v; };

__device__ __forceinline__ unsigned pack2bf(float a, float b) {
  unsigned ua = __float_as_uint(a); ua += 0x7fffu + ((ua >> 16) & 1u);
  unsigned ub = __float_as_uint(b); ub += 0x7fffu + ((ub >> 16) & 1u);
  return (ua >> 16) | (ub & 0xffff0000u);
}
__device__ __forceinline__ unsigned short f2bf(float x) {
  unsigned u = __float_as_uint(x); u += 0x7fffu + ((u >> 16) & 1u);
  return (unsigned short)(u >> 16);
}
__device__ __forceinline__ float bflo(unsigned u) { return __uint_as_float(u << 16); }
__device__ __forceinline__ float bfhi(unsigned u) { return __uint_as_float(u & 0xffff0000u); }

// ---------------- prep: v = eW@a_e, gv = lng*v, G = sum(lng*v), C = sum(lnb*v) ----------------
__global__ void vprep2(const float* __restrict__ eW, const float* __restrict__ a_e,
                       const float* __restrict__ lng, const float* __restrict__ lnb,
                       float* __restrict__ vg) {
  __shared__ float sv[96];
  int t = threadIdx.x;  // 128 threads
  if (t < 96) {
    int l = t >> 5, i = t & 31;
    const float* w = eW + l * 2048 + i * 64;
    const float* a = a_e + l * 64;
    float s = 0.f;
    for (int c = 0; c < 64; ++c) s += w[c] * a[c];
    sv[t] = s;
    vg[t] = s * lng[i];
  }
  __syncthreads();
  if (t < 3) {
    float G = 0.f, C = 0.f;
    for (int i = 0; i < 32; ++i) {
      float vv = sv[t * 32 + i];
      G += lng[i] * vv;
      C += lnb[i] * vv;
    }
    vg[96 + t] = G;
    vg[99 + t] = C;
  }
}

// pack W1[32x64], W2[64x32] into bf16 MFMA B-fragment order (edge MLP).
__global__ void wpack(const float* __restrict__ W1, const float* __restrict__ W2,
                      unsigned short* __restrict__ wb) {
  int t = threadIdx.x;  // 256
  for (int i = t; i < 2048; i += 256) {
    int nt = i >> 9, rem = i & 511, l = rem >> 3, j = rem & 7;
    int k = ((l >> 4) << 3) + j, col = (nt << 4) + (l & 15);
    wb[i] = f2bf(W1[k * 64 + col]);
  }
  for (int i = t; i < 2048; i += 256) {
    int sn = i >> 9, rem = i & 511, l = rem >> 3, j = rem & 7;
    int s = sn >> 1, nt = sn & 1;
    int k = s * 32 + ((l >> 4) << 3) + j, col = (nt << 4) + (l & 15);
    wb[2048 + i] = f2bf(W2[k * 32 + col]);
  }
}

// pack node-path weights: np_W1[128x256] (64 frags), np_W2[256x128] (64), enc_W[128x64] (16)
__global__ void npack(const float* __restrict__ W1, const float* __restrict__ W2,
                      const float* __restrict__ eW, unsigned short* __restrict__ wnb) {
  int i = blockIdx.x * blockDim.x + threadIdx.x;  // 73728 total
  if (i < 32768) {
    int fi = i >> 9, rem = i & 511, l = rem >> 3, j = rem & 7;
    int nt = fi >> 2, ks = fi & 3;
    int k = ks * 32 + ((l >> 4) << 3) + j, col = nt * 16 + (l & 15);
    wnb[i] = f2bf(W1[k * 256 + col]);
  } else if (i < 65536) {
    int i2 = i - 32768;
    int fi = i2 >> 9, rem = i2 & 511, l = rem >> 3, j = rem & 7;
    int nt = fi >> 3, ks = fi & 7;
    int k = ks * 32 + ((l >> 4) << 3) + j, col = nt * 16 + (l & 15);
    wnb[i] = f2bf(W2[k * 128 + col]);
  } else if (i < 73728) {
    int i3 = i - 65536;
    int fi = i3 >> 9, rem = i3 & 511, l = rem >> 3, j = rem & 7;
    int nt = fi >> 2, ks = fi & 3;
    int k = ks * 32 + ((l >> 4) << 3) + j, col = nt * 16 + (l & 15);
    wnb[i] = f2bf(eW[k * 64 + col]);
  }
}

__global__ void deg_kernel(const int* __restrict__ dst, int ne, int* __restrict__ deg) {
  int i = blockIdx.x * blockDim.x + threadIdx.x;
  int stride = gridDim.x * blockDim.x;
  for (; i < ne; i += stride) atomicAdd(&deg[dst[i]], 1);
}

__global__ __launch_bounds__(1024) void scan2(const int* __restrict__ deg,
                                              int* __restrict__ off, int n) {
  __shared__ int sh[1024];
  int t = threadIdx.x;
  int C = (n + 1023) >> 10;
  int b0 = t * C, b1 = min(n, b0 + C);
  int s = 0;
  for (int j = b0; j < b1; ++j) s += deg[j];
  sh[t] = s;
  __syncthreads();
  for (int o = 1; o < 1024; o <<= 1) {
    int add = (t >= o) ? sh[t - o] : 0;
    __syncthreads();
    sh[t] += add;
    __syncthreads();
  }
  int run = (t == 0) ? 0 : sh[t - 1];
  if (t == 0) off[0] = 0;
  for (int j = b0; j < b1; ++j) { run += deg[j]; off[j + 1] = run; }
}

__global__ void scatter_kernel(const int* __restrict__ src, const int* __restrict__ dst,
                               int ne, const int* __restrict__ off, int* __restrict__ cnt,
                               int2* __restrict__ csrt) {
  int i = blockIdx.x * blockDim.x + threadIdx.x;
  int stride = gridDim.x * blockDim.x;
  for (; i < ne; i += stride) {
    int d = dst[i];
    int p = off[d] + atomicAdd(&cnt[d], 1);
    csrt[p] = make_int2(src[i], i);
  }
}

// ---- deterministic per-segment sort by edge id (atomics arrival order erased) ----
#define SCAP 128
__global__ __launch_bounds__(256) void csr_sort(const int* __restrict__ off,
                                                const int2* __restrict__ csrt,
                                                int2* __restrict__ csr, int n) {
  __shared__ int seid[16][SCAP];
  int tid = threadIdx.x;
  int qt = tid >> 4, q = tid & 15;
  for (int node = blockIdx.x * 16 + qt; node < n; node += gridDim.x * 16) {
    int s0 = off[node], deg = off[node + 1] - s0;
    if (deg <= SCAP) {
      for (int k = q; k < deg; k += 16) seid[qt][k] = csrt[s0 + k].y;
      // same-wave LDS writes are visible to subsequent same-wave reads
      for (int k = q; k < deg; k += 16) {
        int e = seid[qt][k];
        int r = 0;
        for (int m = 0; m < deg; ++m) r += (seid[qt][m] < e) ? 1 : 0;
        csr[s0 + r] = csrt[s0 + k];
      }
    } else {
      for (int k = q; k < deg; k += 16) {
        int e = csrt[s0 + k].y;
        int r = 0;
        for (int m = 0; m < deg; ++m) r += (csrt[s0 + m].y < e) ? 1 : 0;
        csr[s0 + r] = csrt[s0 + k];
      }
    }
  }
}

// ---------------- edge preproc v3: MFMA. block=256 (4 waves), 128 edges ----------------
#define EB 128
__global__ __launch_bounds__(256) void edge_pre3(
    const float* __restrict__ ea, const unsigned short* __restrict__ wb,
    const float* __restrict__ b1, const float* __restrict__ b2,
    const float* __restrict__ vg, float* __restrict__ ale, int ne) {
  __shared__ __align__(16) unsigned short swb[4096];
  __shared__ __align__(16) unsigned short sT[4][32 * 72];
  int tid = threadIdx.x, w = tid >> 6, lane = tid & 63;
  {
    const uint4* g = (const uint4*)wb;
    uint4* s = (uint4*)swb;
    for (int i = tid; i < 512; i += 256) s[i] = g[i];
  }
  __syncthreads();
  int lm = lane & 15, lq = lane >> 4;
  long e0 = (long)blockIdx.x * EB + w * 32;
  bf16x8 afr[2];
#pragma unroll
  for (int h = 0; h < 2; ++h) {
    long e = e0 + h * 16 + lm;
    if (e >= ne) e = ne - 1;
    const float4* p = (const float4*)(ea + e * 32 + lq * 8);
    float4 u = p[0], v = p[1];
    U8 cc;
    cc.u = make_uint4(pack2bf(u.x, u.y), pack2bf(u.z, u.w), pack2bf(v.x, v.y), pack2bf(v.z, v.w));
    afr[h] = cc.v;
  }
  f32x4 zero = {0.f, 0.f, 0.f, 0.f};
  f32x4 c1[2][4];
#pragma unroll
  for (int h = 0; h < 2; ++h)
#pragma unroll
    for (int nt = 0; nt < 4; ++nt) c1[h][nt] = zero;
#pragma unroll
  for (int nt = 0; nt < 4; ++nt) {
    bf16x8 bf = *(const bf16x8*)&swb[nt * 512 + lane * 8];
#pragma unroll
    for (int h = 0; h < 2; ++h)
      c1[h][nt] = __builtin_amdgcn_mfma_f32_16x16x32_bf16(afr[h], bf, c1[h][nt], 0, 0, 0);
  }
  {
    float b1v[4];
#pragma unroll
    for (int nt = 0; nt < 4; ++nt) b1v[nt] = b1[nt * 16 + lm];
#pragma unroll
    for (int h = 0; h < 2; ++h)
#pragma unroll
      for (int nt = 0; nt < 4; ++nt)
#pragma unroll
        for (int r = 0; r < 4; ++r) {
          float tv = fmaxf(c1[h][nt][r] + b1v[nt], 0.f);
          sT[w][(h * 16 + lq * 4 + r) * 72 + nt * 16 + lm] = f2bf(tv);
        }
  }
  __syncthreads();
  f32x4 c2[2][2];
#pragma unroll
  for (int h = 0; h < 2; ++h)
#pragma unroll
    for (int nt = 0; nt < 2; ++nt) c2[h][nt] = zero;
#pragma unroll
  for (int h = 0; h < 2; ++h)
#pragma unroll
    for (int s = 0; s < 2; ++s) {
      bf16x8 at = *(const bf16x8*)&sT[w][(h * 16 + lm) * 72 + s * 32 + lq * 8];
#pragma unroll
      for (int nt = 0; nt < 2; ++nt) {
        bf16x8 bf = *(const bf16x8*)&swb[2048 + (s * 2 + nt) * 512 + lane * 8];
        c2[h][nt] = __builtin_amdgcn_mfma_f32_16x16x32_bf16(at, bf, c2[h][nt], 0, 0, 0);
      }
    }
  float b2v0 = b2[lm], b2v1 = b2[16 + lm];
  float gv00 = vg[lm], gv01 = vg[16 + lm];
  float gv10 = vg[32 + lm], gv11 = vg[48 + lm];
  float gv20 = vg[64 + lm], gv21 = vg[80 + lm];
  float G0 = vg[96], G1 = vg[97], G2 = vg[98];
  float C0 = vg[99], C1 = vg[100], C2 = vg[101];
#pragma unroll
  for (int h = 0; h < 2; ++h) {
    float s4[4], q4[4], d0[4], d1[4], d2[4];
#pragma unroll
    for (int r = 0; r < 4; ++r) {
      float ya = c2[h][0][r] + b2v0;
      float yb = c2[h][1][r] + b2v1;
      s4[r] = ya + yb;
      q4[r] = ya * ya + yb * yb;
      d0[r] = ya * gv00 + yb * gv01;
      d1[r] = ya * gv10 + yb * gv11;
      d2[r] = ya * gv20 + yb * gv21;
    }
#pragma unroll
    for (int o = 1; o < 16; o <<= 1) {
#pragma unroll
      for (int r = 0; r < 4; ++r) {
        s4[r] += __shfl_xor(s4[r], o);
        q4[r] += __shfl_xor(q4[r], o);
        d0[r] += __shfl_xor(d0[r], o);
        d1[r] += __shfl_xor(d1[r], o);
        d2[r] += __shfl_xor(d2[r], o);
      }
    }
    if (lm < 4) {
      int r = lm;
      long e = e0 + h * 16 + lq * 4 + r;
      if (e < ne) {
        float mean = s4[r] * (1.f / 32.f);
        float var = q4[r] * (1.f / 32.f) - mean * mean;
        float istd = rsqrtf(var + 1e-5f);
        ale[e] = istd * (d0[r] - mean * G0) + C0;
        ale[(long)ne + e] = istd * (d1[r] - mean * G1) + C1;
        ale[2L * ne + e] = istd * (d2[r] - mean * G2) + C2;
      }
    }
  }
}

// ---------------- node preproc v3: MFMA. block=256 (4 waves), 64 nodes ----------------
__global__ __launch_bounds__(256, 2) void node_pre3(
    const float* __restrict__ x, const unsigned short* __restrict__ wnb,
    const float* __restrict__ b1, const float* __restrict__ b2,
    const float* __restrict__ lng, const float* __restrict__ lnb,
    const float* __restrict__ encb, float* __restrict__ z_out,
    float* __restrict__ part, int n) {
  __shared__ __align__(16) unsigned short swb[16384];      // 32KB weight chunk
  __shared__ __align__(16) unsigned short sT[4][16 * 264]; // per-wave T / h1
  __shared__ float sred[4][128];
  int tid = threadIdx.x, w = tid >> 6, lane = tid & 63;
  int lm = lane & 15, lq = lane >> 4;
  long nb = (long)blockIdx.x * 64;
  const uint4* wg = (const uint4*)wnb;
  f32x4 zero = {0.f, 0.f, 0.f, 0.f};

  long row = nb + w * 16 + lm;
  if (row >= n) row = n - 1;
  bf16x8 ax[4];
  const float4* xp = (const float4*)(x + row * 128);
#pragma unroll
  for (int ks = 0; ks < 4; ++ks) {
    float4 u = xp[ks * 8 + lq * 2];
    float4 v = xp[ks * 8 + lq * 2 + 1];
    U8 cc;
    cc.u = make_uint4(pack2bf(u.x, u.y), pack2bf(u.z, u.w), pack2bf(v.x, v.y), pack2bf(v.z, v.w));
    ax[ks] = cc.v;
  }

  for (int h01 = 0; h01 < 2; ++h01) {
    __syncthreads();
    {
      const uint4* src = wg + h01 * 2048;
      uint4* dstv = (uint4*)swb;
      for (int i = tid; i < 2048; i += 256) dstv[i] = src[i];
    }
    __syncthreads();
    f32x4 acc1[8];
#pragma unroll
    for (int nt8 = 0; nt8 < 8; ++nt8) acc1[nt8] = zero;
#pragma unroll
    for (int ks = 0; ks < 4; ++ks)
#pragma unroll
      for (int nt8 = 0; nt8 < 8; ++nt8) {
        bf16x8 bf = *(const bf16x8*)&swb[(nt8 * 4 + ks) * 512 + lane * 8];
        acc1[nt8] = __builtin_amdgcn_mfma_f32_16x16x32_bf16(ax[ks], bf, acc1[nt8], 0, 0, 0);
      }
#pragma unroll
    for (int nt8 = 0; nt8 < 8; ++nt8) {
      int col = (h01 * 8 + nt8) * 16 + lm;
      float bv = b1[col];
#pragma unroll
      for (int r = 0; r < 4; ++r) {
        int rr = lq * 4 + r;
        sT[w][rr * 264 + (col ^ ((rr & 7) << 3))] = f2bf(fmaxf(acc1[nt8][r] + bv, 0.f));
      }
    }
  }

  f32x4 c2[8];
#pragma unroll
  for (int nt = 0; nt < 8; ++nt) c2[nt] = zero;
  for (int ksh = 0; ksh < 2; ++ksh) {
    __syncthreads();
    {
      uint4* dstv = (uint4*)swb;
      for (int i4 = tid; i4 < 2048; i4 += 256) {
        int e = i4 * 8;
        int fc = e >> 9, nt = fc >> 2, ksl = fc & 3;
        int ks = ksh * 4 + ksl;
        long gi = 32768 + (long)(nt * 8 + ks) * 512 + (e & 511);
        dstv[i4] = wg[gi >> 3];
      }
    }
    __syncthreads();
#pragma unroll
    for (int ksl = 0; ksl < 4; ++ksl) {
      int ks = ksh * 4 + ksl;
      bf16x8 at = *(const bf16x8*)&sT[w][lm * 264 + ((ks * 32 + lq * 8) ^ ((lm & 7) << 3))];
#pragma unroll
      for (int nt = 0; nt < 8; ++nt) {
        bf16x8 bf = *(const bf16x8*)&swb[(nt * 4 + ksl) * 512 + lane * 8];
        c2[nt] = __builtin_amdgcn_mfma_f32_16x16x32_bf16(at, bf, c2[nt], 0, 0, 0);
      }
    }
  }

  {
    float yv[8][4], bcol[8], gcol[8], ocol[8];
#pragma unroll
    for (int nt = 0; nt < 8; ++nt) {
      int col = nt * 16 + lm;
      bcol[nt] = b2[col]; gcol[nt] = lng[col]; ocol[nt] = lnb[col];
    }
    float s4[4], q4[4];
#pragma unroll
    for (int r = 0; r < 4; ++r) { s4[r] = 0.f; q4[r] = 0.f; }
#pragma unroll
    for (int nt = 0; nt < 8; ++nt)
#pragma unroll
      for (int r = 0; r < 4; ++r) {
        float y = c2[nt][r] + bcol[nt];
        yv[nt][r] = y;
        s4[r] += y; q4[r] += y * y;
      }
#pragma unroll
    for (int o = 1; o < 16; o <<= 1)
#pragma unroll
      for (int r = 0; r < 4; ++r) {
        s4[r] += __shfl_xor(s4[r], o);
        q4[r] += __shfl_xor(q4[r], o);
      }
#pragma unroll
    for (int r = 0; r < 4; ++r) {
      float mean = s4[r] * (1.f / 128.f);
      float var = q4[r] * (1.f / 128.f) - mean * mean;
      float istd = rsqrtf(var + 1e-5f);
      int rr = lq * 4 + r;
#pragma unroll
      for (int nt = 0; nt < 8; ++nt) {
        float hv = (yv[nt][r] - mean) * istd * gcol[nt] + ocol[nt];
        int col = nt * 16 + lm;
        if (col < 128)
          sT[w][rr * 264 + (col ^ ((rr & 7) << 3))] = f2bf(hv);
      }
    }
  }

  __syncthreads();
  {
    uint4* dstv = (uint4*)swb;
    const uint4* src = wg + (65536 >> 3);
    for (int i = tid; i < 1024; i += 256) dstv[i] = src[i];
  }
  __syncthreads();
  f32x4 c3[4];
#pragma unroll
  for (int nt = 0; nt < 4; ++nt) c3[nt] = zero;
#pragma unroll
  for (int ks = 0; ks < 4; ++ks) {
    bf16x8 at = *(const bf16x8*)&sT[w][lm * 264 + ((ks * 32 + lq * 8) ^ ((lm & 7) << 3))];
#pragma unroll
    for (int nt = 0; nt < 4; ++nt) {
      bf16x8 bf = *(const bf16x8*)&swb[(nt * 4 + ks) * 512 + lane * 8];
      c3[nt] = __builtin_amdgcn_mfma_f32_16x16x32_bf16(at, bf, c3[nt], 0, 0, 0);
    }
  }
  float ps[4], pq[4];
#pragma unroll
  for (int nt = 0; nt < 4; ++nt) { ps[nt] = 0.f; pq[nt] = 0.f; }
#pragma unroll
  for (int nt = 0; nt < 4; ++nt) {
    int col = nt * 16 + lm;
    float eb = encb[col];
#pragma unroll
    for (int r = 0; r < 4; ++r) {
      long nd = nb + w * 16 + lq * 4 + r;
      float z = c3[nt][r] + eb;
      if (nd < n) {
        z_out[nd * 64 + col] = z;
        ps[nt] += z; pq[nt] += z * z;
      }
    }
  }
#pragma unroll
  for (int o = 16; o < 64; o <<= 1)
#pragma unroll
    for (int nt = 0; nt < 4; ++nt) {
      ps[nt] += __shfl_xor(ps[nt], o);
      pq[nt] += __shfl_xor(pq[nt], o);
    }
  if (lq == 0) {
#pragma unroll
    for (int nt = 0; nt < 4; ++nt) {
      sred[w][nt * 16 + lm] = ps[nt];
      sred[w][64 + nt * 16 + lm] = pq[nt];
    }
  }
  __syncthreads();
  if (tid < 128) {
    float t = 0.f;
#pragma unroll
    for (int g = 0; g < 4; ++g) t += sred[g][tid];
    part[(long)blockIdx.x * 128 + tid] = t;
  }
}

// ---- fused: BN-apply(+residual into h) + xs = h@W (bf16 out) + al_s/al_d ----
__global__ __launch_bounds__(256) void xs_bn(
    const float* __restrict__ z, const float* __restrict__ stats,
    const float* __restrict__ bng, const float* __restrict__ bnb,
    float* __restrict__ hbuf, int mode,
    const float* __restrict__ W, const float* __restrict__ a_s, const float* __restrict__ a_d,
    unsigned short* __restrict__ xsb, float* __restrict__ al_s, float* __restrict__ al_d,
    int n) {
  __shared__ __align__(16) float sW[64 * 64];
  __shared__ __align__(16) float sh[32][64];
  int tid = threadIdx.x, w = tid >> 6, lane = tid & 63;
  for (int i = tid; i < 4096; i += 256) sW[i] = W[i];
  long nodeBase = (long)blockIdx.x * 32;
  float sm = stats[lane], sv = stats[64 + lane], gg = bng[lane], bb = bnb[lane];
  int lm0 = w * 8;
#pragma unroll
  for (int m = 0; m < 8; ++m) {
    long nd = nodeBase + lm0 + m;
    float hv = 0.f;
    if (nd < n) {
      float t = fmaxf((z[nd * 64 + lane] - sm) * sv * gg + bb, 0.f);
      hv = mode ? hbuf[nd * 64 + lane] + t : t;
      hbuf[nd * 64 + lane] = hv;
    }
    sh[lm0 + m][lane] = hv;
  }
  __syncthreads();
  float acc[8];
#pragma unroll
  for (int m = 0; m < 8; ++m) acc[m] = 0.f;
  for (int k = 0; k < 64; k += 4) {
    float w0 = sW[(k + 0) * 64 + lane];
    float w1 = sW[(k + 1) * 64 + lane];
    float w2 = sW[(k + 2) * 64 + lane];
    float w3 = sW[(k + 3) * 64 + lane];
#pragma unroll
    for (int m = 0; m < 8; ++m) {
      float4 h4 = *reinterpret_cast<const float4*>(&sh[lm0 + m][k]);
      acc[m] += h4.x * w0 + h4.y * w1 + h4.z * w2 + h4.w * w3;
    }
  }
  float asv = a_s[lane], adv = a_d[lane];
#pragma unroll
  for (int m = 0; m < 8; ++m) {
    long nd = nodeBase + lm0 + m;
    float ps = acc[m] * asv, pd = acc[m] * adv;
#pragma unroll
    for (int o = 1; o < 64; o <<= 1) {
      ps += __shfl_xor(ps, o);
      pd += __shfl_xor(pd, o);
    }
    if (nd < n) {
      xsb[nd * 64 + lane] = f2bf(acc[m]);
      if (lane == 0) { al_s[nd] = ps; al_d[nd] = pd; }
    }
  }
}

// ---------------- GAT: quarter-wave (16 lanes) per node, bf16 xs gather ----------------
#define QCAP 128
__global__ __launch_bounds__(256) void gat3(
    const int* __restrict__ off, const int2* __restrict__ csr,
    const float* __restrict__ ale,
    const float* __restrict__ al_s, const float* __restrict__ al_d,
    const unsigned short* __restrict__ xsb, const float* __restrict__ bias,
    float* __restrict__ gat_out, float* __restrict__ part, int n) {
  __shared__ float2 sal[16][QCAP];
  __shared__ float sred[4][128];
  int tid = threadIdx.x, w = tid >> 6, lane = tid & 63;
  int qt = tid >> 4, q = tid & 15;
  const uint2* xr = (const uint2*)xsb;
  float4 bv = *(const float4*)&bias[q * 4];
  float4 psum = make_float4(0.f, 0.f, 0.f, 0.f), psq = psum;
  for (int node = blockIdx.x * 16 + qt; node < n; node += gridDim.x * 16) {
    int s0 = off[node];
    int deg = off[node + 1] - s0;
    bool fits = (deg <= QCAP);
    float aldn = al_d[node];
    float lmax = -3.402823466e38f, lsae = 0.f;
    for (int k = q; k < deg; k += 16) {
      int2 ce = csr[s0 + k];
      float ae = ale[ce.y];
      float a = al_s[ce.x] + aldn + ae;
      float al = (a >= 0.f) ? a : 0.2f * a;
      lmax = fmaxf(lmax, al);
      lsae += ae;
      if (fits) sal[qt][k] = make_float2(al, __int_as_float(ce.x));
    }
#pragma unroll
    for (int o = 1; o < 16; o <<= 1) {
      lmax = fmaxf(lmax, __shfl_xor(lmax, o));
      lsae += __shfl_xor(lsae, o);
    }
    float ae_self = lsae / fmaxf((float)deg, 1.f);
    float a_self = al_s[node] + aldn + ae_self;
    float al_self = (a_self >= 0.f) ? a_self : 0.2f * a_self;
    float mx = fmaxf(lmax, al_self);
    float lsum = 0.f;
    if (fits) {
      for (int k = q; k < deg; k += 16) {
        float ex = __expf(sal[qt][k].x - mx);
        sal[qt][k].x = ex;
        lsum += ex;
      }
    } else {
      for (int k = q; k < deg; k += 16) {
        int2 ce = csr[s0 + k];
        float a = al_s[ce.x] + aldn + ale[ce.y];
        float al = (a >= 0.f) ? a : 0.2f * a;
        lsum += __expf(al - mx);
      }
    }
#pragma unroll
    for (int o = 1; o < 16; o <<= 1) lsum += __shfl_xor(lsum, o);
    float exs = __expf(al_self - mx);
    float inv = 1.f / (lsum + exs + 1e-16f);
    uint2 xv = xr[(long)node * 16 + q];
    float4 acc;
    acc.x = exs * bflo(xv.x); acc.y = exs * bfhi(xv.x);
    acc.z = exs * bflo(xv.y); acc.w = exs * bfhi(xv.y);
    if (fits) {
      int k = 0;
      for (; k + 4 <= deg; k += 4) {
        float2 p0 = sal[qt][k], p1 = sal[qt][k + 1], p2 = sal[qt][k + 2], p3 = sal[qt][k + 3];
        uint2 x0 = xr[(long)__float_as_int(p0.y) * 16 + q];
        uint2 x1 = xr[(long)__float_as_int(p1.y) * 16 + q];
        uint2 x2 = xr[(long)__float_as_int(p2.y) * 16 + q];
        uint2 x3 = xr[(long)__float_as_int(p3.y) * 16 + q];
        acc.x += p0.x * bflo(x0.x) + p1.x * bflo(x1.x) + p2.x * bflo(x2.x) + p3.x * bflo(x3.x);
        acc.y += p0.x * bfhi(x0.x) + p1.x * bfhi(x1.x) + p2.x * bfhi(x2.x) + p3.x * bfhi(x3.x);
        acc.z += p0.x * bflo(x0.y) + p1.x * bflo(x1.y) + p2.x * bflo(x2.y) + p3.x * bflo(x3.y);
        acc.w += p0.x * bfhi(x0.y) + p1.x * bfhi(x1.y) + p2.x * bfhi(x2.y) + p3.x * bfhi(x3.y);
      }
      for (; k < deg; ++k) {
        float2 p = sal[qt][k];
        uint2 xk = xr[(long)__float_as_int(p.y) * 16 + q];
        acc.x += p.x * bflo(xk.x); acc.y += p.x * bfhi(xk.x);
        acc.z += p.x * bflo(xk.y); acc.w += p.x * bfhi(xk.y);
      }
    } else {
      for (int k = 0; k < deg; ++k) {
        int2 ce = csr[s0 + k];
        float a = al_s[ce.x] + aldn + ale[ce.y];
        float al = (a >= 0.f) ? a : 0.2f * a;
        float ex = __expf(al - mx);
        uint2 xk = xr[(long)ce.x * 16 + q];
        acc.x += ex * bflo(xk.x); acc.y += ex * bfhi(xk.x);
        acc.z += ex * bflo(xk.y); acc.w += ex * bfhi(xk.y);
      }
    }
    acc.x = acc.x * inv + bv.x; acc.y = acc.y * inv + bv.y;
    acc.z = acc.z * inv + bv.z; acc.w = acc.w * inv + bv.w;
    *(float4*)&gat_out[(long)node * 64 + q * 4] = acc;
    psum.x += acc.x; psum.y += acc.y; psum.z += acc.z; psum.w += acc.w;
    psq.x += acc.x * acc.x; psq.y += acc.y * acc.y; psq.z += acc.z * acc.z; psq.w += acc.w * acc.w;
  }
#pragma unroll
  for (int o = 16; o < 64; o <<= 1) {
    psum.x += __shfl_xor(psum.x, o); psum.y += __shfl_xor(psum.y, o);
    psum.z += __shfl_xor(psum.z, o); psum.w += __shfl_xor(psum.w, o);
    psq.x += __shfl_xor(psq.x, o); psq.y += __shfl_xor(psq.y, o);
    psq.z += __shfl_xor(psq.z, o); psq.w += __shfl_xor(psq.w, o);
  }
  if (lane < 16) {
    sred[w][lane * 4 + 0] = psum.x; sred[w][lane * 4 + 1] = psum.y;
    sred[w][lane * 4 + 2] = psum.z; sred[w][lane * 4 + 3] = psum.w;
    sred[w][64 + lane * 4 + 0] = psq.x; sred[w][64 + lane * 4 + 1] = psq.y;
    sred[w][64 + lane * 4 + 2] = psq.z; sred[w][64 + lane * 4 + 3] = psq.w;
  }
  __syncthreads();
  if (tid < 128)
    part[(long)blockIdx.x * 128 + tid] =
        sred[0][tid] + sred[1][tid] + sred[2][tid] + sred[3][tid];
}

// ---------------- BN finalize ----------------
__global__ __launch_bounds__(1024) void bn_finalize(const float* __restrict__ part, int nblk,
                                                    float invN, float* __restrict__ stats) {
  __shared__ float sh[1024];
  int t = threadIdx.x;
  int c = t & 127, g = t >> 7;
  float s = 0.f;
  for (int b = g; b < nblk; b += 8) s += part[(long)b * 128 + c];
  sh[t] = s;
  __syncthreads();
  if (t < 128) {
    float tot = 0.f;
#pragma unroll
    for (int g2 = 0; g2 < 8; ++g2) tot += sh[g2 * 128 + t];
    sh[t] = tot;
  }
  __syncthreads();
  if (t < 64) {
    float mean = sh[t] * invN;
    float var = sh[64 + t] * invN - mean * mean;
    stats[t] = mean;
    stats[64 + t] = rsqrtf(var + 1e-5f);
  }
}

// ---- fused: last BN-apply + residual + global mean partials (no h write) ----
__global__ void gsum_bn(const float* __restrict__ z, const float* __restrict__ stats,
                        const float* __restrict__ bng, const float* __restrict__ bnb,
                        const float* __restrict__ hprev, int n, float* __restrict__ part) {
  __shared__ float sh[4][64];
  int tid = threadIdx.x, w = tid >> 6, lane = tid & 63;
  float sm = stats[lane], sv = stats[64 + lane], gg = bng[lane], bb = bnb[lane];
  int gw = blockIdx.x * 4 + w, nW = gridDim.x * 4;
  float s = 0.f;
  for (int node = gw; node < n; node += nW) {
    float t = fmaxf((z[(long)node * 64 + lane] - sm) * sv * gg + bb, 0.f);
    s += hprev[(long)node * 64 + lane] + t;
  }
  sh[w][lane] = s;
  __syncthreads();
  if (tid < 64)
    part[(long)blockIdx.x * 64 + tid] =
        sh[0][tid] + sh[1][tid] + sh[2][tid] + sh[3][tid];
}

__global__ void final_kernel(const float* __restrict__ part, int nblk,
                             const float* __restrict__ out_W, const float* __restrict__ out_b,
                             float* __restrict__ out, float invN) {
  __shared__ float g[64];
  int c = threadIdx.x;  // 64 threads
  float s = 0.f;
  for (int b = 0; b < nblk; ++b) s += part[(long)b * 64 + c];
  g[c] = s * invN;
  __syncthreads();
  float acc = out_b[c];
  for (int k = 0; k < 64; ++k) acc += g[k] * out_W[k * 64 + c];
  out[c] = fmaxf(acc, 0.f);
}

// ---------------- host launch ----------------
extern "C" void kernel_launch(void* const* d_in, const int* in_sizes, int n_in,
                              void* d_out, int out_size, void* d_ws, size_t ws_size,
                              hipStream_t stream) {
  const float* x        = (const float*)d_in[0];
  const int*   eidx     = (const int*)d_in[1];
  const float* eattr    = (const float*)d_in[2];
  const float* np_W1    = (const float*)d_in[3];
  const float* np_b1    = (const float*)d_in[4];
  const float* np_W2    = (const float*)d_in[5];
  const float* np_b2    = (const float*)d_in[6];
  const float* np_ln_g  = (const float*)d_in[7];
  const float* np_ln_b  = (const float*)d_in[8];
  const float* ep_W1    = (const float*)d_in[9];
  const float* ep_b1    = (const float*)d_in[10];
  const float* ep_W2    = (const float*)d_in[11];
  const float* ep_b2    = (const float*)d_in[12];
  const float* ep_ln_g  = (const float*)d_in[13];
  const float* ep_ln_b  = (const float*)d_in[14];
  const float* enc_W    = (const float*)d_in[15];
  const float* enc_b    = (const float*)d_in[16];
  const float* enc_bn_g = (const float*)d_in[17];
  const float* enc_bn_b = (const float*)d_in[18];
  const float* gat_W    = (const float*)d_in[19];
  const float* gat_eW   = (const float*)d_in[20];
  const float* att_src  = (const float*)d_in[21];
  const float* att_dst  = (const float*)d_in[22];
  const float* att_edge = (const float*)d_in[23];
  const float* gat_b    = (const float*)d_in[24];
  const float* bn_g     = (const float*)d_in[25];
  const float* bn_b     = (const float*)d_in[26];
  const float* out_W    = (const float*)d_in[27];
  const float* out_b    = (const float*)d_in[28];

  const int n = in_sizes[0] / 128;   // 50000
  const int ne = in_sizes[1] / 2;    // 800000
  const int* srcp = eidx;
  const int* dstp = eidx + ne;

  float* f = (float*)d_ws;
  float* hbuf  = f; f += (long)n * 64;
  float* zbuf  = f; f += (long)n * 64;   // also reused as int2 csrt scratch pre-node_pre3
  float* alsb  = f; f += n;
  float* aldb  = f; f += n;
  float* ale   = f; f += 3L * ne;
  float* vgbuf = f; f += 128;
  float* stats = f; f += 128;
  float* part  = f; f += 131072;      // 1024 x 128
  float* part2 = f; f += 16384;       // 256 x 64
  unsigned short* wbb = (unsigned short*)f; f += 2048;          // 4096 bf16 (edge weights)
  unsigned short* wnb = (unsigned short*)f; f += 36864;         // 73728 bf16 (node weights)
  unsigned short* xsb = (unsigned short*)f; f += (long)n * 32;  // n*64 bf16
  int* ip = (int*)f;
  int2* csr = (int2*)ip; ip += 2L * ne;
  int* degb = ip; ip += n;
  int* cntb = ip; ip += n;
  int* offb = ip; ip += n + 1;
  int2* csrt = (int2*)zbuf;  // ne*8B = 6.4MB <= zbuf 12.8MB; dead until node_pre3

  const int nbEdge = (ne + EB - 1) / EB;     // 6250
  const int nbNode = (n + 63) / 64;          // 782
  const int nbXs   = (n + 31) / 32;          // 1563

  hipMemsetAsync(degb, 0, (size_t)n * sizeof(int), stream);
  hipMemsetAsync(cntb, 0, (size_t)n * sizeof(int), stream);
  vprep2<<<1, 128, 0, stream>>>(gat_eW, att_edge, ep_ln_g, ep_ln_b, vgbuf);
  wpack<<<1, 256, 0, stream>>>(ep_W1, ep_W2, wbb);
  npack<<<288, 256, 0, stream>>>(np_W1, np_W2, enc_W, wnb);
  deg_kernel<<<1024, 256, 0, stream>>>(dstp, ne, degb);
  scan2<<<1, 1024, 0, stream>>>(degb, offb, n);
  scatter_kernel<<<1024, 256, 0, stream>>>(srcp, dstp, ne, offb, cntb, csrt);
  csr_sort<<<1024, 256, 0, stream>>>(offb, csrt, csr, n);
  edge_pre3<<<nbEdge, 256, 0, stream>>>(eattr, wbb, ep_b1, ep_b2, vgbuf, ale, ne);
  node_pre3<<<nbNode, 256, 0, stream>>>(x, wnb, np_b1, np_b2, np_ln_g, np_ln_b,
                                        enc_b, zbuf, part, n);
  bn_finalize<<<1, 1024, 0, stream>>>(part, nbNode, 1.f / n, stats);
  xs_bn<<<nbXs, 256, 0, stream>>>(zbuf, stats, enc_bn_g, enc_bn_b, hbuf, 0,
                                  gat_W, att_src, att_dst, xsb, alsb, aldb, n);
  for (int l = 0; l < 3; ++l) {
    gat3<<<1024, 256, 0, stream>>>(offb, csr, ale + (long)l * ne, alsb, aldb,
                                   xsb, gat_b + l * 64, zbuf, part, n);
    bn_finalize<<<1, 1024, 0, stream>>>(part, 1024, 1.f / n, stats);
    if (l < 2) {
      xs_bn<<<nbXs, 256, 0, stream>>>(zbuf, stats, bn_g + l * 64, bn_b + l * 64, hbuf, 1,
                                      gat_W + (long)(l + 1) * 4096, att_src + (l + 1) * 64,
                                      att_dst + (l + 1) * 64, xsb, alsb, aldb, n);
    } else {
      gsum_bn<<<256, 256, 0, stream>>>(zbuf, stats, bn_g + l * 64, bn_b + l * 64,
                                       hbuf, n, part2);
    }
  }
  final_kernel<<<1, 64, 0, stream>>>(part2, 256, out_W, out_b, (float*)d_out, 1.f / n);
}

// Round 7
// 644.110 us; speedup vs baseline: 3.0445x; 1.3202x over previous
//
#include <hip/hip_runtime.h>
#include <hip/hip_bf16.h>

// GNNEncoder on MI355X. Algebraic reductions:
//  - (ea@eW)@a_e == ea@(eW@a_e): only 3 scalars al_e per edge needed.
//  - loop_attr contribution == mean(incoming al_e) by linearity.
//  - edge LN+dot folded: al = istd*(sum y*(g*v) - mean*G) + C.
// dst-CSR built once; scatter order from atomics made DETERMINISTIC by a
// per-segment sort on edge id (csr_sort) -- graph-replay == launch_once bitwise.
// edge_pre3 / node_pre3 / xs_bn2: MFMA bf16, weights pre-packed into B-fragment
// order, tiny per-lane state (no scratch traffic), XOR-swizzled LDS activations.

typedef short bf16x8 __attribute__((ext_vector_type(8)));
typedef float f32x4 __attribute__((ext_vector_type(4)));
union U8 { uint4 u; bf16x8 v; };

__device__ __forceinline__ unsigned pack2bf(float a, float b) {
  unsigned ua = __float_as_uint(a); ua += 0x7fffu + ((ua >> 16) & 1u);
  unsigned ub = __float_as_uint(b); ub += 0x7fffu + ((ub >> 16) & 1u);
  return (ua >> 16) | (ub & 0xffff0000u);
}
__device__ __forceinline__ unsigned short f2bf(float x) {
  unsigned u = __float_as_uint(x); u += 0x7fffu + ((u >> 16) & 1u);
  return (unsigned short)(u >> 16);
}
__device__ __forceinline__ float bflo(unsigned u) { return __uint_as_float(u << 16); }
__device__ __forceinline__ float bfhi(unsigned u) { return __uint_as_float(u & 0xffff0000u); }

// ---------------- prep: v = eW@a_e, gv = lng*v, G = sum(lng*v), C = sum(lnb*v) ----------------
__global__ void vprep2(const float* __restrict__ eW, const float* __restrict__ a_e,
                       const float* __restrict__ lng, const float* __restrict__ lnb,
                       float* __restrict__ vg) {
  __shared__ float sv[96];
  int t = threadIdx.x;  // 128 threads
  if (t < 96) {
    int l = t >> 5, i = t & 31;
    const float* w = eW + l * 2048 + i * 64;
    const float* a = a_e + l * 64;
    float s = 0.f;
    for (int c = 0; c < 64; ++c) s += w[c] * a[c];
    sv[t] = s;
    vg[t] = s * lng[i];
  }
  __syncthreads();
  if (t < 3) {
    float G = 0.f, C = 0.f;
    for (int i = 0; i < 32; ++i) {
      float vv = sv[t * 32 + i];
      G += lng[i] * vv;
      C += lnb[i] * vv;
    }
    vg[96 + t] = G;
    vg[99 + t] = C;
  }
}

// pack W1[32x64], W2[64x32] into bf16 MFMA B-fragment order (edge MLP).
__global__ void wpack(const float* __restrict__ W1, const float* __restrict__ W2,
                      unsigned short* __restrict__ wb) {
  int t = threadIdx.x;  // 256
  for (int i = t; i < 2048; i += 256) {
    int nt = i >> 9, rem = i & 511, l = rem >> 3, j = rem & 7;
    int k = ((l >> 4) << 3) + j, col = (nt << 4) + (l & 15);
    wb[i] = f2bf(W1[k * 64 + col]);
  }
  for (int i = t; i < 2048; i += 256) {
    int sn = i >> 9, rem = i & 511, l = rem >> 3, j = rem & 7;
    int s = sn >> 1, nt = sn & 1;
    int k = s * 32 + ((l >> 4) << 3) + j, col = (nt << 4) + (l & 15);
    wb[2048 + i] = f2bf(W2[k * 32 + col]);
  }
}

// pack node-path weights: np_W1[128x256] (64 frags), np_W2[256x128] (64), enc_W[128x64] (16)
__global__ void npack(const float* __restrict__ W1, const float* __restrict__ W2,
                      const float* __restrict__ eW, unsigned short* __restrict__ wnb) {
  int i = blockIdx.x * blockDim.x + threadIdx.x;  // 73728 total
  if (i < 32768) {
    int fi = i >> 9, rem = i & 511, l = rem >> 3, j = rem & 7;
    int nt = fi >> 2, ks = fi & 3;
    int k = ks * 32 + ((l >> 4) << 3) + j, col = nt * 16 + (l & 15);
    wnb[i] = f2bf(W1[k * 256 + col]);
  } else if (i < 65536) {
    int i2 = i - 32768;
    int fi = i2 >> 9, rem = i2 & 511, l = rem >> 3, j = rem & 7;
    int nt = fi >> 3, ks = fi & 7;
    int k = ks * 32 + ((l >> 4) << 3) + j, col = nt * 16 + (l & 15);
    wnb[i] = f2bf(W2[k * 128 + col]);
  } else if (i < 73728) {
    int i3 = i - 65536;
    int fi = i3 >> 9, rem = i3 & 511, l = rem >> 3, j = rem & 7;
    int nt = fi >> 2, ks = fi & 3;
    int k = ks * 32 + ((l >> 4) << 3) + j, col = nt * 16 + (l & 15);
    wnb[i] = f2bf(eW[k * 64 + col]);
  }
}

// pack gat_W[3][64][64] into B-frag order: per layer 8 frags [nt*2+ks]
__global__ void gpack(const float* __restrict__ W, unsigned short* __restrict__ wg) {
  int i = blockIdx.x * blockDim.x + threadIdx.x;  // 12288 total
  if (i < 12288) {
    int l = i >> 12, rem = i & 4095;
    int fi = rem >> 9, l8 = rem & 511, ln = l8 >> 3, j = l8 & 7;
    int nt = fi >> 1, ks = fi & 1;
    int k = ks * 32 + ((ln >> 4) << 3) + j, col = nt * 16 + (ln & 15);
    wg[i] = f2bf(W[l * 4096 + k * 64 + col]);
  }
}

__global__ void deg_kernel(const int* __restrict__ dst, int ne, int* __restrict__ deg) {
  int i = blockIdx.x * blockDim.x + threadIdx.x;
  int stride = gridDim.x * blockDim.x;
  for (; i < ne; i += stride) atomicAdd(&deg[dst[i]], 1);
}

__global__ __launch_bounds__(1024) void scan2(const int* __restrict__ deg,
                                              int* __restrict__ off, int n) {
  __shared__ int sh[1024];
  int t = threadIdx.x;
  int C = (n + 1023) >> 10;
  int b0 = t * C, b1 = min(n, b0 + C);
  int s = 0;
  for (int j = b0; j < b1; ++j) s += deg[j];
  sh[t] = s;
  __syncthreads();
  for (int o = 1; o < 1024; o <<= 1) {
    int add = (t >= o) ? sh[t - o] : 0;
    __syncthreads();
    sh[t] += add;
    __syncthreads();
  }
  int run = (t == 0) ? 0 : sh[t - 1];
  if (t == 0) off[0] = 0;
  for (int j = b0; j < b1; ++j) { run += deg[j]; off[j + 1] = run; }
}

__global__ void scatter_kernel(const int* __restrict__ src, const int* __restrict__ dst,
                               int ne, const int* __restrict__ off, int* __restrict__ cnt,
                               int2* __restrict__ csrt) {
  int i = blockIdx.x * blockDim.x + threadIdx.x;
  int stride = gridDim.x * blockDim.x;
  for (; i < ne; i += stride) {
    int d = dst[i];
    int p = off[d] + atomicAdd(&cnt[d], 1);
    csrt[p] = make_int2(src[i], i);
  }
}

// ---- deterministic per-segment sort by edge id ----
#define SCAP 128
__global__ __launch_bounds__(256) void csr_sort(const int* __restrict__ off,
                                                const int2* __restrict__ csrt,
                                                int2* __restrict__ csr, int n) {
  __shared__ int seid[16][SCAP];
  int tid = threadIdx.x;
  int qt = tid >> 4, q = tid & 15;
  for (int node = blockIdx.x * 16 + qt; node < n; node += gridDim.x * 16) {
    int s0 = off[node], deg = off[node + 1] - s0;
    if (deg <= SCAP) {
      for (int k = q; k < deg; k += 16) seid[qt][k] = csrt[s0 + k].y;
      for (int k = q; k < deg; k += 16) {
        int e = seid[qt][k];
        int r = 0;
        for (int m = 0; m < deg; ++m) r += (seid[qt][m] < e) ? 1 : 0;
        csr[s0 + r] = csrt[s0 + k];
      }
    } else {
      for (int k = q; k < deg; k += 16) {
        int e = csrt[s0 + k].y;
        int r = 0;
        for (int m = 0; m < deg; ++m) r += (csrt[s0 + m].y < e) ? 1 : 0;
        csr[s0 + r] = csrt[s0 + k];
      }
    }
  }
}

// ---------------- edge preproc v3: MFMA. block=256 (4 waves), 128 edges ----------------
#define EB 128
__global__ __launch_bounds__(256) void edge_pre3(
    const float* __restrict__ ea, const unsigned short* __restrict__ wb,
    const float* __restrict__ b1, const float* __restrict__ b2,
    const float* __restrict__ vg, float* __restrict__ ale, int ne) {
  __shared__ __align__(16) unsigned short swb[4096];
  __shared__ __align__(16) unsigned short sT[4][32 * 72];
  int tid = threadIdx.x, w = tid >> 6, lane = tid & 63;
  {
    const uint4* g = (const uint4*)wb;
    uint4* s = (uint4*)swb;
    for (int i = tid; i < 512; i += 256) s[i] = g[i];
  }
  __syncthreads();
  int lm = lane & 15, lq = lane >> 4;
  long e0 = (long)blockIdx.x * EB + w * 32;
  bf16x8 afr[2];
#pragma unroll
  for (int h = 0; h < 2; ++h) {
    long e = e0 + h * 16 + lm;
    if (e >= ne) e = ne - 1;
    const float4* p = (const float4*)(ea + e * 32 + lq * 8);
    float4 u = p[0], v = p[1];
    U8 cc;
    cc.u = make_uint4(pack2bf(u.x, u.y), pack2bf(u.z, u.w), pack2bf(v.x, v.y), pack2bf(v.z, v.w));
    afr[h] = cc.v;
  }
  f32x4 zero = {0.f, 0.f, 0.f, 0.f};
  f32x4 c1[2][4];
#pragma unroll
  for (int h = 0; h < 2; ++h)
#pragma unroll
    for (int nt = 0; nt < 4; ++nt) c1[h][nt] = zero;
#pragma unroll
  for (int nt = 0; nt < 4; ++nt) {
    bf16x8 bf = *(const bf16x8*)&swb[nt * 512 + lane * 8];
#pragma unroll
    for (int h = 0; h < 2; ++h)
      c1[h][nt] = __builtin_amdgcn_mfma_f32_16x16x32_bf16(afr[h], bf, c1[h][nt], 0, 0, 0);
  }
  {
    float b1v[4];
#pragma unroll
    for (int nt = 0; nt < 4; ++nt) b1v[nt] = b1[nt * 16 + lm];
#pragma unroll
    for (int h = 0; h < 2; ++h)
#pragma unroll
      for (int nt = 0; nt < 4; ++nt)
#pragma unroll
        for (int r = 0; r < 4; ++r) {
          float tv = fmaxf(c1[h][nt][r] + b1v[nt], 0.f);
          sT[w][(h * 16 + lq * 4 + r) * 72 + nt * 16 + lm] = f2bf(tv);
        }
  }
  __syncthreads();
  f32x4 c2[2][2];
#pragma unroll
  for (int h = 0; h < 2; ++h)
#pragma unroll
    for (int nt = 0; nt < 2; ++nt) c2[h][nt] = zero;
#pragma unroll
  for (int h = 0; h < 2; ++h)
#pragma unroll
    for (int s = 0; s < 2; ++s) {
      bf16x8 at = *(const bf16x8*)&sT[w][(h * 16 + lm) * 72 + s * 32 + lq * 8];
#pragma unroll
      for (int nt = 0; nt < 2; ++nt) {
        bf16x8 bf = *(const bf16x8*)&swb[2048 + (s * 2 + nt) * 512 + lane * 8];
        c2[h][nt] = __builtin_amdgcn_mfma_f32_16x16x32_bf16(at, bf, c2[h][nt], 0, 0, 0);
      }
    }
  float b2v0 = b2[lm], b2v1 = b2[16 + lm];
  float gv00 = vg[lm], gv01 = vg[16 + lm];
  float gv10 = vg[32 + lm], gv11 = vg[48 + lm];
  float gv20 = vg[64 + lm], gv21 = vg[80 + lm];
  float G0 = vg[96], G1 = vg[97], G2 = vg[98];
  float C0 = vg[99], C1 = vg[100], C2 = vg[101];
#pragma unroll
  for (int h = 0; h < 2; ++h) {
    float s4[4], q4[4], d0[4], d1[4], d2[4];
#pragma unroll
    for (int r = 0; r < 4; ++r) {
      float ya = c2[h][0][r] + b2v0;
      float yb = c2[h][1][r] + b2v1;
      s4[r] = ya + yb;
      q4[r] = ya * ya + yb * yb;
      d0[r] = ya * gv00 + yb * gv01;
      d1[r] = ya * gv10 + yb * gv11;
      d2[r] = ya * gv20 + yb * gv21;
    }
#pragma unroll
    for (int o = 1; o < 16; o <<= 1) {
#pragma unroll
      for (int r = 0; r < 4; ++r) {
        s4[r] += __shfl_xor(s4[r], o);
        q4[r] += __shfl_xor(q4[r], o);
        d0[r] += __shfl_xor(d0[r], o);
        d1[r] += __shfl_xor(d1[r], o);
        d2[r] += __shfl_xor(d2[r], o);
      }
    }
    if (lm < 4) {
      int r = lm;
      long e = e0 + h * 16 + lq * 4 + r;
      if (e < ne) {
        float mean = s4[r] * (1.f / 32.f);
        float var = q4[r] * (1.f / 32.f) - mean * mean;
        float istd = rsqrtf(var + 1e-5f);
        ale[e] = istd * (d0[r] - mean * G0) + C0;
        ale[(long)ne + e] = istd * (d1[r] - mean * G1) + C1;
        ale[2L * ne + e] = istd * (d2[r] - mean * G2) + C2;
      }
    }
  }
}

// ---------------- node preproc v3: MFMA. block=256 (4 waves), 64 nodes ----------------
__global__ __launch_bounds__(256, 2) void node_pre3(
    const float* __restrict__ x, const unsigned short* __restrict__ wnb,
    const float* __restrict__ b1, const float* __restrict__ b2,
    const float* __restrict__ lng, const float* __restrict__ lnb,
    const float* __restrict__ encb, float* __restrict__ z_out,
    float* __restrict__ part, int n) {
  __shared__ __align__(16) unsigned short swb[16384];      // 32KB weight chunk
  __shared__ __align__(16) unsigned short sT[4][16 * 264]; // per-wave T / h1
  __shared__ float sred[4][128];
  int tid = threadIdx.x, w = tid >> 6, lane = tid & 63;
  int lm = lane & 15, lq = lane >> 4;
  long nb = (long)blockIdx.x * 64;
  const uint4* wg = (const uint4*)wnb;
  f32x4 zero = {0.f, 0.f, 0.f, 0.f};

  long row = nb + w * 16 + lm;
  if (row >= n) row = n - 1;
  bf16x8 ax[4];
  const float4* xp = (const float4*)(x + row * 128);
#pragma unroll
  for (int ks = 0; ks < 4; ++ks) {
    float4 u = xp[ks * 8 + lq * 2];
    float4 v = xp[ks * 8 + lq * 2 + 1];
    U8 cc;
    cc.u = make_uint4(pack2bf(u.x, u.y), pack2bf(u.z, u.w), pack2bf(v.x, v.y), pack2bf(v.z, v.w));
    ax[ks] = cc.v;
  }

  for (int h01 = 0; h01 < 2; ++h01) {
    __syncthreads();
    {
      const uint4* src = wg + h01 * 2048;
      uint4* dstv = (uint4*)swb;
      for (int i = tid; i < 2048; i += 256) dstv[i] = src[i];
    }
    __syncthreads();
    f32x4 acc1[8];
#pragma unroll
    for (int nt8 = 0; nt8 < 8; ++nt8) acc1[nt8] = zero;
#pragma unroll
    for (int ks = 0; ks < 4; ++ks)
#pragma unroll
      for (int nt8 = 0; nt8 < 8; ++nt8) {
        bf16x8 bf = *(const bf16x8*)&swb[(nt8 * 4 + ks) * 512 + lane * 8];
        acc1[nt8] = __builtin_amdgcn_mfma_f32_16x16x32_bf16(ax[ks], bf, acc1[nt8], 0, 0, 0);
      }
#pragma unroll
    for (int nt8 = 0; nt8 < 8; ++nt8) {
      int col = (h01 * 8 + nt8) * 16 + lm;
      float bv = b1[col];
#pragma unroll
      for (int r = 0; r < 4; ++r) {
        int rr = lq * 4 + r;
        sT[w][rr * 264 + (col ^ ((rr & 7) << 3))] = f2bf(fmaxf(acc1[nt8][r] + bv, 0.f));
      }
    }
  }

  f32x4 c2[8];
#pragma unroll
  for (int nt = 0; nt < 8; ++nt) c2[nt] = zero;
  for (int ksh = 0; ksh < 2; ++ksh) {
    __syncthreads();
    {
      uint4* dstv = (uint4*)swb;
      for (int i4 = tid; i4 < 2048; i4 += 256) {
        int e = i4 * 8;
        int fc = e >> 9, nt = fc >> 2, ksl = fc & 3;
        int ks = ksh * 4 + ksl;
        long gi = 32768 + (long)(nt * 8 + ks) * 512 + (e & 511);
        dstv[i4] = wg[gi >> 3];
      }
    }
    __syncthreads();
#pragma unroll
    for (int ksl = 0; ksl < 4; ++ksl) {
      int ks = ksh * 4 + ksl;
      bf16x8 at = *(const bf16x8*)&sT[w][lm * 264 + ((ks * 32 + lq * 8) ^ ((lm & 7) << 3))];
#pragma unroll
      for (int nt = 0; nt < 8; ++nt) {
        bf16x8 bf = *(const bf16x8*)&swb[(nt * 4 + ksl) * 512 + lane * 8];
        c2[nt] = __builtin_amdgcn_mfma_f32_16x16x32_bf16(at, bf, c2[nt], 0, 0, 0);
      }
    }
  }

  {
    float yv[8][4], bcol[8], gcol[8], ocol[8];
#pragma unroll
    for (int nt = 0; nt < 8; ++nt) {
      int col = nt * 16 + lm;
      bcol[nt] = b2[col]; gcol[nt] = lng[col]; ocol[nt] = lnb[col];
    }
    float s4[4], q4[4];
#pragma unroll
    for (int r = 0; r < 4; ++r) { s4[r] = 0.f; q4[r] = 0.f; }
#pragma unroll
    for (int nt = 0; nt < 8; ++nt)
#pragma unroll
      for (int r = 0; r < 4; ++r) {
        float y = c2[nt][r] + bcol[nt];
        yv[nt][r] = y;
        s4[r] += y; q4[r] += y * y;
      }
#pragma unroll
    for (int o = 1; o < 16; o <<= 1)
#pragma unroll
      for (int r = 0; r < 4; ++r) {
        s4[r] += __shfl_xor(s4[r], o);
        q4[r] += __shfl_xor(q4[r], o);
      }
#pragma unroll
    for (int r = 0; r < 4; ++r) {
      float mean = s4[r] * (1.f / 128.f);
      float var = q4[r] * (1.f / 128.f) - mean * mean;
      float istd = rsqrtf(var + 1e-5f);
      int rr = lq * 4 + r;
#pragma unroll
      for (int nt = 0; nt < 8; ++nt) {
        float hv = (yv[nt][r] - mean) * istd * gcol[nt] + ocol[nt];
        int col = nt * 16 + lm;
        if (col < 128)
          sT[w][rr * 264 + (col ^ ((rr & 7) << 3))] = f2bf(hv);
      }
    }
  }

  __syncthreads();
  {
    uint4* dstv = (uint4*)swb;
    const uint4* src = wg + (65536 >> 3);
    for (int i = tid; i < 1024; i += 256) dstv[i] = src[i];
  }
  __syncthreads();
  f32x4 c3[4];
#pragma unroll
  for (int nt = 0; nt < 4; ++nt) c3[nt] = zero;
#pragma unroll
  for (int ks = 0; ks < 4; ++ks) {
    bf16x8 at = *(const bf16x8*)&sT[w][lm * 264 + ((ks * 32 + lq * 8) ^ ((lm & 7) << 3))];
#pragma unroll
    for (int nt = 0; nt < 4; ++nt) {
      bf16x8 bf = *(const bf16x8*)&swb[(nt * 4 + ks) * 512 + lane * 8];
      c3[nt] = __builtin_amdgcn_mfma_f32_16x16x32_bf16(at, bf, c3[nt], 0, 0, 0);
    }
  }
  float ps[4], pq[4];
#pragma unroll
  for (int nt = 0; nt < 4; ++nt) { ps[nt] = 0.f; pq[nt] = 0.f; }
#pragma unroll
  for (int nt = 0; nt < 4; ++nt) {
    int col = nt * 16 + lm;
    float eb = encb[col];
#pragma unroll
    for (int r = 0; r < 4; ++r) {
      long nd = nb + w * 16 + lq * 4 + r;
      float z = c3[nt][r] + eb;
      if (nd < n) {
        z_out[nd * 64 + col] = z;
        ps[nt] += z; pq[nt] += z * z;
      }
    }
  }
#pragma unroll
  for (int o = 16; o < 64; o <<= 1)
#pragma unroll
    for (int nt = 0; nt < 4; ++nt) {
      ps[nt] += __shfl_xor(ps[nt], o);
      pq[nt] += __shfl_xor(pq[nt], o);
    }
  if (lq == 0) {
#pragma unroll
    for (int nt = 0; nt < 4; ++nt) {
      sred[w][nt * 16 + lm] = ps[nt];
      sred[w][64 + nt * 16 + lm] = pq[nt];
    }
  }
  __syncthreads();
  if (tid < 128) {
    float t = 0.f;
#pragma unroll
    for (int g = 0; g < 4; ++g) t += sred[g][tid];
    part[(long)blockIdx.x * 128 + tid] = t;
  }
}

// ---- fused MFMA: BN-apply(+residual into h) + xs = h@W (bf16) + al_s/al_d ----
// block = 256 thr (4 waves), 64 nodes; wave owns 16 rows. W packed B-frags (8 x 512).
__global__ __launch_bounds__(256) void xs_bn2(
    const float* __restrict__ z, const float* __restrict__ stats,
    const float* __restrict__ bng, const float* __restrict__ bnb,
    float* __restrict__ hbuf, int mode,
    const unsigned short* __restrict__ wgat,
    const float* __restrict__ a_s, const float* __restrict__ a_d,
    unsigned short* __restrict__ xsb, float* __restrict__ al_s, float* __restrict__ al_d,
    int n) {
  __shared__ __align__(16) unsigned short swg[4096];       // 8KB packed W
  __shared__ __align__(16) unsigned short shh[4][1024];    // per-wave h bf16, swizzled
  int tid = threadIdx.x, w = tid >> 6, lane = tid & 63;
  int lm = lane & 15, lq = lane >> 4;
  {
    const uint4* g = (const uint4*)wgat;
    uint4* s = (uint4*)swg;
    for (int i = tid; i < 512; i += 256) s[i] = g[i];
  }
  long nb = (long)blockIdx.x * 64;
  float sm = stats[lane], sv = stats[64 + lane], gg = bng[lane], bb = bnb[lane];
  // BN + residual -> hbuf (f32) and LDS (bf16, XOR-swizzled elements)
#pragma unroll
  for (int m = 0; m < 16; ++m) {
    long nd = nb + w * 16 + m;
    float hv = 0.f;
    if (nd < n) {
      float t = fmaxf((z[nd * 64 + lane] - sm) * sv * gg + bb, 0.f);
      hv = mode ? hbuf[nd * 64 + lane] + t : t;
      hbuf[nd * 64 + lane] = hv;
    }
    shh[w][m * 64 + (lane ^ ((m & 7) << 3))] = f2bf(hv);
  }
  __syncthreads();  // swg staged by all threads
  // GEMM: xs[16x64] = h @ W  (2 K-frags x 4 N-frags)
  f32x4 zero = {0.f, 0.f, 0.f, 0.f};
  f32x4 c[4];
#pragma unroll
  for (int nt = 0; nt < 4; ++nt) c[nt] = zero;
#pragma unroll
  for (int ks = 0; ks < 2; ++ks) {
    bf16x8 at = *(const bf16x8*)&shh[w][lm * 64 + ((ks * 32 + lq * 8) ^ ((lm & 7) << 3))];
#pragma unroll
    for (int nt = 0; nt < 4; ++nt) {
      bf16x8 bf = *(const bf16x8*)&swg[(nt * 2 + ks) * 512 + lane * 8];
      c[nt] = __builtin_amdgcn_mfma_f32_16x16x32_bf16(at, bf, c[nt], 0, 0, 0);
    }
  }
  // al_s / al_d from C-fragments: row = lq*4+r, col = nt*16+lm
  float asv[4], adv[4];
#pragma unroll
  for (int nt = 0; nt < 4; ++nt) { asv[nt] = a_s[nt * 16 + lm]; adv[nt] = a_d[nt * 16 + lm]; }
  float prs[4], prd[4];
#pragma unroll
  for (int r = 0; r < 4; ++r) {
    float s = 0.f, d = 0.f;
#pragma unroll
    for (int nt = 0; nt < 4; ++nt) {
      s += c[nt][r] * asv[nt];
      d += c[nt][r] * adv[nt];
    }
    prs[r] = s; prd[r] = d;
  }
#pragma unroll
  for (int o = 1; o < 16; o <<= 1)
#pragma unroll
    for (int r = 0; r < 4; ++r) {
      prs[r] += __shfl_xor(prs[r], o);
      prd[r] += __shfl_xor(prd[r], o);
    }
  // stores
#pragma unroll
  for (int nt = 0; nt < 4; ++nt)
#pragma unroll
    for (int r = 0; r < 4; ++r) {
      long nd = nb + w * 16 + lq * 4 + r;
      if (nd < n) xsb[nd * 64 + nt * 16 + lm] = f2bf(c[nt][r]);
    }
  if (lm == 0) {
#pragma unroll
    for (int r = 0; r < 4; ++r) {
      long nd = nb + w * 16 + lq * 4 + r;
      if (nd < n) { al_s[nd] = prs[r]; al_d[nd] = prd[r]; }
    }
  }
}

// ---------------- GAT: quarter-wave (16 lanes) per node, bf16 xs gather ----------------
#define QCAP 128
__global__ __launch_bounds__(256) void gat3(
    const int* __restrict__ off, const int2* __restrict__ csr,
    const float* __restrict__ ale,
    const float* __restrict__ al_s, const float* __restrict__ al_d,
    const unsigned short* __restrict__ xsb, const float* __restrict__ bias,
    float* __restrict__ gat_out, float* __restrict__ part, int n) {
  __shared__ float2 sal[16][QCAP];
  __shared__ float sred[4][128];
  int tid = threadIdx.x, w = tid >> 6, lane = tid & 63;
  int qt = tid >> 4, q = tid & 15;
  const uint2* xr = (const uint2*)xsb;
  float4 bv = *(const float4*)&bias[q * 4];
  float4 psum = make_float4(0.f, 0.f, 0.f, 0.f), psq = psum;
  for (int node = blockIdx.x * 16 + qt; node < n; node += gridDim.x * 16) {
    int s0 = off[node];
    int deg = off[node + 1] - s0;
    bool fits = (deg <= QCAP);
    float aldn = al_d[node];
    float lmax = -3.402823466e38f, lsae = 0.f;
    for (int k = q; k < deg; k += 16) {
      int2 ce = csr[s0 + k];
      float ae = ale[ce.y];
      float a = al_s[ce.x] + aldn + ae;
      float al = (a >= 0.f) ? a : 0.2f * a;
      lmax = fmaxf(lmax, al);
      lsae += ae;
      if (fits) sal[qt][k] = make_float2(al, __int_as_float(ce.x));
    }
#pragma unroll
    for (int o = 1; o < 16; o <<= 1) {
      lmax = fmaxf(lmax, __shfl_xor(lmax, o));
      lsae += __shfl_xor(lsae, o);
    }
    float ae_self = lsae / fmaxf((float)deg, 1.f);
    float a_self = al_s[node] + aldn + ae_self;
    float al_self = (a_self >= 0.f) ? a_self : 0.2f * a_self;
    float mx = fmaxf(lmax, al_self);
    float lsum = 0.f;
    if (fits) {
      for (int k = q; k < deg; k += 16) {
        float ex = __expf(sal[qt][k].x - mx);
        sal[qt][k].x = ex;
        lsum += ex;
      }
    } else {
      for (int k = q; k < deg; k += 16) {
        int2 ce = csr[s0 + k];
        float a = al_s[ce.x] + aldn + ale[ce.y];
        float al = (a >= 0.f) ? a : 0.2f * a;
        lsum += __expf(al - mx);
      }
    }
#pragma unroll
    for (int o = 1; o < 16; o <<= 1) lsum += __shfl_xor(lsum, o);
    float exs = __expf(al_self - mx);
    float inv = 1.f / (lsum + exs + 1e-16f);
    uint2 xv = xr[(long)node * 16 + q];
    float4 acc;
    acc.x = exs * bflo(xv.x); acc.y = exs * bfhi(xv.x);
    acc.z = exs * bflo(xv.y); acc.w = exs * bfhi(xv.y);
    if (fits) {
      int k = 0;
      for (; k + 4 <= deg; k += 4) {
        float2 p0 = sal[qt][k], p1 = sal[qt][k + 1], p2 = sal[qt][k + 2], p3 = sal[qt][k + 3];
        uint2 x0 = xr[(long)__float_as_int(p0.y) * 16 + q];
        uint2 x1 = xr[(long)__float_as_int(p1.y) * 16 + q];
        uint2 x2 = xr[(long)__float_as_int(p2.y) * 16 + q];
        uint2 x3 = xr[(long)__float_as_int(p3.y) * 16 + q];
        acc.x += p0.x * bflo(x0.x) + p1.x * bflo(x1.x) + p2.x * bflo(x2.x) + p3.x * bflo(x3.x);
        acc.y += p0.x * bfhi(x0.x) + p1.x * bfhi(x1.x) + p2.x * bfhi(x2.x) + p3.x * bfhi(x3.x);
        acc.z += p0.x * bflo(x0.y) + p1.x * bflo(x1.y) + p2.x * bflo(x2.y) + p3.x * bflo(x3.y);
        acc.w += p0.x * bfhi(x0.y) + p1.x * bfhi(x1.y) + p2.x * bfhi(x2.y) + p3.x * bfhi(x3.y);
      }
      for (; k < deg; ++k) {
        float2 p = sal[qt][k];
        uint2 xk = xr[(long)__float_as_int(p.y) * 16 + q];
        acc.x += p.x * bflo(xk.x); acc.y += p.x * bfhi(xk.x);
        acc.z += p.x * bflo(xk.y); acc.w += p.x * bfhi(xk.y);
      }
    } else {
      for (int k = 0; k < deg; ++k) {
        int2 ce = csr[s0 + k];
        float a = al_s[ce.x] + aldn + ale[ce.y];
        float al = (a >= 0.f) ? a : 0.2f * a;
        float ex = __expf(al - mx);
        uint2 xk = xr[(long)ce.x * 16 + q];
        acc.x += ex * bflo(xk.x); acc.y += ex * bfhi(xk.x);
        acc.z += ex * bflo(xk.y); acc.w += ex * bfhi(xk.y);
      }
    }
    acc.x = acc.x * inv + bv.x; acc.y = acc.y * inv + bv.y;
    acc.z = acc.z * inv + bv.z; acc.w = acc.w * inv + bv.w;
    *(float4*)&gat_out[(long)node * 64 + q * 4] = acc;
    psum.x += acc.x; psum.y += acc.y; psum.z += acc.z; psum.w += acc.w;
    psq.x += acc.x * acc.x; psq.y += acc.y * acc.y; psq.z += acc.z * acc.z; psq.w += acc.w * acc.w;
  }
#pragma unroll
  for (int o = 16; o < 64; o <<= 1) {
    psum.x += __shfl_xor(psum.x, o); psum.y += __shfl_xor(psum.y, o);
    psum.z += __shfl_xor(psum.z, o); psum.w += __shfl_xor(psum.w, o);
    psq.x += __shfl_xor(psq.x, o); psq.y += __shfl_xor(psq.y, o);
    psq.z += __shfl_xor(psq.z, o); psq.w += __shfl_xor(psq.w, o);
  }
  if (lane < 16) {
    sred[w][lane * 4 + 0] = psum.x; sred[w][lane * 4 + 1] = psum.y;
    sred[w][lane * 4 + 2] = psum.z; sred[w][lane * 4 + 3] = psum.w;
    sred[w][64 + lane * 4 + 0] = psq.x; sred[w][64 + lane * 4 + 1] = psq.y;
    sred[w][64 + lane * 4 + 2] = psq.z; sred[w][64 + lane * 4 + 3] = psq.w;
  }
  __syncthreads();
  if (tid < 128)
    part[(long)blockIdx.x * 128 + tid] =
        sred[0][tid] + sred[1][tid] + sred[2][tid] + sred[3][tid];
}

// ---------------- BN finalize ----------------
__global__ __launch_bounds__(1024) void bn_finalize(const float* __restrict__ part, int nblk,
                                                    float invN, float* __restrict__ stats) {
  __shared__ float sh[1024];
  int t = threadIdx.x;
  int c = t & 127, g = t >> 7;
  float s = 0.f;
  for (int b = g; b < nblk; b += 8) s += part[(long)b * 128 + c];
  sh[t] = s;
  __syncthreads();
  if (t < 128) {
    float tot = 0.f;
#pragma unroll
    for (int g2 = 0; g2 < 8; ++g2) tot += sh[g2 * 128 + t];
    sh[t] = tot;
  }
  __syncthreads();
  if (t < 64) {
    float mean = sh[t] * invN;
    float var = sh[64 + t] * invN - mean * mean;
    stats[t] = mean;
    stats[64 + t] = rsqrtf(var + 1e-5f);
  }
}

// ---- fused: last BN-apply + residual + global mean partials (no h write) ----
__global__ void gsum_bn(const float* __restrict__ z, const float* __restrict__ stats,
                        const float* __restrict__ bng, const float* __restrict__ bnb,
                        const float* __restrict__ hprev, int n, float* __restrict__ part) {
  __shared__ float sh[4][64];
  int tid = threadIdx.x, w = tid >> 6, lane = tid & 63;
  float sm = stats[lane], sv = stats[64 + lane], gg = bng[lane], bb = bnb[lane];
  int gw = blockIdx.x * 4 + w, nW = gridDim.x * 4;
  float s = 0.f;
  for (int node = gw; node < n; node += nW) {
    float t = fmaxf((z[(long)node * 64 + lane] - sm) * sv * gg + bb, 0.f);
    s += hprev[(long)node * 64 + lane] + t;
  }
  sh[w][lane] = s;
  __syncthreads();
  if (tid < 64)
    part[(long)blockIdx.x * 64 + tid] =
        sh[0][tid] + sh[1][tid] + sh[2][tid] + sh[3][tid];
}

__global__ void final_kernel(const float* __restrict__ part, int nblk,
                             const float* __restrict__ out_W, const float* __restrict__ out_b,
                             float* __restrict__ out, float invN) {
  __shared__ float g[64];
  int c = threadIdx.x;  // 64 threads
  float s = 0.f;
  for (int b = 0; b < nblk; ++b) s += part[(long)b * 64 + c];
  g[c] = s * invN;
  __syncthreads();
  float acc = out_b[c];
  for (int k = 0; k < 64; ++k) acc += g[k] * out_W[k * 64 + c];
  out[c] = fmaxf(acc, 0.f);
}

// ---------------- host launch ----------------
extern "C" void kernel_launch(void* const* d_in, const int* in_sizes, int n_in,
                              void* d_out, int out_size, void* d_ws, size_t ws_size,
                              hipStream_t stream) {
  const float* x        = (const float*)d_in[0];
  const int*   eidx     = (const int*)d_in[1];
  const float* eattr    = (const float*)d_in[2];
  const float* np_W1    = (const float*)d_in[3];
  const float* np_b1    = (const float*)d_in[4];
  const float* np_W2    = (const float*)d_in[5];
  const float* np_b2    = (const float*)d_in[6];
  const float* np_ln_g  = (const float*)d_in[7];
  const float* np_ln_b  = (const float*)d_in[8];
  const float* ep_W1    = (const float*)d_in[9];
  const float* ep_b1    = (const float*)d_in[10];
  const float* ep_W2    = (const float*)d_in[11];
  const float* ep_b2    = (const float*)d_in[12];
  const float* ep_ln_g  = (const float*)d_in[13];
  const float* ep_ln_b  = (const float*)d_in[14];
  const float* enc_W    = (const float*)d_in[15];
  const float* enc_b    = (const float*)d_in[16];
  const float* enc_bn_g = (const float*)d_in[17];
  const float* enc_bn_b = (const float*)d_in[18];
  const float* gat_W    = (const float*)d_in[19];
  const float* gat_eW   = (const float*)d_in[20];
  const float* att_src  = (const float*)d_in[21];
  const float* att_dst  = (const float*)d_in[22];
  const float* att_edge = (const float*)d_in[23];
  const float* gat_b    = (const float*)d_in[24];
  const float* bn_g     = (const float*)d_in[25];
  const float* bn_b     = (const float*)d_in[26];
  const float* out_W    = (const float*)d_in[27];
  const float* out_b    = (const float*)d_in[28];

  const int n = in_sizes[0] / 128;   // 50000
  const int ne = in_sizes[1] / 2;    // 800000
  const int* srcp = eidx;
  const int* dstp = eidx + ne;

  float* f = (float*)d_ws;
  float* hbuf  = f; f += (long)n * 64;
  float* zbuf  = f; f += (long)n * 64;   // also reused as int2 csrt scratch pre-node_pre3
  float* alsb  = f; f += n;
  float* aldb  = f; f += n;
  float* ale   = f; f += 3L * ne;
  float* vgbuf = f; f += 128;
  float* stats = f; f += 128;
  float* part  = f; f += 131072;      // 1024 x 128
  float* part2 = f; f += 16384;       // 256 x 64
  unsigned short* wbb   = (unsigned short*)f; f += 2048;          // edge weights
  unsigned short* wnb   = (unsigned short*)f; f += 36864;         // node weights
  unsigned short* wgatb = (unsigned short*)f; f += 6144;          // 3 x 4096 gat weights
  unsigned short* xsb   = (unsigned short*)f; f += (long)n * 32;  // n*64 bf16
  int* ip = (int*)f;
  int2* csr = (int2*)ip; ip += 2L * ne;
  int* degb = ip; ip += n;
  int* cntb = ip; ip += n;
  int* offb = ip; ip += n + 1;
  int2* csrt = (int2*)zbuf;  // ne*8B = 6.4MB <= zbuf 12.8MB; dead until node_pre3

  const int nbEdge = (ne + EB - 1) / EB;     // 6250
  const int nbNode = (n + 63) / 64;          // 782

  hipMemsetAsync(degb, 0, (size_t)n * sizeof(int), stream);
  hipMemsetAsync(cntb, 0, (size_t)n * sizeof(int), stream);
  vprep2<<<1, 128, 0, stream>>>(gat_eW, att_edge, ep_ln_g, ep_ln_b, vgbuf);
  wpack<<<1, 256, 0, stream>>>(ep_W1, ep_W2, wbb);
  npack<<<288, 256, 0, stream>>>(np_W1, np_W2, enc_W, wnb);
  gpack<<<48, 256, 0, stream>>>(gat_W, wgatb);
  deg_kernel<<<1024, 256, 0, stream>>>(dstp, ne, degb);
  scan2<<<1, 1024, 0, stream>>>(degb, offb, n);
  scatter_kernel<<<1024, 256, 0, stream>>>(srcp, dstp, ne, offb, cntb, csrt);
  csr_sort<<<1024, 256, 0, stream>>>(offb, csrt, csr, n);
  edge_pre3<<<nbEdge, 256, 0, stream>>>(eattr, wbb, ep_b1, ep_b2, vgbuf, ale, ne);
  node_pre3<<<nbNode, 256, 0, stream>>>(x, wnb, np_b1, np_b2, np_ln_g, np_ln_b,
                                        enc_b, zbuf, part, n);
  bn_finalize<<<1, 1024, 0, stream>>>(part, nbNode, 1.f / n, stats);
  xs_bn2<<<nbNode, 256, 0, stream>>>(zbuf, stats, enc_bn_g, enc_bn_b, hbuf, 0,
                                     wgatb, att_src, att_dst, xsb, alsb, aldb, n);
  for (int l = 0; l < 3; ++l) {
    gat3<<<1024, 256, 0, stream>>>(offb, csr, ale + (long)l * ne, alsb, aldb,
                                   xsb, gat_b + l * 64, zbuf, part, n);
    bn_finalize<<<1, 1024, 0, stream>>>(part, 1024, 1.f / n, stats);
    if (l < 2) {
      xs_bn2<<<nbNode, 256, 0, stream>>>(zbuf, stats, bn_g + l * 64, bn_b + l * 64, hbuf, 1,
                                         wgatb + (long)(l + 1) * 4096,
                                         att_src + (l + 1) * 64, att_dst + (l + 1) * 64,
                                         xsb, alsb, aldb, n);
    } else {
      gsum_bn<<<256, 256, 0, stream>>>(zbuf, stats, bn_g + l * 64, bn_b + l * 64,
                                       hbuf, n, part2);
    }
  }
  final_kernel<<<1, 64, 0, stream>>>(part2, 256, out_W, out_b, (float*)d_out, 1.f / n);
}

// Round 8
// 574.187 us; speedup vs baseline: 3.4152x; 1.1218x over previous
//
#include <hip/hip_runtime.h>
#include <hip/hip_bf16.h>

// GNNEncoder on MI355X. Algebraic reductions:
//  - (ea@eW)@a_e == ea@(eW@a_e): only 3 scalars al_e per edge needed.
//  - loop_attr contribution == mean(incoming al_e) by linearity.
//  - edge LN+dot folded: al = istd*(sum y*(g*v) - mean*G) + C.
// dst-CSR built once; scatter order from atomics made DETERMINISTIC by a
// per-segment sort on edge id (csr_sort) -- graph-replay == launch_once bitwise.
// edge_pre3 / node_pre3 / xs_bn2: MFMA bf16, weights pre-packed into B-fragment
// order, tiny per-lane state (no scratch traffic), XOR-swizzled LDS activations.
// scan: 3-phase multi-block prefix sum (round-7 fix: single-block scan was 78us).

typedef short bf16x8 __attribute__((ext_vector_type(8)));
typedef float f32x4 __attribute__((ext_vector_type(4)));
union U8 { uint4 u; bf16x8 v; };

__device__ __forceinline__ unsigned pack2bf(float a, float b) {
  unsigned ua = __float_as_uint(a); ua += 0x7fffu + ((ua >> 16) & 1u);
  unsigned ub = __float_as_uint(b); ub += 0x7fffu + ((ub >> 16) & 1u);
  return (ua >> 16) | (ub & 0xffff0000u);
}
__device__ __forceinline__ unsigned short f2bf(float x) {
  unsigned u = __float_as_uint(x); u += 0x7fffu + ((u >> 16) & 1u);
  return (unsigned short)(u >> 16);
}
__device__ __forceinline__ float bflo(unsigned u) { return __uint_as_float(u << 16); }
__device__ __forceinline__ float bfhi(unsigned u) { return __uint_as_float(u & 0xffff0000u); }

// ---------------- prep: v = eW@a_e, gv = lng*v, G = sum(lng*v), C = sum(lnb*v) ----------------
__global__ void vprep2(const float* __restrict__ eW, const float* __restrict__ a_e,
                       const float* __restrict__ lng, const float* __restrict__ lnb,
                       float* __restrict__ vg) {
  __shared__ float sv[96];
  int t = threadIdx.x;  // 128 threads
  if (t < 96) {
    int l = t >> 5, i = t & 31;
    const float* w = eW + l * 2048 + i * 64;
    const float* a = a_e + l * 64;
    float s = 0.f;
    for (int c = 0; c < 64; ++c) s += w[c] * a[c];
    sv[t] = s;
    vg[t] = s * lng[i];
  }
  __syncthreads();
  if (t < 3) {
    float G = 0.f, C = 0.f;
    for (int i = 0; i < 32; ++i) {
      float vv = sv[t * 32 + i];
      G += lng[i] * vv;
      C += lnb[i] * vv;
    }
    vg[96 + t] = G;
    vg[99 + t] = C;
  }
}

// pack W1[32x64], W2[64x32] into bf16 MFMA B-fragment order (edge MLP).
__global__ void wpack(const float* __restrict__ W1, const float* __restrict__ W2,
                      unsigned short* __restrict__ wb) {
  int t = threadIdx.x;  // 256
  for (int i = t; i < 2048; i += 256) {
    int nt = i >> 9, rem = i & 511, l = rem >> 3, j = rem & 7;
    int k = ((l >> 4) << 3) + j, col = (nt << 4) + (l & 15);
    wb[i] = f2bf(W1[k * 64 + col]);
  }
  for (int i = t; i < 2048; i += 256) {
    int sn = i >> 9, rem = i & 511, l = rem >> 3, j = rem & 7;
    int s = sn >> 1, nt = sn & 1;
    int k = s * 32 + ((l >> 4) << 3) + j, col = (nt << 4) + (l & 15);
    wb[2048 + i] = f2bf(W2[k * 32 + col]);
  }
}

// pack node-path weights: np_W1[128x256] (64 frags), np_W2[256x128] (64), enc_W[128x64] (16)
__global__ void npack(const float* __restrict__ W1, const float* __restrict__ W2,
                      const float* __restrict__ eW, unsigned short* __restrict__ wnb) {
  int i = blockIdx.x * blockDim.x + threadIdx.x;  // 73728 total
  if (i < 32768) {
    int fi = i >> 9, rem = i & 511, l = rem >> 3, j = rem & 7;
    int nt = fi >> 2, ks = fi & 3;
    int k = ks * 32 + ((l >> 4) << 3) + j, col = nt * 16 + (l & 15);
    wnb[i] = f2bf(W1[k * 256 + col]);
  } else if (i < 65536) {
    int i2 = i - 32768;
    int fi = i2 >> 9, rem = i2 & 511, l = rem >> 3, j = rem & 7;
    int nt = fi >> 3, ks = fi & 7;
    int k = ks * 32 + ((l >> 4) << 3) + j, col = nt * 16 + (l & 15);
    wnb[i] = f2bf(W2[k * 128 + col]);
  } else if (i < 73728) {
    int i3 = i - 65536;
    int fi = i3 >> 9, rem = i3 & 511, l = rem >> 3, j = rem & 7;
    int nt = fi >> 2, ks = fi & 3;
    int k = ks * 32 + ((l >> 4) << 3) + j, col = nt * 16 + (l & 15);
    wnb[i] = f2bf(eW[k * 64 + col]);
  }
}

// pack gat_W[3][64][64] into B-frag order: per layer 8 frags [nt*2+ks]
__global__ void gpack(const float* __restrict__ W, unsigned short* __restrict__ wg) {
  int i = blockIdx.x * blockDim.x + threadIdx.x;  // 12288 total
  if (i < 12288) {
    int l = i >> 12, rem = i & 4095;
    int fi = rem >> 9, l8 = rem & 511, ln = l8 >> 3, j = l8 & 7;
    int nt = fi >> 1, ks = fi & 1;
    int k = ks * 32 + ((ln >> 4) << 3) + j, col = nt * 16 + (ln & 15);
    wg[i] = f2bf(W[l * 4096 + k * 64 + col]);
  }
}

__global__ void deg_kernel(const int* __restrict__ dst, int ne, int* __restrict__ deg) {
  int i = blockIdx.x * blockDim.x + threadIdx.x;
  int stride = gridDim.x * blockDim.x;
  for (; i < ne; i += stride) atomicAdd(&deg[dst[i]], 1);
}

// ---- 3-phase multi-block scan ----
__global__ __launch_bounds__(256) void scan_blk(const int* __restrict__ deg,
                                                int* __restrict__ off,
                                                int* __restrict__ bsum, int n) {
  __shared__ int wsum[4];
  int b = blockIdx.x, t = threadIdx.x;
  int i = b * 256 + t;
  int lane = t & 63, w = t >> 6;
  int v = (i < n) ? deg[i] : 0;
  int s = v;
#pragma unroll
  for (int o = 1; o < 64; o <<= 1) {
    int u = __shfl_up(s, o);
    if (lane >= o) s += u;
  }
  if (lane == 63) wsum[w] = s;
  __syncthreads();
  int add = 0;
#pragma unroll
  for (int ww = 0; ww < 4; ++ww) add += (ww < w) ? wsum[ww] : 0;
  s += add;
  if (i < n) off[i + 1] = s;
  if (t == 255) bsum[b] = s;
}

__global__ __launch_bounds__(256) void scan_bsum(int* __restrict__ bsum, int nb) {
  __shared__ int sh[256];
  int t = threadIdx.x;
  sh[t] = (t < nb) ? bsum[t] : 0;
  __syncthreads();
  for (int o = 1; o < 256; o <<= 1) {
    int u = (t >= o) ? sh[t - o] : 0;
    __syncthreads();
    sh[t] += u;
    __syncthreads();
  }
  if (t < nb) bsum[t] = (t == 0) ? 0 : sh[t - 1];
}

__global__ __launch_bounds__(256) void scan_add(const int* __restrict__ bsum,
                                                int* __restrict__ off, int n) {
  int b = blockIdx.x, t = threadIdx.x;
  int i = b * 256 + t;
  int add = bsum[b];
  if (i < n) off[i + 1] += add;
  if (i == 0) off[0] = 0;
}

__global__ void scatter_kernel(const int* __restrict__ src, const int* __restrict__ dst,
                               int ne, const int* __restrict__ off, int* __restrict__ cnt,
                               int2* __restrict__ csrt) {
  int i = blockIdx.x * blockDim.x + threadIdx.x;
  int stride = gridDim.x * blockDim.x;
  for (; i < ne; i += stride) {
    int d = dst[i];
    int p = off[d] + atomicAdd(&cnt[d], 1);
    csrt[p] = make_int2(src[i], i);
  }
}

// ---- deterministic per-segment sort by edge id ----
#define SCAP 128
__global__ __launch_bounds__(256) void csr_sort(const int* __restrict__ off,
                                                const int2* __restrict__ csrt,
                                                int2* __restrict__ csr, int n) {
  __shared__ int seid[16][SCAP];
  int tid = threadIdx.x;
  int qt = tid >> 4, q = tid & 15;
  for (int node = blockIdx.x * 16 + qt; node < n; node += gridDim.x * 16) {
    int s0 = off[node], deg = off[node + 1] - s0;
    if (deg <= SCAP) {
      for (int k = q; k < deg; k += 16) seid[qt][k] = csrt[s0 + k].y;
      for (int k = q; k < deg; k += 16) {
        int e = seid[qt][k];
        int r = 0;
        for (int m = 0; m < deg; ++m) r += (seid[qt][m] < e) ? 1 : 0;
        csr[s0 + r] = csrt[s0 + k];
      }
    } else {
      for (int k = q; k < deg; k += 16) {
        int e = csrt[s0 + k].y;
        int r = 0;
        for (int m = 0; m < deg; ++m) r += (csrt[s0 + m].y < e) ? 1 : 0;
        csr[s0 + r] = csrt[s0 + k];
      }
    }
  }
}

// ---------------- edge preproc v3: MFMA. block=256 (4 waves), 128 edges ----------------
#define EB 128
__global__ __launch_bounds__(256) void edge_pre3(
    const float* __restrict__ ea, const unsigned short* __restrict__ wb,
    const float* __restrict__ b1, const float* __restrict__ b2,
    const float* __restrict__ vg, float* __restrict__ ale, int ne) {
  __shared__ __align__(16) unsigned short swb[4096];
  __shared__ __align__(16) unsigned short sT[4][32 * 72];
  int tid = threadIdx.x, w = tid >> 6, lane = tid & 63;
  {
    const uint4* g = (const uint4*)wb;
    uint4* s = (uint4*)swb;
    for (int i = tid; i < 512; i += 256) s[i] = g[i];
  }
  __syncthreads();
  int lm = lane & 15, lq = lane >> 4;
  long e0 = (long)blockIdx.x * EB + w * 32;
  bf16x8 afr[2];
#pragma unroll
  for (int h = 0; h < 2; ++h) {
    long e = e0 + h * 16 + lm;
    if (e >= ne) e = ne - 1;
    const float4* p = (const float4*)(ea + e * 32 + lq * 8);
    float4 u = p[0], v = p[1];
    U8 cc;
    cc.u = make_uint4(pack2bf(u.x, u.y), pack2bf(u.z, u.w), pack2bf(v.x, v.y), pack2bf(v.z, v.w));
    afr[h] = cc.v;
  }
  f32x4 zero = {0.f, 0.f, 0.f, 0.f};
  f32x4 c1[2][4];
#pragma unroll
  for (int h = 0; h < 2; ++h)
#pragma unroll
    for (int nt = 0; nt < 4; ++nt) c1[h][nt] = zero;
#pragma unroll
  for (int nt = 0; nt < 4; ++nt) {
    bf16x8 bf = *(const bf16x8*)&swb[nt * 512 + lane * 8];
#pragma unroll
    for (int h = 0; h < 2; ++h)
      c1[h][nt] = __builtin_amdgcn_mfma_f32_16x16x32_bf16(afr[h], bf, c1[h][nt], 0, 0, 0);
  }
  {
    float b1v[4];
#pragma unroll
    for (int nt = 0; nt < 4; ++nt) b1v[nt] = b1[nt * 16 + lm];
#pragma unroll
    for (int h = 0; h < 2; ++h)
#pragma unroll
      for (int nt = 0; nt < 4; ++nt)
#pragma unroll
        for (int r = 0; r < 4; ++r) {
          float tv = fmaxf(c1[h][nt][r] + b1v[nt], 0.f);
          sT[w][(h * 16 + lq * 4 + r) * 72 + nt * 16 + lm] = f2bf(tv);
        }
  }
  __syncthreads();
  f32x4 c2[2][2];
#pragma unroll
  for (int h = 0; h < 2; ++h)
#pragma unroll
    for (int nt = 0; nt < 2; ++nt) c2[h][nt] = zero;
#pragma unroll
  for (int h = 0; h < 2; ++h)
#pragma unroll
    for (int s = 0; s < 2; ++s) {
      bf16x8 at = *(const bf16x8*)&sT[w][(h * 16 + lm) * 72 + s * 32 + lq * 8];
#pragma unroll
      for (int nt = 0; nt < 2; ++nt) {
        bf16x8 bf = *(const bf16x8*)&swb[2048 + (s * 2 + nt) * 512 + lane * 8];
        c2[h][nt] = __builtin_amdgcn_mfma_f32_16x16x32_bf16(at, bf, c2[h][nt], 0, 0, 0);
      }
    }
  float b2v0 = b2[lm], b2v1 = b2[16 + lm];
  float gv00 = vg[lm], gv01 = vg[16 + lm];
  float gv10 = vg[32 + lm], gv11 = vg[48 + lm];
  float gv20 = vg[64 + lm], gv21 = vg[80 + lm];
  float G0 = vg[96], G1 = vg[97], G2 = vg[98];
  float C0 = vg[99], C1 = vg[100], C2 = vg[101];
#pragma unroll
  for (int h = 0; h < 2; ++h) {
    float s4[4], q4[4], d0[4], d1[4], d2[4];
#pragma unroll
    for (int r = 0; r < 4; ++r) {
      float ya = c2[h][0][r] + b2v0;
      float yb = c2[h][1][r] + b2v1;
      s4[r] = ya + yb;
      q4[r] = ya * ya + yb * yb;
      d0[r] = ya * gv00 + yb * gv01;
      d1[r] = ya * gv10 + yb * gv11;
      d2[r] = ya * gv20 + yb * gv21;
    }
#pragma unroll
    for (int o = 1; o < 16; o <<= 1) {
#pragma unroll
      for (int r = 0; r < 4; ++r) {
        s4[r] += __shfl_xor(s4[r], o);
        q4[r] += __shfl_xor(q4[r], o);
        d0[r] += __shfl_xor(d0[r], o);
        d1[r] += __shfl_xor(d1[r], o);
        d2[r] += __shfl_xor(d2[r], o);
      }
    }
    if (lm < 4) {
      int r = lm;
      long e = e0 + h * 16 + lq * 4 + r;
      if (e < ne) {
        float mean = s4[r] * (1.f / 32.f);
        float var = q4[r] * (1.f / 32.f) - mean * mean;
        float istd = rsqrtf(var + 1e-5f);
        ale[e] = istd * (d0[r] - mean * G0) + C0;
        ale[(long)ne + e] = istd * (d1[r] - mean * G1) + C1;
        ale[2L * ne + e] = istd * (d2[r] - mean * G2) + C2;
      }
    }
  }
}

// ---------------- node preproc v3: MFMA. block=256 (4 waves), 64 nodes ----------------
__global__ __launch_bounds__(256, 2) void node_pre3(
    const float* __restrict__ x, const unsigned short* __restrict__ wnb,
    const float* __restrict__ b1, const float* __restrict__ b2,
    const float* __restrict__ lng, const float* __restrict__ lnb,
    const float* __restrict__ encb, float* __restrict__ z_out,
    float* __restrict__ part, int n) {
  __shared__ __align__(16) unsigned short swb[16384];      // 32KB weight chunk
  __shared__ __align__(16) unsigned short sT[4][16 * 264]; // per-wave T / h1
  __shared__ float sred[4][128];
  int tid = threadIdx.x, w = tid >> 6, lane = tid & 63;
  int lm = lane & 15, lq = lane >> 4;
  long nb = (long)blockIdx.x * 64;
  const uint4* wg = (const uint4*)wnb;
  f32x4 zero = {0.f, 0.f, 0.f, 0.f};

  long row = nb + w * 16 + lm;
  if (row >= n) row = n - 1;
  bf16x8 ax[4];
  const float4* xp = (const float4*)(x + row * 128);
#pragma unroll
  for (int ks = 0; ks < 4; ++ks) {
    float4 u = xp[ks * 8 + lq * 2];
    float4 v = xp[ks * 8 + lq * 2 + 1];
    U8 cc;
    cc.u = make_uint4(pack2bf(u.x, u.y), pack2bf(u.z, u.w), pack2bf(v.x, v.y), pack2bf(v.z, v.w));
    ax[ks] = cc.v;
  }

  for (int h01 = 0; h01 < 2; ++h01) {
    __syncthreads();
    {
      const uint4* src = wg + h01 * 2048;
      uint4* dstv = (uint4*)swb;
      for (int i = tid; i < 2048; i += 256) dstv[i] = src[i];
    }
    __syncthreads();
    f32x4 acc1[8];
#pragma unroll
    for (int nt8 = 0; nt8 < 8; ++nt8) acc1[nt8] = zero;
#pragma unroll
    for (int ks = 0; ks < 4; ++ks)
#pragma unroll
      for (int nt8 = 0; nt8 < 8; ++nt8) {
        bf16x8 bf = *(const bf16x8*)&swb[(nt8 * 4 + ks) * 512 + lane * 8];
        acc1[nt8] = __builtin_amdgcn_mfma_f32_16x16x32_bf16(ax[ks], bf, acc1[nt8], 0, 0, 0);
      }
#pragma unroll
    for (int nt8 = 0; nt8 < 8; ++nt8) {
      int col = (h01 * 8 + nt8) * 16 + lm;
      float bv = b1[col];
#pragma unroll
      for (int r = 0; r < 4; ++r) {
        int rr = lq * 4 + r;
        sT[w][rr * 264 + (col ^ ((rr & 7) << 3))] = f2bf(fmaxf(acc1[nt8][r] + bv, 0.f));
      }
    }
  }

  f32x4 c2[8];
#pragma unroll
  for (int nt = 0; nt < 8; ++nt) c2[nt] = zero;
  for (int ksh = 0; ksh < 2; ++ksh) {
    __syncthreads();
    {
      uint4* dstv = (uint4*)swb;
      for (int i4 = tid; i4 < 2048; i4 += 256) {
        int e = i4 * 8;
        int fc = e >> 9, nt = fc >> 2, ksl = fc & 3;
        int ks = ksh * 4 + ksl;
        long gi = 32768 + (long)(nt * 8 + ks) * 512 + (e & 511);
        dstv[i4] = wg[gi >> 3];
      }
    }
    __syncthreads();
#pragma unroll
    for (int ksl = 0; ksl < 4; ++ksl) {
      int ks = ksh * 4 + ksl;
      bf16x8 at = *(const bf16x8*)&sT[w][lm * 264 + ((ks * 32 + lq * 8) ^ ((lm & 7) << 3))];
#pragma unroll
      for (int nt = 0; nt < 8; ++nt) {
        bf16x8 bf = *(const bf16x8*)&swb[(nt * 4 + ksl) * 512 + lane * 8];
        c2[nt] = __builtin_amdgcn_mfma_f32_16x16x32_bf16(at, bf, c2[nt], 0, 0, 0);
      }
    }
  }

  {
    float yv[8][4], bcol[8], gcol[8], ocol[8];
#pragma unroll
    for (int nt = 0; nt < 8; ++nt) {
      int col = nt * 16 + lm;
      bcol[nt] = b2[col]; gcol[nt] = lng[col]; ocol[nt] = lnb[col];
    }
    float s4[4], q4[4];
#pragma unroll
    for (int r = 0; r < 4; ++r) { s4[r] = 0.f; q4[r] = 0.f; }
#pragma unroll
    for (int nt = 0; nt < 8; ++nt)
#pragma unroll
      for (int r = 0; r < 4; ++r) {
        float y = c2[nt][r] + bcol[nt];
        yv[nt][r] = y;
        s4[r] += y; q4[r] += y * y;
      }
#pragma unroll
    for (int o = 1; o < 16; o <<= 1)
#pragma unroll
      for (int r = 0; r < 4; ++r) {
        s4[r] += __shfl_xor(s4[r], o);
        q4[r] += __shfl_xor(q4[r], o);
      }
#pragma unroll
    for (int r = 0; r < 4; ++r) {
      float mean = s4[r] * (1.f / 128.f);
      float var = q4[r] * (1.f / 128.f) - mean * mean;
      float istd = rsqrtf(var + 1e-5f);
      int rr = lq * 4 + r;
#pragma unroll
      for (int nt = 0; nt < 8; ++nt) {
        float hv = (yv[nt][r] - mean) * istd * gcol[nt] + ocol[nt];
        int col = nt * 16 + lm;
        if (col < 128)
          sT[w][rr * 264 + (col ^ ((rr & 7) << 3))] = f2bf(hv);
      }
    }
  }

  __syncthreads();
  {
    uint4* dstv = (uint4*)swb;
    const uint4* src = wg + (65536 >> 3);
    for (int i = tid; i < 1024; i += 256) dstv[i] = src[i];
  }
  __syncthreads();
  f32x4 c3[4];
#pragma unroll
  for (int nt = 0; nt < 4; ++nt) c3[nt] = zero;
#pragma unroll
  for (int ks = 0; ks < 4; ++ks) {
    bf16x8 at = *(const bf16x8*)&sT[w][lm * 264 + ((ks * 32 + lq * 8) ^ ((lm & 7) << 3))];
#pragma unroll
    for (int nt = 0; nt < 4; ++nt) {
      bf16x8 bf = *(const bf16x8*)&swb[(nt * 4 + ks) * 512 + lane * 8];
      c3[nt] = __builtin_amdgcn_mfma_f32_16x16x32_bf16(at, bf, c3[nt], 0, 0, 0);
    }
  }
  float ps[4], pq[4];
#pragma unroll
  for (int nt = 0; nt < 4; ++nt) { ps[nt] = 0.f; pq[nt] = 0.f; }
#pragma unroll
  for (int nt = 0; nt < 4; ++nt) {
    int col = nt * 16 + lm;
    float eb = encb[col];
#pragma unroll
    for (int r = 0; r < 4; ++r) {
      long nd = nb + w * 16 + lq * 4 + r;
      float z = c3[nt][r] + eb;
      if (nd < n) {
        z_out[nd * 64 + col] = z;
        ps[nt] += z; pq[nt] += z * z;
      }
    }
  }
#pragma unroll
  for (int o = 16; o < 64; o <<= 1)
#pragma unroll
    for (int nt = 0; nt < 4; ++nt) {
      ps[nt] += __shfl_xor(ps[nt], o);
      pq[nt] += __shfl_xor(pq[nt], o);
    }
  if (lq == 0) {
#pragma unroll
    for (int nt = 0; nt < 4; ++nt) {
      sred[w][nt * 16 + lm] = ps[nt];
      sred[w][64 + nt * 16 + lm] = pq[nt];
    }
  }
  __syncthreads();
  if (tid < 128) {
    float t = 0.f;
#pragma unroll
    for (int g = 0; g < 4; ++g) t += sred[g][tid];
    part[(long)blockIdx.x * 128 + tid] = t;
  }
}

// ---- fused MFMA: BN-apply(+residual into h) + xs = h@W (bf16) + al_s/al_d ----
__global__ __launch_bounds__(256) void xs_bn2(
    const float* __restrict__ z, const float* __restrict__ stats,
    const float* __restrict__ bng, const float* __restrict__ bnb,
    float* __restrict__ hbuf, int mode,
    const unsigned short* __restrict__ wgat,
    const float* __restrict__ a_s, const float* __restrict__ a_d,
    unsigned short* __restrict__ xsb, float* __restrict__ al_s, float* __restrict__ al_d,
    int n) {
  __shared__ __align__(16) unsigned short swg[4096];       // 8KB packed W
  __shared__ __align__(16) unsigned short shh[4][1024];    // per-wave h bf16, swizzled
  int tid = threadIdx.x, w = tid >> 6, lane = tid & 63;
  int lm = lane & 15, lq = lane >> 4;
  {
    const uint4* g = (const uint4*)wgat;
    uint4* s = (uint4*)swg;
    for (int i = tid; i < 512; i += 256) s[i] = g[i];
  }
  long nb = (long)blockIdx.x * 64;
  float sm = stats[lane], sv = stats[64 + lane], gg = bng[lane], bb = bnb[lane];
#pragma unroll
  for (int m = 0; m < 16; ++m) {
    long nd = nb + w * 16 + m;
    float hv = 0.f;
    if (nd < n) {
      float t = fmaxf((z[nd * 64 + lane] - sm) * sv * gg + bb, 0.f);
      hv = mode ? hbuf[nd * 64 + lane] + t : t;
      hbuf[nd * 64 + lane] = hv;
    }
    shh[w][m * 64 + (lane ^ ((m & 7) << 3))] = f2bf(hv);
  }
  __syncthreads();
  f32x4 zero = {0.f, 0.f, 0.f, 0.f};
  f32x4 c[4];
#pragma unroll
  for (int nt = 0; nt < 4; ++nt) c[nt] = zero;
#pragma unroll
  for (int ks = 0; ks < 2; ++ks) {
    bf16x8 at = *(const bf16x8*)&shh[w][lm * 64 + ((ks * 32 + lq * 8) ^ ((lm & 7) << 3))];
#pragma unroll
    for (int nt = 0; nt < 4; ++nt) {
      bf16x8 bf = *(const bf16x8*)&swg[(nt * 2 + ks) * 512 + lane * 8];
      c[nt] = __builtin_amdgcn_mfma_f32_16x16x32_bf16(at, bf, c[nt], 0, 0, 0);
    }
  }
  float asv[4], adv[4];
#pragma unroll
  for (int nt = 0; nt < 4; ++nt) { asv[nt] = a_s[nt * 16 + lm]; adv[nt] = a_d[nt * 16 + lm]; }
  float prs[4], prd[4];
#pragma unroll
  for (int r = 0; r < 4; ++r) {
    float s = 0.f, d = 0.f;
#pragma unroll
    for (int nt = 0; nt < 4; ++nt) {
      s += c[nt][r] * asv[nt];
      d += c[nt][r] * adv[nt];
    }
    prs[r] = s; prd[r] = d;
  }
#pragma unroll
  for (int o = 1; o < 16; o <<= 1)
#pragma unroll
    for (int r = 0; r < 4; ++r) {
      prs[r] += __shfl_xor(prs[r], o);
      prd[r] += __shfl_xor(prd[r], o);
    }
#pragma unroll
  for (int nt = 0; nt < 4; ++nt)
#pragma unroll
    for (int r = 0; r < 4; ++r) {
      long nd = nb + w * 16 + lq * 4 + r;
      if (nd < n) xsb[nd * 64 + nt * 16 + lm] = f2bf(c[nt][r]);
    }
  if (lm == 0) {
#pragma unroll
    for (int r = 0; r < 4; ++r) {
      long nd = nb + w * 16 + lq * 4 + r;
      if (nd < n) { al_s[nd] = prs[r]; al_d[nd] = prd[r]; }
    }
  }
}

// ---------------- GAT: quarter-wave (16 lanes) per node, bf16 xs gather ----------------
#define QCAP 128
__global__ __launch_bounds__(256) void gat3(
    const int* __restrict__ off, const int2* __restrict__ csr,
    const float* __restrict__ ale,
    const float* __restrict__ al_s, const float* __restrict__ al_d,
    const unsigned short* __restrict__ xsb, const float* __restrict__ bias,
    float* __restrict__ gat_out, float* __restrict__ part, int n) {
  __shared__ float2 sal[16][QCAP];
  __shared__ float sred[4][128];
  int tid = threadIdx.x, w = tid >> 6, lane = tid & 63;
  int qt = tid >> 4, q = tid & 15;
  const uint2* xr = (const uint2*)xsb;
  float4 bv = *(const float4*)&bias[q * 4];
  float4 psum = make_float4(0.f, 0.f, 0.f, 0.f), psq = psum;
  for (int node = blockIdx.x * 16 + qt; node < n; node += gridDim.x * 16) {
    int s0 = off[node];
    int deg = off[node + 1] - s0;
    bool fits = (deg <= QCAP);
    float aldn = al_d[node];
    float lmax = -3.402823466e38f, lsae = 0.f;
    for (int k = q; k < deg; k += 16) {
      int2 ce = csr[s0 + k];
      float ae = ale[ce.y];
      float a = al_s[ce.x] + aldn + ae;
      float al = (a >= 0.f) ? a : 0.2f * a;
      lmax = fmaxf(lmax, al);
      lsae += ae;
      if (fits) sal[qt][k] = make_float2(al, __int_as_float(ce.x));
    }
#pragma unroll
    for (int o = 1; o < 16; o <<= 1) {
      lmax = fmaxf(lmax, __shfl_xor(lmax, o));
      lsae += __shfl_xor(lsae, o);
    }
    float ae_self = lsae / fmaxf((float)deg, 1.f);
    float a_self = al_s[node] + aldn + ae_self;
    float al_self = (a_self >= 0.f) ? a_self : 0.2f * a_self;
    float mx = fmaxf(lmax, al_self);
    float lsum = 0.f;
    if (fits) {
      for (int k = q; k < deg; k += 16) {
        float ex = __expf(sal[qt][k].x - mx);
        sal[qt][k].x = ex;
        lsum += ex;
      }
    } else {
      for (int k = q; k < deg; k += 16) {
        int2 ce = csr[s0 + k];
        float a = al_s[ce.x] + aldn + ale[ce.y];
        float al = (a >= 0.f) ? a : 0.2f * a;
        lsum += __expf(al - mx);
      }
    }
#pragma unroll
    for (int o = 1; o < 16; o <<= 1) lsum += __shfl_xor(lsum, o);
    float exs = __expf(al_self - mx);
    float inv = 1.f / (lsum + exs + 1e-16f);
    uint2 xv = xr[(long)node * 16 + q];
    float4 acc;
    acc.x = exs * bflo(xv.x); acc.y = exs * bfhi(xv.x);
    acc.z = exs * bflo(xv.y); acc.w = exs * bfhi(xv.y);
    if (fits) {
      int k = 0;
      for (; k + 4 <= deg; k += 4) {
        float2 p0 = sal[qt][k], p1 = sal[qt][k + 1], p2 = sal[qt][k + 2], p3 = sal[qt][k + 3];
        uint2 x0 = xr[(long)__float_as_int(p0.y) * 16 + q];
        uint2 x1 = xr[(long)__float_as_int(p1.y) * 16 + q];
        uint2 x2 = xr[(long)__float_as_int(p2.y) * 16 + q];
        uint2 x3 = xr[(long)__float_as_int(p3.y) * 16 + q];
        acc.x += p0.x * bflo(x0.x) + p1.x * bflo(x1.x) + p2.x * bflo(x2.x) + p3.x * bflo(x3.x);
        acc.y += p0.x * bfhi(x0.x) + p1.x * bfhi(x1.x) + p2.x * bfhi(x2.x) + p3.x * bfhi(x3.x);
        acc.z += p0.x * bflo(x0.y) + p1.x * bflo(x1.y) + p2.x * bflo(x2.y) + p3.x * bflo(x3.y);
        acc.w += p0.x * bfhi(x0.y) + p1.x * bfhi(x1.y) + p2.x * bfhi(x2.y) + p3.x * bfhi(x3.y);
      }
      for (; k < deg; ++k) {
        float2 p = sal[qt][k];
        uint2 xk = xr[(long)__float_as_int(p.y) * 16 + q];
        acc.x += p.x * bflo(xk.x); acc.y += p.x * bfhi(xk.x);
        acc.z += p.x * bflo(xk.y); acc.w += p.x * bfhi(xk.y);
      }
    } else {
      for (int k = 0; k < deg; ++k) {
        int2 ce = csr[s0 + k];
        float a = al_s[ce.x] + aldn + ale[ce.y];
        float al = (a >= 0.f) ? a : 0.2f * a;
        float ex = __expf(al - mx);
        uint2 xk = xr[(long)ce.x * 16 + q];
        acc.x += ex * bflo(xk.x); acc.y += ex * bfhi(xk.x);
        acc.z += ex * bflo(xk.y); acc.w += ex * bfhi(xk.y);
      }
    }
    acc.x = acc.x * inv + bv.x; acc.y = acc.y * inv + bv.y;
    acc.z = acc.z * inv + bv.z; acc.w = acc.w * inv + bv.w;
    *(float4*)&gat_out[(long)node * 64 + q * 4] = acc;
    psum.x += acc.x; psum.y += acc.y; psum.z += acc.z; psum.w += acc.w;
    psq.x += acc.x * acc.x; psq.y += acc.y * acc.y; psq.z += acc.z * acc.z; psq.w += acc.w * acc.w;
  }
#pragma unroll
  for (int o = 16; o < 64; o <<= 1) {
    psum.x += __shfl_xor(psum.x, o); psum.y += __shfl_xor(psum.y, o);
    psum.z += __shfl_xor(psum.z, o); psum.w += __shfl_xor(psum.w, o);
    psq.x += __shfl_xor(psq.x, o); psq.y += __shfl_xor(psq.y, o);
    psq.z += __shfl_xor(psq.z, o); psq.w += __shfl_xor(psq.w, o);
  }
  if (lane < 16) {
    sred[w][lane * 4 + 0] = psum.x; sred[w][lane * 4 + 1] = psum.y;
    sred[w][lane * 4 + 2] = psum.z; sred[w][lane * 4 + 3] = psum.w;
    sred[w][64 + lane * 4 + 0] = psq.x; sred[w][64 + lane * 4 + 1] = psq.y;
    sred[w][64 + lane * 4 + 2] = psq.z; sred[w][64 + lane * 4 + 3] = psq.w;
  }
  __syncthreads();
  if (tid < 128)
    part[(long)blockIdx.x * 128 + tid] =
        sred[0][tid] + sred[1][tid] + sred[2][tid] + sred[3][tid];
}

// ---------------- BN finalize ----------------
__global__ __launch_bounds__(1024) void bn_finalize(const float* __restrict__ part, int nblk,
                                                    float invN, float* __restrict__ stats) {
  __shared__ float sh[1024];
  int t = threadIdx.x;
  int c = t & 127, g = t >> 7;
  float s = 0.f;
  for (int b = g; b < nblk; b += 8) s += part[(long)b * 128 + c];
  sh[t] = s;
  __syncthreads();
  if (t < 128) {
    float tot = 0.f;
#pragma unroll
    for (int g2 = 0; g2 < 8; ++g2) tot += sh[g2 * 128 + t];
    sh[t] = tot;
  }
  __syncthreads();
  if (t < 64) {
    float mean = sh[t] * invN;
    float var = sh[64 + t] * invN - mean * mean;
    stats[t] = mean;
    stats[64 + t] = rsqrtf(var + 1e-5f);
  }
}

// ---- fused: last BN-apply + residual + global mean partials (no h write) ----
__global__ void gsum_bn(const float* __restrict__ z, const float* __restrict__ stats,
                        const float* __restrict__ bng, const float* __restrict__ bnb,
                        const float* __restrict__ hprev, int n, float* __restrict__ part) {
  __shared__ float sh[4][64];
  int tid = threadIdx.x, w = tid >> 6, lane = tid & 63;
  float sm = stats[lane], sv = stats[64 + lane], gg = bng[lane], bb = bnb[lane];
  int gw = blockIdx.x * 4 + w, nW = gridDim.x * 4;
  float s = 0.f;
  for (int node = gw; node < n; node += nW) {
    float t = fmaxf((z[(long)node * 64 + lane] - sm) * sv * gg + bb, 0.f);
    s += hprev[(long)node * 64 + lane] + t;
  }
  sh[w][lane] = s;
  __syncthreads();
  if (tid < 64)
    part[(long)blockIdx.x * 64 + tid] =
        sh[0][tid] + sh[1][tid] + sh[2][tid] + sh[3][tid];
}

__global__ void final_kernel(const float* __restrict__ part, int nblk,
                             const float* __restrict__ out_W, const float* __restrict__ out_b,
                             float* __restrict__ out, float invN) {
  __shared__ float g[64];
  int c = threadIdx.x;  // 64 threads
  float s = 0.f;
  for (int b = 0; b < nblk; ++b) s += part[(long)b * 64 + c];
  g[c] = s * invN;
  __syncthreads();
  float acc = out_b[c];
  for (int k = 0; k < 64; ++k) acc += g[k] * out_W[k * 64 + c];
  out[c] = fmaxf(acc, 0.f);
}

// ---------------- host launch ----------------
extern "C" void kernel_launch(void* const* d_in, const int* in_sizes, int n_in,
                              void* d_out, int out_size, void* d_ws, size_t ws_size,
                              hipStream_t stream) {
  const float* x        = (const float*)d_in[0];
  const int*   eidx     = (const int*)d_in[1];
  const float* eattr    = (const float*)d_in[2];
  const float* np_W1    = (const float*)d_in[3];
  const float* np_b1    = (const float*)d_in[4];
  const float* np_W2    = (const float*)d_in[5];
  const float* np_b2    = (const float*)d_in[6];
  const float* np_ln_g  = (const float*)d_in[7];
  const float* np_ln_b  = (const float*)d_in[8];
  const float* ep_W1    = (const float*)d_in[9];
  const float* ep_b1    = (const float*)d_in[10];
  const float* ep_W2    = (const float*)d_in[11];
  const float* ep_b2    = (const float*)d_in[12];
  const float* ep_ln_g  = (const float*)d_in[13];
  const float* ep_ln_b  = (const float*)d_in[14];
  const float* enc_W    = (const float*)d_in[15];
  const float* enc_b    = (const float*)d_in[16];
  const float* enc_bn_g = (const float*)d_in[17];
  const float* enc_bn_b = (const float*)d_in[18];
  const float* gat_W    = (const float*)d_in[19];
  const float* gat_eW   = (const float*)d_in[20];
  const float* att_src  = (const float*)d_in[21];
  const float* att_dst  = (const float*)d_in[22];
  const float* att_edge = (const float*)d_in[23];
  const float* gat_b    = (const float*)d_in[24];
  const float* bn_g     = (const float*)d_in[25];
  const float* bn_b     = (const float*)d_in[26];
  const float* out_W    = (const float*)d_in[27];
  const float* out_b    = (const float*)d_in[28];

  const int n = in_sizes[0] / 128;   // 50000
  const int ne = in_sizes[1] / 2;    // 800000
  const int* srcp = eidx;
  const int* dstp = eidx + ne;

  float* f = (float*)d_ws;
  float* hbuf  = f; f += (long)n * 64;
  float* zbuf  = f; f += (long)n * 64;   // also reused as int2 csrt scratch pre-node_pre3
  float* alsb  = f; f += n;
  float* aldb  = f; f += n;
  float* ale   = f; f += 3L * ne;
  float* vgbuf = f; f += 128;
  float* stats = f; f += 128;
  float* part  = f; f += 131072;      // 1024 x 128
  float* part2 = f; f += 16384;       // 256 x 64
  unsigned short* wbb   = (unsigned short*)f; f += 2048;          // edge weights
  unsigned short* wnb   = (unsigned short*)f; f += 36864;         // node weights
  unsigned short* wgatb = (unsigned short*)f; f += 6144;          // 3 x 4096 gat weights
  unsigned short* xsb   = (unsigned short*)f; f += (long)n * 32;  // n*64 bf16
  int* ip = (int*)f;
  int2* csr = (int2*)ip; ip += 2L * ne;
  int* degb = ip; ip += n;
  int* cntb = ip; ip += n;
  int* offb = ip; ip += n + 1;
  int* bsum = ip; ip += 256;
  int2* csrt = (int2*)zbuf;  // ne*8B = 6.4MB <= zbuf 12.8MB; dead until node_pre3

  const int nbEdge = (ne + EB - 1) / EB;     // 6250
  const int nbNode = (n + 63) / 64;          // 782
  const int nbScan = (n + 255) / 256;        // 196

  hipMemsetAsync(degb, 0, (size_t)n * sizeof(int), stream);
  hipMemsetAsync(cntb, 0, (size_t)n * sizeof(int), stream);
  vprep2<<<1, 128, 0, stream>>>(gat_eW, att_edge, ep_ln_g, ep_ln_b, vgbuf);
  wpack<<<1, 256, 0, stream>>>(ep_W1, ep_W2, wbb);
  npack<<<288, 256, 0, stream>>>(np_W1, np_W2, enc_W, wnb);
  gpack<<<48, 256, 0, stream>>>(gat_W, wgatb);
  deg_kernel<<<1024, 256, 0, stream>>>(dstp, ne, degb);
  scan_blk<<<nbScan, 256, 0, stream>>>(degb, offb, bsum, n);
  scan_bsum<<<1, 256, 0, stream>>>(bsum, nbScan);
  scan_add<<<nbScan, 256, 0, stream>>>(bsum, offb, n);
  scatter_kernel<<<1024, 256, 0, stream>>>(srcp, dstp, ne, offb, cntb, csrt);
  csr_sort<<<1024, 256, 0, stream>>>(offb, csrt, csr, n);
  edge_pre3<<<nbEdge, 256, 0, stream>>>(eattr, wbb, ep_b1, ep_b2, vgbuf, ale, ne);
  node_pre3<<<nbNode, 256, 0, stream>>>(x, wnb, np_b1, np_b2, np_ln_g, np_ln_b,
                                        enc_b, zbuf, part, n);
  bn_finalize<<<1, 1024, 0, stream>>>(part, nbNode, 1.f / n, stats);
  xs_bn2<<<nbNode, 256, 0, stream>>>(zbuf, stats, enc_bn_g, enc_bn_b, hbuf, 0,
                                     wgatb, att_src, att_dst, xsb, alsb, aldb, n);
  for (int l = 0; l < 3; ++l) {
    gat3<<<1024, 256, 0, stream>>>(offb, csr, ale + (long)l * ne, alsb, aldb,
                                   xsb, gat_b + l * 64, zbuf, part, n);
    bn_finalize<<<1, 1024, 0, stream>>>(part, 1024, 1.f / n, stats);
    if (l < 2) {
      xs_bn2<<<nbNode, 256, 0, stream>>>(zbuf, stats, bn_g + l * 64, bn_b + l * 64, hbuf, 1,
                                         wgatb + (long)(l + 1) * 4096,
                                         att_src + (l + 1) * 64, att_dst + (l + 1) * 64,
                                         xsb, alsb, aldb, n);
    } else {
      gsum_bn<<<256, 256, 0, stream>>>(zbuf, stats, bn_g + l * 64, bn_b + l * 64,
                                       hbuf, n, part2);
    }
  }
  final_kernel<<<1, 64, 0, stream>>>(part2, 256, out_W, out_b, (float*)d_out, 1.f / n);
}

// Round 9
// 552.254 us; speedup vs baseline: 3.5508x; 1.0397x over previous
//
#include <hip/hip_runtime.h>
#include <hip/hip_bf16.h>

// GNNEncoder on MI355X. Algebraic reductions:
//  - (ea@eW)@a_e == ea@(eW@a_e): only 3 scalars al_e per edge needed.
//  - loop_attr contribution == mean(incoming al_e) by linearity.
//  - edge LN+dot folded: al = istd*(sum y*(g*v) - mean*G) + C.
// dst-CSR built once; scatter order from atomics made DETERMINISTIC by a
// per-segment sort on edge id (csr_sort) -- graph-replay == launch_once bitwise.
// MFMA kernels: weights pre-packed into fragment order (A-frag(row,k) ==
// B-frag(col,k) byte layout), tiny per-lane state, XOR-swizzled LDS.
// edge_pre4 (round 9): TRANSPOSED GEMMs (T^T=W1^T@ea^T, Y^T=W2^T@T^T) so the
// C-layout puts each edge in ONE lane column: LN fold = 20 shfl (was 160),
// T store = 8x ds_write_b64 (was 32x b16), swizzled reads (was 8-way banks).

typedef short bf16x8 __attribute__((ext_vector_type(8)));
typedef float f32x4 __attribute__((ext_vector_type(4)));
union U8 { uint4 u; bf16x8 v; };

__device__ __forceinline__ unsigned pack2bf(float a, float b) {
  unsigned ua = __float_as_uint(a); ua += 0x7fffu + ((ua >> 16) & 1u);
  unsigned ub = __float_as_uint(b); ub += 0x7fffu + ((ub >> 16) & 1u);
  return (ua >> 16) | (ub & 0xffff0000u);
}
__device__ __forceinline__ unsigned short f2bf(float x) {
  unsigned u = __float_as_uint(x); u += 0x7fffu + ((u >> 16) & 1u);
  return (unsigned short)(u >> 16);
}
__device__ __forceinline__ float bflo(unsigned u) { return __uint_as_float(u << 16); }
__device__ __forceinline__ float bfhi(unsigned u) { return __uint_as_float(u & 0xffff0000u); }

// ---------------- prep: v = eW@a_e, gv = lng*v, G = sum(lng*v), C = sum(lnb*v) ----------------
__global__ void vprep2(const float* __restrict__ eW, const float* __restrict__ a_e,
                       const float* __restrict__ lng, const float* __restrict__ lnb,
                       float* __restrict__ vg) {
  __shared__ float sv[96];
  int t = threadIdx.x;  // 128 threads
  if (t < 96) {
    int l = t >> 5, i = t & 31;
    const float* w = eW + l * 2048 + i * 64;
    const float* a = a_e + l * 64;
    float s = 0.f;
    for (int c = 0; c < 64; ++c) s += w[c] * a[c];
    sv[t] = s;
    vg[t] = s * lng[i];
  }
  __syncthreads();
  if (t < 3) {
    float G = 0.f, C = 0.f;
    for (int i = 0; i < 32; ++i) {
      float vv = sv[t * 32 + i];
      G += lng[i] * vv;
      C += lnb[i] * vv;
    }
    vg[96 + t] = G;
    vg[99 + t] = C;
  }
}

// pack W1[32x64], W2[64x32] into bf16 MFMA fragment order (edge MLP).
__global__ void wpack(const float* __restrict__ W1, const float* __restrict__ W2,
                      unsigned short* __restrict__ wb) {
  int t = threadIdx.x;  // 256
  for (int i = t; i < 2048; i += 256) {
    int nt = i >> 9, rem = i & 511, l = rem >> 3, j = rem & 7;
    int k = ((l >> 4) << 3) + j, col = (nt << 4) + (l & 15);
    wb[i] = f2bf(W1[k * 64 + col]);
  }
  for (int i = t; i < 2048; i += 256) {
    int sn = i >> 9, rem = i & 511, l = rem >> 3, j = rem & 7;
    int s = sn >> 1, nt = sn & 1;
    int k = s * 32 + ((l >> 4) << 3) + j, col = (nt << 4) + (l & 15);
    wb[2048 + i] = f2bf(W2[k * 32 + col]);
  }
}

// pack node-path weights: np_W1[128x256] (64 frags), np_W2[256x128] (64), enc_W[128x64] (16)
__global__ void npack(const float* __restrict__ W1, const float* __restrict__ W2,
                      const float* __restrict__ eW, unsigned short* __restrict__ wnb) {
  int i = blockIdx.x * blockDim.x + threadIdx.x;  // 73728 total
  if (i < 32768) {
    int fi = i >> 9, rem = i & 511, l = rem >> 3, j = rem & 7;
    int nt = fi >> 2, ks = fi & 3;
    int k = ks * 32 + ((l >> 4) << 3) + j, col = nt * 16 + (l & 15);
    wnb[i] = f2bf(W1[k * 256 + col]);
  } else if (i < 65536) {
    int i2 = i - 32768;
    int fi = i2 >> 9, rem = i2 & 511, l = rem >> 3, j = rem & 7;
    int nt = fi >> 3, ks = fi & 7;
    int k = ks * 32 + ((l >> 4) << 3) + j, col = nt * 16 + (l & 15);
    wnb[i] = f2bf(W2[k * 128 + col]);
  } else if (i < 73728) {
    int i3 = i - 65536;
    int fi = i3 >> 9, rem = i3 & 511, l = rem >> 3, j = rem & 7;
    int nt = fi >> 2, ks = fi & 3;
    int k = ks * 32 + ((l >> 4) << 3) + j, col = nt * 16 + (l & 15);
    wnb[i] = f2bf(eW[k * 64 + col]);
  }
}

// pack gat_W[3][64][64] into frag order: per layer 8 frags [nt*2+ks]
__global__ void gpack(const float* __restrict__ W, unsigned short* __restrict__ wg) {
  int i = blockIdx.x * blockDim.x + threadIdx.x;  // 12288 total
  if (i < 12288) {
    int l = i >> 12, rem = i & 4095;
    int fi = rem >> 9, l8 = rem & 511, ln = l8 >> 3, j = l8 & 7;
    int nt = fi >> 1, ks = fi & 1;
    int k = ks * 32 + ((ln >> 4) << 3) + j, col = nt * 16 + (ln & 15);
    wg[i] = f2bf(W[l * 4096 + k * 64 + col]);
  }
}

__global__ void deg_kernel(const int* __restrict__ dst, int ne, int* __restrict__ deg) {
  int i = blockIdx.x * blockDim.x + threadIdx.x;
  int stride = gridDim.x * blockDim.x;
  for (; i < ne; i += stride) atomicAdd(&deg[dst[i]], 1);
}

// ---- 3-phase multi-block scan ----
__global__ __launch_bounds__(256) void scan_blk(const int* __restrict__ deg,
                                                int* __restrict__ off,
                                                int* __restrict__ bsum, int n) {
  __shared__ int wsum[4];
  int b = blockIdx.x, t = threadIdx.x;
  int i = b * 256 + t;
  int lane = t & 63, w = t >> 6;
  int v = (i < n) ? deg[i] : 0;
  int s = v;
#pragma unroll
  for (int o = 1; o < 64; o <<= 1) {
    int u = __shfl_up(s, o);
    if (lane >= o) s += u;
  }
  if (lane == 63) wsum[w] = s;
  __syncthreads();
  int add = 0;
#pragma unroll
  for (int ww = 0; ww < 4; ++ww) add += (ww < w) ? wsum[ww] : 0;
  s += add;
  if (i < n) off[i + 1] = s;
  if (t == 255) bsum[b] = s;
}

__global__ __launch_bounds__(256) void scan_bsum(int* __restrict__ bsum, int nb) {
  __shared__ int sh[256];
  int t = threadIdx.x;
  sh[t] = (t < nb) ? bsum[t] : 0;
  __syncthreads();
  for (int o = 1; o < 256; o <<= 1) {
    int u = (t >= o) ? sh[t - o] : 0;
    __syncthreads();
    sh[t] += u;
    __syncthreads();
  }
  if (t < nb) bsum[t] = (t == 0) ? 0 : sh[t - 1];
}

__global__ __launch_bounds__(256) void scan_add(const int* __restrict__ bsum,
                                                int* __restrict__ off, int n) {
  int b = blockIdx.x, t = threadIdx.x;
  int i = b * 256 + t;
  int add = bsum[b];
  if (i < n) off[i + 1] += add;
  if (i == 0) off[0] = 0;
}

__global__ void scatter_kernel(const int* __restrict__ src, const int* __restrict__ dst,
                               int ne, const int* __restrict__ off, int* __restrict__ cnt,
                               int2* __restrict__ csrt) {
  int i = blockIdx.x * blockDim.x + threadIdx.x;
  int stride = gridDim.x * blockDim.x;
  for (; i < ne; i += stride) {
    int d = dst[i];
    int p = off[d] + atomicAdd(&cnt[d], 1);
    csrt[p] = make_int2(src[i], i);
  }
}

// ---- deterministic per-segment sort by edge id ----
#define SCAP 128
__global__ __launch_bounds__(256) void csr_sort(const int* __restrict__ off,
                                                const int2* __restrict__ csrt,
                                                int2* __restrict__ csr, int n) {
  __shared__ int seid[16][SCAP];
  int tid = threadIdx.x;
  int qt = tid >> 4, q = tid & 15;
  for (int node = blockIdx.x * 16 + qt; node < n; node += gridDim.x * 16) {
    int s0 = off[node], deg = off[node + 1] - s0;
    if (deg <= SCAP) {
      for (int k = q; k < deg; k += 16) seid[qt][k] = csrt[s0 + k].y;
      for (int k = q; k < deg; k += 16) {
        int e = seid[qt][k];
        int r = 0;
        for (int m = 0; m < deg; ++m) r += (seid[qt][m] < e) ? 1 : 0;
        csr[s0 + r] = csrt[s0 + k];
      }
    } else {
      for (int k = q; k < deg; k += 16) {
        int e = csrt[s0 + k].y;
        int r = 0;
        for (int m = 0; m < deg; ++m) r += (csrt[s0 + m].y < e) ? 1 : 0;
        csr[s0 + r] = csrt[s0 + k];
      }
    }
  }
}

// ---------------- edge preproc v4: transposed MFMA. block=256 (4 waves), 128 edges ----------------
#define EB 128
__global__ __launch_bounds__(256) void edge_pre4(
    const float* __restrict__ ea, const unsigned short* __restrict__ wb,
    const float* __restrict__ b1, const float* __restrict__ b2,
    const float* __restrict__ vg, float* __restrict__ ale, int ne) {
  __shared__ __align__(16) unsigned short swb[4096];
  __shared__ __align__(16) unsigned short sT[4][32 * 72];  // T[edge][hidden], 16B-block swizzled
  int tid = threadIdx.x, w = tid >> 6, lane = tid & 63;
  {
    const uint4* g = (const uint4*)wb;
    uint4* s = (uint4*)swb;
    for (int i = tid; i < 512; i += 256) s[i] = g[i];
  }
  __syncthreads();
  int lm = lane & 15, lq = lane >> 4;
  long e0 = (long)blockIdx.x * EB + w * 32;
  // ---- ea as B-fragments straight from global (col=edge, k=feature) ----
  bf16x8 eab[2];
#pragma unroll
  for (int eh = 0; eh < 2; ++eh) {
    long e = e0 + eh * 16 + lm;
    if (e >= ne) e = ne - 1;
    const float4* p = (const float4*)(ea + e * 32 + lq * 8);
    float4 u = p[0], v = p[1];
    U8 cc;
    cc.u = make_uint4(pack2bf(u.x, u.y), pack2bf(u.z, u.w), pack2bf(v.x, v.y), pack2bf(v.z, v.w));
    eab[eh] = cc.v;
  }
  // ---- GEMM1 (transposed): T^T[64h x 32e] = W1^T @ ea^T ----
  f32x4 zero = {0.f, 0.f, 0.f, 0.f};
  f32x4 c1[2][4];
#pragma unroll
  for (int eh = 0; eh < 2; ++eh)
#pragma unroll
    for (int nt = 0; nt < 4; ++nt) c1[eh][nt] = zero;
#pragma unroll
  for (int nt = 0; nt < 4; ++nt) {
    bf16x8 wf = *(const bf16x8*)&swb[nt * 512 + lane * 8];
#pragma unroll
    for (int eh = 0; eh < 2; ++eh)
      c1[eh][nt] = __builtin_amdgcn_mfma_f32_16x16x32_bf16(wf, eab[eh], c1[eh][nt], 0, 0, 0);
  }
  // relu+bias -> T[edge][hidden] in LDS, r=0..3 packed as one b64, block-swizzled
#pragma unroll
  for (int nt = 0; nt < 4; ++nt) {
    float4 b1v = *(const float4*)&b1[nt * 16 + lq * 4];
#pragma unroll
    for (int eh = 0; eh < 2; ++eh) {
      int el = eh * 16 + lm;
      unsigned lo = pack2bf(fmaxf(c1[eh][nt][0] + b1v.x, 0.f), fmaxf(c1[eh][nt][1] + b1v.y, 0.f));
      unsigned hi = pack2bf(fmaxf(c1[eh][nt][2] + b1v.z, 0.f), fmaxf(c1[eh][nt][3] + b1v.w, 0.f));
      int blk = nt * 2 + (lq >> 1);
      int addr = el * 72 + (((blk ^ (el & 7)) << 3) | ((lq & 1) << 2));
      *(uint2*)&sT[w][addr] = make_uint2(lo, hi);
    }
  }
  __syncthreads();
  // ---- GEMM2 (transposed): Y^T[32i x 32e] = W2^T @ T^T ----
  f32x4 c2[2][2];
#pragma unroll
  for (int eh = 0; eh < 2; ++eh)
#pragma unroll
    for (int ih = 0; ih < 2; ++ih) c2[eh][ih] = zero;
#pragma unroll
  for (int eh = 0; eh < 2; ++eh) {
    int el = eh * 16 + lm;
#pragma unroll
    for (int s = 0; s < 2; ++s) {
      int blk = s * 4 + lq;
      bf16x8 tb = *(const bf16x8*)&sT[w][el * 72 + ((blk ^ (el & 7)) << 3)];
#pragma unroll
      for (int ih = 0; ih < 2; ++ih) {
        bf16x8 wf = *(const bf16x8*)&swb[2048 + (s * 2 + ih) * 512 + lane * 8];
        c2[eh][ih] = __builtin_amdgcn_mfma_f32_16x16x32_bf16(wf, tb, c2[eh][ih], 0, 0, 0);
      }
    }
  }
  // ---- LN + fold, per-lane channels (ch = ih*16 + lq*4 + r), 2-round butterfly over lq ----
  float4 b2v[2], g0v[2], g1v[2], g2v[2];
#pragma unroll
  for (int ih = 0; ih < 2; ++ih) {
    int ch0 = ih * 16 + lq * 4;
    b2v[ih] = *(const float4*)&b2[ch0];
    g0v[ih] = *(const float4*)&vg[ch0];
    g1v[ih] = *(const float4*)&vg[32 + ch0];
    g2v[ih] = *(const float4*)&vg[64 + ch0];
  }
  float G0 = vg[96], G1 = vg[97], G2 = vg[98];
  float C0 = vg[99], C1 = vg[100], C2 = vg[101];
#pragma unroll
  for (int eh = 0; eh < 2; ++eh) {
    float s = 0.f, q = 0.f, d0 = 0.f, d1 = 0.f, d2 = 0.f;
#pragma unroll
    for (int ih = 0; ih < 2; ++ih) {
      float bb[4] = {b2v[ih].x, b2v[ih].y, b2v[ih].z, b2v[ih].w};
      float g0[4] = {g0v[ih].x, g0v[ih].y, g0v[ih].z, g0v[ih].w};
      float g1[4] = {g1v[ih].x, g1v[ih].y, g1v[ih].z, g1v[ih].w};
      float g2[4] = {g2v[ih].x, g2v[ih].y, g2v[ih].z, g2v[ih].w};
#pragma unroll
      for (int r = 0; r < 4; ++r) {
        float y = c2[eh][ih][r] + bb[r];
        s += y; q += y * y;
        d0 += y * g0[r]; d1 += y * g1[r]; d2 += y * g2[r];
      }
    }
    s += __shfl_xor(s, 16); s += __shfl_xor(s, 32);
    q += __shfl_xor(q, 16); q += __shfl_xor(q, 32);
    d0 += __shfl_xor(d0, 16); d0 += __shfl_xor(d0, 32);
    d1 += __shfl_xor(d1, 16); d1 += __shfl_xor(d1, 32);
    d2 += __shfl_xor(d2, 16); d2 += __shfl_xor(d2, 32);
    long e = e0 + eh * 16 + lm;
    if (lq >= 1 && e < ne) {
      float mean = s * (1.f / 32.f);
      float var = q * (1.f / 32.f) - mean * mean;
      float istd = rsqrtf(var + 1e-5f);
      float d = (lq == 1) ? d0 : (lq == 2) ? d1 : d2;
      float Gp = (lq == 1) ? G0 : (lq == 2) ? G1 : G2;
      float Cp = (lq == 1) ? C0 : (lq == 2) ? C1 : C2;
      ale[(long)(lq - 1) * ne + e] = istd * (d - mean * Gp) + Cp;
    }
  }
}

// ---------------- node preproc v3: MFMA. block=256 (4 waves), 64 nodes ----------------
__global__ __launch_bounds__(256, 2) void node_pre3(
    const float* __restrict__ x, const unsigned short* __restrict__ wnb,
    const float* __restrict__ b1, const float* __restrict__ b2,
    const float* __restrict__ lng, const float* __restrict__ lnb,
    const float* __restrict__ encb, float* __restrict__ z_out,
    float* __restrict__ part, int n) {
  __shared__ __align__(16) unsigned short swb[16384];      // 32KB weight chunk
  __shared__ __align__(16) unsigned short sT[4][16 * 264]; // per-wave T / h1
  __shared__ float sred[4][128];
  int tid = threadIdx.x, w = tid >> 6, lane = tid & 63;
  int lm = lane & 15, lq = lane >> 4;
  long nb = (long)blockIdx.x * 64;
  const uint4* wg = (const uint4*)wnb;
  f32x4 zero = {0.f, 0.f, 0.f, 0.f};

  long row = nb + w * 16 + lm;
  if (row >= n) row = n - 1;
  bf16x8 ax[4];
  const float4* xp = (const float4*)(x + row * 128);
#pragma unroll
  for (int ks = 0; ks < 4; ++ks) {
    float4 u = xp[ks * 8 + lq * 2];
    float4 v = xp[ks * 8 + lq * 2 + 1];
    U8 cc;
    cc.u = make_uint4(pack2bf(u.x, u.y), pack2bf(u.z, u.w), pack2bf(v.x, v.y), pack2bf(v.z, v.w));
    ax[ks] = cc.v;
  }

  for (int h01 = 0; h01 < 2; ++h01) {
    __syncthreads();
    {
      const uint4* src = wg + h01 * 2048;
      uint4* dstv = (uint4*)swb;
      for (int i = tid; i < 2048; i += 256) dstv[i] = src[i];
    }
    __syncthreads();
    f32x4 acc1[8];
#pragma unroll
    for (int nt8 = 0; nt8 < 8; ++nt8) acc1[nt8] = zero;
#pragma unroll
    for (int ks = 0; ks < 4; ++ks)
#pragma unroll
      for (int nt8 = 0; nt8 < 8; ++nt8) {
        bf16x8 bf = *(const bf16x8*)&swb[(nt8 * 4 + ks) * 512 + lane * 8];
        acc1[nt8] = __builtin_amdgcn_mfma_f32_16x16x32_bf16(ax[ks], bf, acc1[nt8], 0, 0, 0);
      }
#pragma unroll
    for (int nt8 = 0; nt8 < 8; ++nt8) {
      int col = (h01 * 8 + nt8) * 16 + lm;
      float bv = b1[col];
#pragma unroll
      for (int r = 0; r < 4; ++r) {
        int rr = lq * 4 + r;
        sT[w][rr * 264 + (col ^ ((rr & 7) << 3))] = f2bf(fmaxf(acc1[nt8][r] + bv, 0.f));
      }
    }
  }

  f32x4 c2[8];
#pragma unroll
  for (int nt = 0; nt < 8; ++nt) c2[nt] = zero;
  for (int ksh = 0; ksh < 2; ++ksh) {
    __syncthreads();
    {
      uint4* dstv = (uint4*)swb;
      for (int i4 = tid; i4 < 2048; i4 += 256) {
        int e = i4 * 8;
        int fc = e >> 9, nt = fc >> 2, ksl = fc & 3;
        int ks = ksh * 4 + ksl;
        long gi = 32768 + (long)(nt * 8 + ks) * 512 + (e & 511);
        dstv[i4] = wg[gi >> 3];
      }
    }
    __syncthreads();
#pragma unroll
    for (int ksl = 0; ksl < 4; ++ksl) {
      int ks = ksh * 4 + ksl;
      bf16x8 at = *(const bf16x8*)&sT[w][lm * 264 + ((ks * 32 + lq * 8) ^ ((lm & 7) << 3))];
#pragma unroll
      for (int nt = 0; nt < 8; ++nt) {
        bf16x8 bf = *(const bf16x8*)&swb[(nt * 4 + ksl) * 512 + lane * 8];
        c2[nt] = __builtin_amdgcn_mfma_f32_16x16x32_bf16(at, bf, c2[nt], 0, 0, 0);
      }
    }
  }

  {
    float yv[8][4], bcol[8], gcol[8], ocol[8];
#pragma unroll
    for (int nt = 0; nt < 8; ++nt) {
      int col = nt * 16 + lm;
      bcol[nt] = b2[col]; gcol[nt] = lng[col]; ocol[nt] = lnb[col];
    }
    float s4[4], q4[4];
#pragma unroll
    for (int r = 0; r < 4; ++r) { s4[r] = 0.f; q4[r] = 0.f; }
#pragma unroll
    for (int nt = 0; nt < 8; ++nt)
#pragma unroll
      for (int r = 0; r < 4; ++r) {
        float y = c2[nt][r] + bcol[nt];
        yv[nt][r] = y;
        s4[r] += y; q4[r] += y * y;
      }
#pragma unroll
    for (int o = 1; o < 16; o <<= 1)
#pragma unroll
      for (int r = 0; r < 4; ++r) {
        s4[r] += __shfl_xor(s4[r], o);
        q4[r] += __shfl_xor(q4[r], o);
      }
#pragma unroll
    for (int r = 0; r < 4; ++r) {
      float mean = s4[r] * (1.f / 128.f);
      float var = q4[r] * (1.f / 128.f) - mean * mean;
      float istd = rsqrtf(var + 1e-5f);
      int rr = lq * 4 + r;
#pragma unroll
      for (int nt = 0; nt < 8; ++nt) {
        float hv = (yv[nt][r] - mean) * istd * gcol[nt] + ocol[nt];
        int col = nt * 16 + lm;
        if (col < 128)
          sT[w][rr * 264 + (col ^ ((rr & 7) << 3))] = f2bf(hv);
      }
    }
  }

  __syncthreads();
  {
    uint4* dstv = (uint4*)swb;
    const uint4* src = wg + (65536 >> 3);
    for (int i = tid; i < 1024; i += 256) dstv[i] = src[i];
  }
  __syncthreads();
  f32x4 c3[4];
#pragma unroll
  for (int nt = 0; nt < 4; ++nt) c3[nt] = zero;
#pragma unroll
  for (int ks = 0; ks < 4; ++ks) {
    bf16x8 at = *(const bf16x8*)&sT[w][lm * 264 + ((ks * 32 + lq * 8) ^ ((lm & 7) << 3))];
#pragma unroll
    for (int nt = 0; nt < 4; ++nt) {
      bf16x8 bf = *(const bf16x8*)&swb[(nt * 4 + ks) * 512 + lane * 8];
      c3[nt] = __builtin_amdgcn_mfma_f32_16x16x32_bf16(at, bf, c3[nt], 0, 0, 0);
    }
  }
  float ps[4], pq[4];
#pragma unroll
  for (int nt = 0; nt < 4; ++nt) { ps[nt] = 0.f; pq[nt] = 0.f; }
#pragma unroll
  for (int nt = 0; nt < 4; ++nt) {
    int col = nt * 16 + lm;
    float eb = encb[col];
#pragma unroll
    for (int r = 0; r < 4; ++r) {
      long nd = nb + w * 16 + lq * 4 + r;
      float z = c3[nt][r] + eb;
      if (nd < n) {
        z_out[nd * 64 + col] = z;
        ps[nt] += z; pq[nt] += z * z;
      }
    }
  }
#pragma unroll
  for (int o = 16; o < 64; o <<= 1)
#pragma unroll
    for (int nt = 0; nt < 4; ++nt) {
      ps[nt] += __shfl_xor(ps[nt], o);
      pq[nt] += __shfl_xor(pq[nt], o);
    }
  if (lq == 0) {
#pragma unroll
    for (int nt = 0; nt < 4; ++nt) {
      sred[w][nt * 16 + lm] = ps[nt];
      sred[w][64 + nt * 16 + lm] = pq[nt];
    }
  }
  __syncthreads();
  if (tid < 128) {
    float t = 0.f;
#pragma unroll
    for (int g = 0; g < 4; ++g) t += sred[g][tid];
    part[(long)blockIdx.x * 128 + tid] = t;
  }
}

// ---- fused MFMA: BN-apply(+residual into h) + xs = h@W (bf16) + al_s/al_d ----
__global__ __launch_bounds__(256) void xs_bn2(
    const float* __restrict__ z, const float* __restrict__ stats,
    const float* __restrict__ bng, const float* __restrict__ bnb,
    float* __restrict__ hbuf, int mode,
    const unsigned short* __restrict__ wgat,
    const float* __restrict__ a_s, const float* __restrict__ a_d,
    unsigned short* __restrict__ xsb, float* __restrict__ al_s, float* __restrict__ al_d,
    int n) {
  __shared__ __align__(16) unsigned short swg[4096];       // 8KB packed W
  __shared__ __align__(16) unsigned short shh[4][1024];    // per-wave h bf16, swizzled
  int tid = threadIdx.x, w = tid >> 6, lane = tid & 63;
  int lm = lane & 15, lq = lane >> 4;
  {
    const uint4* g = (const uint4*)wgat;
    uint4* s = (uint4*)swg;
    for (int i = tid; i < 512; i += 256) s[i] = g[i];
  }
  long nb = (long)blockIdx.x * 64;
  float sm = stats[lane], sv = stats[64 + lane], gg = bng[lane], bb = bnb[lane];
#pragma unroll
  for (int m = 0; m < 16; ++m) {
    long nd = nb + w * 16 + m;
    float hv = 0.f;
    if (nd < n) {
      float t = fmaxf((z[nd * 64 + lane] - sm) * sv * gg + bb, 0.f);
      hv = mode ? hbuf[nd * 64 + lane] + t : t;
      hbuf[nd * 64 + lane] = hv;
    }
    shh[w][m * 64 + (lane ^ ((m & 7) << 3))] = f2bf(hv);
  }
  __syncthreads();
  f32x4 zero = {0.f, 0.f, 0.f, 0.f};
  f32x4 c[4];
#pragma unroll
  for (int nt = 0; nt < 4; ++nt) c[nt] = zero;
#pragma unroll
  for (int ks = 0; ks < 2; ++ks) {
    bf16x8 at = *(const bf16x8*)&shh[w][lm * 64 + ((ks * 32 + lq * 8) ^ ((lm & 7) << 3))];
#pragma unroll
    for (int nt = 0; nt < 4; ++nt) {
      bf16x8 bf = *(const bf16x8*)&swg[(nt * 2 + ks) * 512 + lane * 8];
      c[nt] = __builtin_amdgcn_mfma_f32_16x16x32_bf16(at, bf, c[nt], 0, 0, 0);
    }
  }
  float asv[4], adv[4];
#pragma unroll
  for (int nt = 0; nt < 4; ++nt) { asv[nt] = a_s[nt * 16 + lm]; adv[nt] = a_d[nt * 16 + lm]; }
  float prs[4], prd[4];
#pragma unroll
  for (int r = 0; r < 4; ++r) {
    float s = 0.f, d = 0.f;
#pragma unroll
    for (int nt = 0; nt < 4; ++nt) {
      s += c[nt][r] * asv[nt];
      d += c[nt][r] * adv[nt];
    }
    prs[r] = s; prd[r] = d;
  }
#pragma unroll
  for (int o = 1; o < 16; o <<= 1)
#pragma unroll
    for (int r = 0; r < 4; ++r) {
      prs[r] += __shfl_xor(prs[r], o);
      prd[r] += __shfl_xor(prd[r], o);
    }
#pragma unroll
  for (int nt = 0; nt < 4; ++nt)
#pragma unroll
    for (int r = 0; r < 4; ++r) {
      long nd = nb + w * 16 + lq * 4 + r;
      if (nd < n) xsb[nd * 64 + nt * 16 + lm] = f2bf(c[nt][r]);
    }
  if (lm == 0) {
#pragma unroll
    for (int r = 0; r < 4; ++r) {
      long nd = nb + w * 16 + lq * 4 + r;
      if (nd < n) { al_s[nd] = prs[r]; al_d[nd] = prd[r]; }
    }
  }
}

// ---------------- GAT: quarter-wave (16 lanes) per node, bf16 xs gather ----------------
#define QCAP 128
__global__ __launch_bounds__(256) void gat3(
    const int* __restrict__ off, const int2* __restrict__ csr,
    const float* __restrict__ ale,
    const float* __restrict__ al_s, const float* __restrict__ al_d,
    const unsigned short* __restrict__ xsb, const float* __restrict__ bias,
    float* __restrict__ gat_out, float* __restrict__ part, int n) {
  __shared__ float2 sal[16][QCAP];
  __shared__ float sred[4][128];
  int tid = threadIdx.x, w = tid >> 6, lane = tid & 63;
  int qt = tid >> 4, q = tid & 15;
  const uint2* xr = (const uint2*)xsb;
  float4 bv = *(const float4*)&bias[q * 4];
  float4 psum = make_float4(0.f, 0.f, 0.f, 0.f), psq = psum;
  for (int node = blockIdx.x * 16 + qt; node < n; node += gridDim.x * 16) {
    int s0 = off[node];
    int deg = off[node + 1] - s0;
    bool fits = (deg <= QCAP);
    float aldn = al_d[node];
    float lmax = -3.402823466e38f, lsae = 0.f;
    for (int k = q; k < deg; k += 16) {
      int2 ce = csr[s0 + k];
      float ae = ale[ce.y];
      float a = al_s[ce.x] + aldn + ae;
      float al = (a >= 0.f) ? a : 0.2f * a;
      lmax = fmaxf(lmax, al);
      lsae += ae;
      if (fits) sal[qt][k] = make_float2(al, __int_as_float(ce.x));
    }
#pragma unroll
    for (int o = 1; o < 16; o <<= 1) {
      lmax = fmaxf(lmax, __shfl_xor(lmax, o));
      lsae += __shfl_xor(lsae, o);
    }
    float ae_self = lsae / fmaxf((float)deg, 1.f);
    float a_self = al_s[node] + aldn + ae_self;
    float al_self = (a_self >= 0.f) ? a_self : 0.2f * a_self;
    float mx = fmaxf(lmax, al_self);
    float lsum = 0.f;
    if (fits) {
      for (int k = q; k < deg; k += 16) {
        float ex = __expf(sal[qt][k].x - mx);
        sal[qt][k].x = ex;
        lsum += ex;
      }
    } else {
      for (int k = q; k < deg; k += 16) {
        int2 ce = csr[s0 + k];
        float a = al_s[ce.x] + aldn + ale[ce.y];
        float al = (a >= 0.f) ? a : 0.2f * a;
        lsum += __expf(al - mx);
      }
    }
#pragma unroll
    for (int o = 1; o < 16; o <<= 1) lsum += __shfl_xor(lsum, o);
    float exs = __expf(al_self - mx);
    float inv = 1.f / (lsum + exs + 1e-16f);
    uint2 xv = xr[(long)node * 16 + q];
    float4 acc;
    acc.x = exs * bflo(xv.x); acc.y = exs * bfhi(xv.x);
    acc.z = exs * bflo(xv.y); acc.w = exs * bfhi(xv.y);
    if (fits) {
      int k = 0;
      for (; k + 4 <= deg; k += 4) {
        float2 p0 = sal[qt][k], p1 = sal[qt][k + 1], p2 = sal[qt][k + 2], p3 = sal[qt][k + 3];
        uint2 x0 = xr[(long)__float_as_int(p0.y) * 16 + q];
        uint2 x1 = xr[(long)__float_as_int(p1.y) * 16 + q];
        uint2 x2 = xr[(long)__float_as_int(p2.y) * 16 + q];
        uint2 x3 = xr[(long)__float_as_int(p3.y) * 16 + q];
        acc.x += p0.x * bflo(x0.x) + p1.x * bflo(x1.x) + p2.x * bflo(x2.x) + p3.x * bflo(x3.x);
        acc.y += p0.x * bfhi(x0.x) + p1.x * bfhi(x1.x) + p2.x * bfhi(x2.x) + p3.x * bfhi(x3.x);
        acc.z += p0.x * bflo(x0.y) + p1.x * bflo(x1.y) + p2.x * bflo(x2.y) + p3.x * bflo(x3.y);
        acc.w += p0.x * bfhi(x0.y) + p1.x * bfhi(x1.y) + p2.x * bfhi(x2.y) + p3.x * bfhi(x3.y);
      }
      for (; k < deg; ++k) {
        float2 p = sal[qt][k];
        uint2 xk = xr[(long)__float_as_int(p.y) * 16 + q];
        acc.x += p.x * bflo(xk.x); acc.y += p.x * bfhi(xk.x);
        acc.z += p.x * bflo(xk.y); acc.w += p.x * bfhi(xk.y);
      }
    } else {
      for (int k = 0; k < deg; ++k) {
        int2 ce = csr[s0 + k];
        float a = al_s[ce.x] + aldn + ale[ce.y];
        float al = (a >= 0.f) ? a : 0.2f * a;
        float ex = __expf(al - mx);
        uint2 xk = xr[(long)ce.x * 16 + q];
        acc.x += ex * bflo(xk.x); acc.y += ex * bfhi(xk.x);
        acc.z += ex * bflo(xk.y); acc.w += ex * bfhi(xk.y);
      }
    }
    acc.x = acc.x * inv + bv.x; acc.y = acc.y * inv + bv.y;
    acc.z = acc.z * inv + bv.z; acc.w = acc.w * inv + bv.w;
    *(float4*)&gat_out[(long)node * 64 + q * 4] = acc;
    psum.x += acc.x; psum.y += acc.y; psum.z += acc.z; psum.w += acc.w;
    psq.x += acc.x * acc.x; psq.y += acc.y * acc.y; psq.z += acc.z * acc.z; psq.w += acc.w * acc.w;
  }
#pragma unroll
  for (int o = 16; o < 64; o <<= 1) {
    psum.x += __shfl_xor(psum.x, o); psum.y += __shfl_xor(psum.y, o);
    psum.z += __shfl_xor(psum.z, o); psum.w += __shfl_xor(psum.w, o);
    psq.x += __shfl_xor(psq.x, o); psq.y += __shfl_xor(psq.y, o);
    psq.z += __shfl_xor(psq.z, o); psq.w += __shfl_xor(psq.w, o);
  }
  if (lane < 16) {
    sred[w][lane * 4 + 0] = psum.x; sred[w][lane * 4 + 1] = psum.y;
    sred[w][lane * 4 + 2] = psum.z; sred[w][lane * 4 + 3] = psum.w;
    sred[w][64 + lane * 4 + 0] = psq.x; sred[w][64 + lane * 4 + 1] = psq.y;
    sred[w][64 + lane * 4 + 2] = psq.z; sred[w][64 + lane * 4 + 3] = psq.w;
  }
  __syncthreads();
  if (tid < 128)
    part[(long)blockIdx.x * 128 + tid] =
        sred[0][tid] + sred[1][tid] + sred[2][tid] + sred[3][tid];
}

// ---------------- BN finalize ----------------
__global__ __launch_bounds__(1024) void bn_finalize(const float* __restrict__ part, int nblk,
                                                    float invN, float* __restrict__ stats) {
  __shared__ float sh[1024];
  int t = threadIdx.x;
  int c = t & 127, g = t >> 7;
  float s = 0.f;
  for (int b = g; b < nblk; b += 8) s += part[(long)b * 128 + c];
  sh[t] = s;
  __syncthreads();
  if (t < 128) {
    float tot = 0.f;
#pragma unroll
    for (int g2 = 0; g2 < 8; ++g2) tot += sh[g2 * 128 + t];
    sh[t] = tot;
  }
  __syncthreads();
  if (t < 64) {
    float mean = sh[t] * invN;
    float var = sh[64 + t] * invN - mean * mean;
    stats[t] = mean;
    stats[64 + t] = rsqrtf(var + 1e-5f);
  }
}

// ---- fused: last BN-apply + residual + global mean partials (no h write) ----
__global__ void gsum_bn(const float* __restrict__ z, const float* __restrict__ stats,
                        const float* __restrict__ bng, const float* __restrict__ bnb,
                        const float* __restrict__ hprev, int n, float* __restrict__ part) {
  __shared__ float sh[4][64];
  int tid = threadIdx.x, w = tid >> 6, lane = tid & 63;
  float sm = stats[lane], sv = stats[64 + lane], gg = bng[lane], bb = bnb[lane];
  int gw = blockIdx.x * 4 + w, nW = gridDim.x * 4;
  float s = 0.f;
  for (int node = gw; node < n; node += nW) {
    float t = fmaxf((z[(long)node * 64 + lane] - sm) * sv * gg + bb, 0.f);
    s += hprev[(long)node * 64 + lane] + t;
  }
  sh[w][lane] = s;
  __syncthreads();
  if (tid < 64)
    part[(long)blockIdx.x * 64 + tid] =
        sh[0][tid] + sh[1][tid] + sh[2][tid] + sh[3][tid];
}

__global__ void final_kernel(const float* __restrict__ part, int nblk,
                             const float* __restrict__ out_W, const float* __restrict__ out_b,
                             float* __restrict__ out, float invN) {
  __shared__ float g[64];
  int c = threadIdx.x;  // 64 threads
  float s = 0.f;
  for (int b = 0; b < nblk; ++b) s += part[(long)b * 64 + c];
  g[c] = s * invN;
  __syncthreads();
  float acc = out_b[c];
  for (int k = 0; k < 64; ++k) acc += g[k] * out_W[k * 64 + c];
  out[c] = fmaxf(acc, 0.f);
}

// ---------------- host launch ----------------
extern "C" void kernel_launch(void* const* d_in, const int* in_sizes, int n_in,
                              void* d_out, int out_size, void* d_ws, size_t ws_size,
                              hipStream_t stream) {
  const float* x        = (const float*)d_in[0];
  const int*   eidx     = (const int*)d_in[1];
  const float* eattr    = (const float*)d_in[2];
  const float* np_W1    = (const float*)d_in[3];
  const float* np_b1    = (const float*)d_in[4];
  const float* np_W2    = (const float*)d_in[5];
  const float* np_b2    = (const float*)d_in[6];
  const float* np_ln_g  = (const float*)d_in[7];
  const float* np_ln_b  = (const float*)d_in[8];
  const float* ep_W1    = (const float*)d_in[9];
  const float* ep_b1    = (const float*)d_in[10];
  const float* ep_W2    = (const float*)d_in[11];
  const float* ep_b2    = (const float*)d_in[12];
  const float* ep_ln_g  = (const float*)d_in[13];
  const float* ep_ln_b  = (const float*)d_in[14];
  const float* enc_W    = (const float*)d_in[15];
  const float* enc_b    = (const float*)d_in[16];
  const float* enc_bn_g = (const float*)d_in[17];
  const float* enc_bn_b = (const float*)d_in[18];
  const float* gat_W    = (const float*)d_in[19];
  const float* gat_eW   = (const float*)d_in[20];
  const float* att_src  = (const float*)d_in[21];
  const float* att_dst  = (const float*)d_in[22];
  const float* att_edge = (const float*)d_in[23];
  const float* gat_b    = (const float*)d_in[24];
  const float* bn_g     = (const float*)d_in[25];
  const float* bn_b     = (const float*)d_in[26];
  const float* out_W    = (const float*)d_in[27];
  const float* out_b    = (const float*)d_in[28];

  const int n = in_sizes[0] / 128;   // 50000
  const int ne = in_sizes[1] / 2;    // 800000
  const int* srcp = eidx;
  const int* dstp = eidx + ne;

  float* f = (float*)d_ws;
  float* hbuf  = f; f += (long)n * 64;
  float* zbuf  = f; f += (long)n * 64;   // also reused as int2 csrt scratch pre-node_pre3
  float* alsb  = f; f += n;
  float* aldb  = f; f += n;
  float* ale   = f; f += 3L * ne;
  float* vgbuf = f; f += 128;
  float* stats = f; f += 128;
  float* part  = f; f += 131072;      // 1024 x 128
  float* part2 = f; f += 16384;       // 256 x 64
  unsigned short* wbb   = (unsigned short*)f; f += 2048;          // edge weights
  unsigned short* wnb   = (unsigned short*)f; f += 36864;         // node weights
  unsigned short* wgatb = (unsigned short*)f; f += 6144;          // 3 x 4096 gat weights
  unsigned short* xsb   = (unsigned short*)f; f += (long)n * 32;  // n*64 bf16
  int* ip = (int*)f;
  int2* csr = (int2*)ip; ip += 2L * ne;
  int* degb = ip; ip += n;
  int* cntb = ip; ip += n;
  int* offb = ip; ip += n + 1;
  int* bsum = ip; ip += 256;
  int2* csrt = (int2*)zbuf;  // ne*8B = 6.4MB <= zbuf 12.8MB; dead until node_pre3

  const int nbEdge = (ne + EB - 1) / EB;     // 6250
  const int nbNode = (n + 63) / 64;          // 782
  const int nbScan = (n + 255) / 256;        // 196

  hipMemsetAsync(degb, 0, (size_t)n * sizeof(int), stream);
  hipMemsetAsync(cntb, 0, (size_t)n * sizeof(int), stream);
  vprep2<<<1, 128, 0, stream>>>(gat_eW, att_edge, ep_ln_g, ep_ln_b, vgbuf);
  wpack<<<1, 256, 0, stream>>>(ep_W1, ep_W2, wbb);
  npack<<<288, 256, 0, stream>>>(np_W1, np_W2, enc_W, wnb);
  gpack<<<48, 256, 0, stream>>>(gat_W, wgatb);
  deg_kernel<<<1024, 256, 0, stream>>>(dstp, ne, degb);
  scan_blk<<<nbScan, 256, 0, stream>>>(degb, offb, bsum, n);
  scan_bsum<<<1, 256, 0, stream>>>(bsum, nbScan);
  scan_add<<<nbScan, 256, 0, stream>>>(bsum, offb, n);
  scatter_kernel<<<1024, 256, 0, stream>>>(srcp, dstp, ne, offb, cntb, csrt);
  csr_sort<<<1024, 256, 0, stream>>>(offb, csrt, csr, n);
  edge_pre4<<<nbEdge, 256, 0, stream>>>(eattr, wbb, ep_b1, ep_b2, vgbuf, ale, ne);
  node_pre3<<<nbNode, 256, 0, stream>>>(x, wnb, np_b1, np_b2, np_ln_g, np_ln_b,
                                        enc_b, zbuf, part, n);
  bn_finalize<<<1, 1024, 0, stream>>>(part, nbNode, 1.f / n, stats);
  xs_bn2<<<nbNode, 256, 0, stream>>>(zbuf, stats, enc_bn_g, enc_bn_b, hbuf, 0,
                                     wgatb, att_src, att_dst, xsb, alsb, aldb, n);
  for (int l = 0; l < 3; ++l) {
    gat3<<<1024, 256, 0, stream>>>(offb, csr, ale + (long)l * ne, alsb, aldb,
                                   xsb, gat_b + l * 64, zbuf, part, n);
    bn_finalize<<<1, 1024, 0, stream>>>(part, 1024, 1.f / n, stats);
    if (l < 2) {
      xs_bn2<<<nbNode, 256, 0, stream>>>(zbuf, stats, bn_g + l * 64, bn_b + l * 64, hbuf, 1,
                                         wgatb + (long)(l + 1) * 4096,
                                         att_src + (l + 1) * 64, att_dst + (l + 1) * 64,
                                         xsb, alsb, aldb, n);
    } else {
      gsum_bn<<<256, 256, 0, stream>>>(zbuf, stats, bn_g + l * 64, bn_b + l * 64,
                                       hbuf, n, part2);
    }
  }
  final_kernel<<<1, 64, 0, stream>>>(part2, 256, out_W, out_b, (float*)d_out, 1.f / n);
}

// Round 10
// 486.060 us; speedup vs baseline: 4.0344x; 1.1362x over previous
//
#include <hip/hip_runtime.h>
#include <hip/hip_bf16.h>

// GNNEncoder on MI355X. Algebraic reductions:
//  - (ea@eW)@a_e == ea@(eW@a_e): only 3 scalars al_e per edge needed.
//  - loop_attr contribution == mean(incoming al_e) by linearity.
//  - edge LN+dot folded: al = istd*(sum y*(g*v) - mean*G) + C.
// dst-CSR built once; scatter order from atomics made DETERMINISTIC by a
// per-segment sort on edge id (csr_sort) -- graph-replay == launch_once bitwise.
// MFMA kernels: weights pre-packed into fragment order (A-frag(row,k) ==
// B-frag(col,k) byte layout), tiny per-lane state, XOR-swizzled LDS.
// edge_pre4: transposed GEMMs so C-layout puts each edge in ONE lane.
// final2 (round 10): 1024-thr parallel reduce + LDS-resident out_W MLP
// (was: 1-wave kernel with 256 serial latency-bound loads = 63us).

typedef short bf16x8 __attribute__((ext_vector_type(8)));
typedef float f32x4 __attribute__((ext_vector_type(4)));
union U8 { uint4 u; bf16x8 v; };

__device__ __forceinline__ unsigned pack2bf(float a, float b) {
  unsigned ua = __float_as_uint(a); ua += 0x7fffu + ((ua >> 16) & 1u);
  unsigned ub = __float_as_uint(b); ub += 0x7fffu + ((ub >> 16) & 1u);
  return (ua >> 16) | (ub & 0xffff0000u);
}
__device__ __forceinline__ unsigned short f2bf(float x) {
  unsigned u = __float_as_uint(x); u += 0x7fffu + ((u >> 16) & 1u);
  return (unsigned short)(u >> 16);
}
__device__ __forceinline__ float bflo(unsigned u) { return __uint_as_float(u << 16); }
__device__ __forceinline__ float bfhi(unsigned u) { return __uint_as_float(u & 0xffff0000u); }

// ---------------- prep: v = eW@a_e, gv = lng*v, G = sum(lng*v), C = sum(lnb*v) ----------------
__global__ void vprep2(const float* __restrict__ eW, const float* __restrict__ a_e,
                       const float* __restrict__ lng, const float* __restrict__ lnb,
                       float* __restrict__ vg) {
  __shared__ float sv[96];
  int t = threadIdx.x;  // 128 threads
  if (t < 96) {
    int l = t >> 5, i = t & 31;
    const float* w = eW + l * 2048 + i * 64;
    const float* a = a_e + l * 64;
    float s = 0.f;
    for (int c = 0; c < 64; ++c) s += w[c] * a[c];
    sv[t] = s;
    vg[t] = s * lng[i];
  }
  __syncthreads();
  if (t < 3) {
    float G = 0.f, C = 0.f;
    for (int i = 0; i < 32; ++i) {
      float vv = sv[t * 32 + i];
      G += lng[i] * vv;
      C += lnb[i] * vv;
    }
    vg[96 + t] = G;
    vg[99 + t] = C;
  }
}

// pack W1[32x64], W2[64x32] into bf16 MFMA fragment order (edge MLP).
__global__ void wpack(const float* __restrict__ W1, const float* __restrict__ W2,
                      unsigned short* __restrict__ wb) {
  int t = threadIdx.x;  // 256
  for (int i = t; i < 2048; i += 256) {
    int nt = i >> 9, rem = i & 511, l = rem >> 3, j = rem & 7;
    int k = ((l >> 4) << 3) + j, col = (nt << 4) + (l & 15);
    wb[i] = f2bf(W1[k * 64 + col]);
  }
  for (int i = t; i < 2048; i += 256) {
    int sn = i >> 9, rem = i & 511, l = rem >> 3, j = rem & 7;
    int s = sn >> 1, nt = sn & 1;
    int k = s * 32 + ((l >> 4) << 3) + j, col = (nt << 4) + (l & 15);
    wb[2048 + i] = f2bf(W2[k * 32 + col]);
  }
}

// pack node-path weights: np_W1[128x256] (64 frags), np_W2[256x128] (64), enc_W[128x64] (16)
__global__ void npack(const float* __restrict__ W1, const float* __restrict__ W2,
                      const float* __restrict__ eW, unsigned short* __restrict__ wnb) {
  int i = blockIdx.x * blockDim.x + threadIdx.x;  // 73728 total
  if (i < 32768) {
    int fi = i >> 9, rem = i & 511, l = rem >> 3, j = rem & 7;
    int nt = fi >> 2, ks = fi & 3;
    int k = ks * 32 + ((l >> 4) << 3) + j, col = nt * 16 + (l & 15);
    wnb[i] = f2bf(W1[k * 256 + col]);
  } else if (i < 65536) {
    int i2 = i - 32768;
    int fi = i2 >> 9, rem = i2 & 511, l = rem >> 3, j = rem & 7;
    int nt = fi >> 3, ks = fi & 7;
    int k = ks * 32 + ((l >> 4) << 3) + j, col = nt * 16 + (l & 15);
    wnb[i] = f2bf(W2[k * 128 + col]);
  } else if (i < 73728) {
    int i3 = i - 65536;
    int fi = i3 >> 9, rem = i3 & 511, l = rem >> 3, j = rem & 7;
    int nt = fi >> 2, ks = fi & 3;
    int k = ks * 32 + ((l >> 4) << 3) + j, col = nt * 16 + (l & 15);
    wnb[i] = f2bf(eW[k * 64 + col]);
  }
}

// pack gat_W[3][64][64] into frag order: per layer 8 frags [nt*2+ks]
__global__ void gpack(const float* __restrict__ W, unsigned short* __restrict__ wg) {
  int i = blockIdx.x * blockDim.x + threadIdx.x;  // 12288 total
  if (i < 12288) {
    int l = i >> 12, rem = i & 4095;
    int fi = rem >> 9, l8 = rem & 511, ln = l8 >> 3, j = l8 & 7;
    int nt = fi >> 1, ks = fi & 1;
    int k = ks * 32 + ((ln >> 4) << 3) + j, col = nt * 16 + (ln & 15);
    wg[i] = f2bf(W[l * 4096 + k * 64 + col]);
  }
}

__global__ void deg_kernel(const int* __restrict__ dst, int ne, int* __restrict__ deg) {
  int i = blockIdx.x * blockDim.x + threadIdx.x;
  int stride = gridDim.x * blockDim.x;
  for (; i < ne; i += stride) atomicAdd(&deg[dst[i]], 1);
}

// ---- 3-phase multi-block scan ----
__global__ __launch_bounds__(256) void scan_blk(const int* __restrict__ deg,
                                                int* __restrict__ off,
                                                int* __restrict__ bsum, int n) {
  __shared__ int wsum[4];
  int b = blockIdx.x, t = threadIdx.x;
  int i = b * 256 + t;
  int lane = t & 63, w = t >> 6;
  int v = (i < n) ? deg[i] : 0;
  int s = v;
#pragma unroll
  for (int o = 1; o < 64; o <<= 1) {
    int u = __shfl_up(s, o);
    if (lane >= o) s += u;
  }
  if (lane == 63) wsum[w] = s;
  __syncthreads();
  int add = 0;
#pragma unroll
  for (int ww = 0; ww < 4; ++ww) add += (ww < w) ? wsum[ww] : 0;
  s += add;
  if (i < n) off[i + 1] = s;
  if (t == 255) bsum[b] = s;
}

__global__ __launch_bounds__(256) void scan_bsum(int* __restrict__ bsum, int nb) {
  __shared__ int sh[256];
  int t = threadIdx.x;
  sh[t] = (t < nb) ? bsum[t] : 0;
  __syncthreads();
  for (int o = 1; o < 256; o <<= 1) {
    int u = (t >= o) ? sh[t - o] : 0;
    __syncthreads();
    sh[t] += u;
    __syncthreads();
  }
  if (t < nb) bsum[t] = (t == 0) ? 0 : sh[t - 1];
}

__global__ __launch_bounds__(256) void scan_add(const int* __restrict__ bsum,
                                                int* __restrict__ off, int n) {
  int b = blockIdx.x, t = threadIdx.x;
  int i = b * 256 + t;
  int add = bsum[b];
  if (i < n) off[i + 1] += add;
  if (i == 0) off[0] = 0;
}

__global__ void scatter_kernel(const int* __restrict__ src, const int* __restrict__ dst,
                               int ne, const int* __restrict__ off, int* __restrict__ cnt,
                               int2* __restrict__ csrt) {
  int i = blockIdx.x * blockDim.x + threadIdx.x;
  int stride = gridDim.x * blockDim.x;
  for (; i < ne; i += stride) {
    int d = dst[i];
    int p = off[d] + atomicAdd(&cnt[d], 1);
    csrt[p] = make_int2(src[i], i);
  }
}

// ---- deterministic per-segment sort by edge id ----
#define SCAP 128
__global__ __launch_bounds__(256) void csr_sort(const int* __restrict__ off,
                                                const int2* __restrict__ csrt,
                                                int2* __restrict__ csr, int n) {
  __shared__ int seid[16][SCAP];
  int tid = threadIdx.x;
  int qt = tid >> 4, q = tid & 15;
  for (int node = blockIdx.x * 16 + qt; node < n; node += gridDim.x * 16) {
    int s0 = off[node], deg = off[node + 1] - s0;
    if (deg <= SCAP) {
      for (int k = q; k < deg; k += 16) seid[qt][k] = csrt[s0 + k].y;
      for (int k = q; k < deg; k += 16) {
        int e = seid[qt][k];
        int r = 0;
        for (int m = 0; m < deg; ++m) r += (seid[qt][m] < e) ? 1 : 0;
        csr[s0 + r] = csrt[s0 + k];
      }
    } else {
      for (int k = q; k < deg; k += 16) {
        int e = csrt[s0 + k].y;
        int r = 0;
        for (int m = 0; m < deg; ++m) r += (csrt[s0 + m].y < e) ? 1 : 0;
        csr[s0 + r] = csrt[s0 + k];
      }
    }
  }
}

// ---------------- edge preproc v4: transposed MFMA. block=256 (4 waves), 128 edges ----------------
#define EB 128
__global__ __launch_bounds__(256) void edge_pre4(
    const float* __restrict__ ea, const unsigned short* __restrict__ wb,
    const float* __restrict__ b1, const float* __restrict__ b2,
    const float* __restrict__ vg, float* __restrict__ ale, int ne) {
  __shared__ __align__(16) unsigned short swb[4096];
  __shared__ __align__(16) unsigned short sT[4][32 * 72];  // T[edge][hidden], 16B-block swizzled
  int tid = threadIdx.x, w = tid >> 6, lane = tid & 63;
  {
    const uint4* g = (const uint4*)wb;
    uint4* s = (uint4*)swb;
    for (int i = tid; i < 512; i += 256) s[i] = g[i];
  }
  __syncthreads();
  int lm = lane & 15, lq = lane >> 4;
  long e0 = (long)blockIdx.x * EB + w * 32;
  bf16x8 eab[2];
#pragma unroll
  for (int eh = 0; eh < 2; ++eh) {
    long e = e0 + eh * 16 + lm;
    if (e >= ne) e = ne - 1;
    const float4* p = (const float4*)(ea + e * 32 + lq * 8);
    float4 u = p[0], v = p[1];
    U8 cc;
    cc.u = make_uint4(pack2bf(u.x, u.y), pack2bf(u.z, u.w), pack2bf(v.x, v.y), pack2bf(v.z, v.w));
    eab[eh] = cc.v;
  }
  f32x4 zero = {0.f, 0.f, 0.f, 0.f};
  f32x4 c1[2][4];
#pragma unroll
  for (int eh = 0; eh < 2; ++eh)
#pragma unroll
    for (int nt = 0; nt < 4; ++nt) c1[eh][nt] = zero;
#pragma unroll
  for (int nt = 0; nt < 4; ++nt) {
    bf16x8 wf = *(const bf16x8*)&swb[nt * 512 + lane * 8];
#pragma unroll
    for (int eh = 0; eh < 2; ++eh)
      c1[eh][nt] = __builtin_amdgcn_mfma_f32_16x16x32_bf16(wf, eab[eh], c1[eh][nt], 0, 0, 0);
  }
#pragma unroll
  for (int nt = 0; nt < 4; ++nt) {
    float4 b1v = *(const float4*)&b1[nt * 16 + lq * 4];
#pragma unroll
    for (int eh = 0; eh < 2; ++eh) {
      int el = eh * 16 + lm;
      unsigned lo = pack2bf(fmaxf(c1[eh][nt][0] + b1v.x, 0.f), fmaxf(c1[eh][nt][1] + b1v.y, 0.f));
      unsigned hi = pack2bf(fmaxf(c1[eh][nt][2] + b1v.z, 0.f), fmaxf(c1[eh][nt][3] + b1v.w, 0.f));
      int blk = nt * 2 + (lq >> 1);
      int addr = el * 72 + (((blk ^ (el & 7)) << 3) | ((lq & 1) << 2));
      *(uint2*)&sT[w][addr] = make_uint2(lo, hi);
    }
  }
  __syncthreads();
  f32x4 c2[2][2];
#pragma unroll
  for (int eh = 0; eh < 2; ++eh)
#pragma unroll
    for (int ih = 0; ih < 2; ++ih) c2[eh][ih] = zero;
#pragma unroll
  for (int eh = 0; eh < 2; ++eh) {
    int el = eh * 16 + lm;
#pragma unroll
    for (int s = 0; s < 2; ++s) {
      int blk = s * 4 + lq;
      bf16x8 tb = *(const bf16x8*)&sT[w][el * 72 + ((blk ^ (el & 7)) << 3)];
#pragma unroll
      for (int ih = 0; ih < 2; ++ih) {
        bf16x8 wf = *(const bf16x8*)&swb[2048 + (s * 2 + ih) * 512 + lane * 8];
        c2[eh][ih] = __builtin_amdgcn_mfma_f32_16x16x32_bf16(wf, tb, c2[eh][ih], 0, 0, 0);
      }
    }
  }
  float4 b2v[2], g0v[2], g1v[2], g2v[2];
#pragma unroll
  for (int ih = 0; ih < 2; ++ih) {
    int ch0 = ih * 16 + lq * 4;
    b2v[ih] = *(const float4*)&b2[ch0];
    g0v[ih] = *(const float4*)&vg[ch0];
    g1v[ih] = *(const float4*)&vg[32 + ch0];
    g2v[ih] = *(const float4*)&vg[64 + ch0];
  }
  float G0 = vg[96], G1 = vg[97], G2 = vg[98];
  float C0 = vg[99], C1 = vg[100], C2 = vg[101];
#pragma unroll
  for (int eh = 0; eh < 2; ++eh) {
    float s = 0.f, q = 0.f, d0 = 0.f, d1 = 0.f, d2 = 0.f;
#pragma unroll
    for (int ih = 0; ih < 2; ++ih) {
      float bb[4] = {b2v[ih].x, b2v[ih].y, b2v[ih].z, b2v[ih].w};
      float g0[4] = {g0v[ih].x, g0v[ih].y, g0v[ih].z, g0v[ih].w};
      float g1[4] = {g1v[ih].x, g1v[ih].y, g1v[ih].z, g1v[ih].w};
      float g2[4] = {g2v[ih].x, g2v[ih].y, g2v[ih].z, g2v[ih].w};
#pragma unroll
      for (int r = 0; r < 4; ++r) {
        float y = c2[eh][ih][r] + bb[r];
        s += y; q += y * y;
        d0 += y * g0[r]; d1 += y * g1[r]; d2 += y * g2[r];
      }
    }
    s += __shfl_xor(s, 16); s += __shfl_xor(s, 32);
    q += __shfl_xor(q, 16); q += __shfl_xor(q, 32);
    d0 += __shfl_xor(d0, 16); d0 += __shfl_xor(d0, 32);
    d1 += __shfl_xor(d1, 16); d1 += __shfl_xor(d1, 32);
    d2 += __shfl_xor(d2, 16); d2 += __shfl_xor(d2, 32);
    long e = e0 + eh * 16 + lm;
    if (lq >= 1 && e < ne) {
      float mean = s * (1.f / 32.f);
      float var = q * (1.f / 32.f) - mean * mean;
      float istd = rsqrtf(var + 1e-5f);
      float d = (lq == 1) ? d0 : (lq == 2) ? d1 : d2;
      float Gp = (lq == 1) ? G0 : (lq == 2) ? G1 : G2;
      float Cp = (lq == 1) ? C0 : (lq == 2) ? C1 : C2;
      ale[(long)(lq - 1) * ne + e] = istd * (d - mean * Gp) + Cp;
    }
  }
}

// ---------------- node preproc v3: MFMA. block=256 (4 waves), 64 nodes ----------------
__global__ __launch_bounds__(256, 2) void node_pre3(
    const float* __restrict__ x, const unsigned short* __restrict__ wnb,
    const float* __restrict__ b1, const float* __restrict__ b2,
    const float* __restrict__ lng, const float* __restrict__ lnb,
    const float* __restrict__ encb, float* __restrict__ z_out,
    float* __restrict__ part, int n) {
  __shared__ __align__(16) unsigned short swb[16384];      // 32KB weight chunk
  __shared__ __align__(16) unsigned short sT[4][16 * 264]; // per-wave T / h1
  __shared__ float sred[4][128];
  int tid = threadIdx.x, w = tid >> 6, lane = tid & 63;
  int lm = lane & 15, lq = lane >> 4;
  long nb = (long)blockIdx.x * 64;
  const uint4* wg = (const uint4*)wnb;
  f32x4 zero = {0.f, 0.f, 0.f, 0.f};

  long row = nb + w * 16 + lm;
  if (row >= n) row = n - 1;
  bf16x8 ax[4];
  const float4* xp = (const float4*)(x + row * 128);
#pragma unroll
  for (int ks = 0; ks < 4; ++ks) {
    float4 u = xp[ks * 8 + lq * 2];
    float4 v = xp[ks * 8 + lq * 2 + 1];
    U8 cc;
    cc.u = make_uint4(pack2bf(u.x, u.y), pack2bf(u.z, u.w), pack2bf(v.x, v.y), pack2bf(v.z, v.w));
    ax[ks] = cc.v;
  }

  for (int h01 = 0; h01 < 2; ++h01) {
    __syncthreads();
    {
      const uint4* src = wg + h01 * 2048;
      uint4* dstv = (uint4*)swb;
      for (int i = tid; i < 2048; i += 256) dstv[i] = src[i];
    }
    __syncthreads();
    f32x4 acc1[8];
#pragma unroll
    for (int nt8 = 0; nt8 < 8; ++nt8) acc1[nt8] = zero;
#pragma unroll
    for (int ks = 0; ks < 4; ++ks)
#pragma unroll
      for (int nt8 = 0; nt8 < 8; ++nt8) {
        bf16x8 bf = *(const bf16x8*)&swb[(nt8 * 4 + ks) * 512 + lane * 8];
        acc1[nt8] = __builtin_amdgcn_mfma_f32_16x16x32_bf16(ax[ks], bf, acc1[nt8], 0, 0, 0);
      }
#pragma unroll
    for (int nt8 = 0; nt8 < 8; ++nt8) {
      int col = (h01 * 8 + nt8) * 16 + lm;
      float bv = b1[col];
#pragma unroll
      for (int r = 0; r < 4; ++r) {
        int rr = lq * 4 + r;
        sT[w][rr * 264 + (col ^ ((rr & 7) << 3))] = f2bf(fmaxf(acc1[nt8][r] + bv, 0.f));
      }
    }
  }

  f32x4 c2[8];
#pragma unroll
  for (int nt = 0; nt < 8; ++nt) c2[nt] = zero;
  for (int ksh = 0; ksh < 2; ++ksh) {
    __syncthreads();
    {
      uint4* dstv = (uint4*)swb;
      for (int i4 = tid; i4 < 2048; i4 += 256) {
        int e = i4 * 8;
        int fc = e >> 9, nt = fc >> 2, ksl = fc & 3;
        int ks = ksh * 4 + ksl;
        long gi = 32768 + (long)(nt * 8 + ks) * 512 + (e & 511);
        dstv[i4] = wg[gi >> 3];
      }
    }
    __syncthreads();
#pragma unroll
    for (int ksl = 0; ksl < 4; ++ksl) {
      int ks = ksh * 4 + ksl;
      bf16x8 at = *(const bf16x8*)&sT[w][lm * 264 + ((ks * 32 + lq * 8) ^ ((lm & 7) << 3))];
#pragma unroll
      for (int nt = 0; nt < 8; ++nt) {
        bf16x8 bf = *(const bf16x8*)&swb[(nt * 4 + ksl) * 512 + lane * 8];
        c2[nt] = __builtin_amdgcn_mfma_f32_16x16x32_bf16(at, bf, c2[nt], 0, 0, 0);
      }
    }
  }

  {
    float yv[8][4], bcol[8], gcol[8], ocol[8];
#pragma unroll
    for (int nt = 0; nt < 8; ++nt) {
      int col = nt * 16 + lm;
      bcol[nt] = b2[col]; gcol[nt] = lng[col]; ocol[nt] = lnb[col];
    }
    float s4[4], q4[4];
#pragma unroll
    for (int r = 0; r < 4; ++r) { s4[r] = 0.f; q4[r] = 0.f; }
#pragma unroll
    for (int nt = 0; nt < 8; ++nt)
#pragma unroll
      for (int r = 0; r < 4; ++r) {
        float y = c2[nt][r] + bcol[nt];
        yv[nt][r] = y;
        s4[r] += y; q4[r] += y * y;
      }
#pragma unroll
    for (int o = 1; o < 16; o <<= 1)
#pragma unroll
      for (int r = 0; r < 4; ++r) {
        s4[r] += __shfl_xor(s4[r], o);
        q4[r] += __shfl_xor(q4[r], o);
      }
#pragma unroll
    for (int r = 0; r < 4; ++r) {
      float mean = s4[r] * (1.f / 128.f);
      float var = q4[r] * (1.f / 128.f) - mean * mean;
      float istd = rsqrtf(var + 1e-5f);
      int rr = lq * 4 + r;
#pragma unroll
      for (int nt = 0; nt < 8; ++nt) {
        float hv = (yv[nt][r] - mean) * istd * gcol[nt] + ocol[nt];
        int col = nt * 16 + lm;
        if (col < 128)
          sT[w][rr * 264 + (col ^ ((rr & 7) << 3))] = f2bf(hv);
      }
    }
  }

  __syncthreads();
  {
    uint4* dstv = (uint4*)swb;
    const uint4* src = wg + (65536 >> 3);
    for (int i = tid; i < 1024; i += 256) dstv[i] = src[i];
  }
  __syncthreads();
  f32x4 c3[4];
#pragma unroll
  for (int nt = 0; nt < 4; ++nt) c3[nt] = zero;
#pragma unroll
  for (int ks = 0; ks < 4; ++ks) {
    bf16x8 at = *(const bf16x8*)&sT[w][lm * 264 + ((ks * 32 + lq * 8) ^ ((lm & 7) << 3))];
#pragma unroll
    for (int nt = 0; nt < 4; ++nt) {
      bf16x8 bf = *(const bf16x8*)&swb[(nt * 4 + ks) * 512 + lane * 8];
      c3[nt] = __builtin_amdgcn_mfma_f32_16x16x32_bf16(at, bf, c3[nt], 0, 0, 0);
    }
  }
  float ps[4], pq[4];
#pragma unroll
  for (int nt = 0; nt < 4; ++nt) { ps[nt] = 0.f; pq[nt] = 0.f; }
#pragma unroll
  for (int nt = 0; nt < 4; ++nt) {
    int col = nt * 16 + lm;
    float eb = encb[col];
#pragma unroll
    for (int r = 0; r < 4; ++r) {
      long nd = nb + w * 16 + lq * 4 + r;
      float z = c3[nt][r] + eb;
      if (nd < n) {
        z_out[nd * 64 + col] = z;
        ps[nt] += z; pq[nt] += z * z;
      }
    }
  }
#pragma unroll
  for (int o = 16; o < 64; o <<= 1)
#pragma unroll
    for (int nt = 0; nt < 4; ++nt) {
      ps[nt] += __shfl_xor(ps[nt], o);
      pq[nt] += __shfl_xor(pq[nt], o);
    }
  if (lq == 0) {
#pragma unroll
    for (int nt = 0; nt < 4; ++nt) {
      sred[w][nt * 16 + lm] = ps[nt];
      sred[w][64 + nt * 16 + lm] = pq[nt];
    }
  }
  __syncthreads();
  if (tid < 128) {
    float t = 0.f;
#pragma unroll
    for (int g = 0; g < 4; ++g) t += sred[g][tid];
    part[(long)blockIdx.x * 128 + tid] = t;
  }
}

// ---- fused MFMA: BN-apply(+residual into h) + xs = h@W (bf16) + al_s/al_d ----
__global__ __launch_bounds__(256) void xs_bn2(
    const float* __restrict__ z, const float* __restrict__ stats,
    const float* __restrict__ bng, const float* __restrict__ bnb,
    float* __restrict__ hbuf, int mode,
    const unsigned short* __restrict__ wgat,
    const float* __restrict__ a_s, const float* __restrict__ a_d,
    unsigned short* __restrict__ xsb, float* __restrict__ al_s, float* __restrict__ al_d,
    int n) {
  __shared__ __align__(16) unsigned short swg[4096];       // 8KB packed W
  __shared__ __align__(16) unsigned short shh[4][1024];    // per-wave h bf16, swizzled
  int tid = threadIdx.x, w = tid >> 6, lane = tid & 63;
  int lm = lane & 15, lq = lane >> 4;
  {
    const uint4* g = (const uint4*)wgat;
    uint4* s = (uint4*)swg;
    for (int i = tid; i < 512; i += 256) s[i] = g[i];
  }
  long nb = (long)blockIdx.x * 64;
  float sm = stats[lane], sv = stats[64 + lane], gg = bng[lane], bb = bnb[lane];
#pragma unroll
  for (int m = 0; m < 16; ++m) {
    long nd = nb + w * 16 + m;
    float hv = 0.f;
    if (nd < n) {
      float t = fmaxf((z[nd * 64 + lane] - sm) * sv * gg + bb, 0.f);
      hv = mode ? hbuf[nd * 64 + lane] + t : t;
      hbuf[nd * 64 + lane] = hv;
    }
    shh[w][m * 64 + (lane ^ ((m & 7) << 3))] = f2bf(hv);
  }
  __syncthreads();
  f32x4 zero = {0.f, 0.f, 0.f, 0.f};
  f32x4 c[4];
#pragma unroll
  for (int nt = 0; nt < 4; ++nt) c[nt] = zero;
#pragma unroll
  for (int ks = 0; ks < 2; ++ks) {
    bf16x8 at = *(const bf16x8*)&shh[w][lm * 64 + ((ks * 32 + lq * 8) ^ ((lm & 7) << 3))];
#pragma unroll
    for (int nt = 0; nt < 4; ++nt) {
      bf16x8 bf = *(const bf16x8*)&swg[(nt * 2 + ks) * 512 + lane * 8];
      c[nt] = __builtin_amdgcn_mfma_f32_16x16x32_bf16(at, bf, c[nt], 0, 0, 0);
    }
  }
  float asv[4], adv[4];
#pragma unroll
  for (int nt = 0; nt < 4; ++nt) { asv[nt] = a_s[nt * 16 + lm]; adv[nt] = a_d[nt * 16 + lm]; }
  float prs[4], prd[4];
#pragma unroll
  for (int r = 0; r < 4; ++r) {
    float s = 0.f, d = 0.f;
#pragma unroll
    for (int nt = 0; nt < 4; ++nt) {
      s += c[nt][r] * asv[nt];
      d += c[nt][r] * adv[nt];
    }
    prs[r] = s; prd[r] = d;
  }
#pragma unroll
  for (int o = 1; o < 16; o <<= 1)
#pragma unroll
    for (int r = 0; r < 4; ++r) {
      prs[r] += __shfl_xor(prs[r], o);
      prd[r] += __shfl_xor(prd[r], o);
    }
#pragma unroll
  for (int nt = 0; nt < 4; ++nt)
#pragma unroll
    for (int r = 0; r < 4; ++r) {
      long nd = nb + w * 16 + lq * 4 + r;
      if (nd < n) xsb[nd * 64 + nt * 16 + lm] = f2bf(c[nt][r]);
    }
  if (lm == 0) {
#pragma unroll
    for (int r = 0; r < 4; ++r) {
      long nd = nb + w * 16 + lq * 4 + r;
      if (nd < n) { al_s[nd] = prs[r]; al_d[nd] = prd[r]; }
    }
  }
}

// ---------------- GAT: quarter-wave (16 lanes) per node, bf16 xs gather ----------------
#define QCAP 128
__global__ __launch_bounds__(256) void gat3(
    const int* __restrict__ off, const int2* __restrict__ csr,
    const float* __restrict__ ale,
    const float* __restrict__ al_s, const float* __restrict__ al_d,
    const unsigned short* __restrict__ xsb, const float* __restrict__ bias,
    float* __restrict__ gat_out, float* __restrict__ part, int n) {
  __shared__ float2 sal[16][QCAP];
  __shared__ float sred[4][128];
  int tid = threadIdx.x, w = tid >> 6, lane = tid & 63;
  int qt = tid >> 4, q = tid & 15;
  const uint2* xr = (const uint2*)xsb;
  float4 bv = *(const float4*)&bias[q * 4];
  float4 psum = make_float4(0.f, 0.f, 0.f, 0.f), psq = psum;
  for (int node = blockIdx.x * 16 + qt; node < n; node += gridDim.x * 16) {
    int s0 = off[node];
    int deg = off[node + 1] - s0;
    bool fits = (deg <= QCAP);
    float aldn = al_d[node];
    float lmax = -3.402823466e38f, lsae = 0.f;
    for (int k = q; k < deg; k += 16) {
      int2 ce = csr[s0 + k];
      float ae = ale[ce.y];
      float a = al_s[ce.x] + aldn + ae;
      float al = (a >= 0.f) ? a : 0.2f * a;
      lmax = fmaxf(lmax, al);
      lsae += ae;
      if (fits) sal[qt][k] = make_float2(al, __int_as_float(ce.x));
    }
#pragma unroll
    for (int o = 1; o < 16; o <<= 1) {
      lmax = fmaxf(lmax, __shfl_xor(lmax, o));
      lsae += __shfl_xor(lsae, o);
    }
    float ae_self = lsae / fmaxf((float)deg, 1.f);
    float a_self = al_s[node] + aldn + ae_self;
    float al_self = (a_self >= 0.f) ? a_self : 0.2f * a_self;
    float mx = fmaxf(lmax, al_self);
    float lsum = 0.f;
    if (fits) {
      for (int k = q; k < deg; k += 16) {
        float ex = __expf(sal[qt][k].x - mx);
        sal[qt][k].x = ex;
        lsum += ex;
      }
    } else {
      for (int k = q; k < deg; k += 16) {
        int2 ce = csr[s0 + k];
        float a = al_s[ce.x] + aldn + ale[ce.y];
        float al = (a >= 0.f) ? a : 0.2f * a;
        lsum += __expf(al - mx);
      }
    }
#pragma unroll
    for (int o = 1; o < 16; o <<= 1) lsum += __shfl_xor(lsum, o);
    float exs = __expf(al_self - mx);
    float inv = 1.f / (lsum + exs + 1e-16f);
    uint2 xv = xr[(long)node * 16 + q];
    float4 acc;
    acc.x = exs * bflo(xv.x); acc.y = exs * bfhi(xv.x);
    acc.z = exs * bflo(xv.y); acc.w = exs * bfhi(xv.y);
    if (fits) {
      int k = 0;
      for (; k + 4 <= deg; k += 4) {
        float2 p0 = sal[qt][k], p1 = sal[qt][k + 1], p2 = sal[qt][k + 2], p3 = sal[qt][k + 3];
        uint2 x0 = xr[(long)__float_as_int(p0.y) * 16 + q];
        uint2 x1 = xr[(long)__float_as_int(p1.y) * 16 + q];
        uint2 x2 = xr[(long)__float_as_int(p2.y) * 16 + q];
        uint2 x3 = xr[(long)__float_as_int(p3.y) * 16 + q];
        acc.x += p0.x * bflo(x0.x) + p1.x * bflo(x1.x) + p2.x * bflo(x2.x) + p3.x * bflo(x3.x);
        acc.y += p0.x * bfhi(x0.x) + p1.x * bfhi(x1.x) + p2.x * bfhi(x2.x) + p3.x * bfhi(x3.x);
        acc.z += p0.x * bflo(x0.y) + p1.x * bflo(x1.y) + p2.x * bflo(x2.y) + p3.x * bflo(x3.y);
        acc.w += p0.x * bfhi(x0.y) + p1.x * bfhi(x1.y) + p2.x * bfhi(x2.y) + p3.x * bfhi(x3.y);
      }
      for (; k < deg; ++k) {
        float2 p = sal[qt][k];
        uint2 xk = xr[(long)__float_as_int(p.y) * 16 + q];
        acc.x += p.x * bflo(xk.x); acc.y += p.x * bfhi(xk.x);
        acc.z += p.x * bflo(xk.y); acc.w += p.x * bfhi(xk.y);
      }
    } else {
      for (int k = 0; k < deg; ++k) {
        int2 ce = csr[s0 + k];
        float a = al_s[ce.x] + aldn + ale[ce.y];
        float al = (a >= 0.f) ? a : 0.2f * a;
        float ex = __expf(al - mx);
        uint2 xk = xr[(long)ce.x * 16 + q];
        acc.x += ex * bflo(xk.x); acc.y += ex * bfhi(xk.x);
        acc.z += ex * bflo(xk.y); acc.w += ex * bfhi(xk.y);
      }
    }
    acc.x = acc.x * inv + bv.x; acc.y = acc.y * inv + bv.y;
    acc.z = acc.z * inv + bv.z; acc.w = acc.w * inv + bv.w;
    *(float4*)&gat_out[(long)node * 64 + q * 4] = acc;
    psum.x += acc.x; psum.y += acc.y; psum.z += acc.z; psum.w += acc.w;
    psq.x += acc.x * acc.x; psq.y += acc.y * acc.y; psq.z += acc.z * acc.z; psq.w += acc.w * acc.w;
  }
#pragma unroll
  for (int o = 16; o < 64; o <<= 1) {
    psum.x += __shfl_xor(psum.x, o); psum.y += __shfl_xor(psum.y, o);
    psum.z += __shfl_xor(psum.z, o); psum.w += __shfl_xor(psum.w, o);
    psq.x += __shfl_xor(psq.x, o); psq.y += __shfl_xor(psq.y, o);
    psq.z += __shfl_xor(psq.z, o); psq.w += __shfl_xor(psq.w, o);
  }
  if (lane < 16) {
    sred[w][lane * 4 + 0] = psum.x; sred[w][lane * 4 + 1] = psum.y;
    sred[w][lane * 4 + 2] = psum.z; sred[w][lane * 4 + 3] = psum.w;
    sred[w][64 + lane * 4 + 0] = psq.x; sred[w][64 + lane * 4 + 1] = psq.y;
    sred[w][64 + lane * 4 + 2] = psq.z; sred[w][64 + lane * 4 + 3] = psq.w;
  }
  __syncthreads();
  if (tid < 128)
    part[(long)blockIdx.x * 128 + tid] =
        sred[0][tid] + sred[1][tid] + sred[2][tid] + sred[3][tid];
}

// ---------------- BN finalize ----------------
__global__ __launch_bounds__(1024) void bn_finalize(const float* __restrict__ part, int nblk,
                                                    float invN, float* __restrict__ stats) {
  __shared__ float sh[1024];
  int t = threadIdx.x;
  int c = t & 127, g = t >> 7;
  float s = 0.f;
  for (int b = g; b < nblk; b += 8) s += part[(long)b * 128 + c];
  sh[t] = s;
  __syncthreads();
  if (t < 128) {
    float tot = 0.f;
#pragma unroll
    for (int g2 = 0; g2 < 8; ++g2) tot += sh[g2 * 128 + t];
    sh[t] = tot;
  }
  __syncthreads();
  if (t < 64) {
    float mean = sh[t] * invN;
    float var = sh[64 + t] * invN - mean * mean;
    stats[t] = mean;
    stats[64 + t] = rsqrtf(var + 1e-5f);
  }
}

// ---- fused: last BN-apply + residual + global mean partials (no h write) ----
__global__ void gsum_bn(const float* __restrict__ z, const float* __restrict__ stats,
                        const float* __restrict__ bng, const float* __restrict__ bnb,
                        const float* __restrict__ hprev, int n, float* __restrict__ part) {
  __shared__ float sh[4][64];
  int tid = threadIdx.x, w = tid >> 6, lane = tid & 63;
  float sm = stats[lane], sv = stats[64 + lane], gg = bng[lane], bb = bnb[lane];
  int gw = blockIdx.x * 4 + w, nW = gridDim.x * 4;
  float s = 0.f;
  for (int node = gw; node < n; node += nW) {
    float t = fmaxf((z[(long)node * 64 + lane] - sm) * sv * gg + bb, 0.f);
    s += hprev[(long)node * 64 + lane] + t;
  }
  sh[w][lane] = s;
  __syncthreads();
  if (tid < 64)
    part[(long)blockIdx.x * 64 + tid] =
        sh[0][tid] + sh[1][tid] + sh[2][tid] + sh[3][tid];
}

// ---- final: 1024-thr parallel reduce of part2 + LDS out_W MLP ----
__global__ __launch_bounds__(1024) void final2(const float* __restrict__ part, int nblk,
                                               const float* __restrict__ out_W,
                                               const float* __restrict__ out_b,
                                               float* __restrict__ out, float invN) {
  __shared__ float sh[1024];
  __shared__ float gmean[64];
  __shared__ __align__(16) float sW[4096];
  int t = threadIdx.x;
  {  // preload out_W (16KB) cooperatively
    for (int i = t; i < 1024; i += 1024)
      *(float4*)&sW[i * 4] = *(const float4*)&out_W[i * 4];
  }
  int c = t & 63, gr = t >> 6;  // 16 groups of 64 lanes
  float s = 0.f;
  for (int b = gr; b < nblk; b += 16) s += part[(long)b * 64 + c];
  sh[t] = s;
  __syncthreads();
  if (t < 64) {
    float tot = 0.f;
#pragma unroll
    for (int q = 0; q < 16; ++q) tot += sh[q * 64 + t];
    gmean[t] = tot * invN;
  }
  __syncthreads();
  if (t < 64) {
    float acc = out_b[t];
#pragma unroll
    for (int k = 0; k < 64; ++k) acc += gmean[k] * sW[k * 64 + t];
    out[t] = fmaxf(acc, 0.f);
  }
}

// ---------------- host launch ----------------
extern "C" void kernel_launch(void* const* d_in, const int* in_sizes, int n_in,
                              void* d_out, int out_size, void* d_ws, size_t ws_size,
                              hipStream_t stream) {
  const float* x        = (const float*)d_in[0];
  const int*   eidx     = (const int*)d_in[1];
  const float* eattr    = (const float*)d_in[2];
  const float* np_W1    = (const float*)d_in[3];
  const float* np_b1    = (const float*)d_in[4];
  const float* np_W2    = (const float*)d_in[5];
  const float* np_b2    = (const float*)d_in[6];
  const float* np_ln_g  = (const float*)d_in[7];
  const float* np_ln_b  = (const float*)d_in[8];
  const float* ep_W1    = (const float*)d_in[9];
  const float* ep_b1    = (const float*)d_in[10];
  const float* ep_W2    = (const float*)d_in[11];
  const float* ep_b2    = (const float*)d_in[12];
  const float* ep_ln_g  = (const float*)d_in[13];
  const float* ep_ln_b  = (const float*)d_in[14];
  const float* enc_W    = (const float*)d_in[15];
  const float* enc_b    = (const float*)d_in[16];
  const float* enc_bn_g = (const float*)d_in[17];
  const float* enc_bn_b = (const float*)d_in[18];
  const float* gat_W    = (const float*)d_in[19];
  const float* gat_eW   = (const float*)d_in[20];
  const float* att_src  = (const float*)d_in[21];
  const float* att_dst  = (const float*)d_in[22];
  const float* att_edge = (const float*)d_in[23];
  const float* gat_b    = (const float*)d_in[24];
  const float* bn_g     = (const float*)d_in[25];
  const float* bn_b     = (const float*)d_in[26];
  const float* out_W    = (const float*)d_in[27];
  const float* out_b    = (const float*)d_in[28];

  const int n = in_sizes[0] / 128;   // 50000
  const int ne = in_sizes[1] / 2;    // 800000
  const int* srcp = eidx;
  const int* dstp = eidx + ne;

  float* f = (float*)d_ws;
  float* hbuf  = f; f += (long)n * 64;
  float* zbuf  = f; f += (long)n * 64;   // also reused as int2 csrt scratch pre-node_pre3
  float* alsb  = f; f += n;
  float* aldb  = f; f += n;
  float* ale   = f; f += 3L * ne;
  float* vgbuf = f; f += 128;
  float* stats = f; f += 128;
  float* part  = f; f += 131072;      // 1024 x 128
  float* part2 = f; f += 16384;       // 256 x 64
  unsigned short* wbb   = (unsigned short*)f; f += 2048;          // edge weights
  unsigned short* wnb   = (unsigned short*)f; f += 36864;         // node weights
  unsigned short* wgatb = (unsigned short*)f; f += 6144;          // 3 x 4096 gat weights
  unsigned short* xsb   = (unsigned short*)f; f += (long)n * 32;  // n*64 bf16
  int* ip = (int*)f;
  int2* csr = (int2*)ip; ip += 2L * ne;
  int* degb = ip; ip += n;
  int* cntb = ip; ip += n;
  int* offb = ip; ip += n + 1;
  int* bsum = ip; ip += 256;
  int2* csrt = (int2*)zbuf;  // ne*8B = 6.4MB <= zbuf 12.8MB; dead until node_pre3

  const int nbEdge = (ne + EB - 1) / EB;     // 6250
  const int nbNode = (n + 63) / 64;          // 782
  const int nbScan = (n + 255) / 256;        // 196

  hipMemsetAsync(degb, 0, (size_t)n * sizeof(int), stream);
  hipMemsetAsync(cntb, 0, (size_t)n * sizeof(int), stream);
  vprep2<<<1, 128, 0, stream>>>(gat_eW, att_edge, ep_ln_g, ep_ln_b, vgbuf);
  wpack<<<1, 256, 0, stream>>>(ep_W1, ep_W2, wbb);
  npack<<<288, 256, 0, stream>>>(np_W1, np_W2, enc_W, wnb);
  gpack<<<48, 256, 0, stream>>>(gat_W, wgatb);
  deg_kernel<<<1024, 256, 0, stream>>>(dstp, ne, degb);
  scan_blk<<<nbScan, 256, 0, stream>>>(degb, offb, bsum, n);
  scan_bsum<<<1, 256, 0, stream>>>(bsum, nbScan);
  scan_add<<<nbScan, 256, 0, stream>>>(bsum, offb, n);
  scatter_kernel<<<1024, 256, 0, stream>>>(srcp, dstp, ne, offb, cntb, csrt);
  csr_sort<<<1024, 256, 0, stream>>>(offb, csrt, csr, n);
  edge_pre4<<<nbEdge, 256, 0, stream>>>(eattr, wbb, ep_b1, ep_b2, vgbuf, ale, ne);
  node_pre3<<<nbNode, 256, 0, stream>>>(x, wnb, np_b1, np_b2, np_ln_g, np_ln_b,
                                        enc_b, zbuf, part, n);
  bn_finalize<<<1, 1024, 0, stream>>>(part, nbNode, 1.f / n, stats);
  xs_bn2<<<nbNode, 256, 0, stream>>>(zbuf, stats, enc_bn_g, enc_bn_b, hbuf, 0,
                                     wgatb, att_src, att_dst, xsb, alsb, aldb, n);
  for (int l = 0; l < 3; ++l) {
    gat3<<<1024, 256, 0, stream>>>(offb, csr, ale + (long)l * ne, alsb, aldb,
                                   xsb, gat_b + l * 64, zbuf, part, n);
    bn_finalize<<<1, 1024, 0, stream>>>(part, 1024, 1.f / n, stats);
    if (l < 2) {
      xs_bn2<<<nbNode, 256, 0, stream>>>(zbuf, stats, bn_g + l * 64, bn_b + l * 64, hbuf, 1,
                                         wgatb + (long)(l + 1) * 4096,
                                         att_src + (l + 1) * 64, att_dst + (l + 1) * 64,
                                         xsb, alsb, aldb, n);
    } else {
      gsum_bn<<<256, 256, 0, stream>>>(zbuf, stats, bn_g + l * 64, bn_b + l * 64,
                                       hbuf, n, part2);
    }
  }
  final2<<<1, 1024, 0, stream>>>(part2, 256, out_W, out_b, (float*)d_out, 1.f / n);
}

// Round 11
// 435.876 us; speedup vs baseline: 4.4989x; 1.1151x over previous
//
#include <hip/hip_runtime.h>
#include <hip/hip_bf16.h>

// GNNEncoder on MI355X. Algebraic reductions:
//  - (ea@eW)@a_e == ea@(eW@a_e): only 3 scalars al_e per edge needed.
//  - loop_attr contribution == mean(incoming al_e) by linearity.
//  - edge LN+dot folded: al = istd*(sum y*(g*v) - mean*G) + C.
// dst-CSR built once; scatter order from atomics made DETERMINISTIC by a
// per-segment sort on edge id (csr_sort) -- graph-replay == launch_once bitwise.
// MFMA kernels: weights pre-packed into fragment order, tiny per-lane state,
// XOR-swizzled LDS. edge_pre4: transposed GEMMs (edge lives in ONE lane).
// Round 11: edge_b precomputes CSR-ordered {al_s[src]+ae, ae} + src so gat4's
// attention passes are fully coalesced (only the feature gather stays random);
// bn_finalize split into bn_red16 (16 blocks) + bn_stats (was 1-block 512KB).

typedef short bf16x8 __attribute__((ext_vector_type(8)));
typedef float f32x4 __attribute__((ext_vector_type(4)));
union U8 { uint4 u; bf16x8 v; };

__device__ __forceinline__ unsigned pack2bf(float a, float b) {
  unsigned ua = __float_as_uint(a); ua += 0x7fffu + ((ua >> 16) & 1u);
  unsigned ub = __float_as_uint(b); ub += 0x7fffu + ((ub >> 16) & 1u);
  return (ua >> 16) | (ub & 0xffff0000u);
}
__device__ __forceinline__ unsigned short f2bf(float x) {
  unsigned u = __float_as_uint(x); u += 0x7fffu + ((u >> 16) & 1u);
  return (unsigned short)(u >> 16);
}
__device__ __forceinline__ float bflo(unsigned u) { return __uint_as_float(u << 16); }
__device__ __forceinline__ float bfhi(unsigned u) { return __uint_as_float(u & 0xffff0000u); }

// ---------------- prep: v = eW@a_e, gv = lng*v, G = sum(lng*v), C = sum(lnb*v) ----------------
__global__ void vprep2(const float* __restrict__ eW, const float* __restrict__ a_e,
                       const float* __restrict__ lng, const float* __restrict__ lnb,
                       float* __restrict__ vg) {
  __shared__ float sv[96];
  int t = threadIdx.x;  // 128 threads
  if (t < 96) {
    int l = t >> 5, i = t & 31;
    const float* w = eW + l * 2048 + i * 64;
    const float* a = a_e + l * 64;
    float s = 0.f;
    for (int c = 0; c < 64; ++c) s += w[c] * a[c];
    sv[t] = s;
    vg[t] = s * lng[i];
  }
  __syncthreads();
  if (t < 3) {
    float G = 0.f, C = 0.f;
    for (int i = 0; i < 32; ++i) {
      float vv = sv[t * 32 + i];
      G += lng[i] * vv;
      C += lnb[i] * vv;
    }
    vg[96 + t] = G;
    vg[99 + t] = C;
  }
}

// pack W1[32x64], W2[64x32] into bf16 MFMA fragment order (edge MLP).
__global__ void wpack(const float* __restrict__ W1, const float* __restrict__ W2,
                      unsigned short* __restrict__ wb) {
  int t = threadIdx.x;  // 256
  for (int i = t; i < 2048; i += 256) {
    int nt = i >> 9, rem = i & 511, l = rem >> 3, j = rem & 7;
    int k = ((l >> 4) << 3) + j, col = (nt << 4) + (l & 15);
    wb[i] = f2bf(W1[k * 64 + col]);
  }
  for (int i = t; i < 2048; i += 256) {
    int sn = i >> 9, rem = i & 511, l = rem >> 3, j = rem & 7;
    int s = sn >> 1, nt = sn & 1;
    int k = s * 32 + ((l >> 4) << 3) + j, col = (nt << 4) + (l & 15);
    wb[2048 + i] = f2bf(W2[k * 32 + col]);
  }
}

// pack node-path weights: np_W1[128x256] (64 frags), np_W2[256x128] (64), enc_W[128x64] (16)
__global__ void npack(const float* __restrict__ W1, const float* __restrict__ W2,
                      const float* __restrict__ eW, unsigned short* __restrict__ wnb) {
  int i = blockIdx.x * blockDim.x + threadIdx.x;  // 73728 total
  if (i < 32768) {
    int fi = i >> 9, rem = i & 511, l = rem >> 3, j = rem & 7;
    int nt = fi >> 2, ks = fi & 3;
    int k = ks * 32 + ((l >> 4) << 3) + j, col = nt * 16 + (l & 15);
    wnb[i] = f2bf(W1[k * 256 + col]);
  } else if (i < 65536) {
    int i2 = i - 32768;
    int fi = i2 >> 9, rem = i2 & 511, l = rem >> 3, j = rem & 7;
    int nt = fi >> 3, ks = fi & 7;
    int k = ks * 32 + ((l >> 4) << 3) + j, col = nt * 16 + (l & 15);
    wnb[i] = f2bf(W2[k * 128 + col]);
  } else if (i < 73728) {
    int i3 = i - 65536;
    int fi = i3 >> 9, rem = i3 & 511, l = rem >> 3, j = rem & 7;
    int nt = fi >> 2, ks = fi & 3;
    int k = ks * 32 + ((l >> 4) << 3) + j, col = nt * 16 + (l & 15);
    wnb[i] = f2bf(eW[k * 64 + col]);
  }
}

// pack gat_W[3][64][64] into frag order: per layer 8 frags [nt*2+ks]
__global__ void gpack(const float* __restrict__ W, unsigned short* __restrict__ wg) {
  int i = blockIdx.x * blockDim.x + threadIdx.x;  // 12288 total
  if (i < 12288) {
    int l = i >> 12, rem = i & 4095;
    int fi = rem >> 9, l8 = rem & 511, ln = l8 >> 3, j = l8 & 7;
    int nt = fi >> 1, ks = fi & 1;
    int k = ks * 32 + ((ln >> 4) << 3) + j, col = nt * 16 + (ln & 15);
    wg[i] = f2bf(W[l * 4096 + k * 64 + col]);
  }
}

__global__ void deg_kernel(const int* __restrict__ dst, int ne, int* __restrict__ deg) {
  int i = blockIdx.x * blockDim.x + threadIdx.x;
  int stride = gridDim.x * blockDim.x;
  for (; i < ne; i += stride) atomicAdd(&deg[dst[i]], 1);
}

// ---- 3-phase multi-block scan ----
__global__ __launch_bounds__(256) void scan_blk(const int* __restrict__ deg,
                                                int* __restrict__ off,
                                                int* __restrict__ bsum, int n) {
  __shared__ int wsum[4];
  int b = blockIdx.x, t = threadIdx.x;
  int i = b * 256 + t;
  int lane = t & 63, w = t >> 6;
  int v = (i < n) ? deg[i] : 0;
  int s = v;
#pragma unroll
  for (int o = 1; o < 64; o <<= 1) {
    int u = __shfl_up(s, o);
    if (lane >= o) s += u;
  }
  if (lane == 63) wsum[w] = s;
  __syncthreads();
  int add = 0;
#pragma unroll
  for (int ww = 0; ww < 4; ++ww) add += (ww < w) ? wsum[ww] : 0;
  s += add;
  if (i < n) off[i + 1] = s;
  if (t == 255) bsum[b] = s;
}

__global__ __launch_bounds__(256) void scan_bsum(int* __restrict__ bsum, int nb) {
  __shared__ int sh[256];
  int t = threadIdx.x;
  sh[t] = (t < nb) ? bsum[t] : 0;
  __syncthreads();
  for (int o = 1; o < 256; o <<= 1) {
    int u = (t >= o) ? sh[t - o] : 0;
    __syncthreads();
    sh[t] += u;
    __syncthreads();
  }
  if (t < nb) bsum[t] = (t == 0) ? 0 : sh[t - 1];
}

__global__ __launch_bounds__(256) void scan_add(const int* __restrict__ bsum,
                                                int* __restrict__ off, int n) {
  int b = blockIdx.x, t = threadIdx.x;
  int i = b * 256 + t;
  int add = bsum[b];
  if (i < n) off[i + 1] += add;
  if (i == 0) off[0] = 0;
}

__global__ void scatter_kernel(const int* __restrict__ src, const int* __restrict__ dst,
                               int ne, const int* __restrict__ off, int* __restrict__ cnt,
                               int2* __restrict__ csrt) {
  int i = blockIdx.x * blockDim.x + threadIdx.x;
  int stride = gridDim.x * blockDim.x;
  for (; i < ne; i += stride) {
    int d = dst[i];
    int p = off[d] + atomicAdd(&cnt[d], 1);
    csrt[p] = make_int2(src[i], i);
  }
}

// ---- deterministic per-segment sort by edge id ----
#define SCAP 128
__global__ __launch_bounds__(256) void csr_sort(const int* __restrict__ off,
                                                const int2* __restrict__ csrt,
                                                int2* __restrict__ csr, int n) {
  __shared__ int seid[16][SCAP];
  int tid = threadIdx.x;
  int qt = tid >> 4, q = tid & 15;
  for (int node = blockIdx.x * 16 + qt; node < n; node += gridDim.x * 16) {
    int s0 = off[node], deg = off[node + 1] - s0;
    if (deg <= SCAP) {
      for (int k = q; k < deg; k += 16) seid[qt][k] = csrt[s0 + k].y;
      for (int k = q; k < deg; k += 16) {
        int e = seid[qt][k];
        int r = 0;
        for (int m = 0; m < deg; ++m) r += (seid[qt][m] < e) ? 1 : 0;
        csr[s0 + r] = csrt[s0 + k];
      }
    } else {
      for (int k = q; k < deg; k += 16) {
        int e = csrt[s0 + k].y;
        int r = 0;
        for (int m = 0; m < deg; ++m) r += (csrt[s0 + m].y < e) ? 1 : 0;
        csr[s0 + r] = csrt[s0 + k];
      }
    }
  }
}

// ---- per-layer: CSR-ordered b = al_s[src]+ae, ae, src (coalesced for gat4) ----
__global__ void edge_b(const int2* __restrict__ csr, const float* __restrict__ ale,
                       const float* __restrict__ al_s, float2* __restrict__ bcsr,
                       int* __restrict__ srcb, int ne) {
  int i = blockIdx.x * blockDim.x + threadIdx.x;
  int stride = gridDim.x * blockDim.x;
  for (; i < ne; i += stride) {
    int2 ce = csr[i];
    float ae = ale[ce.y];
    bcsr[i] = make_float2(al_s[ce.x] + ae, ae);
    srcb[i] = ce.x;
  }
}

// ---------------- edge preproc v4: transposed MFMA. block=256 (4 waves), 128 edges ----------------
#define EB 128
__global__ __launch_bounds__(256) void edge_pre4(
    const float* __restrict__ ea, const unsigned short* __restrict__ wb,
    const float* __restrict__ b1, const float* __restrict__ b2,
    const float* __restrict__ vg, float* __restrict__ ale, int ne) {
  __shared__ __align__(16) unsigned short swb[4096];
  __shared__ __align__(16) unsigned short sT[4][32 * 72];  // T[edge][hidden], 16B-block swizzled
  int tid = threadIdx.x, w = tid >> 6, lane = tid & 63;
  {
    const uint4* g = (const uint4*)wb;
    uint4* s = (uint4*)swb;
    for (int i = tid; i < 512; i += 256) s[i] = g[i];
  }
  __syncthreads();
  int lm = lane & 15, lq = lane >> 4;
  long e0 = (long)blockIdx.x * EB + w * 32;
  bf16x8 eab[2];
#pragma unroll
  for (int eh = 0; eh < 2; ++eh) {
    long e = e0 + eh * 16 + lm;
    if (e >= ne) e = ne - 1;
    const float4* p = (const float4*)(ea + e * 32 + lq * 8);
    float4 u = p[0], v = p[1];
    U8 cc;
    cc.u = make_uint4(pack2bf(u.x, u.y), pack2bf(u.z, u.w), pack2bf(v.x, v.y), pack2bf(v.z, v.w));
    eab[eh] = cc.v;
  }
  f32x4 zero = {0.f, 0.f, 0.f, 0.f};
  f32x4 c1[2][4];
#pragma unroll
  for (int eh = 0; eh < 2; ++eh)
#pragma unroll
    for (int nt = 0; nt < 4; ++nt) c1[eh][nt] = zero;
#pragma unroll
  for (int nt = 0; nt < 4; ++nt) {
    bf16x8 wf = *(const bf16x8*)&swb[nt * 512 + lane * 8];
#pragma unroll
    for (int eh = 0; eh < 2; ++eh)
      c1[eh][nt] = __builtin_amdgcn_mfma_f32_16x16x32_bf16(wf, eab[eh], c1[eh][nt], 0, 0, 0);
  }
#pragma unroll
  for (int nt = 0; nt < 4; ++nt) {
    float4 b1v = *(const float4*)&b1[nt * 16 + lq * 4];
#pragma unroll
    for (int eh = 0; eh < 2; ++eh) {
      int el = eh * 16 + lm;
      unsigned lo = pack2bf(fmaxf(c1[eh][nt][0] + b1v.x, 0.f), fmaxf(c1[eh][nt][1] + b1v.y, 0.f));
      unsigned hi = pack2bf(fmaxf(c1[eh][nt][2] + b1v.z, 0.f), fmaxf(c1[eh][nt][3] + b1v.w, 0.f));
      int blk = nt * 2 + (lq >> 1);
      int addr = el * 72 + (((blk ^ (el & 7)) << 3) | ((lq & 1) << 2));
      *(uint2*)&sT[w][addr] = make_uint2(lo, hi);
    }
  }
  __syncthreads();
  f32x4 c2[2][2];
#pragma unroll
  for (int eh = 0; eh < 2; ++eh)
#pragma unroll
    for (int ih = 0; ih < 2; ++ih) c2[eh][ih] = zero;
#pragma unroll
  for (int eh = 0; eh < 2; ++eh) {
    int el = eh * 16 + lm;
#pragma unroll
    for (int s = 0; s < 2; ++s) {
      int blk = s * 4 + lq;
      bf16x8 tb = *(const bf16x8*)&sT[w][el * 72 + ((blk ^ (el & 7)) << 3)];
#pragma unroll
      for (int ih = 0; ih < 2; ++ih) {
        bf16x8 wf = *(const bf16x8*)&swb[2048 + (s * 2 + ih) * 512 + lane * 8];
        c2[eh][ih] = __builtin_amdgcn_mfma_f32_16x16x32_bf16(wf, tb, c2[eh][ih], 0, 0, 0);
      }
    }
  }
  float4 b2v[2], g0v[2], g1v[2], g2v[2];
#pragma unroll
  for (int ih = 0; ih < 2; ++ih) {
    int ch0 = ih * 16 + lq * 4;
    b2v[ih] = *(const float4*)&b2[ch0];
    g0v[ih] = *(const float4*)&vg[ch0];
    g1v[ih] = *(const float4*)&vg[32 + ch0];
    g2v[ih] = *(const float4*)&vg[64 + ch0];
  }
  float G0 = vg[96], G1 = vg[97], G2 = vg[98];
  float C0 = vg[99], C1 = vg[100], C2 = vg[101];
#pragma unroll
  for (int eh = 0; eh < 2; ++eh) {
    float s = 0.f, q = 0.f, d0 = 0.f, d1 = 0.f, d2 = 0.f;
#pragma unroll
    for (int ih = 0; ih < 2; ++ih) {
      float bb[4] = {b2v[ih].x, b2v[ih].y, b2v[ih].z, b2v[ih].w};
      float g0[4] = {g0v[ih].x, g0v[ih].y, g0v[ih].z, g0v[ih].w};
      float g1[4] = {g1v[ih].x, g1v[ih].y, g1v[ih].z, g1v[ih].w};
      float g2[4] = {g2v[ih].x, g2v[ih].y, g2v[ih].z, g2v[ih].w};
#pragma unroll
      for (int r = 0; r < 4; ++r) {
        float y = c2[eh][ih][r] + bb[r];
        s += y; q += y * y;
        d0 += y * g0[r]; d1 += y * g1[r]; d2 += y * g2[r];
      }
    }
    s += __shfl_xor(s, 16); s += __shfl_xor(s, 32);
    q += __shfl_xor(q, 16); q += __shfl_xor(q, 32);
    d0 += __shfl_xor(d0, 16); d0 += __shfl_xor(d0, 32);
    d1 += __shfl_xor(d1, 16); d1 += __shfl_xor(d1, 32);
    d2 += __shfl_xor(d2, 16); d2 += __shfl_xor(d2, 32);
    long e = e0 + eh * 16 + lm;
    if (lq >= 1 && e < ne) {
      float mean = s * (1.f / 32.f);
      float var = q * (1.f / 32.f) - mean * mean;
      float istd = rsqrtf(var + 1e-5f);
      float d = (lq == 1) ? d0 : (lq == 2) ? d1 : d2;
      float Gp = (lq == 1) ? G0 : (lq == 2) ? G1 : G2;
      float Cp = (lq == 1) ? C0 : (lq == 2) ? C1 : C2;
      ale[(long)(lq - 1) * ne + e] = istd * (d - mean * Gp) + Cp;
    }
  }
}

// ---------------- node preproc v3: MFMA. block=256 (4 waves), 64 nodes ----------------
__global__ __launch_bounds__(256, 2) void node_pre3(
    const float* __restrict__ x, const unsigned short* __restrict__ wnb,
    const float* __restrict__ b1, const float* __restrict__ b2,
    const float* __restrict__ lng, const float* __restrict__ lnb,
    const float* __restrict__ encb, float* __restrict__ z_out,
    float* __restrict__ part, int n) {
  __shared__ __align__(16) unsigned short swb[16384];      // 32KB weight chunk
  __shared__ __align__(16) unsigned short sT[4][16 * 264]; // per-wave T / h1
  __shared__ float sred[4][128];
  int tid = threadIdx.x, w = tid >> 6, lane = tid & 63;
  int lm = lane & 15, lq = lane >> 4;
  long nb = (long)blockIdx.x * 64;
  const uint4* wg = (const uint4*)wnb;
  f32x4 zero = {0.f, 0.f, 0.f, 0.f};

  long row = nb + w * 16 + lm;
  if (row >= n) row = n - 1;
  bf16x8 ax[4];
  const float4* xp = (const float4*)(x + row * 128);
#pragma unroll
  for (int ks = 0; ks < 4; ++ks) {
    float4 u = xp[ks * 8 + lq * 2];
    float4 v = xp[ks * 8 + lq * 2 + 1];
    U8 cc;
    cc.u = make_uint4(pack2bf(u.x, u.y), pack2bf(u.z, u.w), pack2bf(v.x, v.y), pack2bf(v.z, v.w));
    ax[ks] = cc.v;
  }

  for (int h01 = 0; h01 < 2; ++h01) {
    __syncthreads();
    {
      const uint4* src = wg + h01 * 2048;
      uint4* dstv = (uint4*)swb;
      for (int i = tid; i < 2048; i += 256) dstv[i] = src[i];
    }
    __syncthreads();
    f32x4 acc1[8];
#pragma unroll
    for (int nt8 = 0; nt8 < 8; ++nt8) acc1[nt8] = zero;
#pragma unroll
    for (int ks = 0; ks < 4; ++ks)
#pragma unroll
      for (int nt8 = 0; nt8 < 8; ++nt8) {
        bf16x8 bf = *(const bf16x8*)&swb[(nt8 * 4 + ks) * 512 + lane * 8];
        acc1[nt8] = __builtin_amdgcn_mfma_f32_16x16x32_bf16(ax[ks], bf, acc1[nt8], 0, 0, 0);
      }
#pragma unroll
    for (int nt8 = 0; nt8 < 8; ++nt8) {
      int col = (h01 * 8 + nt8) * 16 + lm;
      float bv = b1[col];
#pragma unroll
      for (int r = 0; r < 4; ++r) {
        int rr = lq * 4 + r;
        sT[w][rr * 264 + (col ^ ((rr & 7) << 3))] = f2bf(fmaxf(acc1[nt8][r] + bv, 0.f));
      }
    }
  }

  f32x4 c2[8];
#pragma unroll
  for (int nt = 0; nt < 8; ++nt) c2[nt] = zero;
  for (int ksh = 0; ksh < 2; ++ksh) {
    __syncthreads();
    {
      uint4* dstv = (uint4*)swb;
      for (int i4 = tid; i4 < 2048; i4 += 256) {
        int e = i4 * 8;
        int fc = e >> 9, nt = fc >> 2, ksl = fc & 3;
        int ks = ksh * 4 + ksl;
        long gi = 32768 + (long)(nt * 8 + ks) * 512 + (e & 511);
        dstv[i4] = wg[gi >> 3];
      }
    }
    __syncthreads();
#pragma unroll
    for (int ksl = 0; ksl < 4; ++ksl) {
      int ks = ksh * 4 + ksl;
      bf16x8 at = *(const bf16x8*)&sT[w][lm * 264 + ((ks * 32 + lq * 8) ^ ((lm & 7) << 3))];
#pragma unroll
      for (int nt = 0; nt < 8; ++nt) {
        bf16x8 bf = *(const bf16x8*)&swb[(nt * 4 + ksl) * 512 + lane * 8];
        c2[nt] = __builtin_amdgcn_mfma_f32_16x16x32_bf16(at, bf, c2[nt], 0, 0, 0);
      }
    }
  }

  {
    float yv[8][4], bcol[8], gcol[8], ocol[8];
#pragma unroll
    for (int nt = 0; nt < 8; ++nt) {
      int col = nt * 16 + lm;
      bcol[nt] = b2[col]; gcol[nt] = lng[col]; ocol[nt] = lnb[col];
    }
    float s4[4], q4[4];
#pragma unroll
    for (int r = 0; r < 4; ++r) { s4[r] = 0.f; q4[r] = 0.f; }
#pragma unroll
    for (int nt = 0; nt < 8; ++nt)
#pragma unroll
      for (int r = 0; r < 4; ++r) {
        float y = c2[nt][r] + bcol[nt];
        yv[nt][r] = y;
        s4[r] += y; q4[r] += y * y;
      }
#pragma unroll
    for (int o = 1; o < 16; o <<= 1)
#pragma unroll
      for (int r = 0; r < 4; ++r) {
        s4[r] += __shfl_xor(s4[r], o);
        q4[r] += __shfl_xor(q4[r], o);
      }
#pragma unroll
    for (int r = 0; r < 4; ++r) {
      float mean = s4[r] * (1.f / 128.f);
      float var = q4[r] * (1.f / 128.f) - mean * mean;
      float istd = rsqrtf(var + 1e-5f);
      int rr = lq * 4 + r;
#pragma unroll
      for (int nt = 0; nt < 8; ++nt) {
        float hv = (yv[nt][r] - mean) * istd * gcol[nt] + ocol[nt];
        int col = nt * 16 + lm;
        if (col < 128)
          sT[w][rr * 264 + (col ^ ((rr & 7) << 3))] = f2bf(hv);
      }
    }
  }

  __syncthreads();
  {
    uint4* dstv = (uint4*)swb;
    const uint4* src = wg + (65536 >> 3);
    for (int i = tid; i < 1024; i += 256) dstv[i] = src[i];
  }
  __syncthreads();
  f32x4 c3[4];
#pragma unroll
  for (int nt = 0; nt < 4; ++nt) c3[nt] = zero;
#pragma unroll
  for (int ks = 0; ks < 4; ++ks) {
    bf16x8 at = *(const bf16x8*)&sT[w][lm * 264 + ((ks * 32 + lq * 8) ^ ((lm & 7) << 3))];
#pragma unroll
    for (int nt = 0; nt < 4; ++nt) {
      bf16x8 bf = *(const bf16x8*)&swb[(nt * 4 + ks) * 512 + lane * 8];
      c3[nt] = __builtin_amdgcn_mfma_f32_16x16x32_bf16(at, bf, c3[nt], 0, 0, 0);
    }
  }
  float ps[4], pq[4];
#pragma unroll
  for (int nt = 0; nt < 4; ++nt) { ps[nt] = 0.f; pq[nt] = 0.f; }
#pragma unroll
  for (int nt = 0; nt < 4; ++nt) {
    int col = nt * 16 + lm;
    float eb = encb[col];
#pragma unroll
    for (int r = 0; r < 4; ++r) {
      long nd = nb + w * 16 + lq * 4 + r;
      float z = c3[nt][r] + eb;
      if (nd < n) {
        z_out[nd * 64 + col] = z;
        ps[nt] += z; pq[nt] += z * z;
      }
    }
  }
#pragma unroll
  for (int o = 16; o < 64; o <<= 1)
#pragma unroll
    for (int nt = 0; nt < 4; ++nt) {
      ps[nt] += __shfl_xor(ps[nt], o);
      pq[nt] += __shfl_xor(pq[nt], o);
    }
  if (lq == 0) {
#pragma unroll
    for (int nt = 0; nt < 4; ++nt) {
      sred[w][nt * 16 + lm] = ps[nt];
      sred[w][64 + nt * 16 + lm] = pq[nt];
    }
  }
  __syncthreads();
  if (tid < 128) {
    float t = 0.f;
#pragma unroll
    for (int g = 0; g < 4; ++g) t += sred[g][tid];
    part[(long)blockIdx.x * 128 + tid] = t;
  }
}

// ---- fused MFMA: BN-apply(+residual into h) + xs = h@W (bf16) + al_s/al_d ----
__global__ __launch_bounds__(256) void xs_bn2(
    const float* __restrict__ z, const float* __restrict__ stats,
    const float* __restrict__ bng, const float* __restrict__ bnb,
    float* __restrict__ hbuf, int mode,
    const unsigned short* __restrict__ wgat,
    const float* __restrict__ a_s, const float* __restrict__ a_d,
    unsigned short* __restrict__ xsb, float* __restrict__ al_s, float* __restrict__ al_d,
    int n) {
  __shared__ __align__(16) unsigned short swg[4096];       // 8KB packed W
  __shared__ __align__(16) unsigned short shh[4][1024];    // per-wave h bf16, swizzled
  int tid = threadIdx.x, w = tid >> 6, lane = tid & 63;
  int lm = lane & 15, lq = lane >> 4;
  {
    const uint4* g = (const uint4*)wgat;
    uint4* s = (uint4*)swg;
    for (int i = tid; i < 512; i += 256) s[i] = g[i];
  }
  long nb = (long)blockIdx.x * 64;
  float sm = stats[lane], sv = stats[64 + lane], gg = bng[lane], bb = bnb[lane];
#pragma unroll
  for (int m = 0; m < 16; ++m) {
    long nd = nb + w * 16 + m;
    float hv = 0.f;
    if (nd < n) {
      float t = fmaxf((z[nd * 64 + lane] - sm) * sv * gg + bb, 0.f);
      hv = mode ? hbuf[nd * 64 + lane] + t : t;
      hbuf[nd * 64 + lane] = hv;
    }
    shh[w][m * 64 + (lane ^ ((m & 7) << 3))] = f2bf(hv);
  }
  __syncthreads();
  f32x4 zero = {0.f, 0.f, 0.f, 0.f};
  f32x4 c[4];
#pragma unroll
  for (int nt = 0; nt < 4; ++nt) c[nt] = zero;
#pragma unroll
  for (int ks = 0; ks < 2; ++ks) {
    bf16x8 at = *(const bf16x8*)&shh[w][lm * 64 + ((ks * 32 + lq * 8) ^ ((lm & 7) << 3))];
#pragma unroll
    for (int nt = 0; nt < 4; ++nt) {
      bf16x8 bf = *(const bf16x8*)&swg[(nt * 2 + ks) * 512 + lane * 8];
      c[nt] = __builtin_amdgcn_mfma_f32_16x16x32_bf16(at, bf, c[nt], 0, 0, 0);
    }
  }
  float asv[4], adv[4];
#pragma unroll
  for (int nt = 0; nt < 4; ++nt) { asv[nt] = a_s[nt * 16 + lm]; adv[nt] = a_d[nt * 16 + lm]; }
  float prs[4], prd[4];
#pragma unroll
  for (int r = 0; r < 4; ++r) {
    float s = 0.f, d = 0.f;
#pragma unroll
    for (int nt = 0; nt < 4; ++nt) {
      s += c[nt][r] * asv[nt];
      d += c[nt][r] * adv[nt];
    }
    prs[r] = s; prd[r] = d;
  }
#pragma unroll
  for (int o = 1; o < 16; o <<= 1)
#pragma unroll
    for (int r = 0; r < 4; ++r) {
      prs[r] += __shfl_xor(prs[r], o);
      prd[r] += __shfl_xor(prd[r], o);
    }
#pragma unroll
  for (int nt = 0; nt < 4; ++nt)
#pragma unroll
    for (int r = 0; r < 4; ++r) {
      long nd = nb + w * 16 + lq * 4 + r;
      if (nd < n) xsb[nd * 64 + nt * 16 + lm] = f2bf(c[nt][r]);
    }
  if (lm == 0) {
#pragma unroll
    for (int r = 0; r < 4; ++r) {
      long nd = nb + w * 16 + lq * 4 + r;
      if (nd < n) { al_s[nd] = prs[r]; al_d[nd] = prd[r]; }
    }
  }
}

// ---------------- GAT v4: coalesced bcsr/srcb streams; only xr gather random ----------------
#define QCAP 128
__global__ __launch_bounds__(256) void gat4(
    const int* __restrict__ off, const float2* __restrict__ bcsr,
    const int* __restrict__ srcb,
    const float* __restrict__ al_s, const float* __restrict__ al_d,
    const unsigned short* __restrict__ xsb, const float* __restrict__ bias,
    float* __restrict__ gat_out, float* __restrict__ part, int n) {
  __shared__ float2 sal[16][QCAP];
  __shared__ float sred[4][128];
  int tid = threadIdx.x, w = tid >> 6, lane = tid & 63;
  int qt = tid >> 4, q = tid & 15;
  const uint2* xr = (const uint2*)xsb;
  float4 bv = *(const float4*)&bias[q * 4];
  float4 psum = make_float4(0.f, 0.f, 0.f, 0.f), psq = psum;
  for (int node = blockIdx.x * 16 + qt; node < n; node += gridDim.x * 16) {
    int s0 = off[node];
    int deg = off[node + 1] - s0;
    bool fits = (deg <= QCAP);
    float aldn = al_d[node];
    float lmax = -3.402823466e38f, lsae = 0.f;
    for (int k = q; k < deg; k += 16) {
      float2 be = bcsr[s0 + k];
      float a = be.x + aldn;
      float al = (a >= 0.f) ? a : 0.2f * a;
      lmax = fmaxf(lmax, al);
      lsae += be.y;
      if (fits) sal[qt][k] = make_float2(al, __int_as_float(srcb[s0 + k]));
    }
#pragma unroll
    for (int o = 1; o < 16; o <<= 1) {
      lmax = fmaxf(lmax, __shfl_xor(lmax, o));
      lsae += __shfl_xor(lsae, o);
    }
    float ae_self = lsae / fmaxf((float)deg, 1.f);
    float a_self = al_s[node] + aldn + ae_self;
    float al_self = (a_self >= 0.f) ? a_self : 0.2f * a_self;
    float mx = fmaxf(lmax, al_self);
    float lsum = 0.f;
    if (fits) {
      for (int k = q; k < deg; k += 16) {
        float ex = __expf(sal[qt][k].x - mx);
        sal[qt][k].x = ex;
        lsum += ex;
      }
    } else {
      for (int k = q; k < deg; k += 16) {
        float2 be = bcsr[s0 + k];
        float a = be.x + aldn;
        float al = (a >= 0.f) ? a : 0.2f * a;
        lsum += __expf(al - mx);
      }
    }
#pragma unroll
    for (int o = 1; o < 16; o <<= 1) lsum += __shfl_xor(lsum, o);
    float exs = __expf(al_self - mx);
    float inv = 1.f / (lsum + exs + 1e-16f);
    uint2 xv = xr[(long)node * 16 + q];
    float4 acc;
    acc.x = exs * bflo(xv.x); acc.y = exs * bfhi(xv.x);
    acc.z = exs * bflo(xv.y); acc.w = exs * bfhi(xv.y);
    if (fits) {
      int k = 0;
      for (; k + 4 <= deg; k += 4) {
        float2 p0 = sal[qt][k], p1 = sal[qt][k + 1], p2 = sal[qt][k + 2], p3 = sal[qt][k + 3];
        uint2 x0 = xr[(long)__float_as_int(p0.y) * 16 + q];
        uint2 x1 = xr[(long)__float_as_int(p1.y) * 16 + q];
        uint2 x2 = xr[(long)__float_as_int(p2.y) * 16 + q];
        uint2 x3 = xr[(long)__float_as_int(p3.y) * 16 + q];
        acc.x += p0.x * bflo(x0.x) + p1.x * bflo(x1.x) + p2.x * bflo(x2.x) + p3.x * bflo(x3.x);
        acc.y += p0.x * bfhi(x0.x) + p1.x * bfhi(x1.x) + p2.x * bfhi(x2.x) + p3.x * bfhi(x3.x);
        acc.z += p0.x * bflo(x0.y) + p1.x * bflo(x1.y) + p2.x * bflo(x2.y) + p3.x * bflo(x3.y);
        acc.w += p0.x * bfhi(x0.y) + p1.x * bfhi(x1.y) + p2.x * bfhi(x2.y) + p3.x * bfhi(x3.y);
      }
      for (; k < deg; ++k) {
        float2 p = sal[qt][k];
        uint2 xk = xr[(long)__float_as_int(p.y) * 16 + q];
        acc.x += p.x * bflo(xk.x); acc.y += p.x * bfhi(xk.x);
        acc.z += p.x * bflo(xk.y); acc.w += p.x * bfhi(xk.y);
      }
    } else {
      for (int k = 0; k < deg; ++k) {
        float2 be = bcsr[s0 + k];
        float a = be.x + aldn;
        float al = (a >= 0.f) ? a : 0.2f * a;
        float ex = __expf(al - mx);
        uint2 xk = xr[(long)srcb[s0 + k] * 16 + q];
        acc.x += ex * bflo(xk.x); acc.y += ex * bfhi(xk.x);
        acc.z += ex * bflo(xk.y); acc.w += ex * bfhi(xk.y);
      }
    }
    acc.x = acc.x * inv + bv.x; acc.y = acc.y * inv + bv.y;
    acc.z = acc.z * inv + bv.z; acc.w = acc.w * inv + bv.w;
    *(float4*)&gat_out[(long)node * 64 + q * 4] = acc;
    psum.x += acc.x; psum.y += acc.y; psum.z += acc.z; psum.w += acc.w;
    psq.x += acc.x * acc.x; psq.y += acc.y * acc.y; psq.z += acc.z * acc.z; psq.w += acc.w * acc.w;
  }
#pragma unroll
  for (int o = 16; o < 64; o <<= 1) {
    psum.x += __shfl_xor(psum.x, o); psum.y += __shfl_xor(psum.y, o);
    psum.z += __shfl_xor(psum.z, o); psum.w += __shfl_xor(psum.w, o);
    psq.x += __shfl_xor(psq.x, o); psq.y += __shfl_xor(psq.y, o);
    psq.z += __shfl_xor(psq.z, o); psq.w += __shfl_xor(psq.w, o);
  }
  if (lane < 16) {
    sred[w][lane * 4 + 0] = psum.x; sred[w][lane * 4 + 1] = psum.y;
    sred[w][lane * 4 + 2] = psum.z; sred[w][lane * 4 + 3] = psum.w;
    sred[w][64 + lane * 4 + 0] = psq.x; sred[w][64 + lane * 4 + 1] = psq.y;
    sred[w][64 + lane * 4 + 2] = psq.z; sred[w][64 + lane * 4 + 3] = psq.w;
  }
  __syncthreads();
  if (tid < 128)
    part[(long)blockIdx.x * 128 + tid] =
        sred[0][tid] + sred[1][tid] + sred[2][tid] + sred[3][tid];
}

// ---------------- BN finalize: 2-stage (16 blocks + tiny) ----------------
__global__ __launch_bounds__(256) void bn_red16(const float* __restrict__ part, int nblk,
                                                float* __restrict__ part3) {
  int t = threadIdx.x, c = t & 127, g2 = t >> 7;
  int row0 = blockIdx.x * 2 + g2;  // 0..31
  float s = 0.f;
  for (int b = row0; b < nblk; b += 32) s += part[(long)b * 128 + c];
  part3[(long)row0 * 128 + c] = s;
}

__global__ __launch_bounds__(128) void bn_stats(const float* __restrict__ part3,
                                                float invN, float* __restrict__ stats) {
  __shared__ float sh[128];
  int t = threadIdx.x;
  float s = 0.f;
#pragma unroll 4
  for (int g = 0; g < 32; ++g) s += part3[g * 128 + t];
  sh[t] = s;
  __syncthreads();
  if (t < 64) {
    float mean = sh[t] * invN;
    float var = sh[64 + t] * invN - mean * mean;
    stats[t] = mean;
    stats[64 + t] = rsqrtf(var + 1e-5f);
  }
}

// ---- fused: last BN-apply + residual + global mean partials (no h write) ----
__global__ void gsum_bn(const float* __restrict__ z, const float* __restrict__ stats,
                        const float* __restrict__ bng, const float* __restrict__ bnb,
                        const float* __restrict__ hprev, int n, float* __restrict__ part) {
  __shared__ float sh[4][64];
  int tid = threadIdx.x, w = tid >> 6, lane = tid & 63;
  float sm = stats[lane], sv = stats[64 + lane], gg = bng[lane], bb = bnb[lane];
  int gw = blockIdx.x * 4 + w, nW = gridDim.x * 4;
  float s = 0.f;
  for (int node = gw; node < n; node += nW) {
    float t = fmaxf((z[(long)node * 64 + lane] - sm) * sv * gg + bb, 0.f);
    s += hprev[(long)node * 64 + lane] + t;
  }
  sh[w][lane] = s;
  __syncthreads();
  if (tid < 64)
    part[(long)blockIdx.x * 64 + tid] =
        sh[0][tid] + sh[1][tid] + sh[2][tid] + sh[3][tid];
}

// ---- final: 1024-thr parallel reduce of part2 + LDS out_W MLP ----
__global__ __launch_bounds__(1024) void final2(const float* __restrict__ part, int nblk,
                                               const float* __restrict__ out_W,
                                               const float* __restrict__ out_b,
                                               float* __restrict__ out, float invN) {
  __shared__ float sh[1024];
  __shared__ float gmean[64];
  __shared__ __align__(16) float sW[4096];
  int t = threadIdx.x;
  {
    for (int i = t; i < 1024; i += 1024)
      *(float4*)&sW[i * 4] = *(const float4*)&out_W[i * 4];
  }
  int c = t & 63, gr = t >> 6;
  float s = 0.f;
  for (int b = gr; b < nblk; b += 16) s += part[(long)b * 64 + c];
  sh[t] = s;
  __syncthreads();
  if (t < 64) {
    float tot = 0.f;
#pragma unroll
    for (int q = 0; q < 16; ++q) tot += sh[q * 64 + t];
    gmean[t] = tot * invN;
  }
  __syncthreads();
  if (t < 64) {
    float acc = out_b[t];
#pragma unroll
    for (int k = 0; k < 64; ++k) acc += gmean[k] * sW[k * 64 + t];
    out[t] = fmaxf(acc, 0.f);
  }
}

// ---------------- host launch ----------------
extern "C" void kernel_launch(void* const* d_in, const int* in_sizes, int n_in,
                              void* d_out, int out_size, void* d_ws, size_t ws_size,
                              hipStream_t stream) {
  const float* x        = (const float*)d_in[0];
  const int*   eidx     = (const int*)d_in[1];
  const float* eattr    = (const float*)d_in[2];
  const float* np_W1    = (const float*)d_in[3];
  const float* np_b1    = (const float*)d_in[4];
  const float* np_W2    = (const float*)d_in[5];
  const float* np_b2    = (const float*)d_in[6];
  const float* np_ln_g  = (const float*)d_in[7];
  const float* np_ln_b  = (const float*)d_in[8];
  const float* ep_W1    = (const float*)d_in[9];
  const float* ep_b1    = (const float*)d_in[10];
  const float* ep_W2    = (const float*)d_in[11];
  const float* ep_b2    = (const float*)d_in[12];
  const float* ep_ln_g  = (const float*)d_in[13];
  const float* ep_ln_b  = (const float*)d_in[14];
  const float* enc_W    = (const float*)d_in[15];
  const float* enc_b    = (const float*)d_in[16];
  const float* enc_bn_g = (const float*)d_in[17];
  const float* enc_bn_b = (const float*)d_in[18];
  const float* gat_W    = (const float*)d_in[19];
  const float* gat_eW   = (const float*)d_in[20];
  const float* att_src  = (const float*)d_in[21];
  const float* att_dst  = (const float*)d_in[22];
  const float* att_edge = (const float*)d_in[23];
  const float* gat_b    = (const float*)d_in[24];
  const float* bn_g     = (const float*)d_in[25];
  const float* bn_b     = (const float*)d_in[26];
  const float* out_W    = (const float*)d_in[27];
  const float* out_b    = (const float*)d_in[28];

  const int n = in_sizes[0] / 128;   // 50000
  const int ne = in_sizes[1] / 2;    // 800000
  const int* srcp = eidx;
  const int* dstp = eidx + ne;

  float* f = (float*)d_ws;
  float* hbuf  = f; f += (long)n * 64;
  float* zbuf  = f; f += (long)n * 64;   // also reused as int2 csrt scratch pre-node_pre3
  float* alsb  = f; f += n;
  float* aldb  = f; f += n;
  float* ale   = f; f += 3L * ne;
  float* vgbuf = f; f += 128;
  float* stats = f; f += 128;
  float* part  = f; f += 131072;      // 1024 x 128
  float* part2 = f; f += 16384;       // 256 x 64
  float* part3 = f; f += 4096;        // 32 x 128
  float2* bcsr = (float2*)f; f += 2L * ne;   // CSR-ordered {b, ae}
  unsigned short* wbb   = (unsigned short*)f; f += 2048;          // edge weights
  unsigned short* wnb   = (unsigned short*)f; f += 36864;         // node weights
  unsigned short* wgatb = (unsigned short*)f; f += 6144;          // 3 x 4096 gat weights
  unsigned short* xsb   = (unsigned short*)f; f += (long)n * 32;  // n*64 bf16
  int* ip = (int*)f;
  int2* csr = (int2*)ip; ip += 2L * ne;
  int* srcb = ip; ip += ne;            // CSR-ordered src
  int* degb = ip; ip += n;
  int* cntb = ip; ip += n;
  int* offb = ip; ip += n + 1;
  int* bsum = ip; ip += 256;
  int2* csrt = (int2*)zbuf;  // ne*8B = 6.4MB <= zbuf 12.8MB; dead until node_pre3

  const int nbEdge = (ne + EB - 1) / EB;     // 6250
  const int nbNode = (n + 63) / 64;          // 782
  const int nbScan = (n + 255) / 256;        // 196

  hipMemsetAsync(degb, 0, (size_t)n * sizeof(int), stream);
  hipMemsetAsync(cntb, 0, (size_t)n * sizeof(int), stream);
  vprep2<<<1, 128, 0, stream>>>(gat_eW, att_edge, ep_ln_g, ep_ln_b, vgbuf);
  wpack<<<1, 256, 0, stream>>>(ep_W1, ep_W2, wbb);
  npack<<<288, 256, 0, stream>>>(np_W1, np_W2, enc_W, wnb);
  gpack<<<48, 256, 0, stream>>>(gat_W, wgatb);
  deg_kernel<<<1024, 256, 0, stream>>>(dstp, ne, degb);
  scan_blk<<<nbScan, 256, 0, stream>>>(degb, offb, bsum, n);
  scan_bsum<<<1, 256, 0, stream>>>(bsum, nbScan);
  scan_add<<<nbScan, 256, 0, stream>>>(bsum, offb, n);
  scatter_kernel<<<1024, 256, 0, stream>>>(srcp, dstp, ne, offb, cntb, csrt);
  csr_sort<<<1024, 256, 0, stream>>>(offb, csrt, csr, n);
  edge_pre4<<<nbEdge, 256, 0, stream>>>(eattr, wbb, ep_b1, ep_b2, vgbuf, ale, ne);
  node_pre3<<<nbNode, 256, 0, stream>>>(x, wnb, np_b1, np_b2, np_ln_g, np_ln_b,
                                        enc_b, zbuf, part, n);
  bn_red16<<<16, 256, 0, stream>>>(part, nbNode, part3);
  bn_stats<<<1, 128, 0, stream>>>(part3, 1.f / n, stats);
  xs_bn2<<<nbNode, 256, 0, stream>>>(zbuf, stats, enc_bn_g, enc_bn_b, hbuf, 0,
                                     wgatb, att_src, att_dst, xsb, alsb, aldb, n);
  for (int l = 0; l < 3; ++l) {
    edge_b<<<1024, 256, 0, stream>>>(csr, ale + (long)l * ne, alsb, bcsr, srcb, ne);
    gat4<<<1024, 256, 0, stream>>>(offb, bcsr, srcb, alsb, aldb,
                                   xsb, gat_b + l * 64, zbuf, part, n);
    bn_red16<<<16, 256, 0, stream>>>(part, 1024, part3);
    bn_stats<<<1, 128, 0, stream>>>(part3, 1.f / n, stats);
    if (l < 2) {
      xs_bn2<<<nbNode, 256, 0, stream>>>(zbuf, stats, bn_g + l * 64, bn_b + l * 64, hbuf, 1,
                                         wgatb + (long)(l + 1) * 4096,
                                         att_src + (l + 1) * 64, att_dst + (l + 1) * 64,
                                         xsb, alsb, aldb, n);
    } else {
      gsum_bn<<<256, 256, 0, stream>>>(zbuf, stats, bn_g + l * 64, bn_b + l * 64,
                                       hbuf, n, part2);
    }
  }
  final2<<<1, 1024, 0, stream>>>(part2, 256, out_W, out_b, (float*)d_out, 1.f / n);
}

// Round 12
// 434.055 us; speedup vs baseline: 4.5178x; 1.0042x over previous
//
#include <hip/hip_runtime.h>
#include <hip/hip_bf16.h>

// GNNEncoder on MI355X. Algebraic reductions:
//  - (ea@eW)@a_e == ea@(eW@a_e): only 3 scalars al_e per edge needed.
//  - loop_attr contribution == mean(incoming al_e) by linearity.
//  - edge LN+dot folded: al = istd*(sum y*(g*v) - mean*G) + C.
// dst-CSR built once; scatter order from atomics made DETERMINISTIC by a
// per-segment sort on edge id (csr_sort) -- graph-replay == launch_once bitwise.
// MFMA kernels: weights pre-packed into fragment order, tiny per-lane state,
// XOR-swizzled LDS. edge_pre4: transposed GEMMs (edge lives in ONE lane).
// Round 12: xs stored FP8 e4m3 (64B rows, 3.2MB table -> per-XCD L2-resident);
// decode via exact bit trick f32(((b&80)<<24)|((b&7f)<<20)) * 2^120 folded into
// the attention weight. al_s/al_d still from f32 fragments (logits unchanged).

typedef short bf16x8 __attribute__((ext_vector_type(8)));
typedef float f32x4 __attribute__((ext_vector_type(4)));
union U8 { uint4 u; bf16x8 v; };

__device__ __forceinline__ unsigned pack2bf(float a, float b) {
  unsigned ua = __float_as_uint(a); ua += 0x7fffu + ((ua >> 16) & 1u);
  unsigned ub = __float_as_uint(b); ub += 0x7fffu + ((ub >> 16) & 1u);
  return (ua >> 16) | (ub & 0xffff0000u);
}
__device__ __forceinline__ unsigned short f2bf(float x) {
  unsigned u = __float_as_uint(x); u += 0x7fffu + ((u >> 16) & 1u);
  return (unsigned short)(u >> 16);
}
__device__ __forceinline__ float bflo(unsigned u) { return __uint_as_float(u << 16); }
__device__ __forceinline__ float bfhi(unsigned u) { return __uint_as_float(u & 0xffff0000u); }

// fp8 e4m3fn encode (RNE on normals, exact denormals, sat at 448)
__device__ __forceinline__ unsigned char f2fp8(float x) {
  unsigned u = __float_as_uint(x);
  unsigned s = (u >> 24) & 0x80u;
  float ax = fabsf(x);
  if (ax >= 448.f) return (unsigned char)(s | 0x7E);
  if (ax < 0.015625f) {                    // denormal: units of 2^-9
    int m = (int)(ax * 512.f + 0.5f);      // 0..8 (8 == 0x08 == min normal, bit-pattern valid)
    return (unsigned char)(s | (unsigned)m);
  }
  unsigned au = u & 0x7fffffffu;
  au += 0xFFFFFu + ((au >> 20) & 1u);      // RNE to 3-bit mantissa
  unsigned e = (au >> 23) - 120u;          // 1..15
  unsigned m = (au >> 20) & 7u;
  return (unsigned char)(s | (e << 3) | m);
}
// decode to value * 2^-120 (exact for normals, denormals, +-0)
__device__ __forceinline__ float fp8dec(unsigned b) {
  return __uint_as_float(((b & 0x80u) << 24) | ((b & 0x7fu) << 20));
}

// ---------------- prep: v = eW@a_e, gv = lng*v, G = sum(lng*v), C = sum(lnb*v) ----------------
__global__ void vprep2(const float* __restrict__ eW, const float* __restrict__ a_e,
                       const float* __restrict__ lng, const float* __restrict__ lnb,
                       float* __restrict__ vg) {
  __shared__ float sv[96];
  int t = threadIdx.x;  // 128 threads
  if (t < 96) {
    int l = t >> 5, i = t & 31;
    const float* w = eW + l * 2048 + i * 64;
    const float* a = a_e + l * 64;
    float s = 0.f;
    for (int c = 0; c < 64; ++c) s += w[c] * a[c];
    sv[t] = s;
    vg[t] = s * lng[i];
  }
  __syncthreads();
  if (t < 3) {
    float G = 0.f, C = 0.f;
    for (int i = 0; i < 32; ++i) {
      float vv = sv[t * 32 + i];
      G += lng[i] * vv;
      C += lnb[i] * vv;
    }
    vg[96 + t] = G;
    vg[99 + t] = C;
  }
}

// pack W1[32x64], W2[64x32] into bf16 MFMA fragment order (edge MLP).
__global__ void wpack(const float* __restrict__ W1, const float* __restrict__ W2,
                      unsigned short* __restrict__ wb) {
  int t = threadIdx.x;  // 256
  for (int i = t; i < 2048; i += 256) {
    int nt = i >> 9, rem = i & 511, l = rem >> 3, j = rem & 7;
    int k = ((l >> 4) << 3) + j, col = (nt << 4) + (l & 15);
    wb[i] = f2bf(W1[k * 64 + col]);
  }
  for (int i = t; i < 2048; i += 256) {
    int sn = i >> 9, rem = i & 511, l = rem >> 3, j = rem & 7;
    int s = sn >> 1, nt = sn & 1;
    int k = s * 32 + ((l >> 4) << 3) + j, col = (nt << 4) + (l & 15);
    wb[2048 + i] = f2bf(W2[k * 32 + col]);
  }
}

// pack node-path weights: np_W1[128x256] (64 frags), np_W2[256x128] (64), enc_W[128x64] (16)
__global__ void npack(const float* __restrict__ W1, const float* __restrict__ W2,
                      const float* __restrict__ eW, unsigned short* __restrict__ wnb) {
  int i = blockIdx.x * blockDim.x + threadIdx.x;  // 73728 total
  if (i < 32768) {
    int fi = i >> 9, rem = i & 511, l = rem >> 3, j = rem & 7;
    int nt = fi >> 2, ks = fi & 3;
    int k = ks * 32 + ((l >> 4) << 3) + j, col = nt * 16 + (l & 15);
    wnb[i] = f2bf(W1[k * 256 + col]);
  } else if (i < 65536) {
    int i2 = i - 32768;
    int fi = i2 >> 9, rem = i2 & 511, l = rem >> 3, j = rem & 7;
    int nt = fi >> 3, ks = fi & 7;
    int k = ks * 32 + ((l >> 4) << 3) + j, col = nt * 16 + (l & 15);
    wnb[i] = f2bf(W2[k * 128 + col]);
  } else if (i < 73728) {
    int i3 = i - 65536;
    int fi = i3 >> 9, rem = i3 & 511, l = rem >> 3, j = rem & 7;
    int nt = fi >> 2, ks = fi & 3;
    int k = ks * 32 + ((l >> 4) << 3) + j, col = nt * 16 + (l & 15);
    wnb[i] = f2bf(eW[k * 64 + col]);
  }
}

// pack gat_W[3][64][64] into frag order: per layer 8 frags [nt*2+ks]
__global__ void gpack(const float* __restrict__ W, unsigned short* __restrict__ wg) {
  int i = blockIdx.x * blockDim.x + threadIdx.x;  // 12288 total
  if (i < 12288) {
    int l = i >> 12, rem = i & 4095;
    int fi = rem >> 9, l8 = rem & 511, ln = l8 >> 3, j = l8 & 7;
    int nt = fi >> 1, ks = fi & 1;
    int k = ks * 32 + ((ln >> 4) << 3) + j, col = nt * 16 + (ln & 15);
    wg[i] = f2bf(W[l * 4096 + k * 64 + col]);
  }
}

__global__ void deg_kernel(const int* __restrict__ dst, int ne, int* __restrict__ deg) {
  int i = blockIdx.x * blockDim.x + threadIdx.x;
  int stride = gridDim.x * blockDim.x;
  for (; i < ne; i += stride) atomicAdd(&deg[dst[i]], 1);
}

// ---- 3-phase multi-block scan ----
__global__ __launch_bounds__(256) void scan_blk(const int* __restrict__ deg,
                                                int* __restrict__ off,
                                                int* __restrict__ bsum, int n) {
  __shared__ int wsum[4];
  int b = blockIdx.x, t = threadIdx.x;
  int i = b * 256 + t;
  int lane = t & 63, w = t >> 6;
  int v = (i < n) ? deg[i] : 0;
  int s = v;
#pragma unroll
  for (int o = 1; o < 64; o <<= 1) {
    int u = __shfl_up(s, o);
    if (lane >= o) s += u;
  }
  if (lane == 63) wsum[w] = s;
  __syncthreads();
  int add = 0;
#pragma unroll
  for (int ww = 0; ww < 4; ++ww) add += (ww < w) ? wsum[ww] : 0;
  s += add;
  if (i < n) off[i + 1] = s;
  if (t == 255) bsum[b] = s;
}

__global__ __launch_bounds__(256) void scan_bsum(int* __restrict__ bsum, int nb) {
  __shared__ int sh[256];
  int t = threadIdx.x;
  sh[t] = (t < nb) ? bsum[t] : 0;
  __syncthreads();
  for (int o = 1; o < 256; o <<= 1) {
    int u = (t >= o) ? sh[t - o] : 0;
    __syncthreads();
    sh[t] += u;
    __syncthreads();
  }
  if (t < nb) bsum[t] = (t == 0) ? 0 : sh[t - 1];
}

__global__ __launch_bounds__(256) void scan_add(const int* __restrict__ bsum,
                                                int* __restrict__ off, int n) {
  int b = blockIdx.x, t = threadIdx.x;
  int i = b * 256 + t;
  int add = bsum[b];
  if (i < n) off[i + 1] += add;
  if (i == 0) off[0] = 0;
}

__global__ void scatter_kernel(const int* __restrict__ src, const int* __restrict__ dst,
                               int ne, const int* __restrict__ off, int* __restrict__ cnt,
                               int2* __restrict__ csrt) {
  int i = blockIdx.x * blockDim.x + threadIdx.x;
  int stride = gridDim.x * blockDim.x;
  for (; i < ne; i += stride) {
    int d = dst[i];
    int p = off[d] + atomicAdd(&cnt[d], 1);
    csrt[p] = make_int2(src[i], i);
  }
}

// ---- deterministic per-segment sort by edge id ----
#define SCAP 128
__global__ __launch_bounds__(256) void csr_sort(const int* __restrict__ off,
                                                const int2* __restrict__ csrt,
                                                int2* __restrict__ csr, int n) {
  __shared__ int seid[16][SCAP];
  int tid = threadIdx.x;
  int qt = tid >> 4, q = tid & 15;
  for (int node = blockIdx.x * 16 + qt; node < n; node += gridDim.x * 16) {
    int s0 = off[node], deg = off[node + 1] - s0;
    if (deg <= SCAP) {
      for (int k = q; k < deg; k += 16) seid[qt][k] = csrt[s0 + k].y;
      for (int k = q; k < deg; k += 16) {
        int e = seid[qt][k];
        int r = 0;
        for (int m = 0; m < deg; ++m) r += (seid[qt][m] < e) ? 1 : 0;
        csr[s0 + r] = csrt[s0 + k];
      }
    } else {
      for (int k = q; k < deg; k += 16) {
        int e = csrt[s0 + k].y;
        int r = 0;
        for (int m = 0; m < deg; ++m) r += (csrt[s0 + m].y < e) ? 1 : 0;
        csr[s0 + r] = csrt[s0 + k];
      }
    }
  }
}

// ---- per-layer: CSR-ordered b = al_s[src]+ae, ae, src (coalesced for gat4) ----
__global__ void edge_b(const int2* __restrict__ csr, const float* __restrict__ ale,
                       const float* __restrict__ al_s, float2* __restrict__ bcsr,
                       int* __restrict__ srcb, int ne) {
  int i = blockIdx.x * blockDim.x + threadIdx.x;
  int stride = gridDim.x * blockDim.x;
  for (; i < ne; i += stride) {
    int2 ce = csr[i];
    float ae = ale[ce.y];
    bcsr[i] = make_float2(al_s[ce.x] + ae, ae);
    srcb[i] = ce.x;
  }
}

// ---------------- edge preproc v4: transposed MFMA. block=256 (4 waves), 128 edges ----------------
#define EB 128
__global__ __launch_bounds__(256) void edge_pre4(
    const float* __restrict__ ea, const unsigned short* __restrict__ wb,
    const float* __restrict__ b1, const float* __restrict__ b2,
    const float* __restrict__ vg, float* __restrict__ ale, int ne) {
  __shared__ __align__(16) unsigned short swb[4096];
  __shared__ __align__(16) unsigned short sT[4][32 * 72];  // T[edge][hidden], 16B-block swizzled
  int tid = threadIdx.x, w = tid >> 6, lane = tid & 63;
  {
    const uint4* g = (const uint4*)wb;
    uint4* s = (uint4*)swb;
    for (int i = tid; i < 512; i += 256) s[i] = g[i];
  }
  __syncthreads();
  int lm = lane & 15, lq = lane >> 4;
  long e0 = (long)blockIdx.x * EB + w * 32;
  bf16x8 eab[2];
#pragma unroll
  for (int eh = 0; eh < 2; ++eh) {
    long e = e0 + eh * 16 + lm;
    if (e >= ne) e = ne - 1;
    const float4* p = (const float4*)(ea + e * 32 + lq * 8);
    float4 u = p[0], v = p[1];
    U8 cc;
    cc.u = make_uint4(pack2bf(u.x, u.y), pack2bf(u.z, u.w), pack2bf(v.x, v.y), pack2bf(v.z, v.w));
    eab[eh] = cc.v;
  }
  f32x4 zero = {0.f, 0.f, 0.f, 0.f};
  f32x4 c1[2][4];
#pragma unroll
  for (int eh = 0; eh < 2; ++eh)
#pragma unroll
    for (int nt = 0; nt < 4; ++nt) c1[eh][nt] = zero;
#pragma unroll
  for (int nt = 0; nt < 4; ++nt) {
    bf16x8 wf = *(const bf16x8*)&swb[nt * 512 + lane * 8];
#pragma unroll
    for (int eh = 0; eh < 2; ++eh)
      c1[eh][nt] = __builtin_amdgcn_mfma_f32_16x16x32_bf16(wf, eab[eh], c1[eh][nt], 0, 0, 0);
  }
#pragma unroll
  for (int nt = 0; nt < 4; ++nt) {
    float4 b1v = *(const float4*)&b1[nt * 16 + lq * 4];
#pragma unroll
    for (int eh = 0; eh < 2; ++eh) {
      int el = eh * 16 + lm;
      unsigned lo = pack2bf(fmaxf(c1[eh][nt][0] + b1v.x, 0.f), fmaxf(c1[eh][nt][1] + b1v.y, 0.f));
      unsigned hi = pack2bf(fmaxf(c1[eh][nt][2] + b1v.z, 0.f), fmaxf(c1[eh][nt][3] + b1v.w, 0.f));
      int blk = nt * 2 + (lq >> 1);
      int addr = el * 72 + (((blk ^ (el & 7)) << 3) | ((lq & 1) << 2));
      *(uint2*)&sT[w][addr] = make_uint2(lo, hi);
    }
  }
  __syncthreads();
  f32x4 c2[2][2];
#pragma unroll
  for (int eh = 0; eh < 2; ++eh)
#pragma unroll
    for (int ih = 0; ih < 2; ++ih) c2[eh][ih] = zero;
#pragma unroll
  for (int eh = 0; eh < 2; ++eh) {
    int el = eh * 16 + lm;
#pragma unroll
    for (int s = 0; s < 2; ++s) {
      int blk = s * 4 + lq;
      bf16x8 tb = *(const bf16x8*)&sT[w][el * 72 + ((blk ^ (el & 7)) << 3)];
#pragma unroll
      for (int ih = 0; ih < 2; ++ih) {
        bf16x8 wf = *(const bf16x8*)&swb[2048 + (s * 2 + ih) * 512 + lane * 8];
        c2[eh][ih] = __builtin_amdgcn_mfma_f32_16x16x32_bf16(wf, tb, c2[eh][ih], 0, 0, 0);
      }
    }
  }
  float4 b2v[2], g0v[2], g1v[2], g2v[2];
#pragma unroll
  for (int ih = 0; ih < 2; ++ih) {
    int ch0 = ih * 16 + lq * 4;
    b2v[ih] = *(const float4*)&b2[ch0];
    g0v[ih] = *(const float4*)&vg[ch0];
    g1v[ih] = *(const float4*)&vg[32 + ch0];
    g2v[ih] = *(const float4*)&vg[64 + ch0];
  }
  float G0 = vg[96], G1 = vg[97], G2 = vg[98];
  float C0 = vg[99], C1 = vg[100], C2 = vg[101];
#pragma unroll
  for (int eh = 0; eh < 2; ++eh) {
    float s = 0.f, q = 0.f, d0 = 0.f, d1 = 0.f, d2 = 0.f;
#pragma unroll
    for (int ih = 0; ih < 2; ++ih) {
      float bb[4] = {b2v[ih].x, b2v[ih].y, b2v[ih].z, b2v[ih].w};
      float g0[4] = {g0v[ih].x, g0v[ih].y, g0v[ih].z, g0v[ih].w};
      float g1[4] = {g1v[ih].x, g1v[ih].y, g1v[ih].z, g1v[ih].w};
      float g2[4] = {g2v[ih].x, g2v[ih].y, g2v[ih].z, g2v[ih].w};
#pragma unroll
      for (int r = 0; r < 4; ++r) {
        float y = c2[eh][ih][r] + bb[r];
        s += y; q += y * y;
        d0 += y * g0[r]; d1 += y * g1[r]; d2 += y * g2[r];
      }
    }
    s += __shfl_xor(s, 16); s += __shfl_xor(s, 32);
    q += __shfl_xor(q, 16); q += __shfl_xor(q, 32);
    d0 += __shfl_xor(d0, 16); d0 += __shfl_xor(d0, 32);
    d1 += __shfl_xor(d1, 16); d1 += __shfl_xor(d1, 32);
    d2 += __shfl_xor(d2, 16); d2 += __shfl_xor(d2, 32);
    long e = e0 + eh * 16 + lm;
    if (lq >= 1 && e < ne) {
      float mean = s * (1.f / 32.f);
      float var = q * (1.f / 32.f) - mean * mean;
      float istd = rsqrtf(var + 1e-5f);
      float d = (lq == 1) ? d0 : (lq == 2) ? d1 : d2;
      float Gp = (lq == 1) ? G0 : (lq == 2) ? G1 : G2;
      float Cp = (lq == 1) ? C0 : (lq == 2) ? C1 : C2;
      ale[(long)(lq - 1) * ne + e] = istd * (d - mean * Gp) + Cp;
    }
  }
}

// ---------------- node preproc v3: MFMA. block=256 (4 waves), 64 nodes ----------------
__global__ __launch_bounds__(256, 2) void node_pre3(
    const float* __restrict__ x, const unsigned short* __restrict__ wnb,
    const float* __restrict__ b1, const float* __restrict__ b2,
    const float* __restrict__ lng, const float* __restrict__ lnb,
    const float* __restrict__ encb, float* __restrict__ z_out,
    float* __restrict__ part, int n) {
  __shared__ __align__(16) unsigned short swb[16384];      // 32KB weight chunk
  __shared__ __align__(16) unsigned short sT[4][16 * 264]; // per-wave T / h1
  __shared__ float sred[4][128];
  int tid = threadIdx.x, w = tid >> 6, lane = tid & 63;
  int lm = lane & 15, lq = lane >> 4;
  long nb = (long)blockIdx.x * 64;
  const uint4* wg = (const uint4*)wnb;
  f32x4 zero = {0.f, 0.f, 0.f, 0.f};

  long row = nb + w * 16 + lm;
  if (row >= n) row = n - 1;
  bf16x8 ax[4];
  const float4* xp = (const float4*)(x + row * 128);
#pragma unroll
  for (int ks = 0; ks < 4; ++ks) {
    float4 u = xp[ks * 8 + lq * 2];
    float4 v = xp[ks * 8 + lq * 2 + 1];
    U8 cc;
    cc.u = make_uint4(pack2bf(u.x, u.y), pack2bf(u.z, u.w), pack2bf(v.x, v.y), pack2bf(v.z, v.w));
    ax[ks] = cc.v;
  }

  for (int h01 = 0; h01 < 2; ++h01) {
    __syncthreads();
    {
      const uint4* src = wg + h01 * 2048;
      uint4* dstv = (uint4*)swb;
      for (int i = tid; i < 2048; i += 256) dstv[i] = src[i];
    }
    __syncthreads();
    f32x4 acc1[8];
#pragma unroll
    for (int nt8 = 0; nt8 < 8; ++nt8) acc1[nt8] = zero;
#pragma unroll
    for (int ks = 0; ks < 4; ++ks)
#pragma unroll
      for (int nt8 = 0; nt8 < 8; ++nt8) {
        bf16x8 bf = *(const bf16x8*)&swb[(nt8 * 4 + ks) * 512 + lane * 8];
        acc1[nt8] = __builtin_amdgcn_mfma_f32_16x16x32_bf16(ax[ks], bf, acc1[nt8], 0, 0, 0);
      }
#pragma unroll
    for (int nt8 = 0; nt8 < 8; ++nt8) {
      int col = (h01 * 8 + nt8) * 16 + lm;
      float bv = b1[col];
#pragma unroll
      for (int r = 0; r < 4; ++r) {
        int rr = lq * 4 + r;
        sT[w][rr * 264 + (col ^ ((rr & 7) << 3))] = f2bf(fmaxf(acc1[nt8][r] + bv, 0.f));
      }
    }
  }

  f32x4 c2[8];
#pragma unroll
  for (int nt = 0; nt < 8; ++nt) c2[nt] = zero;
  for (int ksh = 0; ksh < 2; ++ksh) {
    __syncthreads();
    {
      uint4* dstv = (uint4*)swb;
      for (int i4 = tid; i4 < 2048; i4 += 256) {
        int e = i4 * 8;
        int fc = e >> 9, nt = fc >> 2, ksl = fc & 3;
        int ks = ksh * 4 + ksl;
        long gi = 32768 + (long)(nt * 8 + ks) * 512 + (e & 511);
        dstv[i4] = wg[gi >> 3];
      }
    }
    __syncthreads();
#pragma unroll
    for (int ksl = 0; ksl < 4; ++ksl) {
      int ks = ksh * 4 + ksl;
      bf16x8 at = *(const bf16x8*)&sT[w][lm * 264 + ((ks * 32 + lq * 8) ^ ((lm & 7) << 3))];
#pragma unroll
      for (int nt = 0; nt < 8; ++nt) {
        bf16x8 bf = *(const bf16x8*)&swb[(nt * 4 + ksl) * 512 + lane * 8];
        c2[nt] = __builtin_amdgcn_mfma_f32_16x16x32_bf16(at, bf, c2[nt], 0, 0, 0);
      }
    }
  }

  {
    float yv[8][4], bcol[8], gcol[8], ocol[8];
#pragma unroll
    for (int nt = 0; nt < 8; ++nt) {
      int col = nt * 16 + lm;
      bcol[nt] = b2[col]; gcol[nt] = lng[col]; ocol[nt] = lnb[col];
    }
    float s4[4], q4[4];
#pragma unroll
    for (int r = 0; r < 4; ++r) { s4[r] = 0.f; q4[r] = 0.f; }
#pragma unroll
    for (int nt = 0; nt < 8; ++nt)
#pragma unroll
      for (int r = 0; r < 4; ++r) {
        float y = c2[nt][r] + bcol[nt];
        yv[nt][r] = y;
        s4[r] += y; q4[r] += y * y;
      }
#pragma unroll
    for (int o = 1; o < 16; o <<= 1)
#pragma unroll
      for (int r = 0; r < 4; ++r) {
        s4[r] += __shfl_xor(s4[r], o);
        q4[r] += __shfl_xor(q4[r], o);
      }
#pragma unroll
    for (int r = 0; r < 4; ++r) {
      float mean = s4[r] * (1.f / 128.f);
      float var = q4[r] * (1.f / 128.f) - mean * mean;
      float istd = rsqrtf(var + 1e-5f);
      int rr = lq * 4 + r;
#pragma unroll
      for (int nt = 0; nt < 8; ++nt) {
        float hv = (yv[nt][r] - mean) * istd * gcol[nt] + ocol[nt];
        int col = nt * 16 + lm;
        if (col < 128)
          sT[w][rr * 264 + (col ^ ((rr & 7) << 3))] = f2bf(hv);
      }
    }
  }

  __syncthreads();
  {
    uint4* dstv = (uint4*)swb;
    const uint4* src = wg + (65536 >> 3);
    for (int i = tid; i < 1024; i += 256) dstv[i] = src[i];
  }
  __syncthreads();
  f32x4 c3[4];
#pragma unroll
  for (int nt = 0; nt < 4; ++nt) c3[nt] = zero;
#pragma unroll
  for (int ks = 0; ks < 4; ++ks) {
    bf16x8 at = *(const bf16x8*)&sT[w][lm * 264 + ((ks * 32 + lq * 8) ^ ((lm & 7) << 3))];
#pragma unroll
    for (int nt = 0; nt < 4; ++nt) {
      bf16x8 bf = *(const bf16x8*)&swb[(nt * 4 + ks) * 512 + lane * 8];
      c3[nt] = __builtin_amdgcn_mfma_f32_16x16x32_bf16(at, bf, c3[nt], 0, 0, 0);
    }
  }
  float ps[4], pq[4];
#pragma unroll
  for (int nt = 0; nt < 4; ++nt) { ps[nt] = 0.f; pq[nt] = 0.f; }
#pragma unroll
  for (int nt = 0; nt < 4; ++nt) {
    int col = nt * 16 + lm;
    float eb = encb[col];
#pragma unroll
    for (int r = 0; r < 4; ++r) {
      long nd = nb + w * 16 + lq * 4 + r;
      float z = c3[nt][r] + eb;
      if (nd < n) {
        z_out[nd * 64 + col] = z;
        ps[nt] += z; pq[nt] += z * z;
      }
    }
  }
#pragma unroll
  for (int o = 16; o < 64; o <<= 1)
#pragma unroll
    for (int nt = 0; nt < 4; ++nt) {
      ps[nt] += __shfl_xor(ps[nt], o);
      pq[nt] += __shfl_xor(pq[nt], o);
    }
  if (lq == 0) {
#pragma unroll
    for (int nt = 0; nt < 4; ++nt) {
      sred[w][nt * 16 + lm] = ps[nt];
      sred[w][64 + nt * 16 + lm] = pq[nt];
    }
  }
  __syncthreads();
  if (tid < 128) {
    float t = 0.f;
#pragma unroll
    for (int g = 0; g < 4; ++g) t += sred[g][tid];
    part[(long)blockIdx.x * 128 + tid] = t;
  }
}

// ---- fused MFMA: BN-apply(+residual into h) + xs = h@W (FP8 out) + al_s/al_d ----
__global__ __launch_bounds__(256) void xs_bn2(
    const float* __restrict__ z, const float* __restrict__ stats,
    const float* __restrict__ bng, const float* __restrict__ bnb,
    float* __restrict__ hbuf, int mode,
    const unsigned short* __restrict__ wgat,
    const float* __restrict__ a_s, const float* __restrict__ a_d,
    unsigned char* __restrict__ xsb, float* __restrict__ al_s, float* __restrict__ al_d,
    int n) {
  __shared__ __align__(16) unsigned short swg[4096];       // 8KB packed W
  __shared__ __align__(16) unsigned short shh[4][1024];    // per-wave h bf16, swizzled
  int tid = threadIdx.x, w = tid >> 6, lane = tid & 63;
  int lm = lane & 15, lq = lane >> 4;
  {
    const uint4* g = (const uint4*)wgat;
    uint4* s = (uint4*)swg;
    for (int i = tid; i < 512; i += 256) s[i] = g[i];
  }
  long nb = (long)blockIdx.x * 64;
  float sm = stats[lane], sv = stats[64 + lane], gg = bng[lane], bb = bnb[lane];
#pragma unroll
  for (int m = 0; m < 16; ++m) {
    long nd = nb + w * 16 + m;
    float hv = 0.f;
    if (nd < n) {
      float t = fmaxf((z[nd * 64 + lane] - sm) * sv * gg + bb, 0.f);
      hv = mode ? hbuf[nd * 64 + lane] + t : t;
      hbuf[nd * 64 + lane] = hv;
    }
    shh[w][m * 64 + (lane ^ ((m & 7) << 3))] = f2bf(hv);
  }
  __syncthreads();
  f32x4 zero = {0.f, 0.f, 0.f, 0.f};
  f32x4 c[4];
#pragma unroll
  for (int nt = 0; nt < 4; ++nt) c[nt] = zero;
#pragma unroll
  for (int ks = 0; ks < 2; ++ks) {
    bf16x8 at = *(const bf16x8*)&shh[w][lm * 64 + ((ks * 32 + lq * 8) ^ ((lm & 7) << 3))];
#pragma unroll
    for (int nt = 0; nt < 4; ++nt) {
      bf16x8 bf = *(const bf16x8*)&swg[(nt * 2 + ks) * 512 + lane * 8];
      c[nt] = __builtin_amdgcn_mfma_f32_16x16x32_bf16(at, bf, c[nt], 0, 0, 0);
    }
  }
  float asv[4], adv[4];
#pragma unroll
  for (int nt = 0; nt < 4; ++nt) { asv[nt] = a_s[nt * 16 + lm]; adv[nt] = a_d[nt * 16 + lm]; }
  float prs[4], prd[4];
#pragma unroll
  for (int r = 0; r < 4; ++r) {
    float s = 0.f, d = 0.f;
#pragma unroll
    for (int nt = 0; nt < 4; ++nt) {
      s += c[nt][r] * asv[nt];
      d += c[nt][r] * adv[nt];
    }
    prs[r] = s; prd[r] = d;
  }
#pragma unroll
  for (int o = 1; o < 16; o <<= 1)
#pragma unroll
    for (int r = 0; r < 4; ++r) {
      prs[r] += __shfl_xor(prs[r], o);
      prd[r] += __shfl_xor(prd[r], o);
    }
#pragma unroll
  for (int nt = 0; nt < 4; ++nt)
#pragma unroll
    for (int r = 0; r < 4; ++r) {
      long nd = nb + w * 16 + lq * 4 + r;
      if (nd < n) xsb[nd * 64 + nt * 16 + lm] = f2fp8(c[nt][r]);
    }
  if (lm == 0) {
#pragma unroll
    for (int r = 0; r < 4; ++r) {
      long nd = nb + w * 16 + lq * 4 + r;
      if (nd < n) { al_s[nd] = prs[r]; al_d[nd] = prd[r]; }
    }
  }
}

// ---------------- GAT v4: coalesced bcsr/srcb; FP8 xs gather (64B rows, L2-fit) ----------------
#define QCAP 128
__global__ __launch_bounds__(256) void gat4(
    const int* __restrict__ off, const float2* __restrict__ bcsr,
    const int* __restrict__ srcb,
    const float* __restrict__ al_s, const float* __restrict__ al_d,
    const unsigned char* __restrict__ xsb, const float* __restrict__ bias,
    float* __restrict__ gat_out, float* __restrict__ part, int n) {
  __shared__ float2 sal[16][QCAP];
  __shared__ float sred[4][128];
  int tid = threadIdx.x, w = tid >> 6, lane = tid & 63;
  int qt = tid >> 4, q = tid & 15;
  const unsigned* xr = (const unsigned*)xsb;   // row = 16 uints (64B)
  float4 bv = *(const float4*)&bias[q * 4];
  float4 psum = make_float4(0.f, 0.f, 0.f, 0.f), psq = psum;
  for (int node = blockIdx.x * 16 + qt; node < n; node += gridDim.x * 16) {
    int s0 = off[node];
    int deg = off[node + 1] - s0;
    bool fits = (deg <= QCAP);
    float aldn = al_d[node];
    float lmax = -3.402823466e38f, lsae = 0.f;
    for (int k = q; k < deg; k += 16) {
      float2 be = bcsr[s0 + k];
      float a = be.x + aldn;
      float al = (a >= 0.f) ? a : 0.2f * a;
      lmax = fmaxf(lmax, al);
      lsae += be.y;
      if (fits) sal[qt][k] = make_float2(al, __int_as_float(srcb[s0 + k]));
    }
#pragma unroll
    for (int o = 1; o < 16; o <<= 1) {
      lmax = fmaxf(lmax, __shfl_xor(lmax, o));
      lsae += __shfl_xor(lsae, o);
    }
    float ae_self = lsae / fmaxf((float)deg, 1.f);
    float a_self = al_s[node] + aldn + ae_self;
    float al_self = (a_self >= 0.f) ? a_self : 0.2f * a_self;
    float mx = fmaxf(lmax, al_self);
    float lsum = 0.f;
    if (fits) {
      for (int k = q; k < deg; k += 16) {
        float ex = __expf(sal[qt][k].x - mx);
        sal[qt][k].x = ex;
        lsum += ex;
      }
    } else {
      for (int k = q; k < deg; k += 16) {
        float2 be = bcsr[s0 + k];
        float a = be.x + aldn;
        float al = (a >= 0.f) ? a : 0.2f * a;
        lsum += __expf(al - mx);
      }
    }
#pragma unroll
    for (int o = 1; o < 16; o <<= 1) lsum += __shfl_xor(lsum, o);
    float exs = __expf(al_self - mx);
    float inv = 1.f / (lsum + exs + 1e-16f);
    unsigned xv = xr[(long)node * 16 + q];
    float es = exs * 0x1p120f;
    float4 acc;
    acc.x = es * fp8dec(xv & 0xFFu);
    acc.y = es * fp8dec((xv >> 8) & 0xFFu);
    acc.z = es * fp8dec((xv >> 16) & 0xFFu);
    acc.w = es * fp8dec(xv >> 24);
    if (fits) {
      int k = 0;
      for (; k + 4 <= deg; k += 4) {
        float2 p0 = sal[qt][k], p1 = sal[qt][k + 1], p2 = sal[qt][k + 2], p3 = sal[qt][k + 3];
        unsigned x0 = xr[(long)__float_as_int(p0.y) * 16 + q];
        unsigned x1 = xr[(long)__float_as_int(p1.y) * 16 + q];
        unsigned x2 = xr[(long)__float_as_int(p2.y) * 16 + q];
        unsigned x3 = xr[(long)__float_as_int(p3.y) * 16 + q];
        float s0s = p0.x * 0x1p120f, s1s = p1.x * 0x1p120f;
        float s2s = p2.x * 0x1p120f, s3s = p3.x * 0x1p120f;
        acc.x += s0s * fp8dec(x0 & 0xFFu) + s1s * fp8dec(x1 & 0xFFu) +
                 s2s * fp8dec(x2 & 0xFFu) + s3s * fp8dec(x3 & 0xFFu);
        acc.y += s0s * fp8dec((x0 >> 8) & 0xFFu) + s1s * fp8dec((x1 >> 8) & 0xFFu) +
                 s2s * fp8dec((x2 >> 8) & 0xFFu) + s3s * fp8dec((x3 >> 8) & 0xFFu);
        acc.z += s0s * fp8dec((x0 >> 16) & 0xFFu) + s1s * fp8dec((x1 >> 16) & 0xFFu) +
                 s2s * fp8dec((x2 >> 16) & 0xFFu) + s3s * fp8dec((x3 >> 16) & 0xFFu);
        acc.w += s0s * fp8dec(x0 >> 24) + s1s * fp8dec(x1 >> 24) +
                 s2s * fp8dec(x2 >> 24) + s3s * fp8dec(x3 >> 24);
      }
      for (; k < deg; ++k) {
        float2 p = sal[qt][k];
        unsigned xk = xr[(long)__float_as_int(p.y) * 16 + q];
        float ss = p.x * 0x1p120f;
        acc.x += ss * fp8dec(xk & 0xFFu);
        acc.y += ss * fp8dec((xk >> 8) & 0xFFu);
        acc.z += ss * fp8dec((xk >> 16) & 0xFFu);
        acc.w += ss * fp8dec(xk >> 24);
      }
    } else {
      for (int k = 0; k < deg; ++k) {
        float2 be = bcsr[s0 + k];
        float a = be.x + aldn;
        float al = (a >= 0.f) ? a : 0.2f * a;
        float ss = __expf(al - mx) * 0x1p120f;
        unsigned xk = xr[(long)srcb[s0 + k] * 16 + q];
        acc.x += ss * fp8dec(xk & 0xFFu);
        acc.y += ss * fp8dec((xk >> 8) & 0xFFu);
        acc.z += ss * fp8dec((xk >> 16) & 0xFFu);
        acc.w += ss * fp8dec(xk >> 24);
      }
    }
    acc.x = acc.x * inv + bv.x; acc.y = acc.y * inv + bv.y;
    acc.z = acc.z * inv + bv.z; acc.w = acc.w * inv + bv.w;
    *(float4*)&gat_out[(long)node * 64 + q * 4] = acc;
    psum.x += acc.x; psum.y += acc.y; psum.z += acc.z; psum.w += acc.w;
    psq.x += acc.x * acc.x; psq.y += acc.y * acc.y; psq.z += acc.z * acc.z; psq.w += acc.w * acc.w;
  }
#pragma unroll
  for (int o = 16; o < 64; o <<= 1) {
    psum.x += __shfl_xor(psum.x, o); psum.y += __shfl_xor(psum.y, o);
    psum.z += __shfl_xor(psum.z, o); psum.w += __shfl_xor(psum.w, o);
    psq.x += __shfl_xor(psq.x, o); psq.y += __shfl_xor(psq.y, o);
    psq.z += __shfl_xor(psq.z, o); psq.w += __shfl_xor(psq.w, o);
  }
  if (lane < 16) {
    sred[w][lane * 4 + 0] = psum.x; sred[w][lane * 4 + 1] = psum.y;
    sred[w][lane * 4 + 2] = psum.z; sred[w][lane * 4 + 3] = psum.w;
    sred[w][64 + lane * 4 + 0] = psq.x; sred[w][64 + lane * 4 + 1] = psq.y;
    sred[w][64 + lane * 4 + 2] = psq.z; sred[w][64 + lane * 4 + 3] = psq.w;
  }
  __syncthreads();
  if (tid < 128)
    part[(long)blockIdx.x * 128 + tid] =
        sred[0][tid] + sred[1][tid] + sred[2][tid] + sred[3][tid];
}

// ---------------- BN finalize: 2-stage (16 blocks + tiny) ----------------
__global__ __launch_bounds__(256) void bn_red16(const float* __restrict__ part, int nblk,
                                                float* __restrict__ part3) {
  int t = threadIdx.x, c = t & 127, g2 = t >> 7;
  int row0 = blockIdx.x * 2 + g2;  // 0..31
  float s = 0.f;
  for (int b = row0; b < nblk; b += 32) s += part[(long)b * 128 + c];
  part3[(long)row0 * 128 + c] = s;
}

__global__ __launch_bounds__(128) void bn_stats(const float* __restrict__ part3,
                                                float invN, float* __restrict__ stats) {
  __shared__ float sh[128];
  int t = threadIdx.x;
  float s = 0.f;
#pragma unroll 4
  for (int g = 0; g < 32; ++g) s += part3[g * 128 + t];
  sh[t] = s;
  __syncthreads();
  if (t < 64) {
    float mean = sh[t] * invN;
    float var = sh[64 + t] * invN - mean * mean;
    stats[t] = mean;
    stats[64 + t] = rsqrtf(var + 1e-5f);
  }
}

// ---- fused: last BN-apply + residual + global mean partials (no h write) ----
__global__ void gsum_bn(const float* __restrict__ z, const float* __restrict__ stats,
                        const float* __restrict__ bng, const float* __restrict__ bnb,
                        const float* __restrict__ hprev, int n, float* __restrict__ part) {
  __shared__ float sh[4][64];
  int tid = threadIdx.x, w = tid >> 6, lane = tid & 63;
  float sm = stats[lane], sv = stats[64 + lane], gg = bng[lane], bb = bnb[lane];
  int gw = blockIdx.x * 4 + w, nW = gridDim.x * 4;
  float s = 0.f;
  for (int node = gw; node < n; node += nW) {
    float t = fmaxf((z[(long)node * 64 + lane] - sm) * sv * gg + bb, 0.f);
    s += hprev[(long)node * 64 + lane] + t;
  }
  sh[w][lane] = s;
  __syncthreads();
  if (tid < 64)
    part[(long)blockIdx.x * 64 + tid] =
        sh[0][tid] + sh[1][tid] + sh[2][tid] + sh[3][tid];
}

// ---- final: 1024-thr parallel reduce of part2 + LDS out_W MLP ----
__global__ __launch_bounds__(1024) void final2(const float* __restrict__ part, int nblk,
                                               const float* __restrict__ out_W,
                                               const float* __restrict__ out_b,
                                               float* __restrict__ out, float invN) {
  __shared__ float sh[1024];
  __shared__ float gmean[64];
  __shared__ __align__(16) float sW[4096];
  int t = threadIdx.x;
  {
    for (int i = t; i < 1024; i += 1024)
      *(float4*)&sW[i * 4] = *(const float4*)&out_W[i * 4];
  }
  int c = t & 63, gr = t >> 6;
  float s = 0.f;
  for (int b = gr; b < nblk; b += 16) s += part[(long)b * 64 + c];
  sh[t] = s;
  __syncthreads();
  if (t < 64) {
    float tot = 0.f;
#pragma unroll
    for (int q = 0; q < 16; ++q) tot += sh[q * 64 + t];
    gmean[t] = tot * invN;
  }
  __syncthreads();
  if (t < 64) {
    float acc = out_b[t];
#pragma unroll
    for (int k = 0; k < 64; ++k) acc += gmean[k] * sW[k * 64 + t];
    out[t] = fmaxf(acc, 0.f);
  }
}

// ---------------- host launch ----------------
extern "C" void kernel_launch(void* const* d_in, const int* in_sizes, int n_in,
                              void* d_out, int out_size, void* d_ws, size_t ws_size,
                              hipStream_t stream) {
  const float* x        = (const float*)d_in[0];
  const int*   eidx     = (const int*)d_in[1];
  const float* eattr    = (const float*)d_in[2];
  const float* np_W1    = (const float*)d_in[3];
  const float* np_b1    = (const float*)d_in[4];
  const float* np_W2    = (const float*)d_in[5];
  const float* np_b2    = (const float*)d_in[6];
  const float* np_ln_g  = (const float*)d_in[7];
  const float* np_ln_b  = (const float*)d_in[8];
  const float* ep_W1    = (const float*)d_in[9];
  const float* ep_b1    = (const float*)d_in[10];
  const float* ep_W2    = (const float*)d_in[11];
  const float* ep_b2    = (const float*)d_in[12];
  const float* ep_ln_g  = (const float*)d_in[13];
  const float* ep_ln_b  = (const float*)d_in[14];
  const float* enc_W    = (const float*)d_in[15];
  const float* enc_b    = (const float*)d_in[16];
  const float* enc_bn_g = (const float*)d_in[17];
  const float* enc_bn_b = (const float*)d_in[18];
  const float* gat_W    = (const float*)d_in[19];
  const float* gat_eW   = (const float*)d_in[20];
  const float* att_src  = (const float*)d_in[21];
  const float* att_dst  = (const float*)d_in[22];
  const float* att_edge = (const float*)d_in[23];
  const float* gat_b    = (const float*)d_in[24];
  const float* bn_g     = (const float*)d_in[25];
  const float* bn_b     = (const float*)d_in[26];
  const float* out_W    = (const float*)d_in[27];
  const float* out_b    = (const float*)d_in[28];

  const int n = in_sizes[0] / 128;   // 50000
  const int ne = in_sizes[1] / 2;    // 800000
  const int* srcp = eidx;
  const int* dstp = eidx + ne;

  float* f = (float*)d_ws;
  float* hbuf  = f; f += (long)n * 64;
  float* zbuf  = f; f += (long)n * 64;   // also reused as int2 csrt scratch pre-node_pre3
  float* alsb  = f; f += n;
  float* aldb  = f; f += n;
  float* ale   = f; f += 3L * ne;
  float* vgbuf = f; f += 128;
  float* stats = f; f += 128;
  float* part  = f; f += 131072;      // 1024 x 128
  float* part2 = f; f += 16384;       // 256 x 64
  float* part3 = f; f += 4096;        // 32 x 128
  float2* bcsr = (float2*)f; f += 2L * ne;   // CSR-ordered {b, ae}
  unsigned short* wbb   = (unsigned short*)f; f += 2048;          // edge weights
  unsigned short* wnb   = (unsigned short*)f; f += 36864;         // node weights
  unsigned short* wgatb = (unsigned short*)f; f += 6144;          // 3 x 4096 gat weights
  unsigned char*  xsb   = (unsigned char*)f;  f += (long)n * 16;  // n*64 fp8
  int* ip = (int*)f;
  int2* csr = (int2*)ip; ip += 2L * ne;
  int* srcb = ip; ip += ne;            // CSR-ordered src
  int* degb = ip; ip += n;
  int* cntb = ip; ip += n;
  int* offb = ip; ip += n + 1;
  int* bsum = ip; ip += 256;
  int2* csrt = (int2*)zbuf;  // ne*8B = 6.4MB <= zbuf 12.8MB; dead until node_pre3

  const int nbEdge = (ne + EB - 1) / EB;     // 6250
  const int nbNode = (n + 63) / 64;          // 782
  const int nbScan = (n + 255) / 256;        // 196

  hipMemsetAsync(degb, 0, (size_t)n * sizeof(int), stream);
  hipMemsetAsync(cntb, 0, (size_t)n * sizeof(int), stream);
  vprep2<<<1, 128, 0, stream>>>(gat_eW, att_edge, ep_ln_g, ep_ln_b, vgbuf);
  wpack<<<1, 256, 0, stream>>>(ep_W1, ep_W2, wbb);
  npack<<<288, 256, 0, stream>>>(np_W1, np_W2, enc_W, wnb);
  gpack<<<48, 256, 0, stream>>>(gat_W, wgatb);
  deg_kernel<<<1024, 256, 0, stream>>>(dstp, ne, degb);
  scan_blk<<<nbScan, 256, 0, stream>>>(degb, offb, bsum, n);
  scan_bsum<<<1, 256, 0, stream>>>(bsum, nbScan);
  scan_add<<<nbScan, 256, 0, stream>>>(bsum, offb, n);
  scatter_kernel<<<1024, 256, 0, stream>>>(srcp, dstp, ne, offb, cntb, csrt);
  csr_sort<<<1024, 256, 0, stream>>>(offb, csrt, csr, n);
  edge_pre4<<<nbEdge, 256, 0, stream>>>(eattr, wbb, ep_b1, ep_b2, vgbuf, ale, ne);
  node_pre3<<<nbNode, 256, 0, stream>>>(x, wnb, np_b1, np_b2, np_ln_g, np_ln_b,
                                        enc_b, zbuf, part, n);
  bn_red16<<<16, 256, 0, stream>>>(part, nbNode, part3);
  bn_stats<<<1, 128, 0, stream>>>(part3, 1.f / n, stats);
  xs_bn2<<<nbNode, 256, 0, stream>>>(zbuf, stats, enc_bn_g, enc_bn_b, hbuf, 0,
                                     wgatb, att_src, att_dst, xsb, alsb, aldb, n);
  for (int l = 0; l < 3; ++l) {
    edge_b<<<1024, 256, 0, stream>>>(csr, ale + (long)l * ne, alsb, bcsr, srcb, ne);
    gat4<<<1024, 256, 0, stream>>>(offb, bcsr, srcb, alsb, aldb,
                                   xsb, gat_b + l * 64, zbuf, part, n);
    bn_red16<<<16, 256, 0, stream>>>(part, 1024, part3);
    bn_stats<<<1, 128, 0, stream>>>(part3, 1.f / n, stats);
    if (l < 2) {
      xs_bn2<<<nbNode, 256, 0, stream>>>(zbuf, stats, bn_g + l * 64, bn_b + l * 64, hbuf, 1,
                                         wgatb + (long)(l + 1) * 4096,
                                         att_src + (l + 1) * 64, att_dst + (l + 1) * 64,
                                         xsb, alsb, aldb, n);
    } else {
      gsum_bn<<<256, 256, 0, stream>>>(zbuf, stats, bn_g + l * 64, bn_b + l * 64,
                                       hbuf, n, part2);
    }
  }
  final2<<<1, 1024, 0, stream>>>(part2, 256, out_W, out_b, (float*)d_out, 1.f / n);
}